// Round 1
// 3511.901 us; speedup vs baseline: 2.1248x; 2.1248x over previous
//
#include <hip/hip_runtime.h>
#include <hip/hip_bf16.h>

typedef unsigned int u32;
typedef unsigned short u16;

#define DI __device__ __forceinline__

// ---------- bf16 helpers (bf16 == fp32 high 16 bits; RNE on store) ----------
DI float b2f_u(u32 u){ return __uint_as_float(u << 16); }
DI u16 f2b_u(float f){
  u32 x = __float_as_uint(f);
  x += 0x7fffu + ((x >> 16) & 1u);
  return (u16)(x >> 16);
}
DI void ld8b(const u16* p, float* o){
  uint4 v = *reinterpret_cast<const uint4*>(p);
  o[0] = b2f_u(v.x & 0xffffu); o[1] = b2f_u(v.x >> 16);
  o[2] = b2f_u(v.y & 0xffffu); o[3] = b2f_u(v.y >> 16);
  o[4] = b2f_u(v.z & 0xffffu); o[5] = b2f_u(v.z >> 16);
  o[6] = b2f_u(v.w & 0xffffu); o[7] = b2f_u(v.w >> 16);
}
DI void st8b(u16* p, const float* i){
  uint4 v;
  v.x = (u32)f2b_u(i[0]) | ((u32)f2b_u(i[1]) << 16);
  v.y = (u32)f2b_u(i[2]) | ((u32)f2b_u(i[3]) << 16);
  v.z = (u32)f2b_u(i[4]) | ((u32)f2b_u(i[5]) << 16);
  v.w = (u32)f2b_u(i[6]) | ((u32)f2b_u(i[7]) << 16);
  *reinterpret_cast<uint4*>(p) = v;
}

// ---------- K_detect: is d_in fp32 (flag=1) or packed bf16 (flag=0)? ----------
__global__ void k_detect(const u32* __restrict__ xw, int* __restrict__ flag){
  __shared__ int cnt;
  int t = threadIdx.x;
  if (t == 0) cnt = 0;
  __syncthreads();
  int c = 0;
  for (int i = t; i < 2048; i += 256){
    u32 lo = xw[i] & 0xffffu;
    u32 e = (lo >> 7) & 0xffu;
    if (e < 100u || e > 140u) c++;
  }
  atomicAdd(&cnt, c);
  __syncthreads();
  if (t == 0) *flag = (cnt > 200) ? 1 : 0;
}

// ---------- K0: weight transpose ([O][K] -> fp32 [K][O]), dtype-adaptive ----------
__global__ void k_transpose(const void* __restrict__ in, float* __restrict__ out, int O, int K,
                            const int* __restrict__ flag){
  int idx = blockIdx.x*256 + threadIdx.x;
  if (idx < O*K){
    int o = idx % O, k = idx / O;
    if (*flag) out[idx] = ((const float*)in)[o*K + k];
    else       out[idx] = b2f_u((u32)((const u16*)in)[o*K + k]);
  }
}

// ---------- K0b: bias convert -> fp32 ----------
__global__ void k_cvtvec(const void* __restrict__ in, float* __restrict__ out, int n,
                         const int* __restrict__ flag){
  int i = blockIdx.x*256 + threadIdx.x;
  if (i < n){
    if (*flag) out[i] = ((const float*)in)[i];
    else       out[i] = b2f_u((u32)((const u16*)in)[i]);
  }
}

// ---------- K1: conv 2x2 stride 2 + window partition -> bufA [b][g][l][c] ----------
__global__ __launch_bounds__(256) void k_conv(const void* __restrict__ x_raw, const float* __restrict__ wT,
                                              const float* __restrict__ bias, u16* __restrict__ outA,
                                              const int* __restrict__ flag){
  __shared__ float patch[128*64];   // [ci][py*8+px], 32 KB
  int t = threadIdx.x, bid = blockIdx.x;
  int b = bid >> 8, g = bid & 255;
  int yg = g >> 4, xg = g & 15;
  size_t base = (size_t)b*2097152 + (size_t)(yg*8)*128 + xg*8;
  if (*flag){
    const float* xb = (const float*)x_raw + base;
    for (int r = t; r < 1024; r += 256){
      int ci = r >> 3, py = r & 7;
      const float4* s4 = reinterpret_cast<const float4*>(xb + ci*16384 + py*128);
      float4* dst = reinterpret_cast<float4*>(&patch[ci*64 + py*8]);
      dst[0] = s4[0]; dst[1] = s4[1];
    }
  } else {
    const u16* xb = (const u16*)x_raw + base;
    for (int r = t; r < 1024; r += 256){
      int ci = r >> 3, py = r & 7;
      float v[8]; ld8b(xb + ci*16384 + py*128, v);
      float4* dst = reinterpret_cast<float4*>(&patch[ci*64 + py*8]);
      dst[0] = make_float4(v[0],v[1],v[2],v[3]);
      dst[1] = make_float4(v[4],v[5],v[6],v[7]);
    }
  }
  __syncthreads();
  int l = t & 15, cog = t >> 4;
  int co0 = cog*8;
  int yo = l >> 2, xo = l & 3;
  int pixbase = yo*16 + xo*2;
  float acc[8];
  #pragma unroll
  for (int j=0;j<8;j++) acc[j] = bias[co0+j];
  for (int k=0;k<512;k++){
    int ci = k >> 2, ky = (k>>1)&1, kx = k&1;
    float pv = patch[ci*64 + pixbase + ky*8 + kx];
    const float4* wp = reinterpret_cast<const float4*>(wT + k*128 + co0);
    float4 w0 = wp[0], w1 = wp[1];
    acc[0]+=pv*w0.x; acc[1]+=pv*w0.y; acc[2]+=pv*w0.z; acc[3]+=pv*w0.w;
    acc[4]+=pv*w1.x; acc[5]+=pv*w1.y; acc[6]+=pv*w1.z; acc[7]+=pv*w1.w;
  }
  st8b(outA + (size_t)(bid*16 + l)*128 + co0, acc);
}

// ---------- K2: LocalMSA (L=16) + residual: bufA -> bufB (same layout) ----------
__global__ __launch_bounds__(256) void k_msa1(const u16* __restrict__ A, const float* __restrict__ wT,
                                              const float* __restrict__ qbias, u16* __restrict__ B){
  __shared__ float Xs[16*132];
  __shared__ float QKV[16*388];
  __shared__ float S[512];          // [h][l][m]
  int t = threadIdx.x, bid = blockIdx.x;
  const u16* Ab = A + (size_t)bid*2048;
  {
    int l = t >> 4, c0 = (t & 15)*8;
    float v[8]; ld8b(Ab + l*128 + c0, v);
    float4* d = reinterpret_cast<float4*>(&Xs[l*132 + c0]);
    d[0] = make_float4(v[0],v[1],v[2],v[3]);
    d[1] = make_float4(v[4],v[5],v[6],v[7]);
  }
  __syncthreads();
  {
    int l = t >> 4, og = t & 15, o0 = og*24;
    float acc[24];
    #pragma unroll
    for (int j=0;j<24;j++) acc[j] = qbias[o0+j];
    for (int k=0;k<128;k++){
      float xv = Xs[l*132+k];
      float w[24];
      const float4* wp = reinterpret_cast<const float4*>(wT + k*384 + o0);
      #pragma unroll
      for (int q=0;q<6;q++){
        float4 wv = wp[q];
        w[q*4+0]=wv.x; w[q*4+1]=wv.y; w[q*4+2]=wv.z; w[q*4+3]=wv.w;
      }
      #pragma unroll
      for (int j=0;j<24;j++) acc[j] += xv*w[j];
    }
    #pragma unroll
    for (int j=0;j<24;j++) QKV[l*388 + o0 + j] = acc[j];
  }
  __syncthreads();
  const float scale = 0.08838834764831845f;   // 1/sqrt(128)
  for (int e = t; e < 512; e += 256){
    int h = e >> 8, l = (e>>4)&15, m = e&15;
    const float* q = &QKV[l*388 + h*64];
    const float* kk = &QKV[m*388 + 128 + h*64];
    float s = 0.f;
    #pragma unroll
    for (int d=0; d<64; d++) s += q[d]*kk[d];
    S[(h*16+l)*16 + m] = s*scale;
  }
  __syncthreads();
  if (t < 32){
    float* row = &S[t*16];
    float mx = row[0];
    #pragma unroll
    for (int m=1;m<16;m++) mx = fmaxf(mx,row[m]);
    float sum = 0.f;
    #pragma unroll
    for (int m=0;m<16;m++){ float e = expf(row[m]-mx); row[m]=e; sum+=e; }
    float inv = 1.0f/sum;
    #pragma unroll
    for (int m=0;m<16;m++) row[m] *= inv;
  }
  __syncthreads();
  {
    int l = t >> 4, og = t & 15, o0 = og*8;
    int h = o0 >> 6;
    const float* p = &S[(h*16+l)*16];
    float out8[8];
    #pragma unroll
    for (int j=0;j<8;j++){
      int o = o0+j, d = o & 63;
      float s = 0.f;
      #pragma unroll
      for (int m=0;m<16;m++) s += p[m]*QKV[m*388 + 256 + h*64 + d];
      out8[j] = s + Xs[l*132 + o];
    }
    st8b(B + (size_t)bid*2048 + l*128 + o0, out8);
  }
}

// ---------- K3/K5: MLP (+residual), register-tiled fp32 GEMMs.
//            MODE1: bufB [b][g][l][c] -> bufC [b][l][g][c].
//            MODE2: y [b][l][g][c] -> bufD [n][pix][c] (window reverse).
// GEMM1: thread owns outputs {t, t+256} x all 16 tokens (32 acc, 32 FMA / 8B wt).
// GEMM2: K split in 2 halves across thread-groups; thread owns 8 tok x 2 out.
//        Partials reduced through the (dead) H region of LDS.
template<int MODE>
__global__ __launch_bounds__(256) void k_mlp(const u16* __restrict__ in,
    const float* __restrict__ w1T, const float* __restrict__ b1,
    const float* __restrict__ w2T, const float* __restrict__ b2,
    u16* __restrict__ out){
  __shared__ float Xs[16*132];       // 8448 B, kept for residual
  __shared__ float H[16*516];        // 33024 B; Yred overlays after GEMM2
  int t = threadIdx.x, bid = blockIdx.x;
  {
    int l = t >> 4, c0 = (t & 15)*8;
    float v[8]; ld8b(in + (size_t)bid*2048 + l*128 + c0, v);
    float4* d = reinterpret_cast<float4*>(&Xs[l*132 + c0]);
    d[0] = make_float4(v[0],v[1],v[2],v[3]);
    d[1] = make_float4(v[4],v[5],v[6],v[7]);
  }
  __syncthreads();

  // ---- GEMM1: H[tok][o] = gelu(X @ W1 + b1), o in {t, t+256} ----
  {
    float acc0[16], acc1[16];
    float bb0 = b1[t], bb1 = b1[t + 256];
    #pragma unroll
    for (int i=0;i<16;i++){ acc0[i] = bb0; acc1[i] = bb1; }
    const float* w = w1T + t;        // row stride 512
    for (int k=0;k<128;k+=4){
      float w00 = w[0],    w01 = w[256];
      float w10 = w[512],  w11 = w[768];
      float w20 = w[1024], w21 = w[1280];
      float w30 = w[1536], w31 = w[1792];
      w += 2048;
      #pragma unroll
      for (int i=0;i<16;i++){
        const float* xp = &Xs[i*132 + k];     // 16B-aligned -> ds_read_b128
        float x0 = xp[0], x1 = xp[1], x2 = xp[2], x3 = xp[3];
        acc0[i] += x0*w00; acc1[i] += x0*w01;
        acc0[i] += x1*w10; acc1[i] += x1*w11;
        acc0[i] += x2*w20; acc1[i] += x2*w21;
        acc0[i] += x3*w30; acc1[i] += x3*w31;
      }
    }
    #pragma unroll
    for (int i=0;i<16;i++){
      float a0 = acc0[i], a1 = acc1[i];
      // lane-consecutive addresses -> conflict-free LDS stores
      H[i*516 + t]       = 0.5f*a0*(1.0f + erff(a0*0.70710678118654752f));
      H[i*516 + t + 256] = 0.5f*a1*(1.0f + erff(a1*0.70710678118654752f));
    }
  }
  __syncthreads();

  // ---- GEMM2: Y = H @ W2 (K split 2-way), partials to LDS ----
  int kg = t >> 7;                   // 0/1: k-range [kg*256, kg*256+256)
  int s  = t & 127;
  int o0 = s & 63;                   // outputs o0 and o0+64
  int tb = (s >> 6) * 8;             // tokens tb..tb+7
  float acc[8][2];
  #pragma unroll
  for (int i=0;i<8;i++){ acc[i][0] = 0.f; acc[i][1] = 0.f; }
  {
    const float* w = w2T + (size_t)(kg*256)*128 + o0;   // row stride 128
    const int hbase = kg*256;
    for (int k=0;k<256;k+=4){
      float wA0 = w[0],   wA1 = w[64];
      float wB0 = w[128], wB1 = w[192];
      float wC0 = w[256], wC1 = w[320];
      float wD0 = w[384], wD1 = w[448];
      w += 512;
      #pragma unroll
      for (int i=0;i<8;i++){
        const float* hh = &H[(tb+i)*516 + hbase + k];   // 16B-aligned broadcast
        float h0 = hh[0], h1 = hh[1], h2 = hh[2], h3 = hh[3];
        acc[i][0] += h0*wA0; acc[i][1] += h0*wA1;
        acc[i][0] += h1*wB0; acc[i][1] += h1*wB1;
        acc[i][0] += h2*wC0; acc[i][1] += h2*wC1;
        acc[i][0] += h3*wD0; acc[i][1] += h3*wD1;
      }
    }
  }
  __syncthreads();                    // H fully consumed; safe to overlay
  float* Yred = H;                    // [2][16][132]
  #pragma unroll
  for (int i=0;i<8;i++){
    Yred[(kg*16 + tb + i)*132 + o0]      = acc[i][0];
    Yred[(kg*16 + tb + i)*132 + o0 + 64] = acc[i][1];
  }
  __syncthreads();

  // ---- combine + bias + residual + store (same output mapping as before) ----
  {
    int tok = t >> 4, oc = (t & 15)*8;
    float outv[8];
    #pragma unroll
    for (int j=0;j<8;j++){
      int o = oc + j;
      outv[j] = b2[o] + Yred[tok*132 + o] + Yred[(16 + tok)*132 + o] + Xs[tok*132 + o];
    }
    int T = bid*16 + tok;
    size_t addr;
    if (MODE == 1){
      int b = T >> 12, g = (T >> 4) & 255, ll = T & 15;
      addr = ((size_t)((b*16 + ll)*256 + g))*128 + oc;
    } else {
      int b = T >> 12, ll = (T >> 8) & 15, g = T & 255;
      int pcoord = ((g >> 4)*4 + (ll >> 2))*64 + ((g & 15)*4 + (ll & 3));
      addr = ((size_t)(b*4096 + pcoord))*128 + oc;
    }
    st8b(out + addr, outv);
  }
}

// ---------- K4a: QKV projection for DilatedMSA: bufC -> qbuf [tok][128] + kvbuf [tok][256] ----------
__global__ __launch_bounds__(256) void k_qkv2(const u16* __restrict__ in, const float* __restrict__ wT,
                                              const float* __restrict__ bias,
                                              u16* __restrict__ qbuf, u16* __restrict__ kvbuf){
  __shared__ float Xs[16*132];
  int t = threadIdx.x, bid = blockIdx.x;
  int l = t >> 4, og = t & 15;
  {
    int c0 = og*8;
    float v[8]; ld8b(in + (size_t)bid*2048 + l*128 + c0, v);
    float4* d = reinterpret_cast<float4*>(&Xs[l*132 + c0]);
    d[0] = make_float4(v[0],v[1],v[2],v[3]);
    d[1] = make_float4(v[4],v[5],v[6],v[7]);
  }
  __syncthreads();
  int o0 = og*24;
  float acc[24];
  #pragma unroll
  for (int j=0;j<24;j++) acc[j] = bias[o0+j];
  for (int k=0;k<128;k++){
    float xv = Xs[l*132+k];
    float w[24];
    const float4* wp = reinterpret_cast<const float4*>(wT + k*384 + o0);
    #pragma unroll
    for (int q=0;q<6;q++){
      float4 wv = wp[q];
      w[q*4+0]=wv.x; w[q*4+1]=wv.y; w[q*4+2]=wv.z; w[q*4+3]=wv.w;
    }
    #pragma unroll
    for (int j=0;j<24;j++) acc[j] += xv*w[j];
  }
  size_t tok = (size_t)bid*16 + l;
  #pragma unroll
  for (int m=0; m<3; m++){
    int oc = o0 + m*8;
    if (oc < 128) st8b(qbuf + tok*128 + oc, acc + m*8);
    else          st8b(kvbuf + tok*256 + (oc-128), acc + m*8);
  }
}

// ---------- K4b: DilatedMSA flash attention (L=256); writes y = x + attn IN PLACE over bufC ----------
__global__ __launch_bounds__(256) void k_attn2(const u16* __restrict__ qbuf, const u16* __restrict__ kvbuf,
                                               u16* __restrict__ y){
  __shared__ float Qs[64*66];
  __shared__ float Ks[32*64];
  __shared__ float Vs[32*64];
  __shared__ float Ss[64*33];
  __shared__ float mrow[64], lrow[64], crow[64];
  int t = threadIdx.x, bid = blockIdx.x;
  int qt = bid & 3, h = (bid >> 2) & 1, bl = bid >> 3;
  size_t tokbase = (size_t)bl * 256;
  {
    int r = t >> 2, seg = t & 3;
    const u16* src = qbuf + (tokbase + qt*64 + r)*128 + h*64 + seg*16;
    float v[16]; ld8b(src, v); ld8b(src+8, v+8);
    #pragma unroll
    for (int j=0;j<16;j++) Qs[r*66 + seg*16 + j] = v[j];
  }
  if (t < 64){ mrow[t] = -1e30f; lrow[t] = 0.0f; }
  float Oacc[16];
  #pragma unroll
  for (int j=0;j<16;j++) Oacc[j] = 0.0f;
  int lq = t & 63, grp = t >> 6;
  __syncthreads();
  for (int kt=0; kt<8; kt++){
    {
      int r = t >> 3, seg = t & 7;
      const u16* base = kvbuf + (tokbase + kt*32 + r)*256 + h*64;
      float v[8];
      ld8b(base + seg*8, v);
      #pragma unroll
      for (int j=0;j<8;j++) Ks[r*64 + seg*8 + j] = v[j];
      ld8b(base + 128 + seg*8, v);
      #pragma unroll
      for (int j=0;j<8;j++) Vs[r*64 + seg*8 + j] = v[j];
    }
    __syncthreads();
    {
      float acc[8];
      #pragma unroll
      for (int j=0;j<8;j++) acc[j] = 0.0f;
      for (int dc=0; dc<8; dc++){
        const float2* qp = reinterpret_cast<const float2*>(&Qs[lq*66 + dc*8]);
        float2 q0 = qp[0], q1 = qp[1], q2 = qp[2], q3 = qp[3];
        #pragma unroll
        for (int j=0;j<8;j++){
          const float4* kp = reinterpret_cast<const float4*>(&Ks[(grp*8+j)*64 + dc*8]);
          float4 k0 = kp[0], k1 = kp[1];
          acc[j] += q0.x*k0.x + q0.y*k0.y + q1.x*k0.z + q1.y*k0.w
                  + q2.x*k1.x + q2.y*k1.y + q3.x*k1.z + q3.y*k1.w;
        }
      }
      #pragma unroll
      for (int j=0;j<8;j++) Ss[lq*33 + grp*8 + j] = acc[j] * 0.08838834764831845f;
    }
    __syncthreads();
    if (t < 64){
      float* row = &Ss[t*33];
      float m = mrow[t];
      #pragma unroll
      for (int i=0;i<32;i++) m = fmaxf(m, row[i]);
      float corr = expf(mrow[t] - m);
      float s = lrow[t] * corr;
      #pragma unroll
      for (int i=0;i<32;i++){ float e = expf(row[i]-m); row[i] = e; s += e; }
      mrow[t] = m; lrow[t] = s; crow[t] = corr;
    }
    __syncthreads();
    {
      float corr = crow[lq];
      #pragma unroll
      for (int j=0;j<16;j++) Oacc[j] *= corr;
      for (int m=0;m<32;m++){
        float pp = Ss[lq*33 + m];
        const float4* vp = reinterpret_cast<const float4*>(&Vs[m*64 + grp*16]);
        float4 v0 = vp[0], v1 = vp[1], v2 = vp[2], v3 = vp[3];
        Oacc[0]+=pp*v0.x; Oacc[1]+=pp*v0.y; Oacc[2]+=pp*v0.z; Oacc[3]+=pp*v0.w;
        Oacc[4]+=pp*v1.x; Oacc[5]+=pp*v1.y; Oacc[6]+=pp*v1.z; Oacc[7]+=pp*v1.w;
        Oacc[8]+=pp*v2.x; Oacc[9]+=pp*v2.y; Oacc[10]+=pp*v2.z; Oacc[11]+=pp*v2.w;
        Oacc[12]+=pp*v3.x; Oacc[13]+=pp*v3.y; Oacc[14]+=pp*v3.z; Oacc[15]+=pp*v3.w;
      }
    }
    __syncthreads();
  }
  float inv = 1.0f / lrow[lq];
  u16* dst = y + (tokbase + qt*64 + lq)*128 + h*64 + grp*16;
  float res[16]; ld8b(dst, res); ld8b(dst+8, res+8);
  float o16[16];
  #pragma unroll
  for (int j=0;j<16;j++) o16[j] = Oacc[j]*inv + res[j];
  st8b(dst, o16); st8b(dst+8, o16+8);
}

// ---------- K_init: h,C state from h0,c0 (dtype-adaptive) ----------
__global__ __launch_bounds__(256) void k_init(const void* __restrict__ h0, const void* __restrict__ c0,
                                              float* __restrict__ hws, float* __restrict__ Cst,
                                              const int* __restrict__ flag){
  int i = (blockIdx.x*256 + threadIdx.x)*4;
  if (*flag){
    *reinterpret_cast<float4*>(hws + i) = *reinterpret_cast<const float4*>((const float*)h0 + i);
    *reinterpret_cast<float4*>(Cst + i) = *reinterpret_cast<const float4*>((const float*)c0 + i);
  } else {
    uint2 hv = *reinterpret_cast<const uint2*>((const u16*)h0 + i);
    uint2 cv = *reinterpret_cast<const uint2*>((const u16*)c0 + i);
    *reinterpret_cast<float4*>(hws + i) = make_float4(b2f_u(hv.x & 0xffffu), b2f_u(hv.x >> 16),
                                                      b2f_u(hv.y & 0xffffu), b2f_u(hv.y >> 16));
    *reinterpret_cast<float4*>(Cst + i) = make_float4(b2f_u(cv.x & 0xffffu), b2f_u(cv.x >> 16),
                                                      b2f_u(cv.y & 0xffffu), b2f_u(cv.y >> 16));
  }
}

// ---------- K6a: LSTM gates GEMM + softmax/tanh; block = (32 pixels, one gate type) ----------
__global__ __launch_bounds__(256) void k_lstm_gates(const u16* __restrict__ xD, const float* __restrict__ hws,
    const float* __restrict__ wx, const float* __restrict__ wh, const float* __restrict__ bh,
    float* __restrict__ gates, int n){
  __shared__ float tile[256*33];   // [k][p], k<128: x ch, k>=128: h ch
  __shared__ float red[8*33];
  __shared__ float fin[33];
  int t = threadIdx.x, bid = blockIdx.x;
  int pt = bid >> 2, gt = bid & 3;
  int pix0 = pt*32;
  {
    int po = t >> 3, cg = t & 7;
    const u16* src = xD + ((size_t)n*4096 + pix0 + po)*128 + cg*16;
    float v[16]; ld8b(src, v); ld8b(src+8, v+8);
    #pragma unroll
    for (int j=0;j<16;j++) tile[(cg*16+j)*33 + po] = v[j];
  }
  {
    int c = t >> 1, half = t & 1;
    const float4* src = reinterpret_cast<const float4*>(hws + c*4096 + pix0 + half*16);
    #pragma unroll
    for (int q=0;q<4;q++){
      float4 v = src[q];
      int base = (128+c)*33 + half*16 + q*4;
      tile[base+0]=v.x; tile[base+1]=v.y; tile[base+2]=v.z; tile[base+3]=v.w;
    }
  }
  __syncthreads();
  int po = t & 31, og = t >> 5;
  int o0 = gt*128 + og*16;
  float acc[16];
  #pragma unroll
  for (int j=0;j<16;j++) acc[j] = bh[o0+j];
  for (int k=0;k<128;k++){
    float tv = tile[k*33+po];
    const float4* wp = reinterpret_cast<const float4*>(wx + k*512 + o0);
    float4 w0=wp[0], w1=wp[1], w2=wp[2], w3=wp[3];
    acc[0]+=tv*w0.x; acc[1]+=tv*w0.y; acc[2]+=tv*w0.z; acc[3]+=tv*w0.w;
    acc[4]+=tv*w1.x; acc[5]+=tv*w1.y; acc[6]+=tv*w1.z; acc[7]+=tv*w1.w;
    acc[8]+=tv*w2.x; acc[9]+=tv*w2.y; acc[10]+=tv*w2.z; acc[11]+=tv*w2.w;
    acc[12]+=tv*w3.x; acc[13]+=tv*w3.y; acc[14]+=tv*w3.z; acc[15]+=tv*w3.w;
  }
  for (int k=0;k<128;k++){
    float tv = tile[(128+k)*33+po];
    const float4* wp = reinterpret_cast<const float4*>(wh + k*512 + o0);
    float4 w0=wp[0], w1=wp[1], w2=wp[2], w3=wp[3];
    acc[0]+=tv*w0.x; acc[1]+=tv*w0.y; acc[2]+=tv*w0.z; acc[3]+=tv*w0.w;
    acc[4]+=tv*w1.x; acc[5]+=tv*w1.y; acc[6]+=tv*w1.z; acc[7]+=tv*w1.w;
    acc[8]+=tv*w2.x; acc[9]+=tv*w2.y; acc[10]+=tv*w2.z; acc[11]+=tv*w2.w;
    acc[12]+=tv*w3.x; acc[13]+=tv*w3.y; acc[14]+=tv*w3.z; acc[15]+=tv*w3.w;
  }
  float* gout = gates + (size_t)gt*524288 + pix0 + po;
  if (gt == 2){
    #pragma unroll
    for (int j=0;j<16;j++) gout[(og*16+j)*4096] = tanhf(acc[j]);
  } else {
    float m = -1e30f;
    #pragma unroll
    for (int j=0;j<16;j++) m = fmaxf(m, acc[j]);
    red[og*33+po] = m;
    __syncthreads();
    if (t < 32){
      float mm = red[t];
      for (int sg=1; sg<8; sg++) mm = fmaxf(mm, red[sg*33+t]);
      fin[t] = mm;
    }
    __syncthreads();
    float gm = fin[po];
    float e[16]; float ssum = 0.f;
    #pragma unroll
    for (int j=0;j<16;j++){ e[j] = expf(acc[j]-gm); ssum += e[j]; }
    __syncthreads();
    red[og*33+po] = ssum;
    __syncthreads();
    if (t < 32){
      float s2 = 0.f;
      for (int sg=0; sg<8; sg++) s2 += red[sg*33+t];
      fin[t] = s2;
    }
    __syncthreads();
    float inv = 1.0f/fin[po];
    #pragma unroll
    for (int j=0;j<16;j++) gout[(og*16+j)*4096] = e[j]*inv;
  }
}

// ---------- K6b: LSTM pointwise update; writes hs[n] to d_out (dtype-adaptive) ----------
__global__ __launch_bounds__(256) void k_lstm_post(const float* __restrict__ g, float* __restrict__ Cst,
    float* __restrict__ hws, void* __restrict__ dout, int n, const int* __restrict__ flag){
  int i = (blockIdx.x*256 + threadIdx.x)*4;
  float4 f  = *reinterpret_cast<const float4*>(g + i);
  float4 iv = *reinterpret_cast<const float4*>(g + 524288 + i);
  float4 s  = *reinterpret_cast<const float4*>(g + 1048576 + i);
  float4 o  = *reinterpret_cast<const float4*>(g + 1572864 + i);
  float4 c  = *reinterpret_cast<const float4*>(Cst + i);
  float4 cn, hn;
  cn.x = f.x*c.x + iv.x*s.x; cn.y = f.y*c.y + iv.y*s.y;
  cn.z = f.z*c.z + iv.z*s.z; cn.w = f.w*c.w + iv.w*s.w;
  hn.x = o.x*tanhf(cn.x); hn.y = o.y*tanhf(cn.y);
  hn.z = o.z*tanhf(cn.z); hn.w = o.w*tanhf(cn.w);
  *reinterpret_cast<float4*>(Cst + i) = cn;
  *reinterpret_cast<float4*>(hws + i) = hn;
  size_t off = (size_t)n*524288 + i;
  if (*flag){
    *reinterpret_cast<float4*>((float*)dout + off) = hn;
  } else {
    uint2 pk;
    pk.x = (u32)f2b_u(hn.x) | ((u32)f2b_u(hn.y) << 16);
    pk.y = (u32)f2b_u(hn.z) | ((u32)f2b_u(hn.w) << 16);
    *reinterpret_cast<uint2*>((u16*)dout + off) = pk;
  }
}

// ---------- K7: final hf, Cf (dtype-adaptive) ----------
__global__ __launch_bounds__(256) void k_final(const float* __restrict__ hws, const float* __restrict__ Cst,
                                               void* __restrict__ dout, const int* __restrict__ flag){
  int i = (blockIdx.x*256 + threadIdx.x)*4;
  float4 h = *reinterpret_cast<const float4*>(hws + i);
  float4 c = *reinterpret_cast<const float4*>(Cst + i);
  if (*flag){
    *reinterpret_cast<float4*>((float*)dout + 8388608 + i) = h;
    *reinterpret_cast<float4*>((float*)dout + 8912896 + i) = c;
  } else {
    uint2 ho, co;
    ho.x = (u32)f2b_u(h.x) | ((u32)f2b_u(h.y) << 16);
    ho.y = (u32)f2b_u(h.z) | ((u32)f2b_u(h.w) << 16);
    co.x = (u32)f2b_u(c.x) | ((u32)f2b_u(c.y) << 16);
    co.y = (u32)f2b_u(c.z) | ((u32)f2b_u(c.w) << 16);
    *reinterpret_cast<uint2*>((u16*)dout + 8388608 + i) = ho;
    *reinterpret_cast<uint2*>((u16*)dout + 8912896 + i) = co;
  }
}

extern "C" void kernel_launch(void* const* d_in, const int* in_sizes, int n_in,
                              void* d_out, int out_size, void* d_ws, size_t ws_size,
                              hipStream_t stream) {
  const void* x      = d_in[0];
  const void* h0     = d_in[1];
  const void* c0     = d_in[2];
  const void* conv_w = d_in[3];
  const void* conv_b = d_in[4];
  const void* qkv1_w = d_in[5];
  const void* qkv1_b = d_in[6];
  const void* m1w1   = d_in[7];
  const void* m1b1   = d_in[8];
  const void* m1w2   = d_in[9];
  const void* m1b2   = d_in[10];
  const void* qkv2_w = d_in[11];
  const void* qkv2_b = d_in[12];
  const void* m2w1   = d_in[13];
  const void* m2b1   = d_in[14];
  const void* m2w2   = d_in[15];
  const void* m2b2   = d_in[16];
  const void* lwx    = d_in[17];
  const void* lwh    = d_in[18];
  const void* lbh    = d_in[19];

  char* p = (char*)d_ws;
  auto alloc = [&](size_t bytes)->void*{
    void* r = (void*)p; p += (bytes + 255) & ~(size_t)255; return r;
  };
  int*   flag    = (int*)alloc(256);
  float* wT_conv = (float*)alloc(512*128*4);
  float* wT_qkv1 = (float*)alloc(128*384*4);
  float* wT_m1a  = (float*)alloc(128*512*4);
  float* wT_m1b  = (float*)alloc(512*128*4);
  float* wT_qkv2 = (float*)alloc(128*384*4);
  float* wT_m2a  = (float*)alloc(128*512*4);
  float* wT_m2b  = (float*)alloc(512*128*4);
  float* wT_lx   = (float*)alloc(128*512*4);
  float* wT_lh   = (float*)alloc(128*512*4);
  float* bf_conv = (float*)alloc(128*4);
  float* bf_qkv1 = (float*)alloc(384*4);
  float* bf_m1b1 = (float*)alloc(512*4);
  float* bf_m1b2 = (float*)alloc(128*4);
  float* bf_qkv2 = (float*)alloc(384*4);
  float* bf_m2b1 = (float*)alloc(512*4);
  float* bf_m2b2 = (float*)alloc(128*4);
  float* bf_lbh  = (float*)alloc(512*4);
  u16* R0   = (u16*)alloc(16777216);   // bufA -> bufC/y -> (gates, hws, Cst)
  u16* Rbig = (u16*)alloc(33554432);   // bufB (front) -> kvbuf -> bufD (front)

  u16* bufA = R0;
  u16* bufB = Rbig;
  u16* bufC = R0;          // also y (attn writes in place)
  u16* qbuf = (u16*)d_out; // hs region used as scratch; dead before first LSTM write
  u16* kvbuf = Rbig;
  u16* bufD = Rbig;
  float* gates = (float*)R0;                          // 8.39 MB
  float* hws = (float*)((char*)R0 + 8388608);         // 2 MB
  float* Cst = (float*)((char*)R0 + 10485760);        // 2 MB

  k_detect<<<1, 256, 0, stream>>>((const u32*)x, flag);

  auto T = [&](const void* in, float* o, int O, int K){
    int n = O*K;
    k_transpose<<<(n+255)/256, 256, 0, stream>>>(in, o, O, K, flag);
  };
  T(conv_w, wT_conv, 128, 512);
  T(qkv1_w, wT_qkv1, 384, 128);
  T(m1w1,   wT_m1a,  512, 128);
  T(m1w2,   wT_m1b,  128, 512);
  T(qkv2_w, wT_qkv2, 384, 128);
  T(m2w1,   wT_m2a,  512, 128);
  T(m2w2,   wT_m2b,  128, 512);
  T(lwx,    wT_lx,   512, 128);
  T(lwh,    wT_lh,   512, 128);

  auto V = [&](const void* in, float* o, int n){
    k_cvtvec<<<(n+255)/256, 256, 0, stream>>>(in, o, n, flag);
  };
  V(conv_b, bf_conv, 128);
  V(qkv1_b, bf_qkv1, 384);
  V(m1b1,   bf_m1b1, 512);
  V(m1b2,   bf_m1b2, 128);
  V(qkv2_b, bf_qkv2, 384);
  V(m2b1,   bf_m2b1, 512);
  V(m2b2,   bf_m2b2, 128);
  V(lbh,    bf_lbh,  512);

  k_conv<<<4096, 256, 0, stream>>>(x, wT_conv, bf_conv, bufA, flag);
  k_msa1<<<4096, 256, 0, stream>>>(bufA, wT_qkv1, bf_qkv1, bufB);
  k_mlp<1><<<4096, 256, 0, stream>>>(bufB, wT_m1a, bf_m1b1, wT_m1b, bf_m1b2, bufC);
  k_qkv2<<<4096, 256, 0, stream>>>(bufC, wT_qkv2, bf_qkv2, qbuf, kvbuf);
  k_attn2<<<2048, 256, 0, stream>>>(qbuf, kvbuf, bufC);          // y = x + attn, in place
  k_mlp<2><<<4096, 256, 0, stream>>>(bufC, wT_m2a, bf_m2b1, wT_m2b, bf_m2b2, bufD);

  k_init<<<512, 256, 0, stream>>>(h0, c0, hws, Cst, flag);       // R0 now free for state
  for (int n = 0; n < 16; n++){
    k_lstm_gates<<<512, 256, 0, stream>>>(bufD, hws, wT_lx, wT_lh, bf_lbh, gates, n);
    k_lstm_post<<<512, 256, 0, stream>>>(gates, Cst, hws, d_out, n, flag);
  }
  k_final<<<512, 256, 0, stream>>>(hws, Cst, d_out, flag);
}

// Round 2
// 3099.227 us; speedup vs baseline: 2.4077x; 1.1332x over previous
//
#include <hip/hip_runtime.h>
#include <hip/hip_bf16.h>

typedef unsigned int u32;
typedef unsigned short u16;

#define DI __device__ __forceinline__

// ---------- bf16 helpers (bf16 == fp32 high 16 bits; RNE on store) ----------
DI float b2f_u(u32 u){ return __uint_as_float(u << 16); }
DI u16 f2b_u(float f){
  u32 x = __float_as_uint(f);
  x += 0x7fffu + ((x >> 16) & 1u);
  return (u16)(x >> 16);
}
DI void ld8b(const u16* p, float* o){
  uint4 v = *reinterpret_cast<const uint4*>(p);
  o[0] = b2f_u(v.x & 0xffffu); o[1] = b2f_u(v.x >> 16);
  o[2] = b2f_u(v.y & 0xffffu); o[3] = b2f_u(v.y >> 16);
  o[4] = b2f_u(v.z & 0xffffu); o[5] = b2f_u(v.z >> 16);
  o[6] = b2f_u(v.w & 0xffffu); o[7] = b2f_u(v.w >> 16);
}
DI void st8b(u16* p, const float* i){
  uint4 v;
  v.x = (u32)f2b_u(i[0]) | ((u32)f2b_u(i[1]) << 16);
  v.y = (u32)f2b_u(i[2]) | ((u32)f2b_u(i[3]) << 16);
  v.z = (u32)f2b_u(i[4]) | ((u32)f2b_u(i[5]) << 16);
  v.w = (u32)f2b_u(i[6]) | ((u32)f2b_u(i[7]) << 16);
  *reinterpret_cast<uint4*>(p) = v;
}

// ---------- K_detect: is d_in fp32 (flag=1) or packed bf16 (flag=0)? ----------
__global__ void k_detect(const u32* __restrict__ xw, int* __restrict__ flag){
  __shared__ int cnt;
  int t = threadIdx.x;
  if (t == 0) cnt = 0;
  __syncthreads();
  int c = 0;
  for (int i = t; i < 2048; i += 256){
    u32 lo = xw[i] & 0xffffu;
    u32 e = (lo >> 7) & 0xffu;
    if (e < 100u || e > 140u) c++;
  }
  atomicAdd(&cnt, c);
  __syncthreads();
  if (t == 0) *flag = (cnt > 200) ? 1 : 0;
}

// ---------- K0: weight transpose ([O][K] -> fp32 [K][O]), dtype-adaptive ----------
__global__ void k_transpose(const void* __restrict__ in, float* __restrict__ out, int O, int K,
                            const int* __restrict__ flag){
  int idx = blockIdx.x*256 + threadIdx.x;
  if (idx < O*K){
    int o = idx % O, k = idx / O;
    if (*flag) out[idx] = ((const float*)in)[o*K + k];
    else       out[idx] = b2f_u((u32)((const u16*)in)[o*K + k]);
  }
}

// ---------- K0b: vector convert -> fp32 (straight copy, also used for [o][k] weights) ----------
__global__ void k_cvtvec(const void* __restrict__ in, float* __restrict__ out, int n,
                         const int* __restrict__ flag){
  int i = blockIdx.x*256 + threadIdx.x;
  if (i < n){
    if (*flag) out[i] = ((const float*)in)[i];
    else       out[i] = b2f_u((u32)((const u16*)in)[i]);
  }
}

// ---------- K1: conv 2x2 stride 2 + window partition -> bufA [b][g][l][c] ----------
// Block = (b, yg, xh): input slab rows [8yg..8yg+8) x cols [64xh..64xh+64), all 128 ci.
// Streams ci in chunks of 32 through 64 KB LDS (contiguous 256 B row segments -> full lines,
// every input byte fetched exactly once). Thread = 8 out-ch x 8 out-px, 64 accumulators.
// Weights read as float4 from ORIGINAL [co][ci][ky][kx] layout (fp32-converted, no transpose).
__global__ __launch_bounds__(256) void k_conv(const void* __restrict__ x_raw,
                                              const float* __restrict__ wO,
                                              const float* __restrict__ bias, u16* __restrict__ outA,
                                              const int* __restrict__ flag){
  __shared__ float patch[32*8*64];   // [ci][row][col], 64 KB
  int t = threadIdx.x, bid = blockIdx.x;
  int xh = bid & 1, yg = (bid >> 1) & 15, b = bid >> 5;
  int chg = t & 15, pxg = t >> 4;    // chg: out-ch group (coalesced stores), pxg: px group
  int co0 = chg*8;
  float bs[8];
  #pragma unroll
  for (int j=0;j<8;j++) bs[j] = bias[co0+j];
  float acc[2][4][8];
  #pragma unroll
  for (int a=0;a<2;a++)
    #pragma unroll
    for (int oy=0;oy<4;oy++)
      #pragma unroll
      for (int j=0;j<8;j++) acc[a][oy][j] = bs[j];

  size_t slab = (size_t)b*2097152 + (size_t)(yg*8)*128 + (size_t)xh*64;
  for (int ci0 = 0; ci0 < 128; ci0 += 32){
    if (ci0) __syncthreads();
    if (*flag){
      const float* xb = (const float*)x_raw + slab + (size_t)ci0*16384;
      #pragma unroll
      for (int i=0;i<16;i++){
        int f = i*256 + t;
        int ci = f >> 7, rem = f & 127, row = rem >> 4, col = (rem & 15)*4;
        float4 v = *reinterpret_cast<const float4*>(xb + ci*16384 + row*128 + col);
        *reinterpret_cast<float4*>(&patch[ci*512 + row*64 + col]) = v;
      }
    } else {
      const u16* xb = (const u16*)x_raw + slab + (size_t)ci0*16384;
      #pragma unroll
      for (int i=0;i<8;i++){
        int f = i*256 + t;
        int ci = f >> 6, rem = f & 63, row = rem >> 3, col = (rem & 7)*8;
        float v[8]; ld8b(xb + ci*16384 + row*128 + col, v);
        float4* d = reinterpret_cast<float4*>(&patch[ci*512 + row*64 + col]);
        d[0] = make_float4(v[0],v[1],v[2],v[3]);
        d[1] = make_float4(v[4],v[5],v[6],v[7]);
      }
    }
    __syncthreads();
    const float* wbase = wO + co0*512 + ci0*4;
    for (int ci=0; ci<32; ci++){
      float4 wv[8];
      #pragma unroll
      for (int j=0;j<8;j++)
        wv[j] = *reinterpret_cast<const float4*>(wbase + j*512 + ci*4);
      #pragma unroll
      for (int a=0;a<2;a++){
        int ox = pxg + a*16;
        #pragma unroll
        for (int oy=0;oy<4;oy++){
          float2 p0 = *reinterpret_cast<const float2*>(&patch[ci*512 + (2*oy)*64 + 2*ox]);
          float2 p1 = *reinterpret_cast<const float2*>(&patch[ci*512 + (2*oy+1)*64 + 2*ox]);
          #pragma unroll
          for (int j=0;j<8;j++){
            acc[a][oy][j] += p0.x*wv[j].x + p0.y*wv[j].y + p1.x*wv[j].z + p1.y*wv[j].w;
          }
        }
      }
    }
  }
  int base_g = yg*16 + xh*8;
  #pragma unroll
  for (int a=0;a<2;a++){
    int ox = pxg + a*16;
    int xg = base_g + (ox >> 2);
    #pragma unroll
    for (int oy=0;oy<4;oy++){
      int l = oy*4 + (ox & 3);
      size_t T = ((size_t)(b*256 + xg)*16 + l);
      st8b(outA + T*128 + co0, acc[a][oy]);
    }
  }
}

// ---------- K2: LocalMSA (L=16) + residual: bufA -> bufB (same layout) ----------
// Projection register-tiled: thread owns QKV rows {oi, oi+128, oi+256} x 8 tokens,
// weights as float4 from ORIGINAL [o][k] layout (96 FMA per 3 global + 8 LDS loads).
__global__ __launch_bounds__(256) void k_msa1(const u16* __restrict__ A, const float* __restrict__ wO,
                                              const float* __restrict__ qbias, u16* __restrict__ B){
  __shared__ float Xs[16*132];
  __shared__ float QKV[16*388];
  __shared__ float S[512];          // [h][l][m]
  int t = threadIdx.x, bid = blockIdx.x;
  const u16* Ab = A + (size_t)bid*2048;
  {
    int l = t >> 4, c0 = (t & 15)*8;
    float v[8]; ld8b(Ab + l*128 + c0, v);
    float4* d = reinterpret_cast<float4*>(&Xs[l*132 + c0]);
    d[0] = make_float4(v[0],v[1],v[2],v[3]);
    d[1] = make_float4(v[4],v[5],v[6],v[7]);
  }
  __syncthreads();
  {
    int tg = t >> 7, oi = t & 127;
    float accq[8], acck[8], accv[8];
    float bq = qbias[oi], bk = qbias[oi+128], bv = qbias[oi+256];
    #pragma unroll
    for (int i=0;i<8;i++){ accq[i]=bq; acck[i]=bk; accv[i]=bv; }
    const float* wq = wO + (size_t)oi*128;
    const float* wk = wO + (size_t)(oi+128)*128;
    const float* wv = wO + (size_t)(oi+256)*128;
    for (int k=0;k<128;k+=4){
      float4 q4 = *reinterpret_cast<const float4*>(wq+k);
      float4 k4 = *reinterpret_cast<const float4*>(wk+k);
      float4 v4 = *reinterpret_cast<const float4*>(wv+k);
      #pragma unroll
      for (int i=0;i<8;i++){
        float4 x4 = *reinterpret_cast<const float4*>(&Xs[(tg*8+i)*132 + k]);
        accq[i] += x4.x*q4.x + x4.y*q4.y + x4.z*q4.z + x4.w*q4.w;
        acck[i] += x4.x*k4.x + x4.y*k4.y + x4.z*k4.z + x4.w*k4.w;
        accv[i] += x4.x*v4.x + x4.y*v4.y + x4.z*v4.z + x4.w*v4.w;
      }
    }
    #pragma unroll
    for (int i=0;i<8;i++){
      int l = tg*8+i;
      QKV[l*388 + oi]       = accq[i];
      QKV[l*388 + 128 + oi] = acck[i];
      QKV[l*388 + 256 + oi] = accv[i];
    }
  }
  __syncthreads();
  const float scale = 0.08838834764831845f;   // 1/sqrt(128)
  for (int e = t; e < 512; e += 256){
    int h = e >> 8, l = (e>>4)&15, m = e&15;
    const float* q = &QKV[l*388 + h*64];
    const float* kk = &QKV[m*388 + 128 + h*64];
    float s = 0.f;
    #pragma unroll
    for (int d=0; d<64; d++) s += q[d]*kk[d];
    S[(h*16+l)*16 + m] = s*scale;
  }
  __syncthreads();
  if (t < 32){
    float* row = &S[t*16];
    float mx = row[0];
    #pragma unroll
    for (int m=1;m<16;m++) mx = fmaxf(mx,row[m]);
    float sum = 0.f;
    #pragma unroll
    for (int m=0;m<16;m++){ float e = expf(row[m]-mx); row[m]=e; sum+=e; }
    float inv = 1.0f/sum;
    #pragma unroll
    for (int m=0;m<16;m++) row[m] *= inv;
  }
  __syncthreads();
  {
    int l = t >> 4, og = t & 15, o0 = og*8;
    int h = o0 >> 6;
    const float* p = &S[(h*16+l)*16];
    float out8[8];
    #pragma unroll
    for (int j=0;j<8;j++){
      int o = o0+j, d = o & 63;
      float s = 0.f;
      #pragma unroll
      for (int m=0;m<16;m++) s += p[m]*QKV[m*388 + 256 + h*64 + d];
      out8[j] = s + Xs[l*132 + o];
    }
    st8b(B + (size_t)bid*2048 + l*128 + o0, out8);
  }
}

// ---------- K3/K5: MLP (+residual), register-tiled fp32 GEMMs.
//            MODE1: bufB [b][g][l][c] -> bufC [b][l][g][c].
//            MODE2: y [b][l][g][c] -> bufD [n][pix][c] (window reverse).
template<int MODE>
__global__ __launch_bounds__(256) void k_mlp(const u16* __restrict__ in,
    const float* __restrict__ w1T, const float* __restrict__ b1,
    const float* __restrict__ w2T, const float* __restrict__ b2,
    u16* __restrict__ out){
  __shared__ float Xs[16*132];       // 8448 B, kept for residual
  __shared__ float H[16*516];        // 33024 B; Yred overlays after GEMM2
  int t = threadIdx.x, bid = blockIdx.x;
  {
    int l = t >> 4, c0 = (t & 15)*8;
    float v[8]; ld8b(in + (size_t)bid*2048 + l*128 + c0, v);
    float4* d = reinterpret_cast<float4*>(&Xs[l*132 + c0]);
    d[0] = make_float4(v[0],v[1],v[2],v[3]);
    d[1] = make_float4(v[4],v[5],v[6],v[7]);
  }
  __syncthreads();

  // ---- GEMM1: H[tok][o] = gelu(X @ W1 + b1), o in {t, t+256} ----
  {
    float acc0[16], acc1[16];
    float bb0 = b1[t], bb1 = b1[t + 256];
    #pragma unroll
    for (int i=0;i<16;i++){ acc0[i] = bb0; acc1[i] = bb1; }
    const float* w = w1T + t;        // row stride 512
    for (int k=0;k<128;k+=4){
      float w00 = w[0],    w01 = w[256];
      float w10 = w[512],  w11 = w[768];
      float w20 = w[1024], w21 = w[1280];
      float w30 = w[1536], w31 = w[1792];
      w += 2048;
      #pragma unroll
      for (int i=0;i<16;i++){
        const float* xp = &Xs[i*132 + k];     // 16B-aligned -> ds_read_b128
        float x0 = xp[0], x1 = xp[1], x2 = xp[2], x3 = xp[3];
        acc0[i] += x0*w00; acc1[i] += x0*w01;
        acc0[i] += x1*w10; acc1[i] += x1*w11;
        acc0[i] += x2*w20; acc1[i] += x2*w21;
        acc0[i] += x3*w30; acc1[i] += x3*w31;
      }
    }
    #pragma unroll
    for (int i=0;i<16;i++){
      float a0 = acc0[i], a1 = acc1[i];
      H[i*516 + t]       = 0.5f*a0*(1.0f + erff(a0*0.70710678118654752f));
      H[i*516 + t + 256] = 0.5f*a1*(1.0f + erff(a1*0.70710678118654752f));
    }
  }
  __syncthreads();

  // ---- GEMM2: Y = H @ W2 (K split 2-way), partials to LDS ----
  int kg = t >> 7;                   // 0/1: k-range [kg*256, kg*256+256)
  int s  = t & 127;
  int o0 = s & 63;                   // outputs o0 and o0+64
  int tb = (s >> 6) * 8;             // tokens tb..tb+7
  float acc[8][2];
  #pragma unroll
  for (int i=0;i<8;i++){ acc[i][0] = 0.f; acc[i][1] = 0.f; }
  {
    const float* w = w2T + (size_t)(kg*256)*128 + o0;   // row stride 128
    const int hbase = kg*256;
    for (int k=0;k<256;k+=4){
      float wA0 = w[0],   wA1 = w[64];
      float wB0 = w[128], wB1 = w[192];
      float wC0 = w[256], wC1 = w[320];
      float wD0 = w[384], wD1 = w[448];
      w += 512;
      #pragma unroll
      for (int i=0;i<8;i++){
        const float* hh = &H[(tb+i)*516 + hbase + k];   // 16B-aligned broadcast
        float h0 = hh[0], h1 = hh[1], h2 = hh[2], h3 = hh[3];
        acc[i][0] += h0*wA0; acc[i][1] += h0*wA1;
        acc[i][0] += h1*wB0; acc[i][1] += h1*wB1;
        acc[i][0] += h2*wC0; acc[i][1] += h2*wC1;
        acc[i][0] += h3*wD0; acc[i][1] += h3*wD1;
      }
    }
  }
  __syncthreads();                    // H fully consumed; safe to overlay
  float* Yred = H;                    // [2][16][132]
  #pragma unroll
  for (int i=0;i<8;i++){
    Yred[(kg*16 + tb + i)*132 + o0]      = acc[i][0];
    Yred[(kg*16 + tb + i)*132 + o0 + 64] = acc[i][1];
  }
  __syncthreads();

  // ---- combine + bias + residual + store (same output mapping as before) ----
  {
    int tok = t >> 4, oc = (t & 15)*8;
    float outv[8];
    #pragma unroll
    for (int j=0;j<8;j++){
      int o = oc + j;
      outv[j] = b2[o] + Yred[tok*132 + o] + Yred[(16 + tok)*132 + o] + Xs[tok*132 + o];
    }
    int T = bid*16 + tok;
    size_t addr;
    if (MODE == 1){
      int b = T >> 12, g = (T >> 4) & 255, ll = T & 15;
      addr = ((size_t)((b*16 + ll)*256 + g))*128 + oc;
    } else {
      int b = T >> 12, ll = (T >> 8) & 15, g = T & 255;
      int pcoord = ((g >> 4)*4 + (ll >> 2))*64 + ((g & 15)*4 + (ll & 3));
      addr = ((size_t)(b*4096 + pcoord))*128 + oc;
    }
    st8b(out + addr, outv);
  }
}

// ---------- K4a: QKV projection for DilatedMSA: bufC -> qbuf [tok][128] + kvbuf [tok][256] ----------
// Same register-tiled projection as k_msa1; output staged through LDS for coalesced stores.
__global__ __launch_bounds__(256) void k_qkv2(const u16* __restrict__ in, const float* __restrict__ wO,
                                              const float* __restrict__ bias,
                                              u16* __restrict__ qbuf, u16* __restrict__ kvbuf){
  __shared__ float Xs[16*132];
  __shared__ float QKVs[16*388];
  int t = threadIdx.x, bid = blockIdx.x;
  {
    int l = t >> 4, c0 = (t & 15)*8;
    float v[8]; ld8b(in + (size_t)bid*2048 + l*128 + c0, v);
    float4* d = reinterpret_cast<float4*>(&Xs[l*132 + c0]);
    d[0] = make_float4(v[0],v[1],v[2],v[3]);
    d[1] = make_float4(v[4],v[5],v[6],v[7]);
  }
  __syncthreads();
  {
    int tg = t >> 7, oi = t & 127;
    float accq[8], acck[8], accv[8];
    float bq = bias[oi], bk = bias[oi+128], bv = bias[oi+256];
    #pragma unroll
    for (int i=0;i<8;i++){ accq[i]=bq; acck[i]=bk; accv[i]=bv; }
    const float* wq = wO + (size_t)oi*128;
    const float* wk = wO + (size_t)(oi+128)*128;
    const float* wv = wO + (size_t)(oi+256)*128;
    for (int k=0;k<128;k+=4){
      float4 q4 = *reinterpret_cast<const float4*>(wq+k);
      float4 k4 = *reinterpret_cast<const float4*>(wk+k);
      float4 v4 = *reinterpret_cast<const float4*>(wv+k);
      #pragma unroll
      for (int i=0;i<8;i++){
        float4 x4 = *reinterpret_cast<const float4*>(&Xs[(tg*8+i)*132 + k]);
        accq[i] += x4.x*q4.x + x4.y*q4.y + x4.z*q4.z + x4.w*q4.w;
        acck[i] += x4.x*k4.x + x4.y*k4.y + x4.z*k4.z + x4.w*k4.w;
        accv[i] += x4.x*v4.x + x4.y*v4.y + x4.z*v4.z + x4.w*v4.w;
      }
    }
    #pragma unroll
    for (int i=0;i<8;i++){
      int l = tg*8+i;
      QKVs[l*388 + oi]       = accq[i];
      QKVs[l*388 + 128 + oi] = acck[i];
      QKVs[l*388 + 256 + oi] = accv[i];
    }
  }
  __syncthreads();
  {
    int l = t >> 4, og = t & 15, o0 = og*24;
    size_t tok = (size_t)bid*16 + l;
    #pragma unroll
    for (int m=0; m<3; m++){
      int oc = o0 + m*8;
      float v8[8];
      #pragma unroll
      for (int j=0;j<8;j++) v8[j] = QKVs[l*388 + oc + j];
      if (oc < 128) st8b(qbuf + tok*128 + oc, v8);
      else          st8b(kvbuf + tok*256 + (oc-128), v8);
    }
  }
}

// ---------- K4b: DilatedMSA flash attention (L=256); writes y = x + attn IN PLACE over bufC ----------
__global__ __launch_bounds__(256) void k_attn2(const u16* __restrict__ qbuf, const u16* __restrict__ kvbuf,
                                               u16* __restrict__ y){
  __shared__ float Qs[64*66];
  __shared__ float Ks[32*64];
  __shared__ float Vs[32*64];
  __shared__ float Ss[64*33];
  __shared__ float mrow[64], lrow[64], crow[64];
  int t = threadIdx.x, bid = blockIdx.x;
  int qt = bid & 3, h = (bid >> 2) & 1, bl = bid >> 3;
  size_t tokbase = (size_t)bl * 256;
  {
    int r = t >> 2, seg = t & 3;
    const u16* src = qbuf + (tokbase + qt*64 + r)*128 + h*64 + seg*16;
    float v[16]; ld8b(src, v); ld8b(src+8, v+8);
    #pragma unroll
    for (int j=0;j<16;j++) Qs[r*66 + seg*16 + j] = v[j];
  }
  if (t < 64){ mrow[t] = -1e30f; lrow[t] = 0.0f; }
  float Oacc[16];
  #pragma unroll
  for (int j=0;j<16;j++) Oacc[j] = 0.0f;
  int lq = t & 63, grp = t >> 6;
  __syncthreads();
  for (int kt=0; kt<8; kt++){
    {
      int r = t >> 3, seg = t & 7;
      const u16* base = kvbuf + (tokbase + kt*32 + r)*256 + h*64;
      float v[8];
      ld8b(base + seg*8, v);
      #pragma unroll
      for (int j=0;j<8;j++) Ks[r*64 + seg*8 + j] = v[j];
      ld8b(base + 128 + seg*8, v);
      #pragma unroll
      for (int j=0;j<8;j++) Vs[r*64 + seg*8 + j] = v[j];
    }
    __syncthreads();
    {
      float acc[8];
      #pragma unroll
      for (int j=0;j<8;j++) acc[j] = 0.0f;
      for (int dc=0; dc<8; dc++){
        const float2* qp = reinterpret_cast<const float2*>(&Qs[lq*66 + dc*8]);
        float2 q0 = qp[0], q1 = qp[1], q2 = qp[2], q3 = qp[3];
        #pragma unroll
        for (int j=0;j<8;j++){
          const float4* kp = reinterpret_cast<const float4*>(&Ks[(grp*8+j)*64 + dc*8]);
          float4 k0 = kp[0], k1 = kp[1];
          acc[j] += q0.x*k0.x + q0.y*k0.y + q1.x*k0.z + q1.y*k0.w
                  + q2.x*k1.x + q2.y*k1.y + q3.x*k1.z + q3.y*k1.w;
        }
      }
      #pragma unroll
      for (int j=0;j<8;j++) Ss[lq*33 + grp*8 + j] = acc[j] * 0.08838834764831845f;
    }
    __syncthreads();
    if (t < 64){
      float* row = &Ss[t*33];
      float m = mrow[t];
      #pragma unroll
      for (int i=0;i<32;i++) m = fmaxf(m, row[i]);
      float corr = expf(mrow[t] - m);
      float s = lrow[t] * corr;
      #pragma unroll
      for (int i=0;i<32;i++){ float e = expf(row[i]-m); row[i] = e; s += e; }
      mrow[t] = m; lrow[t] = s; crow[t] = corr;
    }
    __syncthreads();
    {
      float corr = crow[lq];
      #pragma unroll
      for (int j=0;j<16;j++) Oacc[j] *= corr;
      for (int m=0;m<32;m++){
        float pp = Ss[lq*33 + m];
        const float4* vp = reinterpret_cast<const float4*>(&Vs[m*64 + grp*16]);
        float4 v0 = vp[0], v1 = vp[1], v2 = vp[2], v3 = vp[3];
        Oacc[0]+=pp*v0.x; Oacc[1]+=pp*v0.y; Oacc[2]+=pp*v0.z; Oacc[3]+=pp*v0.w;
        Oacc[4]+=pp*v1.x; Oacc[5]+=pp*v1.y; Oacc[6]+=pp*v1.z; Oacc[7]+=pp*v1.w;
        Oacc[8]+=pp*v2.x; Oacc[9]+=pp*v2.y; Oacc[10]+=pp*v2.z; Oacc[11]+=pp*v2.w;
        Oacc[12]+=pp*v3.x; Oacc[13]+=pp*v3.y; Oacc[14]+=pp*v3.z; Oacc[15]+=pp*v3.w;
      }
    }
    __syncthreads();
  }
  float inv = 1.0f / lrow[lq];
  u16* dst = y + (tokbase + qt*64 + lq)*128 + h*64 + grp*16;
  float res[16]; ld8b(dst, res); ld8b(dst+8, res+8);
  float o16[16];
  #pragma unroll
  for (int j=0;j<16;j++) o16[j] = Oacc[j]*inv + res[j];
  st8b(dst, o16); st8b(dst+8, o16+8);
}

// ---------- K_init: h,C state from h0,c0 (dtype-adaptive) ----------
__global__ __launch_bounds__(256) void k_init(const void* __restrict__ h0, const void* __restrict__ c0,
                                              float* __restrict__ hws, float* __restrict__ Cst,
                                              const int* __restrict__ flag){
  int i = (blockIdx.x*256 + threadIdx.x)*4;
  if (*flag){
    *reinterpret_cast<float4*>(hws + i) = *reinterpret_cast<const float4*>((const float*)h0 + i);
    *reinterpret_cast<float4*>(Cst + i) = *reinterpret_cast<const float4*>((const float*)c0 + i);
  } else {
    uint2 hv = *reinterpret_cast<const uint2*>((const u16*)h0 + i);
    uint2 cv = *reinterpret_cast<const uint2*>((const u16*)c0 + i);
    *reinterpret_cast<float4*>(hws + i) = make_float4(b2f_u(hv.x & 0xffffu), b2f_u(hv.x >> 16),
                                                      b2f_u(hv.y & 0xffffu), b2f_u(hv.y >> 16));
    *reinterpret_cast<float4*>(Cst + i) = make_float4(b2f_u(cv.x & 0xffffu), b2f_u(cv.x >> 16),
                                                      b2f_u(cv.y & 0xffffu), b2f_u(cv.y >> 16));
  }
}

// ---------- K6a: LSTM gates GEMM + softmax/tanh; block = (32 pixels, one gate type) ----------
__global__ __launch_bounds__(256) void k_lstm_gates(const u16* __restrict__ xD, const float* __restrict__ hws,
    const float* __restrict__ wx, const float* __restrict__ wh, const float* __restrict__ bh,
    float* __restrict__ gates, int n){
  __shared__ float tile[256*33];   // [k][p], k<128: x ch, k>=128: h ch
  __shared__ float red[8*33];
  __shared__ float fin[33];
  int t = threadIdx.x, bid = blockIdx.x;
  int pt = bid >> 2, gt = bid & 3;
  int pix0 = pt*32;
  {
    int po = t >> 3, cg = t & 7;
    const u16* src = xD + ((size_t)n*4096 + pix0 + po)*128 + cg*16;
    float v[16]; ld8b(src, v); ld8b(src+8, v+8);
    #pragma unroll
    for (int j=0;j<16;j++) tile[(cg*16+j)*33 + po] = v[j];
  }
  {
    int c = t >> 1, half = t & 1;
    const float4* src = reinterpret_cast<const float4*>(hws + c*4096 + pix0 + half*16);
    #pragma unroll
    for (int q=0;q<4;q++){
      float4 v = src[q];
      int base = (128+c)*33 + half*16 + q*4;
      tile[base+0]=v.x; tile[base+1]=v.y; tile[base+2]=v.z; tile[base+3]=v.w;
    }
  }
  __syncthreads();
  int po = t & 31, og = t >> 5;
  int o0 = gt*128 + og*16;
  float acc[16];
  #pragma unroll
  for (int j=0;j<16;j++) acc[j] = bh[o0+j];
  for (int k=0;k<128;k++){
    float tv = tile[k*33+po];
    const float4* wp = reinterpret_cast<const float4*>(wx + k*512 + o0);
    float4 w0=wp[0], w1=wp[1], w2=wp[2], w3=wp[3];
    acc[0]+=tv*w0.x; acc[1]+=tv*w0.y; acc[2]+=tv*w0.z; acc[3]+=tv*w0.w;
    acc[4]+=tv*w1.x; acc[5]+=tv*w1.y; acc[6]+=tv*w1.z; acc[7]+=tv*w1.w;
    acc[8]+=tv*w2.x; acc[9]+=tv*w2.y; acc[10]+=tv*w2.z; acc[11]+=tv*w2.w;
    acc[12]+=tv*w3.x; acc[13]+=tv*w3.y; acc[14]+=tv*w3.z; acc[15]+=tv*w3.w;
  }
  for (int k=0;k<128;k++){
    float tv = tile[(128+k)*33+po];
    const float4* wp = reinterpret_cast<const float4*>(wh + k*512 + o0);
    float4 w0=wp[0], w1=wp[1], w2=wp[2], w3=wp[3];
    acc[0]+=tv*w0.x; acc[1]+=tv*w0.y; acc[2]+=tv*w0.z; acc[3]+=tv*w0.w;
    acc[4]+=tv*w1.x; acc[5]+=tv*w1.y; acc[6]+=tv*w1.z; acc[7]+=tv*w1.w;
    acc[8]+=tv*w2.x; acc[9]+=tv*w2.y; acc[10]+=tv*w2.z; acc[11]+=tv*w2.w;
    acc[12]+=tv*w3.x; acc[13]+=tv*w3.y; acc[14]+=tv*w3.z; acc[15]+=tv*w3.w;
  }
  float* gout = gates + (size_t)gt*524288 + pix0 + po;
  if (gt == 2){
    #pragma unroll
    for (int j=0;j<16;j++) gout[(og*16+j)*4096] = tanhf(acc[j]);
  } else {
    float m = -1e30f;
    #pragma unroll
    for (int j=0;j<16;j++) m = fmaxf(m, acc[j]);
    red[og*33+po] = m;
    __syncthreads();
    if (t < 32){
      float mm = red[t];
      for (int sg=1; sg<8; sg++) mm = fmaxf(mm, red[sg*33+t]);
      fin[t] = mm;
    }
    __syncthreads();
    float gm = fin[po];
    float e[16]; float ssum = 0.f;
    #pragma unroll
    for (int j=0;j<16;j++){ e[j] = expf(acc[j]-gm); ssum += e[j]; }
    __syncthreads();
    red[og*33+po] = ssum;
    __syncthreads();
    if (t < 32){
      float s2 = 0.f;
      for (int sg=0; sg<8; sg++) s2 += red[sg*33+t];
      fin[t] = s2;
    }
    __syncthreads();
    float inv = 1.0f/fin[po];
    #pragma unroll
    for (int j=0;j<16;j++) gout[(og*16+j)*4096] = e[j]*inv;
  }
}

// ---------- K6b: LSTM pointwise update; writes hs[n] to d_out (dtype-adaptive) ----------
__global__ __launch_bounds__(256) void k_lstm_post(const float* __restrict__ g, float* __restrict__ Cst,
    float* __restrict__ hws, void* __restrict__ dout, int n, const int* __restrict__ flag){
  int i = (blockIdx.x*256 + threadIdx.x)*4;
  float4 f  = *reinterpret_cast<const float4*>(g + i);
  float4 iv = *reinterpret_cast<const float4*>(g + 524288 + i);
  float4 s  = *reinterpret_cast<const float4*>(g + 1048576 + i);
  float4 o  = *reinterpret_cast<const float4*>(g + 1572864 + i);
  float4 c  = *reinterpret_cast<const float4*>(Cst + i);
  float4 cn, hn;
  cn.x = f.x*c.x + iv.x*s.x; cn.y = f.y*c.y + iv.y*s.y;
  cn.z = f.z*c.z + iv.z*s.z; cn.w = f.w*c.w + iv.w*s.w;
  hn.x = o.x*tanhf(cn.x); hn.y = o.y*tanhf(cn.y);
  hn.z = o.z*tanhf(cn.z); hn.w = o.w*tanhf(cn.w);
  *reinterpret_cast<float4*>(Cst + i) = cn;
  *reinterpret_cast<float4*>(hws + i) = hn;
  size_t off = (size_t)n*524288 + i;
  if (*flag){
    *reinterpret_cast<float4*>((float*)dout + off) = hn;
  } else {
    uint2 pk;
    pk.x = (u32)f2b_u(hn.x) | ((u32)f2b_u(hn.y) << 16);
    pk.y = (u32)f2b_u(hn.z) | ((u32)f2b_u(hn.w) << 16);
    *reinterpret_cast<uint2*>((u16*)dout + off) = pk;
  }
}

// ---------- K7: final hf, Cf (dtype-adaptive) ----------
__global__ __launch_bounds__(256) void k_final(const float* __restrict__ hws, const float* __restrict__ Cst,
                                               void* __restrict__ dout, const int* __restrict__ flag){
  int i = (blockIdx.x*256 + threadIdx.x)*4;
  float4 h = *reinterpret_cast<const float4*>(hws + i);
  float4 c = *reinterpret_cast<const float4*>(Cst + i);
  if (*flag){
    *reinterpret_cast<float4*>((float*)dout + 8388608 + i) = h;
    *reinterpret_cast<float4*>((float*)dout + 8912896 + i) = c;
  } else {
    uint2 ho, co;
    ho.x = (u32)f2b_u(h.x) | ((u32)f2b_u(h.y) << 16);
    ho.y = (u32)f2b_u(h.z) | ((u32)f2b_u(h.w) << 16);
    co.x = (u32)f2b_u(c.x) | ((u32)f2b_u(c.y) << 16);
    co.y = (u32)f2b_u(c.z) | ((u32)f2b_u(c.w) << 16);
    *reinterpret_cast<uint2*>((u16*)dout + 8388608 + i) = ho;
    *reinterpret_cast<uint2*>((u16*)dout + 8912896 + i) = co;
  }
}

extern "C" void kernel_launch(void* const* d_in, const int* in_sizes, int n_in,
                              void* d_out, int out_size, void* d_ws, size_t ws_size,
                              hipStream_t stream) {
  const void* x      = d_in[0];
  const void* h0     = d_in[1];
  const void* c0     = d_in[2];
  const void* conv_w = d_in[3];
  const void* conv_b = d_in[4];
  const void* qkv1_w = d_in[5];
  const void* qkv1_b = d_in[6];
  const void* m1w1   = d_in[7];
  const void* m1b1   = d_in[8];
  const void* m1w2   = d_in[9];
  const void* m1b2   = d_in[10];
  const void* qkv2_w = d_in[11];
  const void* qkv2_b = d_in[12];
  const void* m2w1   = d_in[13];
  const void* m2b1   = d_in[14];
  const void* m2w2   = d_in[15];
  const void* m2b2   = d_in[16];
  const void* lwx    = d_in[17];
  const void* lwh    = d_in[18];
  const void* lbh    = d_in[19];

  char* p = (char*)d_ws;
  auto alloc = [&](size_t bytes)->void*{
    void* r = (void*)p; p += (bytes + 255) & ~(size_t)255; return r;
  };
  int*   flag    = (int*)alloc(256);
  float* wO_conv = (float*)alloc(512*128*4);   // original [co][ci*4+ky*2+kx] layout, fp32
  float* wO_qkv1 = (float*)alloc(384*128*4);   // original [o][k] layout, fp32
  float* wT_m1a  = (float*)alloc(128*512*4);
  float* wT_m1b  = (float*)alloc(512*128*4);
  float* wO_qkv2 = (float*)alloc(384*128*4);   // original [o][k] layout, fp32
  float* wT_m2a  = (float*)alloc(128*512*4);
  float* wT_m2b  = (float*)alloc(512*128*4);
  float* wT_lx   = (float*)alloc(128*512*4);
  float* wT_lh   = (float*)alloc(128*512*4);
  float* bf_conv = (float*)alloc(128*4);
  float* bf_qkv1 = (float*)alloc(384*4);
  float* bf_m1b1 = (float*)alloc(512*4);
  float* bf_m1b2 = (float*)alloc(128*4);
  float* bf_qkv2 = (float*)alloc(384*4);
  float* bf_m2b1 = (float*)alloc(512*4);
  float* bf_m2b2 = (float*)alloc(128*4);
  float* bf_lbh  = (float*)alloc(512*4);
  u16* R0   = (u16*)alloc(16777216);   // bufA -> bufC/y -> (gates, hws, Cst)
  u16* Rbig = (u16*)alloc(33554432);   // bufB (front) -> kvbuf -> bufD (front)

  u16* bufA = R0;
  u16* bufB = Rbig;
  u16* bufC = R0;          // also y (attn writes in place)
  u16* qbuf = (u16*)d_out; // hs region used as scratch; dead before first LSTM write
  u16* kvbuf = Rbig;
  u16* bufD = Rbig;
  float* gates = (float*)R0;                          // 8.39 MB
  float* hws = (float*)((char*)R0 + 8388608);         // 2 MB
  float* Cst = (float*)((char*)R0 + 10485760);        // 2 MB

  k_detect<<<1, 256, 0, stream>>>((const u32*)x, flag);

  auto T = [&](const void* in, float* o, int O, int K){
    int n = O*K;
    k_transpose<<<(n+255)/256, 256, 0, stream>>>(in, o, O, K, flag);
  };
  T(m1w1,   wT_m1a,  512, 128);
  T(m1w2,   wT_m1b,  128, 512);
  T(m2w1,   wT_m2a,  512, 128);
  T(m2w2,   wT_m2b,  128, 512);
  T(lwx,    wT_lx,   512, 128);
  T(lwh,    wT_lh,   512, 128);

  auto V = [&](const void* in, float* o, int n){
    k_cvtvec<<<(n+255)/256, 256, 0, stream>>>(in, o, n, flag);
  };
  V(conv_w, wO_conv, 128*512);     // straight copy keeps original layout
  V(qkv1_w, wO_qkv1, 384*128);
  V(qkv2_w, wO_qkv2, 384*128);
  V(conv_b, bf_conv, 128);
  V(qkv1_b, bf_qkv1, 384);
  V(m1b1,   bf_m1b1, 512);
  V(m1b2,   bf_m1b2, 128);
  V(qkv2_b, bf_qkv2, 384);
  V(m2b1,   bf_m2b1, 512);
  V(m2b2,   bf_m2b2, 128);
  V(lbh,    bf_lbh,  512);

  k_conv<<<512, 256, 0, stream>>>(x, wO_conv, bf_conv, bufA, flag);
  k_msa1<<<4096, 256, 0, stream>>>(bufA, wO_qkv1, bf_qkv1, bufB);
  k_mlp<1><<<4096, 256, 0, stream>>>(bufB, wT_m1a, bf_m1b1, wT_m1b, bf_m1b2, bufC);
  k_qkv2<<<4096, 256, 0, stream>>>(bufC, wO_qkv2, bf_qkv2, qbuf, kvbuf);
  k_attn2<<<2048, 256, 0, stream>>>(qbuf, kvbuf, bufC);          // y = x + attn, in place
  k_mlp<2><<<4096, 256, 0, stream>>>(bufC, wT_m2a, bf_m2b1, wT_m2b, bf_m2b2, bufD);

  k_init<<<512, 256, 0, stream>>>(h0, c0, hws, Cst, flag);       // R0 now free for state
  for (int n = 0; n < 16; n++){
    k_lstm_gates<<<512, 256, 0, stream>>>(bufD, hws, wT_lx, wT_lh, bf_lbh, gates, n);
    k_lstm_post<<<512, 256, 0, stream>>>(gates, Cst, hws, d_out, n, flag);
  }
  k_final<<<512, 256, 0, stream>>>(hws, Cst, d_out, flag);
}

// Round 3
// 2726.529 us; speedup vs baseline: 2.7369x; 1.1367x over previous
//
#include <hip/hip_runtime.h>
#include <hip/hip_bf16.h>

typedef unsigned int u32;
typedef unsigned short u16;

#define DI __device__ __forceinline__

// ---------- bf16 helpers (bf16 == fp32 high 16 bits; RNE on store) ----------
DI float b2f_u(u32 u){ return __uint_as_float(u << 16); }
DI u16 f2b_u(float f){
  u32 x = __float_as_uint(f);
  x += 0x7fffu + ((x >> 16) & 1u);
  return (u16)(x >> 16);
}
DI void ld8b(const u16* p, float* o){
  uint4 v = *reinterpret_cast<const uint4*>(p);
  o[0] = b2f_u(v.x & 0xffffu); o[1] = b2f_u(v.x >> 16);
  o[2] = b2f_u(v.y & 0xffffu); o[3] = b2f_u(v.y >> 16);
  o[4] = b2f_u(v.z & 0xffffu); o[5] = b2f_u(v.z >> 16);
  o[6] = b2f_u(v.w & 0xffffu); o[7] = b2f_u(v.w >> 16);
}
DI void st8b(u16* p, const float* i){
  uint4 v;
  v.x = (u32)f2b_u(i[0]) | ((u32)f2b_u(i[1]) << 16);
  v.y = (u32)f2b_u(i[2]) | ((u32)f2b_u(i[3]) << 16);
  v.z = (u32)f2b_u(i[4]) | ((u32)f2b_u(i[5]) << 16);
  v.w = (u32)f2b_u(i[6]) | ((u32)f2b_u(i[7]) << 16);
  *reinterpret_cast<uint4*>(p) = v;
}

// ---------- K_detect: is d_in fp32 (flag=1) or packed bf16 (flag=0)? ----------
__global__ void k_detect(const u32* __restrict__ xw, int* __restrict__ flag){
  __shared__ int cnt;
  int t = threadIdx.x;
  if (t == 0) cnt = 0;
  __syncthreads();
  int c = 0;
  for (int i = t; i < 2048; i += 256){
    u32 lo = xw[i] & 0xffffu;
    u32 e = (lo >> 7) & 0xffu;
    if (e < 100u || e > 140u) c++;
  }
  atomicAdd(&cnt, c);
  __syncthreads();
  if (t == 0) *flag = (cnt > 200) ? 1 : 0;
}

// ---------- K0: weight transpose ([O][K] -> fp32 [K][O]), dtype-adaptive ----------
__global__ void k_transpose(const void* __restrict__ in, float* __restrict__ out, int O, int K,
                            const int* __restrict__ flag){
  int idx = blockIdx.x*256 + threadIdx.x;
  if (idx < O*K){
    int o = idx % O, k = idx / O;
    if (*flag) out[idx] = ((const float*)in)[o*K + k];
    else       out[idx] = b2f_u((u32)((const u16*)in)[o*K + k]);
  }
}

// ---------- K0b: vector convert -> fp32 (straight copy, also used for [o][k] weights) ----------
__global__ void k_cvtvec(const void* __restrict__ in, float* __restrict__ out, int n,
                         const int* __restrict__ flag){
  int i = blockIdx.x*256 + threadIdx.x;
  if (i < n){
    if (*flag) out[i] = ((const float*)in)[i];
    else       out[i] = b2f_u((u32)((const u16*)in)[i]);
  }
}

// ---------- K1: conv 2x2 stride 2 + window partition -> bufA [b][g][l][c] ----------
__global__ __launch_bounds__(256) void k_conv(const void* __restrict__ x_raw,
                                              const float* __restrict__ wO,
                                              const float* __restrict__ bias, u16* __restrict__ outA,
                                              const int* __restrict__ flag){
  __shared__ float patch[32*8*64];   // [ci][row][col], 64 KB
  int t = threadIdx.x, bid = blockIdx.x;
  int xh = bid & 1, yg = (bid >> 1) & 15, b = bid >> 5;
  int chg = t & 15, pxg = t >> 4;
  int co0 = chg*8;
  float bs[8];
  #pragma unroll
  for (int j=0;j<8;j++) bs[j] = bias[co0+j];
  float acc[2][4][8];
  #pragma unroll
  for (int a=0;a<2;a++)
    #pragma unroll
    for (int oy=0;oy<4;oy++)
      #pragma unroll
      for (int j=0;j<8;j++) acc[a][oy][j] = bs[j];

  size_t slab = (size_t)b*2097152 + (size_t)(yg*8)*128 + (size_t)xh*64;
  for (int ci0 = 0; ci0 < 128; ci0 += 32){
    if (ci0) __syncthreads();
    if (*flag){
      const float* xb = (const float*)x_raw + slab + (size_t)ci0*16384;
      #pragma unroll
      for (int i=0;i<16;i++){
        int f = i*256 + t;
        int ci = f >> 7, rem = f & 127, row = rem >> 4, col = (rem & 15)*4;
        float4 v = *reinterpret_cast<const float4*>(xb + ci*16384 + row*128 + col);
        *reinterpret_cast<float4*>(&patch[ci*512 + row*64 + col]) = v;
      }
    } else {
      const u16* xb = (const u16*)x_raw + slab + (size_t)ci0*16384;
      #pragma unroll
      for (int i=0;i<8;i++){
        int f = i*256 + t;
        int ci = f >> 6, rem = f & 63, row = rem >> 3, col = (rem & 7)*8;
        float v[8]; ld8b(xb + ci*16384 + row*128 + col, v);
        float4* d = reinterpret_cast<float4*>(&patch[ci*512 + row*64 + col]);
        d[0] = make_float4(v[0],v[1],v[2],v[3]);
        d[1] = make_float4(v[4],v[5],v[6],v[7]);
      }
    }
    __syncthreads();
    const float* wbase = wO + co0*512 + ci0*4;
    for (int ci=0; ci<32; ci++){
      float4 wv[8];
      #pragma unroll
      for (int j=0;j<8;j++)
        wv[j] = *reinterpret_cast<const float4*>(wbase + j*512 + ci*4);
      #pragma unroll
      for (int a=0;a<2;a++){
        int ox = pxg + a*16;
        #pragma unroll
        for (int oy=0;oy<4;oy++){
          float2 p0 = *reinterpret_cast<const float2*>(&patch[ci*512 + (2*oy)*64 + 2*ox]);
          float2 p1 = *reinterpret_cast<const float2*>(&patch[ci*512 + (2*oy+1)*64 + 2*ox]);
          #pragma unroll
          for (int j=0;j<8;j++){
            acc[a][oy][j] += p0.x*wv[j].x + p0.y*wv[j].y + p1.x*wv[j].z + p1.y*wv[j].w;
          }
        }
      }
    }
  }
  int base_g = yg*16 + xh*8;
  #pragma unroll
  for (int a=0;a<2;a++){
    int ox = pxg + a*16;
    int xg = base_g + (ox >> 2);
    #pragma unroll
    for (int oy=0;oy<4;oy++){
      int l = oy*4 + (ox & 3);
      size_t T = ((size_t)(b*256 + xg)*16 + l);
      st8b(outA + T*128 + co0, acc[a][oy]);
    }
  }
}

// ---------- K2: LocalMSA (L=16) + residual: bufA -> bufB (same layout) ----------
// Projection: thread owns QKV rows {oi, oi+128, oi+256} x 8 tokens; weights from
// TRANSPOSED [k][384] layout with scalar coalesced loads (lane oi -> consecutive addrs).
__global__ __launch_bounds__(256) void k_msa1(const u16* __restrict__ A, const float* __restrict__ wT,
                                              const float* __restrict__ qbias, u16* __restrict__ B){
  __shared__ float Xs[16*132];
  __shared__ float QKV[16*388];
  __shared__ float S[512];          // [h][l][m]
  int t = threadIdx.x, bid = blockIdx.x;
  const u16* Ab = A + (size_t)bid*2048;
  {
    int l = t >> 4, c0 = (t & 15)*8;
    float v[8]; ld8b(Ab + l*128 + c0, v);
    float4* d = reinterpret_cast<float4*>(&Xs[l*132 + c0]);
    d[0] = make_float4(v[0],v[1],v[2],v[3]);
    d[1] = make_float4(v[4],v[5],v[6],v[7]);
  }
  __syncthreads();
  {
    int tg = t >> 7, oi = t & 127;
    float accq[8], acck[8], accv[8];
    float bq = qbias[oi], bk = qbias[oi+128], bv = qbias[oi+256];
    #pragma unroll
    for (int i=0;i<8;i++){ accq[i]=bq; acck[i]=bk; accv[i]=bv; }
    const float* w0 = wT + oi;
    for (int k=0;k<128;k+=4){
      const float* wr = w0 + (size_t)k*384;
      float q0 = wr[0],   q1 = wr[384],  q2 = wr[768],  q3 = wr[1152];
      float k0 = wr[128], k1 = wr[512],  k2 = wr[896],  k3 = wr[1280];
      float v0 = wr[256], v1 = wr[640],  v2 = wr[1024], v3 = wr[1408];
      #pragma unroll
      for (int i=0;i<8;i++){
        float4 x4 = *reinterpret_cast<const float4*>(&Xs[(tg*8+i)*132 + k]);
        accq[i] += x4.x*q0 + x4.y*q1 + x4.z*q2 + x4.w*q3;
        acck[i] += x4.x*k0 + x4.y*k1 + x4.z*k2 + x4.w*k3;
        accv[i] += x4.x*v0 + x4.y*v1 + x4.z*v2 + x4.w*v3;
      }
    }
    #pragma unroll
    for (int i=0;i<8;i++){
      int l = tg*8+i;
      QKV[l*388 + oi]       = accq[i];
      QKV[l*388 + 128 + oi] = acck[i];
      QKV[l*388 + 256 + oi] = accv[i];
    }
  }
  __syncthreads();
  const float scale = 0.08838834764831845f;   // 1/sqrt(128)
  for (int e = t; e < 512; e += 256){
    int h = e >> 8, l = (e>>4)&15, m = e&15;
    const float* q = &QKV[l*388 + h*64];
    const float* kk = &QKV[m*388 + 128 + h*64];
    float s = 0.f;
    #pragma unroll
    for (int d=0; d<64; d++) s += q[d]*kk[d];
    S[(h*16+l)*16 + m] = s*scale;
  }
  __syncthreads();
  if (t < 32){
    float* row = &S[t*16];
    float mx = row[0];
    #pragma unroll
    for (int m=1;m<16;m++) mx = fmaxf(mx,row[m]);
    float sum = 0.f;
    #pragma unroll
    for (int m=0;m<16;m++){ float e = expf(row[m]-mx); row[m]=e; sum+=e; }
    float inv = 1.0f/sum;
    #pragma unroll
    for (int m=0;m<16;m++) row[m] *= inv;
  }
  __syncthreads();
  {
    int l = t >> 4, og = t & 15, o0 = og*8;
    int h = o0 >> 6;
    const float* p = &S[(h*16+l)*16];
    float out8[8];
    #pragma unroll
    for (int j=0;j<8;j++){
      int o = o0+j, d = o & 63;
      float s = 0.f;
      #pragma unroll
      for (int m=0;m<16;m++) s += p[m]*QKV[m*388 + 256 + h*64 + d];
      out8[j] = s + Xs[l*132 + o];
    }
    st8b(B + (size_t)bid*2048 + l*128 + o0, out8);
  }
}

// ---------- K3/K5: MLP (+residual), register-tiled fp32 GEMMs. ----------
template<int MODE>
__global__ __launch_bounds__(256) void k_mlp(const u16* __restrict__ in,
    const float* __restrict__ w1T, const float* __restrict__ b1,
    const float* __restrict__ w2T, const float* __restrict__ b2,
    u16* __restrict__ out){
  __shared__ float Xs[16*132];
  __shared__ float H[16*516];
  int t = threadIdx.x, bid = blockIdx.x;
  {
    int l = t >> 4, c0 = (t & 15)*8;
    float v[8]; ld8b(in + (size_t)bid*2048 + l*128 + c0, v);
    float4* d = reinterpret_cast<float4*>(&Xs[l*132 + c0]);
    d[0] = make_float4(v[0],v[1],v[2],v[3]);
    d[1] = make_float4(v[4],v[5],v[6],v[7]);
  }
  __syncthreads();

  {
    float acc0[16], acc1[16];
    float bb0 = b1[t], bb1 = b1[t + 256];
    #pragma unroll
    for (int i=0;i<16;i++){ acc0[i] = bb0; acc1[i] = bb1; }
    const float* w = w1T + t;
    for (int k=0;k<128;k+=4){
      float w00 = w[0],    w01 = w[256];
      float w10 = w[512],  w11 = w[768];
      float w20 = w[1024], w21 = w[1280];
      float w30 = w[1536], w31 = w[1792];
      w += 2048;
      #pragma unroll
      for (int i=0;i<16;i++){
        const float* xp = &Xs[i*132 + k];
        float x0 = xp[0], x1 = xp[1], x2 = xp[2], x3 = xp[3];
        acc0[i] += x0*w00; acc1[i] += x0*w01;
        acc0[i] += x1*w10; acc1[i] += x1*w11;
        acc0[i] += x2*w20; acc1[i] += x2*w21;
        acc0[i] += x3*w30; acc1[i] += x3*w31;
      }
    }
    #pragma unroll
    for (int i=0;i<16;i++){
      float a0 = acc0[i], a1 = acc1[i];
      H[i*516 + t]       = 0.5f*a0*(1.0f + erff(a0*0.70710678118654752f));
      H[i*516 + t + 256] = 0.5f*a1*(1.0f + erff(a1*0.70710678118654752f));
    }
  }
  __syncthreads();

  int kg = t >> 7;
  int s  = t & 127;
  int o0 = s & 63;
  int tb = (s >> 6) * 8;
  float acc[8][2];
  #pragma unroll
  for (int i=0;i<8;i++){ acc[i][0] = 0.f; acc[i][1] = 0.f; }
  {
    const float* w = w2T + (size_t)(kg*256)*128 + o0;
    const int hbase = kg*256;
    for (int k=0;k<256;k+=4){
      float wA0 = w[0],   wA1 = w[64];
      float wB0 = w[128], wB1 = w[192];
      float wC0 = w[256], wC1 = w[320];
      float wD0 = w[384], wD1 = w[448];
      w += 512;
      #pragma unroll
      for (int i=0;i<8;i++){
        const float* hh = &H[(tb+i)*516 + hbase + k];
        float h0 = hh[0], h1 = hh[1], h2 = hh[2], h3 = hh[3];
        acc[i][0] += h0*wA0; acc[i][1] += h0*wA1;
        acc[i][0] += h1*wB0; acc[i][1] += h1*wB1;
        acc[i][0] += h2*wC0; acc[i][1] += h2*wC1;
        acc[i][0] += h3*wD0; acc[i][1] += h3*wD1;
      }
    }
  }
  __syncthreads();
  float* Yred = H;
  #pragma unroll
  for (int i=0;i<8;i++){
    Yred[(kg*16 + tb + i)*132 + o0]      = acc[i][0];
    Yred[(kg*16 + tb + i)*132 + o0 + 64] = acc[i][1];
  }
  __syncthreads();

  {
    int tok = t >> 4, oc = (t & 15)*8;
    float outv[8];
    #pragma unroll
    for (int j=0;j<8;j++){
      int o = oc + j;
      outv[j] = b2[o] + Yred[tok*132 + o] + Yred[(16 + tok)*132 + o] + Xs[tok*132 + o];
    }
    int T = bid*16 + tok;
    size_t addr;
    if (MODE == 1){
      int b = T >> 12, g = (T >> 4) & 255, ll = T & 15;
      addr = ((size_t)((b*16 + ll)*256 + g))*128 + oc;
    } else {
      int b = T >> 12, ll = (T >> 8) & 15, g = T & 255;
      int pcoord = ((g >> 4)*4 + (ll >> 2))*64 + ((g & 15)*4 + (ll & 3));
      addr = ((size_t)(b*4096 + pcoord))*128 + oc;
    }
    st8b(out + addr, outv);
  }
}

// ---------- K4a: QKV projection for DilatedMSA (coalesced wT loads) ----------
__global__ __launch_bounds__(256) void k_qkv2(const u16* __restrict__ in, const float* __restrict__ wT,
                                              const float* __restrict__ bias,
                                              u16* __restrict__ qbuf, u16* __restrict__ kvbuf){
  __shared__ float Xs[16*132];
  __shared__ float QKVs[16*388];
  int t = threadIdx.x, bid = blockIdx.x;
  {
    int l = t >> 4, c0 = (t & 15)*8;
    float v[8]; ld8b(in + (size_t)bid*2048 + l*128 + c0, v);
    float4* d = reinterpret_cast<float4*>(&Xs[l*132 + c0]);
    d[0] = make_float4(v[0],v[1],v[2],v[3]);
    d[1] = make_float4(v[4],v[5],v[6],v[7]);
  }
  __syncthreads();
  {
    int tg = t >> 7, oi = t & 127;
    float accq[8], acck[8], accv[8];
    float bq = bias[oi], bk = bias[oi+128], bv = bias[oi+256];
    #pragma unroll
    for (int i=0;i<8;i++){ accq[i]=bq; acck[i]=bk; accv[i]=bv; }
    const float* w0 = wT + oi;
    for (int k=0;k<128;k+=4){
      const float* wr = w0 + (size_t)k*384;
      float q0 = wr[0],   q1 = wr[384],  q2 = wr[768],  q3 = wr[1152];
      float k0 = wr[128], k1 = wr[512],  k2 = wr[896],  k3 = wr[1280];
      float v0 = wr[256], v1 = wr[640],  v2 = wr[1024], v3 = wr[1408];
      #pragma unroll
      for (int i=0;i<8;i++){
        float4 x4 = *reinterpret_cast<const float4*>(&Xs[(tg*8+i)*132 + k]);
        accq[i] += x4.x*q0 + x4.y*q1 + x4.z*q2 + x4.w*q3;
        acck[i] += x4.x*k0 + x4.y*k1 + x4.z*k2 + x4.w*k3;
        accv[i] += x4.x*v0 + x4.y*v1 + x4.z*v2 + x4.w*v3;
      }
    }
    #pragma unroll
    for (int i=0;i<8;i++){
      int l = tg*8+i;
      QKVs[l*388 + oi]       = accq[i];
      QKVs[l*388 + 128 + oi] = acck[i];
      QKVs[l*388 + 256 + oi] = accv[i];
    }
  }
  __syncthreads();
  {
    int l = t >> 4, og = t & 15, o0 = og*24;
    size_t tok = (size_t)bid*16 + l;
    #pragma unroll
    for (int m=0; m<3; m++){
      int oc = o0 + m*8;
      float v8[8];
      #pragma unroll
      for (int j=0;j<8;j++) v8[j] = QKVs[l*388 + oc + j];
      if (oc < 128) st8b(qbuf + tok*128 + oc, v8);
      else          st8b(kvbuf + tok*256 + (oc-128), v8);
    }
  }
}

// ---------- K4b: DilatedMSA flash attention (L=256); y = x + attn IN PLACE over bufC ----------
__global__ __launch_bounds__(256) void k_attn2(const u16* __restrict__ qbuf, const u16* __restrict__ kvbuf,
                                               u16* __restrict__ y){
  __shared__ float Qs[64*66];
  __shared__ float Ks[32*64];
  __shared__ float Vs[32*64];
  __shared__ float Ss[64*33];
  __shared__ float mrow[64], lrow[64], crow[64];
  int t = threadIdx.x, bid = blockIdx.x;
  int qt = bid & 3, h = (bid >> 2) & 1, bl = bid >> 3;
  size_t tokbase = (size_t)bl * 256;
  {
    int r = t >> 2, seg = t & 3;
    const u16* src = qbuf + (tokbase + qt*64 + r)*128 + h*64 + seg*16;
    float v[16]; ld8b(src, v); ld8b(src+8, v+8);
    #pragma unroll
    for (int j=0;j<16;j++) Qs[r*66 + seg*16 + j] = v[j];
  }
  if (t < 64){ mrow[t] = -1e30f; lrow[t] = 0.0f; }
  float Oacc[16];
  #pragma unroll
  for (int j=0;j<16;j++) Oacc[j] = 0.0f;
  int lq = t & 63, grp = t >> 6;
  __syncthreads();
  for (int kt=0; kt<8; kt++){
    {
      int r = t >> 3, seg = t & 7;
      const u16* base = kvbuf + (tokbase + kt*32 + r)*256 + h*64;
      float v[8];
      ld8b(base + seg*8, v);
      #pragma unroll
      for (int j=0;j<8;j++) Ks[r*64 + seg*8 + j] = v[j];
      ld8b(base + 128 + seg*8, v);
      #pragma unroll
      for (int j=0;j<8;j++) Vs[r*64 + seg*8 + j] = v[j];
    }
    __syncthreads();
    {
      float acc[8];
      #pragma unroll
      for (int j=0;j<8;j++) acc[j] = 0.0f;
      for (int dc=0; dc<8; dc++){
        const float2* qp = reinterpret_cast<const float2*>(&Qs[lq*66 + dc*8]);
        float2 q0 = qp[0], q1 = qp[1], q2 = qp[2], q3 = qp[3];
        #pragma unroll
        for (int j=0;j<8;j++){
          const float4* kp = reinterpret_cast<const float4*>(&Ks[(grp*8+j)*64 + dc*8]);
          float4 k0 = kp[0], k1 = kp[1];
          acc[j] += q0.x*k0.x + q0.y*k0.y + q1.x*k0.z + q1.y*k0.w
                  + q2.x*k1.x + q2.y*k1.y + q3.x*k1.z + q3.y*k1.w;
        }
      }
      #pragma unroll
      for (int j=0;j<8;j++) Ss[lq*33 + grp*8 + j] = acc[j] * 0.08838834764831845f;
    }
    __syncthreads();
    if (t < 64){
      float* row = &Ss[t*33];
      float m = mrow[t];
      #pragma unroll
      for (int i=0;i<32;i++) m = fmaxf(m, row[i]);
      float corr = expf(mrow[t] - m);
      float s = lrow[t] * corr;
      #pragma unroll
      for (int i=0;i<32;i++){ float e = expf(row[i]-m); row[i] = e; s += e; }
      mrow[t] = m; lrow[t] = s; crow[t] = corr;
    }
    __syncthreads();
    {
      float corr = crow[lq];
      #pragma unroll
      for (int j=0;j<16;j++) Oacc[j] *= corr;
      for (int m=0;m<32;m++){
        float pp = Ss[lq*33 + m];
        const float4* vp = reinterpret_cast<const float4*>(&Vs[m*64 + grp*16]);
        float4 v0 = vp[0], v1 = vp[1], v2 = vp[2], v3 = vp[3];
        Oacc[0]+=pp*v0.x; Oacc[1]+=pp*v0.y; Oacc[2]+=pp*v0.z; Oacc[3]+=pp*v0.w;
        Oacc[4]+=pp*v1.x; Oacc[5]+=pp*v1.y; Oacc[6]+=pp*v1.z; Oacc[7]+=pp*v1.w;
        Oacc[8]+=pp*v2.x; Oacc[9]+=pp*v2.y; Oacc[10]+=pp*v2.z; Oacc[11]+=pp*v2.w;
        Oacc[12]+=pp*v3.x; Oacc[13]+=pp*v3.y; Oacc[14]+=pp*v3.z; Oacc[15]+=pp*v3.w;
      }
    }
    __syncthreads();
  }
  float inv = 1.0f / lrow[lq];
  u16* dst = y + (tokbase + qt*64 + lq)*128 + h*64 + grp*16;
  float res[16]; ld8b(dst, res); ld8b(dst+8, res+8);
  float o16[16];
  #pragma unroll
  for (int j=0;j<16;j++) o16[j] = Oacc[j]*inv + res[j];
  st8b(dst, o16); st8b(dst+8, o16+8);
}

// ---------- K_tr: h0/c0 [c][4096] -> hws/Cst [pix][128] fp32 (LDS-tiled transpose) ----------
__global__ __launch_bounds__(256) void k_tr_pc(const void* __restrict__ h0, const void* __restrict__ c0,
                                               float* __restrict__ hws, float* __restrict__ Cst,
                                               const int* __restrict__ flag){
  __shared__ float lds[32][33];
  int t = threadIdx.x, bid = blockIdx.x;
  int sel = bid >> 9, tile = bid & 511;
  int pt2 = tile >> 2, ct = tile & 3;
  const void* src = sel ? c0 : h0;
  float* dst = sel ? Cst : hws;
  int r = t >> 3, q = t & 7;
  {
    int c = ct*32 + r;
    int px = pt2*32 + q*4;
    if (*flag){
      float4 v = *reinterpret_cast<const float4*>((const float*)src + (size_t)c*4096 + px);
      lds[r][q*4+0]=v.x; lds[r][q*4+1]=v.y; lds[r][q*4+2]=v.z; lds[r][q*4+3]=v.w;
    } else {
      uint2 u = *reinterpret_cast<const uint2*>((const u16*)src + (size_t)c*4096 + px);
      lds[r][q*4+0]=b2f_u(u.x & 0xffffu); lds[r][q*4+1]=b2f_u(u.x >> 16);
      lds[r][q*4+2]=b2f_u(u.y & 0xffffu); lds[r][q*4+3]=b2f_u(u.y >> 16);
    }
  }
  __syncthreads();
  {
    int px = pt2*32 + r;
    int c = ct*32 + q*4;
    float4 o;
    o.x = lds[q*4+0][r]; o.y = lds[q*4+1][r]; o.z = lds[q*4+2][r]; o.w = lds[q*4+3][r];
    *reinterpret_cast<float4*>(dst + (size_t)px*128 + c) = o;
  }
}

// ---------- K6: fused LSTM step: gates GEMM + softmax/tanh + state update + hs store ----------
// Block = 8 pixels x all 512 gate outputs. Thread = (po 0..7, oseg 0..31): 4 ch x 4 gates.
// Weights from transposed [k][512] layout (coalesced float4 per gate).
__global__ __launch_bounds__(256) void k_lstm_step(const u16* __restrict__ xD,
    float* __restrict__ hws, float* __restrict__ Cst,
    const float* __restrict__ wx, const float* __restrict__ wh, const float* __restrict__ bh,
    void* __restrict__ dout, int n, const int* __restrict__ flag){
  __shared__ float tile[256*9];    // [k][px], pad 9
  __shared__ float red[4*32*8];    // [gate][oseg][px]
  __shared__ float fin[4*8];       // [gate][px]
  int t = threadIdx.x, bid = blockIdx.x;
  int pix0 = bid*8;
  if (t < 128){
    int px = t >> 4, cg = t & 15;
    float v[8]; ld8b(xD + ((size_t)n*4096 + pix0 + px)*128 + cg*8, v);
    #pragma unroll
    for (int j=0;j<8;j++) tile[(cg*8+j)*9 + px] = v[j];
  } else {
    int t2 = t - 128;
    int px = t2 >> 4, cg = t2 & 15;
    const float4* hp = reinterpret_cast<const float4*>(hws + (size_t)(pix0+px)*128 + cg*8);
    float4 a = hp[0], b = hp[1];
    tile[(128+cg*8+0)*9+px]=a.x; tile[(128+cg*8+1)*9+px]=a.y;
    tile[(128+cg*8+2)*9+px]=a.z; tile[(128+cg*8+3)*9+px]=a.w;
    tile[(128+cg*8+4)*9+px]=b.x; tile[(128+cg*8+5)*9+px]=b.y;
    tile[(128+cg*8+6)*9+px]=b.z; tile[(128+cg*8+7)*9+px]=b.w;
  }
  __syncthreads();
  int po = t & 7, oseg = t >> 3, c0v = oseg*4;
  float acc[4][4];
  #pragma unroll
  for (int g=0;g<4;g++)
    #pragma unroll
    for (int j=0;j<4;j++) acc[g][j] = bh[g*128 + c0v + j];
  // x part (k = 0..127)
  for (int k=0;k<128;k+=2){
    float x0 = tile[k*9+po], x1 = tile[(k+1)*9+po];
    #pragma unroll
    for (int g=0;g<4;g++){
      float4 w0 = *reinterpret_cast<const float4*>(wx + (size_t)k*512 + g*128 + c0v);
      float4 w1 = *reinterpret_cast<const float4*>(wx + (size_t)(k+1)*512 + g*128 + c0v);
      acc[g][0] += x0*w0.x; acc[g][1] += x0*w0.y; acc[g][2] += x0*w0.z; acc[g][3] += x0*w0.w;
      acc[g][0] += x1*w1.x; acc[g][1] += x1*w1.y; acc[g][2] += x1*w1.z; acc[g][3] += x1*w1.w;
    }
  }
  // h part (k = 0..127)
  for (int k=0;k<128;k+=2){
    float x0 = tile[(128+k)*9+po], x1 = tile[(129+k)*9+po];
    #pragma unroll
    for (int g=0;g<4;g++){
      float4 w0 = *reinterpret_cast<const float4*>(wh + (size_t)k*512 + g*128 + c0v);
      float4 w1 = *reinterpret_cast<const float4*>(wh + (size_t)(k+1)*512 + g*128 + c0v);
      acc[g][0] += x0*w0.x; acc[g][1] += x0*w0.y; acc[g][2] += x0*w0.z; acc[g][3] += x0*w0.w;
      acc[g][0] += x1*w1.x; acc[g][1] += x1*w1.y; acc[g][2] += x1*w1.z; acc[g][3] += x1*w1.w;
    }
  }
  // channel softmax (gates 0,1,3) / tanh (gate 2)
  #pragma unroll
  for (int g=0;g<4;g++){
    float lm = fmaxf(fmaxf(acc[g][0],acc[g][1]), fmaxf(acc[g][2],acc[g][3]));
    red[(g*32 + oseg)*8 + po] = lm;
  }
  __syncthreads();
  if (t < 32){
    int g = t >> 3, p2 = t & 7;
    float m = red[(g*32)*8 + p2];
    for (int s2=1;s2<32;s2++) m = fmaxf(m, red[(g*32+s2)*8 + p2]);
    fin[g*8+p2] = m;
  }
  __syncthreads();
  float sv[4];
  #pragma unroll
  for (int j=0;j<4;j++) sv[j] = tanhf(acc[2][j]);
  #pragma unroll
  for (int g=0;g<4;g++){
    if (g == 2){ red[(g*32+oseg)*8+po] = 1.0f; }
    else {
      float m = fin[g*8+po];
      float ls = 0.f;
      #pragma unroll
      for (int j=0;j<4;j++){ float e = expf(acc[g][j]-m); acc[g][j]=e; ls += e; }
      red[(g*32+oseg)*8+po] = ls;
    }
  }
  __syncthreads();
  if (t < 32){
    int g = t >> 3, p2 = t & 7;
    float s2v = 0.f;
    for (int s2=0;s2<32;s2++) s2v += red[(g*32+s2)*8+p2];
    fin[g*8+p2] = 1.0f/s2v;
  }
  __syncthreads();
  float invf = fin[0*8+po], invi = fin[1*8+po], invo = fin[3*8+po];
  int pix = pix0 + po;
  float4 cold = *reinterpret_cast<const float4*>(Cst + (size_t)pix*128 + c0v);
  float co_[4] = {cold.x, cold.y, cold.z, cold.w};
  float cn[4], hn[4];
  #pragma unroll
  for (int j=0;j<4;j++){
    float fg = acc[0][j]*invf, ig = acc[1][j]*invi, og = acc[3][j]*invo;
    cn[j] = fg*co_[j] + ig*sv[j];
    hn[j] = og*tanhf(cn[j]);
  }
  *reinterpret_cast<float4*>(Cst + (size_t)pix*128 + c0v) = make_float4(cn[0],cn[1],cn[2],cn[3]);
  *reinterpret_cast<float4*>(hws + (size_t)pix*128 + c0v) = make_float4(hn[0],hn[1],hn[2],hn[3]);
  size_t ob = (size_t)n*524288;
  if (*flag){
    float* df = (float*)dout;
    #pragma unroll
    for (int j=0;j<4;j++) df[ob + (size_t)(c0v+j)*4096 + pix] = hn[j];
  } else {
    u16* db = (u16*)dout;
    #pragma unroll
    for (int j=0;j<4;j++) db[ob + (size_t)(c0v+j)*4096 + pix] = f2b_u(hn[j]);
  }
}

// ---------- K7: final hf, Cf: [pix][128] fp32 -> d_out [c][4096] (tiled transpose, dtype) ----------
__global__ __launch_bounds__(256) void k_final_t(const float* __restrict__ hws, const float* __restrict__ Cst,
                                                 void* __restrict__ dout, const int* __restrict__ flag){
  __shared__ float lds[32][33];
  int t = threadIdx.x, bid = blockIdx.x;
  int sel = bid >> 9, tile = bid & 511;
  int pt2 = tile >> 2, ct = tile & 3;
  const float* src = sel ? Cst : hws;
  size_t base = sel ? 8912896u : 8388608u;
  int r = t >> 3, q = t & 7;
  {
    int px = pt2*32 + r, c = ct*32 + q*4;
    float4 v = *reinterpret_cast<const float4*>(src + (size_t)px*128 + c);
    lds[r][q*4+0]=v.x; lds[r][q*4+1]=v.y; lds[r][q*4+2]=v.z; lds[r][q*4+3]=v.w;
  }
  __syncthreads();
  {
    int c = ct*32 + r, px = pt2*32 + q*4;
    float v0 = lds[q*4+0][r], v1 = lds[q*4+1][r], v2 = lds[q*4+2][r], v3 = lds[q*4+3][r];
    if (*flag){
      *reinterpret_cast<float4*>((float*)dout + base + (size_t)c*4096 + px) = make_float4(v0,v1,v2,v3);
    } else {
      uint2 pk;
      pk.x = (u32)f2b_u(v0) | ((u32)f2b_u(v1) << 16);
      pk.y = (u32)f2b_u(v2) | ((u32)f2b_u(v3) << 16);
      *reinterpret_cast<uint2*>((u16*)dout + base + (size_t)c*4096 + px) = pk;
    }
  }
}

extern "C" void kernel_launch(void* const* d_in, const int* in_sizes, int n_in,
                              void* d_out, int out_size, void* d_ws, size_t ws_size,
                              hipStream_t stream) {
  const void* x      = d_in[0];
  const void* h0     = d_in[1];
  const void* c0     = d_in[2];
  const void* conv_w = d_in[3];
  const void* conv_b = d_in[4];
  const void* qkv1_w = d_in[5];
  const void* qkv1_b = d_in[6];
  const void* m1w1   = d_in[7];
  const void* m1b1   = d_in[8];
  const void* m1w2   = d_in[9];
  const void* m1b2   = d_in[10];
  const void* qkv2_w = d_in[11];
  const void* qkv2_b = d_in[12];
  const void* m2w1   = d_in[13];
  const void* m2b1   = d_in[14];
  const void* m2w2   = d_in[15];
  const void* m2b2   = d_in[16];
  const void* lwx    = d_in[17];
  const void* lwh    = d_in[18];
  const void* lbh    = d_in[19];

  char* p = (char*)d_ws;
  auto alloc = [&](size_t bytes)->void*{
    void* r = (void*)p; p += (bytes + 255) & ~(size_t)255; return r;
  };
  int*   flag    = (int*)alloc(256);
  float* wO_conv = (float*)alloc(512*128*4);   // original [co][ci*4+ky*2+kx] layout, fp32
  float* wT_qkv1 = (float*)alloc(128*384*4);   // transposed [k][384]
  float* wT_m1a  = (float*)alloc(128*512*4);
  float* wT_m1b  = (float*)alloc(512*128*4);
  float* wT_qkv2 = (float*)alloc(128*384*4);   // transposed [k][384]
  float* wT_m2a  = (float*)alloc(128*512*4);
  float* wT_m2b  = (float*)alloc(512*128*4);
  float* wT_lx   = (float*)alloc(128*512*4);
  float* wT_lh   = (float*)alloc(128*512*4);
  float* bf_conv = (float*)alloc(128*4);
  float* bf_qkv1 = (float*)alloc(384*4);
  float* bf_m1b1 = (float*)alloc(512*4);
  float* bf_m1b2 = (float*)alloc(128*4);
  float* bf_qkv2 = (float*)alloc(384*4);
  float* bf_m2b1 = (float*)alloc(512*4);
  float* bf_m2b2 = (float*)alloc(128*4);
  float* bf_lbh  = (float*)alloc(512*4);
  u16* R0   = (u16*)alloc(16777216);   // bufA -> bufC/y -> (hws, Cst)
  u16* Rbig = (u16*)alloc(33554432);   // bufB (front) -> kvbuf -> bufD (front)

  u16* bufA = R0;
  u16* bufB = Rbig;
  u16* bufC = R0;          // also y (attn writes in place)
  u16* qbuf = (u16*)d_out; // hs region used as scratch; dead before first LSTM write
  u16* kvbuf = Rbig;
  u16* bufD = Rbig;
  float* hws = (float*)((char*)R0 + 8388608);         // 2 MB, [pix][128]
  float* Cst = (float*)((char*)R0 + 10485760);        // 2 MB, [pix][128]

  k_detect<<<1, 256, 0, stream>>>((const u32*)x, flag);

  auto T = [&](const void* in, float* o, int O, int K){
    int n = O*K;
    k_transpose<<<(n+255)/256, 256, 0, stream>>>(in, o, O, K, flag);
  };
  T(qkv1_w, wT_qkv1, 384, 128);
  T(m1w1,   wT_m1a,  512, 128);
  T(m1w2,   wT_m1b,  128, 512);
  T(qkv2_w, wT_qkv2, 384, 128);
  T(m2w1,   wT_m2a,  512, 128);
  T(m2w2,   wT_m2b,  128, 512);
  T(lwx,    wT_lx,   512, 128);
  T(lwh,    wT_lh,   512, 128);

  auto V = [&](const void* in, float* o, int n){
    k_cvtvec<<<(n+255)/256, 256, 0, stream>>>(in, o, n, flag);
  };
  V(conv_w, wO_conv, 128*512);     // straight copy keeps original layout
  V(conv_b, bf_conv, 128);
  V(qkv1_b, bf_qkv1, 384);
  V(m1b1,   bf_m1b1, 512);
  V(m1b2,   bf_m1b2, 128);
  V(qkv2_b, bf_qkv2, 384);
  V(m2b1,   bf_m2b1, 512);
  V(m2b2,   bf_m2b2, 128);
  V(lbh,    bf_lbh,  512);

  k_conv<<<512, 256, 0, stream>>>(x, wO_conv, bf_conv, bufA, flag);
  k_msa1<<<4096, 256, 0, stream>>>(bufA, wT_qkv1, bf_qkv1, bufB);
  k_mlp<1><<<4096, 256, 0, stream>>>(bufB, wT_m1a, bf_m1b1, wT_m1b, bf_m1b2, bufC);
  k_qkv2<<<4096, 256, 0, stream>>>(bufC, wT_qkv2, bf_qkv2, qbuf, kvbuf);
  k_attn2<<<2048, 256, 0, stream>>>(qbuf, kvbuf, bufC);          // y = x + attn, in place
  k_mlp<2><<<4096, 256, 0, stream>>>(bufC, wT_m2a, bf_m2b1, wT_m2b, bf_m2b2, bufD);

  k_tr_pc<<<1024, 256, 0, stream>>>(h0, c0, hws, Cst, flag);     // R0 state region live now
  for (int n = 0; n < 16; n++){
    k_lstm_step<<<512, 256, 0, stream>>>(bufD, hws, Cst, wT_lx, wT_lh, bf_lbh, d_out, n, flag);
  }
  k_final_t<<<1024, 256, 0, stream>>>(hws, Cst, d_out, flag);
}

// Round 4
// 1824.647 us; speedup vs baseline: 4.0896x; 1.4943x over previous
//
#include <hip/hip_runtime.h>
#include <hip/hip_bf16.h>

typedef unsigned int u32;
typedef unsigned short u16;

#define DI __device__ __forceinline__

typedef __attribute__((ext_vector_type(8))) __bf16 bf16x8;
typedef __attribute__((ext_vector_type(4))) float f32x4;

// ---------- bf16 helpers (bf16 == fp32 high 16 bits; RNE on store) ----------
DI float b2f_u(u32 u){ return __uint_as_float(u << 16); }
DI u16 f2b_u(float f){
  u32 x = __float_as_uint(f);
  x += 0x7fffu + ((x >> 16) & 1u);
  return (u16)(x >> 16);
}
DI void ld8b(const u16* p, float* o){
  uint4 v = *reinterpret_cast<const uint4*>(p);
  o[0] = b2f_u(v.x & 0xffffu); o[1] = b2f_u(v.x >> 16);
  o[2] = b2f_u(v.y & 0xffffu); o[3] = b2f_u(v.y >> 16);
  o[4] = b2f_u(v.z & 0xffffu); o[5] = b2f_u(v.z >> 16);
  o[6] = b2f_u(v.w & 0xffffu); o[7] = b2f_u(v.w >> 16);
}
DI void st8b(u16* p, const float* i){
  uint4 v;
  v.x = (u32)f2b_u(i[0]) | ((u32)f2b_u(i[1]) << 16);
  v.y = (u32)f2b_u(i[2]) | ((u32)f2b_u(i[3]) << 16);
  v.z = (u32)f2b_u(i[4]) | ((u32)f2b_u(i[5]) << 16);
  v.w = (u32)f2b_u(i[6]) | ((u32)f2b_u(i[7]) << 16);
  *reinterpret_cast<uint4*>(p) = v;
}

// ---------- K_detect: is d_in fp32 (flag=1) or packed bf16 (flag=0)? ----------
__global__ void k_detect(const u32* __restrict__ xw, int* __restrict__ flag){
  __shared__ int cnt;
  int t = threadIdx.x;
  if (t == 0) cnt = 0;
  __syncthreads();
  int c = 0;
  for (int i = t; i < 2048; i += 256){
    u32 lo = xw[i] & 0xffffu;
    u32 e = (lo >> 7) & 0xffu;
    if (e < 100u || e > 140u) c++;
  }
  atomicAdd(&cnt, c);
  __syncthreads();
  if (t == 0) *flag = (cnt > 200) ? 1 : 0;
}

// ---------- K0: weight transpose ([O][K] -> fp32 [K][O]), dtype-adaptive ----------
__global__ void k_transpose(const void* __restrict__ in, float* __restrict__ out, int O, int K,
                            const int* __restrict__ flag){
  int idx = blockIdx.x*256 + threadIdx.x;
  if (idx < O*K){
    int o = idx % O, k = idx / O;
    if (*flag) out[idx] = ((const float*)in)[o*K + k];
    else       out[idx] = b2f_u((u32)((const u16*)in)[o*K + k]);
  }
}

// ---------- K0b: vector convert -> fp32 (straight copy, also used for [o][k] weights) ----------
__global__ void k_cvtvec(const void* __restrict__ in, float* __restrict__ out, int n,
                         const int* __restrict__ flag){
  int i = blockIdx.x*256 + threadIdx.x;
  if (i < n){
    if (*flag) out[i] = ((const float*)in)[i];
    else       out[i] = b2f_u((u32)((const u16*)in)[i]);
  }
}

// ---------- K1: conv 2x2 stride 2 + window partition -> bufA [b][g][l][c] ----------
__global__ __launch_bounds__(256) void k_conv(const void* __restrict__ x_raw,
                                              const float* __restrict__ wO,
                                              const float* __restrict__ bias, u16* __restrict__ outA,
                                              const int* __restrict__ flag){
  __shared__ float patch[32*8*64];   // [ci][row][col], 64 KB
  int t = threadIdx.x, bid = blockIdx.x;
  int xh = bid & 1, yg = (bid >> 1) & 15, b = bid >> 5;
  int chg = t & 15, pxg = t >> 4;
  int co0 = chg*8;
  float bs[8];
  #pragma unroll
  for (int j=0;j<8;j++) bs[j] = bias[co0+j];
  float acc[2][4][8];
  #pragma unroll
  for (int a=0;a<2;a++)
    #pragma unroll
    for (int oy=0;oy<4;oy++)
      #pragma unroll
      for (int j=0;j<8;j++) acc[a][oy][j] = bs[j];

  size_t slab = (size_t)b*2097152 + (size_t)(yg*8)*128 + (size_t)xh*64;
  for (int ci0 = 0; ci0 < 128; ci0 += 32){
    if (ci0) __syncthreads();
    if (*flag){
      const float* xb = (const float*)x_raw + slab + (size_t)ci0*16384;
      #pragma unroll
      for (int i=0;i<16;i++){
        int f = i*256 + t;
        int ci = f >> 7, rem = f & 127, row = rem >> 4, col = (rem & 15)*4;
        float4 v = *reinterpret_cast<const float4*>(xb + ci*16384 + row*128 + col);
        *reinterpret_cast<float4*>(&patch[ci*512 + row*64 + col]) = v;
      }
    } else {
      const u16* xb = (const u16*)x_raw + slab + (size_t)ci0*16384;
      #pragma unroll
      for (int i=0;i<8;i++){
        int f = i*256 + t;
        int ci = f >> 6, rem = f & 63, row = rem >> 3, col = (rem & 7)*8;
        float v[8]; ld8b(xb + ci*16384 + row*128 + col, v);
        float4* d = reinterpret_cast<float4*>(&patch[ci*512 + row*64 + col]);
        d[0] = make_float4(v[0],v[1],v[2],v[3]);
        d[1] = make_float4(v[4],v[5],v[6],v[7]);
      }
    }
    __syncthreads();
    const float* wbase = wO + co0*512 + ci0*4;
    for (int ci=0; ci<32; ci++){
      float4 wv[8];
      #pragma unroll
      for (int j=0;j<8;j++)
        wv[j] = *reinterpret_cast<const float4*>(wbase + j*512 + ci*4);
      #pragma unroll
      for (int a=0;a<2;a++){
        int ox = pxg + a*16;
        #pragma unroll
        for (int oy=0;oy<4;oy++){
          float2 p0 = *reinterpret_cast<const float2*>(&patch[ci*512 + (2*oy)*64 + 2*ox]);
          float2 p1 = *reinterpret_cast<const float2*>(&patch[ci*512 + (2*oy+1)*64 + 2*ox]);
          #pragma unroll
          for (int j=0;j<8;j++){
            acc[a][oy][j] += p0.x*wv[j].x + p0.y*wv[j].y + p1.x*wv[j].z + p1.y*wv[j].w;
          }
        }
      }
    }
  }
  int base_g = yg*16 + xh*8;
  #pragma unroll
  for (int a=0;a<2;a++){
    int ox = pxg + a*16;
    int xg = base_g + (ox >> 2);
    #pragma unroll
    for (int oy=0;oy<4;oy++){
      int l = oy*4 + (ox & 3);
      size_t T = ((size_t)(b*256 + xg)*16 + l);
      st8b(outA + T*128 + co0, acc[a][oy]);
    }
  }
}

// ---------- K2: LocalMSA (L=16) + residual: bufA -> bufB (same layout) ----------
__global__ __launch_bounds__(256) void k_msa1(const u16* __restrict__ A, const float* __restrict__ wT,
                                              const float* __restrict__ qbias, u16* __restrict__ B){
  __shared__ float Xs[16*132];
  __shared__ float QKV[16*388];
  __shared__ float S[512];          // [h][l][m]
  int t = threadIdx.x, bid = blockIdx.x;
  const u16* Ab = A + (size_t)bid*2048;
  {
    int l = t >> 4, c0 = (t & 15)*8;
    float v[8]; ld8b(Ab + l*128 + c0, v);
    float4* d = reinterpret_cast<float4*>(&Xs[l*132 + c0]);
    d[0] = make_float4(v[0],v[1],v[2],v[3]);
    d[1] = make_float4(v[4],v[5],v[6],v[7]);
  }
  __syncthreads();
  {
    int tg = t >> 7, oi = t & 127;
    float accq[8], acck[8], accv[8];
    float bq = qbias[oi], bk = qbias[oi+128], bv = qbias[oi+256];
    #pragma unroll
    for (int i=0;i<8;i++){ accq[i]=bq; acck[i]=bk; accv[i]=bv; }
    const float* w0 = wT + oi;
    for (int k=0;k<128;k+=4){
      const float* wr = w0 + (size_t)k*384;
      float q0 = wr[0],   q1 = wr[384],  q2 = wr[768],  q3 = wr[1152];
      float k0 = wr[128], k1 = wr[512],  k2 = wr[896],  k3 = wr[1280];
      float v0 = wr[256], v1 = wr[640],  v2 = wr[1024], v3 = wr[1408];
      #pragma unroll
      for (int i=0;i<8;i++){
        float4 x4 = *reinterpret_cast<const float4*>(&Xs[(tg*8+i)*132 + k]);
        accq[i] += x4.x*q0 + x4.y*q1 + x4.z*q2 + x4.w*q3;
        acck[i] += x4.x*k0 + x4.y*k1 + x4.z*k2 + x4.w*k3;
        accv[i] += x4.x*v0 + x4.y*v1 + x4.z*v2 + x4.w*v3;
      }
    }
    #pragma unroll
    for (int i=0;i<8;i++){
      int l = tg*8+i;
      QKV[l*388 + oi]       = accq[i];
      QKV[l*388 + 128 + oi] = acck[i];
      QKV[l*388 + 256 + oi] = accv[i];
    }
  }
  __syncthreads();
  const float scale = 0.08838834764831845f;   // 1/sqrt(128)
  for (int e = t; e < 512; e += 256){
    int h = e >> 8, l = (e>>4)&15, m = e&15;
    const float* q = &QKV[l*388 + h*64];
    const float* kk = &QKV[m*388 + 128 + h*64];
    float s = 0.f;
    #pragma unroll
    for (int d=0; d<64; d++) s += q[d]*kk[d];
    S[(h*16+l)*16 + m] = s*scale;
  }
  __syncthreads();
  if (t < 32){
    float* row = &S[t*16];
    float mx = row[0];
    #pragma unroll
    for (int m=1;m<16;m++) mx = fmaxf(mx,row[m]);
    float sum = 0.f;
    #pragma unroll
    for (int m=0;m<16;m++){ float e = expf(row[m]-mx); row[m]=e; sum+=e; }
    float inv = 1.0f/sum;
    #pragma unroll
    for (int m=0;m<16;m++) row[m] *= inv;
  }
  __syncthreads();
  {
    int l = t >> 4, og = t & 15, o0 = og*8;
    int h = o0 >> 6;
    const float* p = &S[(h*16+l)*16];
    float out8[8];
    #pragma unroll
    for (int j=0;j<8;j++){
      int o = o0+j, d = o & 63;
      float s = 0.f;
      #pragma unroll
      for (int m=0;m<16;m++) s += p[m]*QKV[m*388 + 256 + h*64 + d];
      out8[j] = s + Xs[l*132 + o];
    }
    st8b(B + (size_t)bid*2048 + l*128 + o0, out8);
  }
}

// ---------- K3/K5: MLP (+residual), register-tiled fp32 GEMMs. ----------
template<int MODE>
__global__ __launch_bounds__(256) void k_mlp(const u16* __restrict__ in,
    const float* __restrict__ w1T, const float* __restrict__ b1,
    const float* __restrict__ w2T, const float* __restrict__ b2,
    u16* __restrict__ out){
  __shared__ float Xs[16*132];
  __shared__ float H[16*516];
  int t = threadIdx.x, bid = blockIdx.x;
  {
    int l = t >> 4, c0 = (t & 15)*8;
    float v[8]; ld8b(in + (size_t)bid*2048 + l*128 + c0, v);
    float4* d = reinterpret_cast<float4*>(&Xs[l*132 + c0]);
    d[0] = make_float4(v[0],v[1],v[2],v[3]);
    d[1] = make_float4(v[4],v[5],v[6],v[7]);
  }
  __syncthreads();

  {
    float acc0[16], acc1[16];
    float bb0 = b1[t], bb1 = b1[t + 256];
    #pragma unroll
    for (int i=0;i<16;i++){ acc0[i] = bb0; acc1[i] = bb1; }
    const float* w = w1T + t;
    for (int k=0;k<128;k+=4){
      float w00 = w[0],    w01 = w[256];
      float w10 = w[512],  w11 = w[768];
      float w20 = w[1024], w21 = w[1280];
      float w30 = w[1536], w31 = w[1792];
      w += 2048;
      #pragma unroll
      for (int i=0;i<16;i++){
        const float* xp = &Xs[i*132 + k];
        float x0 = xp[0], x1 = xp[1], x2 = xp[2], x3 = xp[3];
        acc0[i] += x0*w00; acc1[i] += x0*w01;
        acc0[i] += x1*w10; acc1[i] += x1*w11;
        acc0[i] += x2*w20; acc1[i] += x2*w21;
        acc0[i] += x3*w30; acc1[i] += x3*w31;
      }
    }
    #pragma unroll
    for (int i=0;i<16;i++){
      float a0 = acc0[i], a1 = acc1[i];
      H[i*516 + t]       = 0.5f*a0*(1.0f + erff(a0*0.70710678118654752f));
      H[i*516 + t + 256] = 0.5f*a1*(1.0f + erff(a1*0.70710678118654752f));
    }
  }
  __syncthreads();

  int kg = t >> 7;
  int s  = t & 127;
  int o0 = s & 63;
  int tb = (s >> 6) * 8;
  float acc[8][2];
  #pragma unroll
  for (int i=0;i<8;i++){ acc[i][0] = 0.f; acc[i][1] = 0.f; }
  {
    const float* w = w2T + (size_t)(kg*256)*128 + o0;
    const int hbase = kg*256;
    for (int k=0;k<256;k+=4){
      float wA0 = w[0],   wA1 = w[64];
      float wB0 = w[128], wB1 = w[192];
      float wC0 = w[256], wC1 = w[320];
      float wD0 = w[384], wD1 = w[448];
      w += 512;
      #pragma unroll
      for (int i=0;i<8;i++){
        const float* hh = &H[(tb+i)*516 + hbase + k];
        float h0 = hh[0], h1 = hh[1], h2 = hh[2], h3 = hh[3];
        acc[i][0] += h0*wA0; acc[i][1] += h0*wA1;
        acc[i][0] += h1*wB0; acc[i][1] += h1*wB1;
        acc[i][0] += h2*wC0; acc[i][1] += h2*wC1;
        acc[i][0] += h3*wD0; acc[i][1] += h3*wD1;
      }
    }
  }
  __syncthreads();
  float* Yred = H;
  #pragma unroll
  for (int i=0;i<8;i++){
    Yred[(kg*16 + tb + i)*132 + o0]      = acc[i][0];
    Yred[(kg*16 + tb + i)*132 + o0 + 64] = acc[i][1];
  }
  __syncthreads();

  {
    int tok = t >> 4, oc = (t & 15)*8;
    float outv[8];
    #pragma unroll
    for (int j=0;j<8;j++){
      int o = oc + j;
      outv[j] = b2[o] + Yred[tok*132 + o] + Yred[(16 + tok)*132 + o] + Xs[tok*132 + o];
    }
    int T = bid*16 + tok;
    size_t addr;
    if (MODE == 1){
      int b = T >> 12, g = (T >> 4) & 255, ll = T & 15;
      addr = ((size_t)((b*16 + ll)*256 + g))*128 + oc;
    } else {
      int b = T >> 12, ll = (T >> 8) & 15, g = T & 255;
      int pcoord = ((g >> 4)*4 + (ll >> 2))*64 + ((g & 15)*4 + (ll & 3));
      addr = ((size_t)(b*4096 + pcoord))*128 + oc;
    }
    st8b(out + addr, outv);
  }
}

// ---------- K4a: QKV projection for DilatedMSA (coalesced wT loads) ----------
__global__ __launch_bounds__(256) void k_qkv2(const u16* __restrict__ in, const float* __restrict__ wT,
                                              const float* __restrict__ bias,
                                              u16* __restrict__ qbuf, u16* __restrict__ kvbuf){
  __shared__ float Xs[16*132];
  __shared__ float QKVs[16*388];
  int t = threadIdx.x, bid = blockIdx.x;
  {
    int l = t >> 4, c0 = (t & 15)*8;
    float v[8]; ld8b(in + (size_t)bid*2048 + l*128 + c0, v);
    float4* d = reinterpret_cast<float4*>(&Xs[l*132 + c0]);
    d[0] = make_float4(v[0],v[1],v[2],v[3]);
    d[1] = make_float4(v[4],v[5],v[6],v[7]);
  }
  __syncthreads();
  {
    int tg = t >> 7, oi = t & 127;
    float accq[8], acck[8], accv[8];
    float bq = bias[oi], bk = bias[oi+128], bv = bias[oi+256];
    #pragma unroll
    for (int i=0;i<8;i++){ accq[i]=bq; acck[i]=bk; accv[i]=bv; }
    const float* w0 = wT + oi;
    for (int k=0;k<128;k+=4){
      const float* wr = w0 + (size_t)k*384;
      float q0 = wr[0],   q1 = wr[384],  q2 = wr[768],  q3 = wr[1152];
      float k0 = wr[128], k1 = wr[512],  k2 = wr[896],  k3 = wr[1280];
      float v0 = wr[256], v1 = wr[640],  v2 = wr[1024], v3 = wr[1408];
      #pragma unroll
      for (int i=0;i<8;i++){
        float4 x4 = *reinterpret_cast<const float4*>(&Xs[(tg*8+i)*132 + k]);
        accq[i] += x4.x*q0 + x4.y*q1 + x4.z*q2 + x4.w*q3;
        acck[i] += x4.x*k0 + x4.y*k1 + x4.z*k2 + x4.w*k3;
        accv[i] += x4.x*v0 + x4.y*v1 + x4.z*v2 + x4.w*v3;
      }
    }
    #pragma unroll
    for (int i=0;i<8;i++){
      int l = tg*8+i;
      QKVs[l*388 + oi]       = accq[i];
      QKVs[l*388 + 128 + oi] = acck[i];
      QKVs[l*388 + 256 + oi] = accv[i];
    }
  }
  __syncthreads();
  {
    int l = t >> 4, og = t & 15, o0 = og*24;
    size_t tok = (size_t)bid*16 + l;
    #pragma unroll
    for (int m=0; m<3; m++){
      int oc = o0 + m*8;
      float v8[8];
      #pragma unroll
      for (int j=0;j<8;j++) v8[j] = QKVs[l*388 + oc + j];
      if (oc < 128) st8b(qbuf + tok*128 + oc, v8);
      else          st8b(kvbuf + tok*256 + (oc-128), v8);
    }
  }
}

// ---------- K4b: DilatedMSA flash attention (L=256); y = x + attn IN PLACE over bufC ----------
// QK^T via MFMA (bf16 Q/K staged raw in LDS); softmax + PV in fp32 VALU as before.
__global__ __launch_bounds__(256) void k_attn2(const u16* __restrict__ qbuf, const u16* __restrict__ kvbuf,
                                               u16* __restrict__ y){
  __shared__ u16 Qb[64*72];        // bf16 [qrow][72-padded d]
  __shared__ u16 Kb[32*72];        // bf16 [krow][72-padded d]
  __shared__ float Vs[32*64];
  __shared__ float Ss[64*33];
  __shared__ float mrow[64], lrow[64], crow[64];
  int t = threadIdx.x, bid = blockIdx.x;
  int qt = bid & 3, h = (bid >> 2) & 1, bl = bid >> 3;
  size_t tokbase = (size_t)bl * 256;
  {
    int r = t >> 2, seg = t & 3;
    const u16* src = qbuf + (tokbase + qt*64 + r)*128 + h*64 + seg*16;
    uint4 v0 = *reinterpret_cast<const uint4*>(src);
    uint4 v1 = *reinterpret_cast<const uint4*>(src + 8);
    *reinterpret_cast<uint4*>(&Qb[r*72 + seg*16])     = v0;
    *reinterpret_cast<uint4*>(&Qb[r*72 + seg*16 + 8]) = v1;
  }
  if (t < 64){ mrow[t] = -1e30f; lrow[t] = 0.0f; }
  float Oacc[16];
  #pragma unroll
  for (int j=0;j<16;j++) Oacc[j] = 0.0f;
  int lq = t & 63, grp = t >> 6;
  int fc = lq & 15, fg = lq >> 4;     // MFMA lane coords
  __syncthreads();
  for (int kt=0; kt<8; kt++){
    {
      int r = t >> 3, seg = t & 7;
      const u16* base = kvbuf + (tokbase + kt*32 + r)*256 + h*64;
      *reinterpret_cast<uint4*>(&Kb[r*72 + seg*8]) = *reinterpret_cast<const uint4*>(base + seg*8);
      float v[8];
      ld8b(base + 128 + seg*8, v);
      #pragma unroll
      for (int j=0;j<8;j++) Vs[r*64 + seg*8 + j] = v[j];
    }
    __syncthreads();
    {
      // S[q = grp*16 + fg*4 + r][ktok = tile*16 + fc], K-dim = d (64 -> 2 mfma steps)
      f32x4 s0 = {0.f,0.f,0.f,0.f}, s1 = {0.f,0.f,0.f,0.f};
      bf16x8 a0  = *reinterpret_cast<const bf16x8*>(&Qb[(grp*16+fc)*72 + fg*8]);
      bf16x8 a1  = *reinterpret_cast<const bf16x8*>(&Qb[(grp*16+fc)*72 + 32 + fg*8]);
      bf16x8 b00 = *reinterpret_cast<const bf16x8*>(&Kb[fc*72 + fg*8]);
      bf16x8 b01 = *reinterpret_cast<const bf16x8*>(&Kb[fc*72 + 32 + fg*8]);
      bf16x8 b10 = *reinterpret_cast<const bf16x8*>(&Kb[(16+fc)*72 + fg*8]);
      bf16x8 b11 = *reinterpret_cast<const bf16x8*>(&Kb[(16+fc)*72 + 32 + fg*8]);
      s0 = __builtin_amdgcn_mfma_f32_16x16x32_bf16(a0, b00, s0, 0, 0, 0);
      s0 = __builtin_amdgcn_mfma_f32_16x16x32_bf16(a1, b01, s0, 0, 0, 0);
      s1 = __builtin_amdgcn_mfma_f32_16x16x32_bf16(a0, b10, s1, 0, 0, 0);
      s1 = __builtin_amdgcn_mfma_f32_16x16x32_bf16(a1, b11, s1, 0, 0, 0);
      #pragma unroll
      for (int r2=0;r2<4;r2++){
        int row = grp*16 + fg*4 + r2;
        Ss[row*33 + fc]      = s0[r2] * 0.08838834764831845f;
        Ss[row*33 + 16 + fc] = s1[r2] * 0.08838834764831845f;
      }
    }
    __syncthreads();
    if (t < 64){
      float* row = &Ss[t*33];
      float m = mrow[t];
      #pragma unroll
      for (int i=0;i<32;i++) m = fmaxf(m, row[i]);
      float corr = expf(mrow[t] - m);
      float s = lrow[t] * corr;
      #pragma unroll
      for (int i=0;i<32;i++){ float e = expf(row[i]-m); row[i] = e; s += e; }
      mrow[t] = m; lrow[t] = s; crow[t] = corr;
    }
    __syncthreads();
    {
      float corr = crow[lq];
      #pragma unroll
      for (int j=0;j<16;j++) Oacc[j] *= corr;
      for (int m=0;m<32;m++){
        float pp = Ss[lq*33 + m];
        const float4* vp = reinterpret_cast<const float4*>(&Vs[m*64 + grp*16]);
        float4 v0 = vp[0], v1 = vp[1], v2 = vp[2], v3 = vp[3];
        Oacc[0]+=pp*v0.x; Oacc[1]+=pp*v0.y; Oacc[2]+=pp*v0.z; Oacc[3]+=pp*v0.w;
        Oacc[4]+=pp*v1.x; Oacc[5]+=pp*v1.y; Oacc[6]+=pp*v1.z; Oacc[7]+=pp*v1.w;
        Oacc[8]+=pp*v2.x; Oacc[9]+=pp*v2.y; Oacc[10]+=pp*v2.z; Oacc[11]+=pp*v2.w;
        Oacc[12]+=pp*v3.x; Oacc[13]+=pp*v3.y; Oacc[14]+=pp*v3.z; Oacc[15]+=pp*v3.w;
      }
    }
    __syncthreads();
  }
  float inv = 1.0f / lrow[lq];
  u16* dst = y + (tokbase + qt*64 + lq)*128 + h*64 + grp*16;
  float res[16]; ld8b(dst, res); ld8b(dst+8, res+8);
  float o16[16];
  #pragma unroll
  for (int j=0;j<16;j++) o16[j] = Oacc[j]*inv + res[j];
  st8b(dst, o16); st8b(dst+8, o16+8);
}

// ---------- K_tr: h0/c0 [c][4096] -> hws/Cst [pix][128] fp32 (LDS-tiled transpose) ----------
__global__ __launch_bounds__(256) void k_tr_pc(const void* __restrict__ h0, const void* __restrict__ c0,
                                               float* __restrict__ hws, float* __restrict__ Cst,
                                               const int* __restrict__ flag){
  __shared__ float lds[32][33];
  int t = threadIdx.x, bid = blockIdx.x;
  int sel = bid >> 9, tile = bid & 511;
  int pt2 = tile >> 2, ct = tile & 3;
  const void* src = sel ? c0 : h0;
  float* dst = sel ? Cst : hws;
  int r = t >> 3, q = t & 7;
  {
    int c = ct*32 + r;
    int px = pt2*32 + q*4;
    if (*flag){
      float4 v = *reinterpret_cast<const float4*>((const float*)src + (size_t)c*4096 + px);
      lds[r][q*4+0]=v.x; lds[r][q*4+1]=v.y; lds[r][q*4+2]=v.z; lds[r][q*4+3]=v.w;
    } else {
      uint2 u = *reinterpret_cast<const uint2*>((const u16*)src + (size_t)c*4096 + px);
      lds[r][q*4+0]=b2f_u(u.x & 0xffffu); lds[r][q*4+1]=b2f_u(u.x >> 16);
      lds[r][q*4+2]=b2f_u(u.y & 0xffffu); lds[r][q*4+3]=b2f_u(u.y >> 16);
    }
  }
  __syncthreads();
  {
    int px = pt2*32 + r;
    int c = ct*32 + q*4;
    float4 o;
    o.x = lds[q*4+0][r]; o.y = lds[q*4+1][r]; o.z = lds[q*4+2][r]; o.w = lds[q*4+3][r];
    *reinterpret_cast<float4*>(dst + (size_t)px*128 + c) = o;
  }
}

// ---------- K6: fused LSTM step, register-tiled GEMM + wave softmax ----------
// Block = 8 px, 256 threads. GEMM: wave = gate, lane = 2 channels, 8 px per thread
// (16 acc, each weight float read exactly once per block). Channel softmax via
// __shfl_xor over the 64-lane wave (128 ch = 64 lanes x 2). Gate exchange via LDS.
__global__ __launch_bounds__(256) void k_lstm_step(const u16* __restrict__ xD,
    float* __restrict__ hws, float* __restrict__ Cst,
    const float* __restrict__ wx, const float* __restrict__ wh, const float* __restrict__ bh,
    void* __restrict__ dout, int n, const int* __restrict__ flag){
  __shared__ float tile[256*8];      // [k][px]; k<128: x ch, k>=128: h ch
  __shared__ float glds[4*8*132];    // [gate][px][132-padded ch]
  int t = threadIdx.x, bid = blockIdx.x;
  int pix0 = bid*8;
  if (t < 128){
    int px = t >> 4, cg = t & 15;
    float v[8]; ld8b(xD + ((size_t)n*4096 + pix0 + px)*128 + cg*8, v);
    #pragma unroll
    for (int j=0;j<8;j++) tile[(cg*8+j)*8 + px] = v[j];
  } else {
    int t2 = t - 128;
    int px = t2 >> 4, cg = t2 & 15;
    const float4* hp = reinterpret_cast<const float4*>(hws + (size_t)(pix0+px)*128 + cg*8);
    float4 a = hp[0], b = hp[1];
    tile[(128+cg*8+0)*8+px]=a.x; tile[(128+cg*8+1)*8+px]=a.y;
    tile[(128+cg*8+2)*8+px]=a.z; tile[(128+cg*8+3)*8+px]=a.w;
    tile[(128+cg*8+4)*8+px]=b.x; tile[(128+cg*8+5)*8+px]=b.y;
    tile[(128+cg*8+6)*8+px]=b.z; tile[(128+cg*8+7)*8+px]=b.w;
  }
  __syncthreads();
  int w = t >> 6, l = t & 63;
  int ch = l*2;
  float acc[8][2];
  {
    float b0 = bh[w*128 + ch], b1 = bh[w*128 + ch + 1];
    #pragma unroll
    for (int p=0;p<8;p++){ acc[p][0]=b0; acc[p][1]=b1; }
  }
  const float* wxp = wx + w*128 + ch;
  const float* whp = wh + w*128 + ch;
  for (int k=0;k<128;k+=2){
    float2 wa = *reinterpret_cast<const float2*>(wxp + (size_t)k*512);
    float2 wb = *reinterpret_cast<const float2*>(wxp + (size_t)k*512 + 512);
    const float* xr0 = &tile[k*8];
    const float* xr1 = &tile[k*8 + 8];
    #pragma unroll
    for (int p=0;p<8;p++){
      float x0 = xr0[p], x1 = xr1[p];
      acc[p][0] += x0*wa.x; acc[p][1] += x0*wa.y;
      acc[p][0] += x1*wb.x; acc[p][1] += x1*wb.y;
    }
  }
  for (int k=0;k<128;k+=2){
    float2 wa = *reinterpret_cast<const float2*>(whp + (size_t)k*512);
    float2 wb = *reinterpret_cast<const float2*>(whp + (size_t)k*512 + 512);
    const float* xr0 = &tile[(128+k)*8];
    const float* xr1 = &tile[(128+k)*8 + 8];
    #pragma unroll
    for (int p=0;p<8;p++){
      float x0 = xr0[p], x1 = xr1[p];
      acc[p][0] += x0*wa.x; acc[p][1] += x0*wa.y;
      acc[p][0] += x1*wb.x; acc[p][1] += x1*wb.y;
    }
  }
  // activation: softmax over channels (gates 0,1,3) / tanh (gate 2)
  if (w == 2){
    #pragma unroll
    for (int p=0;p<8;p++){
      float v0 = tanhf(acc[p][0]), v1 = tanhf(acc[p][1]);
      *reinterpret_cast<float2*>(&glds[(w*8+p)*132 + ch]) = make_float2(v0, v1);
    }
  } else {
    #pragma unroll
    for (int p=0;p<8;p++){
      float m2 = fmaxf(acc[p][0], acc[p][1]);
      #pragma unroll
      for (int sft=1; sft<64; sft<<=1) m2 = fmaxf(m2, __shfl_xor(m2, sft));
      float e0 = expf(acc[p][0]-m2), e1 = expf(acc[p][1]-m2);
      float sm = e0 + e1;
      #pragma unroll
      for (int sft=1; sft<64; sft<<=1) sm += __shfl_xor(sm, sft);
      float inv = 1.0f/sm;
      *reinterpret_cast<float2*>(&glds[(w*8+p)*132 + ch]) = make_float2(e0*inv, e1*inv);
    }
  }
  __syncthreads();
  // pointwise update: thread = (px, 4 channels)
  {
    int px = t & 7, ch0 = (t >> 3)*4;
    float4 fv = *reinterpret_cast<const float4*>(&glds[(0*8+px)*132 + ch0]);
    float4 iv = *reinterpret_cast<const float4*>(&glds[(1*8+px)*132 + ch0]);
    float4 sv = *reinterpret_cast<const float4*>(&glds[(2*8+px)*132 + ch0]);
    float4 ov = *reinterpret_cast<const float4*>(&glds[(3*8+px)*132 + ch0]);
    int pix = pix0 + px;
    float4 cold = *reinterpret_cast<const float4*>(Cst + (size_t)pix*128 + ch0);
    float cn[4], hn[4];
    cn[0] = fv.x*cold.x + iv.x*sv.x; hn[0] = ov.x*tanhf(cn[0]);
    cn[1] = fv.y*cold.y + iv.y*sv.y; hn[1] = ov.y*tanhf(cn[1]);
    cn[2] = fv.z*cold.z + iv.z*sv.z; hn[2] = ov.z*tanhf(cn[2]);
    cn[3] = fv.w*cold.w + iv.w*sv.w; hn[3] = ov.w*tanhf(cn[3]);
    *reinterpret_cast<float4*>(Cst + (size_t)pix*128 + ch0) = make_float4(cn[0],cn[1],cn[2],cn[3]);
    *reinterpret_cast<float4*>(hws + (size_t)pix*128 + ch0) = make_float4(hn[0],hn[1],hn[2],hn[3]);
    size_t ob = (size_t)n*524288;
    if (*flag){
      float* df = (float*)dout;
      #pragma unroll
      for (int j=0;j<4;j++) df[ob + (size_t)(ch0+j)*4096 + pix] = hn[j];
    } else {
      u16* db = (u16*)dout;
      #pragma unroll
      for (int j=0;j<4;j++) db[ob + (size_t)(ch0+j)*4096 + pix] = f2b_u(hn[j]);
    }
  }
}

// ---------- K7: final hf, Cf: [pix][128] fp32 -> d_out [c][4096] (tiled transpose, dtype) ----------
__global__ __launch_bounds__(256) void k_final_t(const float* __restrict__ hws, const float* __restrict__ Cst,
                                                 void* __restrict__ dout, const int* __restrict__ flag){
  __shared__ float lds[32][33];
  int t = threadIdx.x, bid = blockIdx.x;
  int sel = bid >> 9, tile = bid & 511;
  int pt2 = tile >> 2, ct = tile & 3;
  const float* src = sel ? Cst : hws;
  size_t base = sel ? 8912896u : 8388608u;
  int r = t >> 3, q = t & 7;
  {
    int px = pt2*32 + r, c = ct*32 + q*4;
    float4 v = *reinterpret_cast<const float4*>(src + (size_t)px*128 + c);
    lds[r][q*4+0]=v.x; lds[r][q*4+1]=v.y; lds[r][q*4+2]=v.z; lds[r][q*4+3]=v.w;
  }
  __syncthreads();
  {
    int c = ct*32 + r, px = pt2*32 + q*4;
    float v0 = lds[q*4+0][r], v1 = lds[q*4+1][r], v2 = lds[q*4+2][r], v3 = lds[q*4+3][r];
    if (*flag){
      *reinterpret_cast<float4*>((float*)dout + base + (size_t)c*4096 + px) = make_float4(v0,v1,v2,v3);
    } else {
      uint2 pk;
      pk.x = (u32)f2b_u(v0) | ((u32)f2b_u(v1) << 16);
      pk.y = (u32)f2b_u(v2) | ((u32)f2b_u(v3) << 16);
      *reinterpret_cast<uint2*>((u16*)dout + base + (size_t)c*4096 + px) = pk;
    }
  }
}

extern "C" void kernel_launch(void* const* d_in, const int* in_sizes, int n_in,
                              void* d_out, int out_size, void* d_ws, size_t ws_size,
                              hipStream_t stream) {
  const void* x      = d_in[0];
  const void* h0     = d_in[1];
  const void* c0     = d_in[2];
  const void* conv_w = d_in[3];
  const void* conv_b = d_in[4];
  const void* qkv1_w = d_in[5];
  const void* qkv1_b = d_in[6];
  const void* m1w1   = d_in[7];
  const void* m1b1   = d_in[8];
  const void* m1w2   = d_in[9];
  const void* m1b2   = d_in[10];
  const void* qkv2_w = d_in[11];
  const void* qkv2_b = d_in[12];
  const void* m2w1   = d_in[13];
  const void* m2b1   = d_in[14];
  const void* m2w2   = d_in[15];
  const void* m2b2   = d_in[16];
  const void* lwx    = d_in[17];
  const void* lwh    = d_in[18];
  const void* lbh    = d_in[19];

  char* p = (char*)d_ws;
  auto alloc = [&](size_t bytes)->void*{
    void* r = (void*)p; p += (bytes + 255) & ~(size_t)255; return r;
  };
  int*   flag    = (int*)alloc(256);
  float* wO_conv = (float*)alloc(512*128*4);   // original [co][ci*4+ky*2+kx] layout, fp32
  float* wT_qkv1 = (float*)alloc(128*384*4);   // transposed [k][384]
  float* wT_m1a  = (float*)alloc(128*512*4);
  float* wT_m1b  = (float*)alloc(512*128*4);
  float* wT_qkv2 = (float*)alloc(128*384*4);   // transposed [k][384]
  float* wT_m2a  = (float*)alloc(128*512*4);
  float* wT_m2b  = (float*)alloc(512*128*4);
  float* wT_lx   = (float*)alloc(128*512*4);
  float* wT_lh   = (float*)alloc(128*512*4);
  float* bf_conv = (float*)alloc(128*4);
  float* bf_qkv1 = (float*)alloc(384*4);
  float* bf_m1b1 = (float*)alloc(512*4);
  float* bf_m1b2 = (float*)alloc(128*4);
  float* bf_qkv2 = (float*)alloc(384*4);
  float* bf_m2b1 = (float*)alloc(512*4);
  float* bf_m2b2 = (float*)alloc(128*4);
  float* bf_lbh  = (float*)alloc(512*4);
  u16* R0   = (u16*)alloc(16777216);   // bufA -> bufC/y -> (hws, Cst)
  u16* Rbig = (u16*)alloc(33554432);   // bufB (front) -> kvbuf -> bufD (front)

  u16* bufA = R0;
  u16* bufB = Rbig;
  u16* bufC = R0;          // also y (attn writes in place)
  u16* qbuf = (u16*)d_out; // hs region used as scratch; dead before first LSTM write
  u16* kvbuf = Rbig;
  u16* bufD = Rbig;
  float* hws = (float*)((char*)R0 + 8388608);         // 2 MB, [pix][128]
  float* Cst = (float*)((char*)R0 + 10485760);        // 2 MB, [pix][128]

  k_detect<<<1, 256, 0, stream>>>((const u32*)x, flag);

  auto T = [&](const void* in, float* o, int O, int K){
    int n = O*K;
    k_transpose<<<(n+255)/256, 256, 0, stream>>>(in, o, O, K, flag);
  };
  T(qkv1_w, wT_qkv1, 384, 128);
  T(m1w1,   wT_m1a,  512, 128);
  T(m1w2,   wT_m1b,  128, 512);
  T(qkv2_w, wT_qkv2, 384, 128);
  T(m2w1,   wT_m2a,  512, 128);
  T(m2w2,   wT_m2b,  128, 512);
  T(lwx,    wT_lx,   512, 128);
  T(lwh,    wT_lh,   512, 128);

  auto V = [&](const void* in, float* o, int n){
    k_cvtvec<<<(n+255)/256, 256, 0, stream>>>(in, o, n, flag);
  };
  V(conv_w, wO_conv, 128*512);     // straight copy keeps original layout
  V(conv_b, bf_conv, 128);
  V(qkv1_b, bf_qkv1, 384);
  V(m1b1,   bf_m1b1, 512);
  V(m1b2,   bf_m1b2, 128);
  V(qkv2_b, bf_qkv2, 384);
  V(m2b1,   bf_m2b1, 512);
  V(m2b2,   bf_m2b2, 128);
  V(lbh,    bf_lbh,  512);

  k_conv<<<512, 256, 0, stream>>>(x, wO_conv, bf_conv, bufA, flag);
  k_msa1<<<4096, 256, 0, stream>>>(bufA, wT_qkv1, bf_qkv1, bufB);
  k_mlp<1><<<4096, 256, 0, stream>>>(bufB, wT_m1a, bf_m1b1, wT_m1b, bf_m1b2, bufC);
  k_qkv2<<<4096, 256, 0, stream>>>(bufC, wT_qkv2, bf_qkv2, qbuf, kvbuf);
  k_attn2<<<2048, 256, 0, stream>>>(qbuf, kvbuf, bufC);          // y = x + attn, in place
  k_mlp<2><<<4096, 256, 0, stream>>>(bufC, wT_m2a, bf_m2b1, wT_m2b, bf_m2b2, bufD);

  k_tr_pc<<<1024, 256, 0, stream>>>(h0, c0, hws, Cst, flag);     // R0 state region live now
  for (int n = 0; n < 16; n++){
    k_lstm_step<<<512, 256, 0, stream>>>(bufD, hws, Cst, wT_lx, wT_lh, bf_lbh, d_out, n, flag);
  }
  k_final_t<<<1024, 256, 0, stream>>>(hws, Cst, d_out, flag);
}

// Round 5
// 1389.808 us; speedup vs baseline: 5.3692x; 1.3129x over previous
//
#include <hip/hip_runtime.h>
#include <hip/hip_bf16.h>

typedef unsigned int u32;
typedef unsigned short u16;

#define DI __device__ __forceinline__

typedef __attribute__((ext_vector_type(8))) __bf16 bf16x8;
typedef __attribute__((ext_vector_type(4))) float f32x4;

// ---------- bf16 helpers (bf16 == fp32 high 16 bits; RNE on store) ----------
DI float b2f_u(u32 u){ return __uint_as_float(u << 16); }
DI u16 f2b_u(float f){
  u32 x = __float_as_uint(f);
  x += 0x7fffu + ((x >> 16) & 1u);
  return (u16)(x >> 16);
}
DI void ld8b(const u16* p, float* o){
  uint4 v = *reinterpret_cast<const uint4*>(p);
  o[0] = b2f_u(v.x & 0xffffu); o[1] = b2f_u(v.x >> 16);
  o[2] = b2f_u(v.y & 0xffffu); o[3] = b2f_u(v.y >> 16);
  o[4] = b2f_u(v.z & 0xffffu); o[5] = b2f_u(v.z >> 16);
  o[6] = b2f_u(v.w & 0xffffu); o[7] = b2f_u(v.w >> 16);
}
DI void st8b(u16* p, const float* i){
  uint4 v;
  v.x = (u32)f2b_u(i[0]) | ((u32)f2b_u(i[1]) << 16);
  v.y = (u32)f2b_u(i[2]) | ((u32)f2b_u(i[3]) << 16);
  v.z = (u32)f2b_u(i[4]) | ((u32)f2b_u(i[5]) << 16);
  v.w = (u32)f2b_u(i[6]) | ((u32)f2b_u(i[7]) << 16);
  *reinterpret_cast<uint4*>(p) = v;
}

// ---------- K_detect: is d_in fp32 (flag=1) or packed bf16 (flag=0)? ----------
__global__ void k_detect(const u32* __restrict__ xw, int* __restrict__ flag){
  __shared__ int cnt;
  int t = threadIdx.x;
  if (t == 0) cnt = 0;
  __syncthreads();
  int c = 0;
  for (int i = t; i < 2048; i += 256){
    u32 lo = xw[i] & 0xffffu;
    u32 e = (lo >> 7) & 0xffu;
    if (e < 100u || e > 140u) c++;
  }
  atomicAdd(&cnt, c);
  __syncthreads();
  if (t == 0) *flag = (cnt > 200) ? 1 : 0;
}

// ---------- K0: weight transpose ([O][K] -> fp32 [K][O]), dtype-adaptive ----------
__global__ void k_transpose(const void* __restrict__ in, float* __restrict__ out, int O, int K,
                            const int* __restrict__ flag){
  int idx = blockIdx.x*256 + threadIdx.x;
  if (idx < O*K){
    int o = idx % O, k = idx / O;
    if (*flag) out[idx] = ((const float*)in)[o*K + k];
    else       out[idx] = b2f_u((u32)((const u16*)in)[o*K + k]);
  }
}

// ---------- K0b: vector convert -> fp32 (straight copy) ----------
__global__ void k_cvtvec(const void* __restrict__ in, float* __restrict__ out, int n,
                         const int* __restrict__ flag){
  int i = blockIdx.x*256 + threadIdx.x;
  if (i < n){
    if (*flag) out[i] = ((const float*)in)[i];
    else       out[i] = b2f_u((u32)((const u16*)in)[i]);
  }
}

// ---------- K0c: convert -> bf16 (layout-preserving; copy when already bf16) ----------
__global__ void k_cvtb16(const void* __restrict__ in, u16* __restrict__ out, int n,
                         const int* __restrict__ flag){
  int i = blockIdx.x*256 + threadIdx.x;
  if (i < n){
    if (*flag) out[i] = f2b_u(((const float*)in)[i]);
    else       out[i] = ((const u16*)in)[i];
  }
}

// ---------- K1: conv 2x2 stride 2 + window partition -> bufA [b][g][l][c] ----------
__global__ __launch_bounds__(256) void k_conv(const void* __restrict__ x_raw,
                                              const float* __restrict__ wO,
                                              const float* __restrict__ bias, u16* __restrict__ outA,
                                              const int* __restrict__ flag){
  __shared__ float patch[32*8*64];   // [ci][row][col], 64 KB
  int t = threadIdx.x, bid = blockIdx.x;
  int xh = bid & 1, yg = (bid >> 1) & 15, b = bid >> 5;
  int chg = t & 15, pxg = t >> 4;
  int co0 = chg*8;
  float bs[8];
  #pragma unroll
  for (int j=0;j<8;j++) bs[j] = bias[co0+j];
  float acc[2][4][8];
  #pragma unroll
  for (int a=0;a<2;a++)
    #pragma unroll
    for (int oy=0;oy<4;oy++)
      #pragma unroll
      for (int j=0;j<8;j++) acc[a][oy][j] = bs[j];

  size_t slab = (size_t)b*2097152 + (size_t)(yg*8)*128 + (size_t)xh*64;
  for (int ci0 = 0; ci0 < 128; ci0 += 32){
    if (ci0) __syncthreads();
    if (*flag){
      const float* xb = (const float*)x_raw + slab + (size_t)ci0*16384;
      #pragma unroll
      for (int i=0;i<16;i++){
        int f = i*256 + t;
        int ci = f >> 7, rem = f & 127, row = rem >> 4, col = (rem & 15)*4;
        float4 v = *reinterpret_cast<const float4*>(xb + ci*16384 + row*128 + col);
        *reinterpret_cast<float4*>(&patch[ci*512 + row*64 + col]) = v;
      }
    } else {
      const u16* xb = (const u16*)x_raw + slab + (size_t)ci0*16384;
      #pragma unroll
      for (int i=0;i<8;i++){
        int f = i*256 + t;
        int ci = f >> 6, rem = f & 63, row = rem >> 3, col = (rem & 7)*8;
        float v[8]; ld8b(xb + ci*16384 + row*128 + col, v);
        float4* d = reinterpret_cast<float4*>(&patch[ci*512 + row*64 + col]);
        d[0] = make_float4(v[0],v[1],v[2],v[3]);
        d[1] = make_float4(v[4],v[5],v[6],v[7]);
      }
    }
    __syncthreads();
    const float* wbase = wO + co0*512 + ci0*4;
    for (int ci=0; ci<32; ci++){
      float4 wv[8];
      #pragma unroll
      for (int j=0;j<8;j++)
        wv[j] = *reinterpret_cast<const float4*>(wbase + j*512 + ci*4);
      #pragma unroll
      for (int a=0;a<2;a++){
        int ox = pxg + a*16;
        #pragma unroll
        for (int oy=0;oy<4;oy++){
          float2 p0 = *reinterpret_cast<const float2*>(&patch[ci*512 + (2*oy)*64 + 2*ox]);
          float2 p1 = *reinterpret_cast<const float2*>(&patch[ci*512 + (2*oy+1)*64 + 2*ox]);
          #pragma unroll
          for (int j=0;j<8;j++){
            acc[a][oy][j] += p0.x*wv[j].x + p0.y*wv[j].y + p1.x*wv[j].z + p1.y*wv[j].w;
          }
        }
      }
    }
  }
  int base_g = yg*16 + xh*8;
  #pragma unroll
  for (int a=0;a<2;a++){
    int ox = pxg + a*16;
    int xg = base_g + (ox >> 2);
    #pragma unroll
    for (int oy=0;oy<4;oy++){
      int l = oy*4 + (ox & 3);
      size_t T = ((size_t)(b*256 + xg)*16 + l);
      st8b(outA + T*128 + co0, acc[a][oy]);
    }
  }
}

// ---------- K2: LocalMSA (L=16) + residual: bufA -> bufB (same layout) ----------
// Projection via MFMA: A = X rows (bf16 LDS), B = qkv weight rows (bf16, original [o][k], L2).
__global__ __launch_bounds__(256) void k_msa1(const u16* __restrict__ A, const u16* __restrict__ wB,
                                              const float* __restrict__ qbias, u16* __restrict__ B){
  __shared__ u16 Xs[16*136];        // bf16, row stride 272 B
  __shared__ float QKV[16*388];
  __shared__ float S[512];          // [h][l][m]
  int t = threadIdx.x, bid = blockIdx.x;
  {
    int l = t >> 4, c0 = (t & 15)*8;
    *reinterpret_cast<uint4*>(&Xs[l*136 + c0]) =
      *reinterpret_cast<const uint4*>(A + (size_t)bid*2048 + l*128 + c0);
  }
  __syncthreads();
  {
    int w = t >> 6, lane = t & 63, fr = lane & 15, fg = lane >> 4;
    bf16x8 a[4];
    #pragma unroll
    for (int k=0;k<4;k++) a[k] = *reinterpret_cast<const bf16x8*>(&Xs[fr*136 + k*32 + fg*8]);
    #pragma unroll
    for (int j=0;j<6;j++){
      int o = w*96 + j*16 + fr;          // 0..383
      float bv = qbias[o];
      f32x4 d = {bv,bv,bv,bv};
      const u16* wp = wB + (size_t)o*128 + fg*8;
      #pragma unroll
      for (int k=0;k<4;k++){
        bf16x8 b = *reinterpret_cast<const bf16x8*>(wp + k*32);
        d = __builtin_amdgcn_mfma_f32_16x16x32_bf16(a[k], b, d, 0, 0, 0);
      }
      #pragma unroll
      for (int r=0;r<4;r++) QKV[(fg*4+r)*388 + o] = d[r];
    }
  }
  __syncthreads();
  const float scale = 0.08838834764831845f;   // 1/sqrt(128)
  for (int e = t; e < 512; e += 256){
    int h = e >> 8, l = (e>>4)&15, m = e&15;
    const float* q = &QKV[l*388 + h*64];
    const float* kk = &QKV[m*388 + 128 + h*64];
    float s = 0.f;
    #pragma unroll
    for (int d=0; d<64; d++) s += q[d]*kk[d];
    S[(h*16+l)*16 + m] = s*scale;
  }
  __syncthreads();
  if (t < 32){
    float* row = &S[t*16];
    float mx = row[0];
    #pragma unroll
    for (int m=1;m<16;m++) mx = fmaxf(mx,row[m]);
    float sum = 0.f;
    #pragma unroll
    for (int m=0;m<16;m++){ float e = expf(row[m]-mx); row[m]=e; sum+=e; }
    float inv = 1.0f/sum;
    #pragma unroll
    for (int m=0;m<16;m++) row[m] *= inv;
  }
  __syncthreads();
  {
    int l = t >> 4, og = t & 15, o0 = og*8;
    int h = o0 >> 6;
    const float* p = &S[(h*16+l)*16];
    float out8[8];
    #pragma unroll
    for (int j=0;j<8;j++){
      int o = o0+j, d = o & 63;
      float s = 0.f;
      #pragma unroll
      for (int m=0;m<16;m++) s += p[m]*QKV[m*388 + 256 + h*64 + d];
      out8[j] = s + b2f_u((u32)Xs[l*136 + o]);
    }
    st8b(B + (size_t)bid*2048 + l*128 + o0, out8);
  }
}

// ---------- K3/K5: MLP (+residual) via MFMA (bf16 in/weights, fp32 accum). ----------
//            MODE1: bufB [b][g][l][c] -> bufC [b][l][g][c].
//            MODE2: y [b][l][g][c] -> bufD [n][pix][c] (window reverse).
template<int MODE>
__global__ __launch_bounds__(256) void k_mlp(const u16* __restrict__ in,
    const u16* __restrict__ w1B, const float* __restrict__ b1,
    const u16* __restrict__ w2B, const float* __restrict__ b2,
    u16* __restrict__ out){
  __shared__ u16 Xs[16*136];        // bf16 input (also residual), 272 B rows
  __shared__ u16 Hs[16*520];        // bf16 hidden, 1040 B rows
  __shared__ u16 Ys[16*136];        // bf16 output staging
  int t = threadIdx.x, bid = blockIdx.x;
  {
    int l = t >> 4, c0 = (t & 15)*8;
    *reinterpret_cast<uint4*>(&Xs[l*136 + c0]) =
      *reinterpret_cast<const uint4*>(in + (size_t)bid*2048 + l*128 + c0);
  }
  __syncthreads();
  int w = t >> 6, lane = t & 63, fr = lane & 15, fg = lane >> 4;

  // ---- GEMM1: H = gelu(X @ W1^T + b1); wave handles 8 n-tiles of 16 ----
  {
    bf16x8 a[4];
    #pragma unroll
    for (int k=0;k<4;k++) a[k] = *reinterpret_cast<const bf16x8*>(&Xs[fr*136 + k*32 + fg*8]);
    #pragma unroll
    for (int j=0;j<8;j++){
      int o = w*128 + j*16 + fr;        // 0..511
      float bv = b1[o];
      f32x4 d = {bv,bv,bv,bv};
      const u16* wp = w1B + (size_t)o*128 + fg*8;
      #pragma unroll
      for (int k=0;k<4;k++){
        bf16x8 b = *reinterpret_cast<const bf16x8*>(wp + k*32);
        d = __builtin_amdgcn_mfma_f32_16x16x32_bf16(a[k], b, d, 0, 0, 0);
      }
      #pragma unroll
      for (int r=0;r<4;r++){
        float v = d[r];
        float g = 0.5f*v*(1.0f + erff(v*0.70710678118654752f));
        Hs[(fg*4+r)*520 + o] = f2b_u(g);
      }
    }
  }
  __syncthreads();

  // ---- GEMM2: Y = H @ W2^T + b2 + X; wave handles 2 n-tiles of 16 ----
  {
    int na = w*32 + fr, nb = na + 16;   // 0..127
    float ba = b2[na], bb = b2[nb];
    f32x4 d0 = {ba,ba,ba,ba}, d1 = {bb,bb,bb,bb};
    const u16* wpa = w2B + (size_t)na*512 + fg*8;
    const u16* wpb = w2B + (size_t)nb*512 + fg*8;
    #pragma unroll
    for (int k=0;k<16;k++){
      bf16x8 a = *reinterpret_cast<const bf16x8*>(&Hs[fr*520 + k*32 + fg*8]);
      bf16x8 bA = *reinterpret_cast<const bf16x8*>(wpa + k*32);
      bf16x8 bBv = *reinterpret_cast<const bf16x8*>(wpb + k*32);
      d0 = __builtin_amdgcn_mfma_f32_16x16x32_bf16(a, bA, d0, 0, 0, 0);
      d1 = __builtin_amdgcn_mfma_f32_16x16x32_bf16(a, bBv, d1, 0, 0, 0);
    }
    #pragma unroll
    for (int r=0;r<4;r++){
      int tok = fg*4 + r;
      float y0 = d0[r] + b2f_u((u32)Xs[tok*136 + na]);
      float y1 = d1[r] + b2f_u((u32)Xs[tok*136 + nb]);
      Ys[tok*136 + na] = f2b_u(y0);
      Ys[tok*136 + nb] = f2b_u(y1);
    }
  }
  __syncthreads();

  // ---- coalesced store with layout mapping ----
  {
    int tok = t >> 4, oc = (t & 15)*8;
    uint4 v = *reinterpret_cast<const uint4*>(&Ys[tok*136 + oc]);
    int T = bid*16 + tok;
    size_t addr;
    if (MODE == 1){
      int b = T >> 12, g = (T >> 4) & 255, ll = T & 15;
      addr = ((size_t)((b*16 + ll)*256 + g))*128 + oc;
    } else {
      int b = T >> 12, ll = (T >> 8) & 15, g = T & 255;
      int pcoord = ((g >> 4)*4 + (ll >> 2))*64 + ((g & 15)*4 + (ll & 3));
      addr = ((size_t)(b*4096 + pcoord))*128 + oc;
    }
    *reinterpret_cast<uint4*>(out + addr) = v;
  }
}

// ---------- K4a: QKV projection for DilatedMSA via MFMA ----------
__global__ __launch_bounds__(256) void k_qkv2(const u16* __restrict__ in, const u16* __restrict__ wB,
                                              const float* __restrict__ bias,
                                              u16* __restrict__ qbuf, u16* __restrict__ kvbuf){
  __shared__ u16 Xs[16*136];
  __shared__ u16 Qs[16*392];        // bf16 [tok][384+pad]
  int t = threadIdx.x, bid = blockIdx.x;
  {
    int l = t >> 4, c0 = (t & 15)*8;
    *reinterpret_cast<uint4*>(&Xs[l*136 + c0]) =
      *reinterpret_cast<const uint4*>(in + (size_t)bid*2048 + l*128 + c0);
  }
  __syncthreads();
  {
    int w = t >> 6, lane = t & 63, fr = lane & 15, fg = lane >> 4;
    bf16x8 a[4];
    #pragma unroll
    for (int k=0;k<4;k++) a[k] = *reinterpret_cast<const bf16x8*>(&Xs[fr*136 + k*32 + fg*8]);
    #pragma unroll
    for (int j=0;j<6;j++){
      int o = w*96 + j*16 + fr;          // 0..383
      float bv = bias[o];
      f32x4 d = {bv,bv,bv,bv};
      const u16* wp = wB + (size_t)o*128 + fg*8;
      #pragma unroll
      for (int k=0;k<4;k++){
        bf16x8 b = *reinterpret_cast<const bf16x8*>(wp + k*32);
        d = __builtin_amdgcn_mfma_f32_16x16x32_bf16(a[k], b, d, 0, 0, 0);
      }
      #pragma unroll
      for (int r=0;r<4;r++) Qs[(fg*4+r)*392 + o] = f2b_u(d[r]);
    }
  }
  __syncthreads();
  {
    int l = t >> 4, og = t & 15, o0 = og*24;
    size_t tok = (size_t)bid*16 + l;
    #pragma unroll
    for (int m=0; m<3; m++){
      int oc = o0 + m*8;
      uint4 v = *reinterpret_cast<const uint4*>(&Qs[l*392 + oc]);
      if (oc < 128) *reinterpret_cast<uint4*>(qbuf + tok*128 + oc) = v;
      else          *reinterpret_cast<uint4*>(kvbuf + tok*256 + (oc-128)) = v;
    }
  }
}

// ---------- K4b: DilatedMSA flash attention (L=256); y = x + attn IN PLACE over bufC ----------
__global__ __launch_bounds__(256) void k_attn2(const u16* __restrict__ qbuf, const u16* __restrict__ kvbuf,
                                               u16* __restrict__ y){
  __shared__ u16 Qb[64*72];        // bf16 [qrow][72-padded d]
  __shared__ u16 Kb[32*72];        // bf16 [krow][72-padded d]
  __shared__ float Vs[32*64];
  __shared__ float Ss[64*33];
  __shared__ float mrow[64], lrow[64], crow[64];
  int t = threadIdx.x, bid = blockIdx.x;
  int qt = bid & 3, h = (bid >> 2) & 1, bl = bid >> 3;
  size_t tokbase = (size_t)bl * 256;
  {
    int r = t >> 2, seg = t & 3;
    const u16* src = qbuf + (tokbase + qt*64 + r)*128 + h*64 + seg*16;
    uint4 v0 = *reinterpret_cast<const uint4*>(src);
    uint4 v1 = *reinterpret_cast<const uint4*>(src + 8);
    *reinterpret_cast<uint4*>(&Qb[r*72 + seg*16])     = v0;
    *reinterpret_cast<uint4*>(&Qb[r*72 + seg*16 + 8]) = v1;
  }
  if (t < 64){ mrow[t] = -1e30f; lrow[t] = 0.0f; }
  float Oacc[16];
  #pragma unroll
  for (int j=0;j<16;j++) Oacc[j] = 0.0f;
  int lq = t & 63, grp = t >> 6;
  int fc = lq & 15, fg = lq >> 4;     // MFMA lane coords
  __syncthreads();
  for (int kt=0; kt<8; kt++){
    {
      int r = t >> 3, seg = t & 7;
      const u16* base = kvbuf + (tokbase + kt*32 + r)*256 + h*64;
      *reinterpret_cast<uint4*>(&Kb[r*72 + seg*8]) = *reinterpret_cast<const uint4*>(base + seg*8);
      float v[8];
      ld8b(base + 128 + seg*8, v);
      #pragma unroll
      for (int j=0;j<8;j++) Vs[r*64 + seg*8 + j] = v[j];
    }
    __syncthreads();
    {
      f32x4 s0 = {0.f,0.f,0.f,0.f}, s1 = {0.f,0.f,0.f,0.f};
      bf16x8 a0  = *reinterpret_cast<const bf16x8*>(&Qb[(grp*16+fc)*72 + fg*8]);
      bf16x8 a1  = *reinterpret_cast<const bf16x8*>(&Qb[(grp*16+fc)*72 + 32 + fg*8]);
      bf16x8 b00 = *reinterpret_cast<const bf16x8*>(&Kb[fc*72 + fg*8]);
      bf16x8 b01 = *reinterpret_cast<const bf16x8*>(&Kb[fc*72 + 32 + fg*8]);
      bf16x8 b10 = *reinterpret_cast<const bf16x8*>(&Kb[(16+fc)*72 + fg*8]);
      bf16x8 b11 = *reinterpret_cast<const bf16x8*>(&Kb[(16+fc)*72 + 32 + fg*8]);
      s0 = __builtin_amdgcn_mfma_f32_16x16x32_bf16(a0, b00, s0, 0, 0, 0);
      s0 = __builtin_amdgcn_mfma_f32_16x16x32_bf16(a1, b01, s0, 0, 0, 0);
      s1 = __builtin_amdgcn_mfma_f32_16x16x32_bf16(a0, b10, s1, 0, 0, 0);
      s1 = __builtin_amdgcn_mfma_f32_16x16x32_bf16(a1, b11, s1, 0, 0, 0);
      #pragma unroll
      for (int r2=0;r2<4;r2++){
        int row = grp*16 + fg*4 + r2;
        Ss[row*33 + fc]      = s0[r2] * 0.08838834764831845f;
        Ss[row*33 + 16 + fc] = s1[r2] * 0.08838834764831845f;
      }
    }
    __syncthreads();
    if (t < 64){
      float* row = &Ss[t*33];
      float m = mrow[t];
      #pragma unroll
      for (int i=0;i<32;i++) m = fmaxf(m, row[i]);
      float corr = expf(mrow[t] - m);
      float s = lrow[t] * corr;
      #pragma unroll
      for (int i=0;i<32;i++){ float e = expf(row[i]-m); row[i] = e; s += e; }
      mrow[t] = m; lrow[t] = s; crow[t] = corr;
    }
    __syncthreads();
    {
      float corr = crow[lq];
      #pragma unroll
      for (int j=0;j<16;j++) Oacc[j] *= corr;
      for (int m=0;m<32;m++){
        float pp = Ss[lq*33 + m];
        const float4* vp = reinterpret_cast<const float4*>(&Vs[m*64 + grp*16]);
        float4 v0 = vp[0], v1 = vp[1], v2 = vp[2], v3 = vp[3];
        Oacc[0]+=pp*v0.x; Oacc[1]+=pp*v0.y; Oacc[2]+=pp*v0.z; Oacc[3]+=pp*v0.w;
        Oacc[4]+=pp*v1.x; Oacc[5]+=pp*v1.y; Oacc[6]+=pp*v1.z; Oacc[7]+=pp*v1.w;
        Oacc[8]+=pp*v2.x; Oacc[9]+=pp*v2.y; Oacc[10]+=pp*v2.z; Oacc[11]+=pp*v2.w;
        Oacc[12]+=pp*v3.x; Oacc[13]+=pp*v3.y; Oacc[14]+=pp*v3.z; Oacc[15]+=pp*v3.w;
      }
    }
    __syncthreads();
  }
  float inv = 1.0f / lrow[lq];
  u16* dst = y + (tokbase + qt*64 + lq)*128 + h*64 + grp*16;
  float res[16]; ld8b(dst, res); ld8b(dst+8, res+8);
  float o16[16];
  #pragma unroll
  for (int j=0;j<16;j++) o16[j] = Oacc[j]*inv + res[j];
  st8b(dst, o16); st8b(dst+8, o16+8);
}

// ---------- K_tr: h0/c0 [c][4096] -> hws/Cst [pix][128] fp32 (LDS-tiled transpose) ----------
__global__ __launch_bounds__(256) void k_tr_pc(const void* __restrict__ h0, const void* __restrict__ c0,
                                               float* __restrict__ hws, float* __restrict__ Cst,
                                               const int* __restrict__ flag){
  __shared__ float lds[32][33];
  int t = threadIdx.x, bid = blockIdx.x;
  int sel = bid >> 9, tile = bid & 511;
  int pt2 = tile >> 2, ct = tile & 3;
  const void* src = sel ? c0 : h0;
  float* dst = sel ? Cst : hws;
  int r = t >> 3, q = t & 7;
  {
    int c = ct*32 + r;
    int px = pt2*32 + q*4;
    if (*flag){
      float4 v = *reinterpret_cast<const float4*>((const float*)src + (size_t)c*4096 + px);
      lds[r][q*4+0]=v.x; lds[r][q*4+1]=v.y; lds[r][q*4+2]=v.z; lds[r][q*4+3]=v.w;
    } else {
      uint2 u = *reinterpret_cast<const uint2*>((const u16*)src + (size_t)c*4096 + px);
      lds[r][q*4+0]=b2f_u(u.x & 0xffffu); lds[r][q*4+1]=b2f_u(u.x >> 16);
      lds[r][q*4+2]=b2f_u(u.y & 0xffffu); lds[r][q*4+3]=b2f_u(u.y >> 16);
    }
  }
  __syncthreads();
  {
    int px = pt2*32 + r;
    int c = ct*32 + q*4;
    float4 o;
    o.x = lds[q*4+0][r]; o.y = lds[q*4+1][r]; o.z = lds[q*4+2][r]; o.w = lds[q*4+3][r];
    *reinterpret_cast<float4*>(dst + (size_t)px*128 + c) = o;
  }
}

// ---------- K6: fused LSTM step, register-tiled GEMM + wave softmax ----------
__global__ __launch_bounds__(256) void k_lstm_step(const u16* __restrict__ xD,
    float* __restrict__ hws, float* __restrict__ Cst,
    const float* __restrict__ wx, const float* __restrict__ wh, const float* __restrict__ bh,
    void* __restrict__ dout, int n, const int* __restrict__ flag){
  __shared__ float tile[256*8];      // [k][px]; k<128: x ch, k>=128: h ch
  __shared__ float glds[4*8*132];    // [gate][px][132-padded ch]
  int t = threadIdx.x, bid = blockIdx.x;
  int pix0 = bid*8;
  if (t < 128){
    int px = t >> 4, cg = t & 15;
    float v[8]; ld8b(xD + ((size_t)n*4096 + pix0 + px)*128 + cg*8, v);
    #pragma unroll
    for (int j=0;j<8;j++) tile[(cg*8+j)*8 + px] = v[j];
  } else {
    int t2 = t - 128;
    int px = t2 >> 4, cg = t2 & 15;
    const float4* hp = reinterpret_cast<const float4*>(hws + (size_t)(pix0+px)*128 + cg*8);
    float4 a = hp[0], b = hp[1];
    tile[(128+cg*8+0)*8+px]=a.x; tile[(128+cg*8+1)*8+px]=a.y;
    tile[(128+cg*8+2)*8+px]=a.z; tile[(128+cg*8+3)*8+px]=a.w;
    tile[(128+cg*8+4)*8+px]=b.x; tile[(128+cg*8+5)*8+px]=b.y;
    tile[(128+cg*8+6)*8+px]=b.z; tile[(128+cg*8+7)*8+px]=b.w;
  }
  __syncthreads();
  int w = t >> 6, l = t & 63;
  int ch = l*2;
  float acc[8][2];
  {
    float b0 = bh[w*128 + ch], b1 = bh[w*128 + ch + 1];
    #pragma unroll
    for (int p=0;p<8;p++){ acc[p][0]=b0; acc[p][1]=b1; }
  }
  const float* wxp = wx + w*128 + ch;
  const float* whp = wh + w*128 + ch;
  for (int k=0;k<128;k+=2){
    float2 wa = *reinterpret_cast<const float2*>(wxp + (size_t)k*512);
    float2 wb = *reinterpret_cast<const float2*>(wxp + (size_t)k*512 + 512);
    const float* xr0 = &tile[k*8];
    const float* xr1 = &tile[k*8 + 8];
    #pragma unroll
    for (int p=0;p<8;p++){
      float x0 = xr0[p], x1 = xr1[p];
      acc[p][0] += x0*wa.x; acc[p][1] += x0*wa.y;
      acc[p][0] += x1*wb.x; acc[p][1] += x1*wb.y;
    }
  }
  for (int k=0;k<128;k+=2){
    float2 wa = *reinterpret_cast<const float2*>(whp + (size_t)k*512);
    float2 wb = *reinterpret_cast<const float2*>(whp + (size_t)k*512 + 512);
    const float* xr0 = &tile[(128+k)*8];
    const float* xr1 = &tile[(128+k)*8 + 8];
    #pragma unroll
    for (int p=0;p<8;p++){
      float x0 = xr0[p], x1 = xr1[p];
      acc[p][0] += x0*wa.x; acc[p][1] += x0*wa.y;
      acc[p][0] += x1*wb.x; acc[p][1] += x1*wb.y;
    }
  }
  if (w == 2){
    #pragma unroll
    for (int p=0;p<8;p++){
      float v0 = tanhf(acc[p][0]), v1 = tanhf(acc[p][1]);
      *reinterpret_cast<float2*>(&glds[(w*8+p)*132 + ch]) = make_float2(v0, v1);
    }
  } else {
    #pragma unroll
    for (int p=0;p<8;p++){
      float m2 = fmaxf(acc[p][0], acc[p][1]);
      #pragma unroll
      for (int sft=1; sft<64; sft<<=1) m2 = fmaxf(m2, __shfl_xor(m2, sft));
      float e0 = expf(acc[p][0]-m2), e1 = expf(acc[p][1]-m2);
      float sm = e0 + e1;
      #pragma unroll
      for (int sft=1; sft<64; sft<<=1) sm += __shfl_xor(sm, sft);
      float inv = 1.0f/sm;
      *reinterpret_cast<float2*>(&glds[(w*8+p)*132 + ch]) = make_float2(e0*inv, e1*inv);
    }
  }
  __syncthreads();
  {
    int px = t & 7, ch0 = (t >> 3)*4;
    float4 fv = *reinterpret_cast<const float4*>(&glds[(0*8+px)*132 + ch0]);
    float4 iv = *reinterpret_cast<const float4*>(&glds[(1*8+px)*132 + ch0]);
    float4 sv = *reinterpret_cast<const float4*>(&glds[(2*8+px)*132 + ch0]);
    float4 ov = *reinterpret_cast<const float4*>(&glds[(3*8+px)*132 + ch0]);
    int pix = pix0 + px;
    float4 cold = *reinterpret_cast<const float4*>(Cst + (size_t)pix*128 + ch0);
    float cn[4], hn[4];
    cn[0] = fv.x*cold.x + iv.x*sv.x; hn[0] = ov.x*tanhf(cn[0]);
    cn[1] = fv.y*cold.y + iv.y*sv.y; hn[1] = ov.y*tanhf(cn[1]);
    cn[2] = fv.z*cold.z + iv.z*sv.z; hn[2] = ov.z*tanhf(cn[2]);
    cn[3] = fv.w*cold.w + iv.w*sv.w; hn[3] = ov.w*tanhf(cn[3]);
    *reinterpret_cast<float4*>(Cst + (size_t)pix*128 + ch0) = make_float4(cn[0],cn[1],cn[2],cn[3]);
    *reinterpret_cast<float4*>(hws + (size_t)pix*128 + ch0) = make_float4(hn[0],hn[1],hn[2],hn[3]);
    size_t ob = (size_t)n*524288;
    if (*flag){
      float* df = (float*)dout;
      #pragma unroll
      for (int j=0;j<4;j++) df[ob + (size_t)(ch0+j)*4096 + pix] = hn[j];
    } else {
      u16* db = (u16*)dout;
      #pragma unroll
      for (int j=0;j<4;j++) db[ob + (size_t)(ch0+j)*4096 + pix] = f2b_u(hn[j]);
    }
  }
}

// ---------- K7: final hf, Cf: [pix][128] fp32 -> d_out [c][4096] (tiled transpose, dtype) ----------
__global__ __launch_bounds__(256) void k_final_t(const float* __restrict__ hws, const float* __restrict__ Cst,
                                                 void* __restrict__ dout, const int* __restrict__ flag){
  __shared__ float lds[32][33];
  int t = threadIdx.x, bid = blockIdx.x;
  int sel = bid >> 9, tile = bid & 511;
  int pt2 = tile >> 2, ct = tile & 3;
  const float* src = sel ? Cst : hws;
  size_t base = sel ? 8912896u : 8388608u;
  int r = t >> 3, q = t & 7;
  {
    int px = pt2*32 + r, c = ct*32 + q*4;
    float4 v = *reinterpret_cast<const float4*>(src + (size_t)px*128 + c);
    lds[r][q*4+0]=v.x; lds[r][q*4+1]=v.y; lds[r][q*4+2]=v.z; lds[r][q*4+3]=v.w;
  }
  __syncthreads();
  {
    int c = ct*32 + r, px = pt2*32 + q*4;
    float v0 = lds[q*4+0][r], v1 = lds[q*4+1][r], v2 = lds[q*4+2][r], v3 = lds[q*4+3][r];
    if (*flag){
      *reinterpret_cast<float4*>((float*)dout + base + (size_t)c*4096 + px) = make_float4(v0,v1,v2,v3);
    } else {
      uint2 pk;
      pk.x = (u32)f2b_u(v0) | ((u32)f2b_u(v1) << 16);
      pk.y = (u32)f2b_u(v2) | ((u32)f2b_u(v3) << 16);
      *reinterpret_cast<uint2*>((u16*)dout + base + (size_t)c*4096 + px) = pk;
    }
  }
}

extern "C" void kernel_launch(void* const* d_in, const int* in_sizes, int n_in,
                              void* d_out, int out_size, void* d_ws, size_t ws_size,
                              hipStream_t stream) {
  const void* x      = d_in[0];
  const void* h0     = d_in[1];
  const void* c0     = d_in[2];
  const void* conv_w = d_in[3];
  const void* conv_b = d_in[4];
  const void* qkv1_w = d_in[5];
  const void* qkv1_b = d_in[6];
  const void* m1w1   = d_in[7];
  const void* m1b1   = d_in[8];
  const void* m1w2   = d_in[9];
  const void* m1b2   = d_in[10];
  const void* qkv2_w = d_in[11];
  const void* qkv2_b = d_in[12];
  const void* m2w1   = d_in[13];
  const void* m2b1   = d_in[14];
  const void* m2w2   = d_in[15];
  const void* m2b2   = d_in[16];
  const void* lwx    = d_in[17];
  const void* lwh    = d_in[18];
  const void* lbh    = d_in[19];

  char* p = (char*)d_ws;
  auto alloc = [&](size_t bytes)->void*{
    void* r = (void*)p; p += (bytes + 255) & ~(size_t)255; return r;
  };
  int*   flag    = (int*)alloc(256);
  float* wO_conv = (float*)alloc(512*128*4);   // original conv layout, fp32
  u16* wB_qkv1 = (u16*)alloc(384*128*2);       // bf16, original [o][k]
  u16* wB_m1a  = (u16*)alloc(512*128*2);
  u16* wB_m1b  = (u16*)alloc(128*512*2);
  u16* wB_qkv2 = (u16*)alloc(384*128*2);
  u16* wB_m2a  = (u16*)alloc(512*128*2);
  u16* wB_m2b  = (u16*)alloc(128*512*2);
  float* wT_lx   = (float*)alloc(128*512*4);   // transposed [k][512] fp32
  float* wT_lh   = (float*)alloc(128*512*4);
  float* bf_conv = (float*)alloc(128*4);
  float* bf_qkv1 = (float*)alloc(384*4);
  float* bf_m1b1 = (float*)alloc(512*4);
  float* bf_m1b2 = (float*)alloc(128*4);
  float* bf_qkv2 = (float*)alloc(384*4);
  float* bf_m2b1 = (float*)alloc(512*4);
  float* bf_m2b2 = (float*)alloc(128*4);
  float* bf_lbh  = (float*)alloc(512*4);
  u16* R0   = (u16*)alloc(16777216);   // bufA -> bufC/y -> (hws, Cst)
  u16* Rbig = (u16*)alloc(33554432);   // bufB (front) -> kvbuf -> bufD (front)

  u16* bufA = R0;
  u16* bufB = Rbig;
  u16* bufC = R0;          // also y (attn writes in place)
  u16* qbuf = (u16*)d_out; // hs region used as scratch; dead before first LSTM write
  u16* kvbuf = Rbig;
  u16* bufD = Rbig;
  float* hws = (float*)((char*)R0 + 8388608);         // 2 MB, [pix][128]
  float* Cst = (float*)((char*)R0 + 10485760);        // 2 MB, [pix][128]

  k_detect<<<1, 256, 0, stream>>>((const u32*)x, flag);

  auto T = [&](const void* in, float* o, int O, int K){
    int n = O*K;
    k_transpose<<<(n+255)/256, 256, 0, stream>>>(in, o, O, K, flag);
  };
  T(lwx,    wT_lx,   512, 128);
  T(lwh,    wT_lh,   512, 128);

  auto V = [&](const void* in, float* o, int n){
    k_cvtvec<<<(n+255)/256, 256, 0, stream>>>(in, o, n, flag);
  };
  V(conv_w, wO_conv, 128*512);
  V(conv_b, bf_conv, 128);
  V(qkv1_b, bf_qkv1, 384);
  V(m1b1,   bf_m1b1, 512);
  V(m1b2,   bf_m1b2, 128);
  V(qkv2_b, bf_qkv2, 384);
  V(m2b1,   bf_m2b1, 512);
  V(m2b2,   bf_m2b2, 128);
  V(lbh,    bf_lbh,  512);

  auto Wb = [&](const void* in, u16* o, int n){
    k_cvtb16<<<(n+255)/256, 256, 0, stream>>>(in, o, n, flag);
  };
  Wb(qkv1_w, wB_qkv1, 384*128);
  Wb(m1w1,   wB_m1a,  512*128);
  Wb(m1w2,   wB_m1b,  128*512);
  Wb(qkv2_w, wB_qkv2, 384*128);
  Wb(m2w1,   wB_m2a,  512*128);
  Wb(m2w2,   wB_m2b,  128*512);

  k_conv<<<512, 256, 0, stream>>>(x, wO_conv, bf_conv, bufA, flag);
  k_msa1<<<4096, 256, 0, stream>>>(bufA, wB_qkv1, bf_qkv1, bufB);
  k_mlp<1><<<4096, 256, 0, stream>>>(bufB, wB_m1a, bf_m1b1, wB_m1b, bf_m1b2, bufC);
  k_qkv2<<<4096, 256, 0, stream>>>(bufC, wB_qkv2, bf_qkv2, qbuf, kvbuf);
  k_attn2<<<2048, 256, 0, stream>>>(qbuf, kvbuf, bufC);          // y = x + attn, in place
  k_mlp<2><<<4096, 256, 0, stream>>>(bufC, wB_m2a, bf_m2b1, wB_m2b, bf_m2b2, bufD);

  k_tr_pc<<<1024, 256, 0, stream>>>(h0, c0, hws, Cst, flag);
  for (int n = 0; n < 16; n++){
    k_lstm_step<<<512, 256, 0, stream>>>(bufD, hws, Cst, wT_lx, wT_lh, bf_lbh, d_out, n, flag);
  }
  k_final_t<<<1024, 256, 0, stream>>>(hws, Cst, d_out, flag);
}

// Round 6
// 1218.652 us; speedup vs baseline: 6.1233x; 1.1404x over previous
//
#include <hip/hip_runtime.h>
#include <hip/hip_bf16.h>

typedef unsigned int u32;
typedef unsigned short u16;

#define DI __device__ __forceinline__

typedef __attribute__((ext_vector_type(8))) __bf16 bf16x8;
typedef __attribute__((ext_vector_type(4))) float f32x4;

// ---------- bf16 helpers (bf16 == fp32 high 16 bits; RNE on store) ----------
DI float b2f_u(u32 u){ return __uint_as_float(u << 16); }
DI u16 f2b_u(float f){
  u32 x = __float_as_uint(f);
  x += 0x7fffu + ((x >> 16) & 1u);
  return (u16)(x >> 16);
}
DI void ld8b(const u16* p, float* o){
  uint4 v = *reinterpret_cast<const uint4*>(p);
  o[0] = b2f_u(v.x & 0xffffu); o[1] = b2f_u(v.x >> 16);
  o[2] = b2f_u(v.y & 0xffffu); o[3] = b2f_u(v.y >> 16);
  o[4] = b2f_u(v.z & 0xffffu); o[5] = b2f_u(v.z >> 16);
  o[6] = b2f_u(v.w & 0xffffu); o[7] = b2f_u(v.w >> 16);
}
DI void st8b(u16* p, const float* i){
  uint4 v;
  v.x = (u32)f2b_u(i[0]) | ((u32)f2b_u(i[1]) << 16);
  v.y = (u32)f2b_u(i[2]) | ((u32)f2b_u(i[3]) << 16);
  v.z = (u32)f2b_u(i[4]) | ((u32)f2b_u(i[5]) << 16);
  v.w = (u32)f2b_u(i[6]) | ((u32)f2b_u(i[7]) << 16);
  *reinterpret_cast<uint4*>(p) = v;
}

// ---------- K_detect: is d_in fp32 (flag=1) or packed bf16 (flag=0)? ----------
__global__ void k_detect(const u32* __restrict__ xw, int* __restrict__ flag){
  __shared__ int cnt;
  int t = threadIdx.x;
  if (t == 0) cnt = 0;
  __syncthreads();
  int c = 0;
  for (int i = t; i < 2048; i += 256){
    u32 lo = xw[i] & 0xffffu;
    u32 e = (lo >> 7) & 0xffu;
    if (e < 100u || e > 140u) c++;
  }
  atomicAdd(&cnt, c);
  __syncthreads();
  if (t == 0) *flag = (cnt > 200) ? 1 : 0;
}

// ---------- K0: weight transpose ([O][K] -> fp32 [K][O]), dtype-adaptive ----------
__global__ void k_transpose(const void* __restrict__ in, float* __restrict__ out, int O, int K,
                            const int* __restrict__ flag){
  int idx = blockIdx.x*256 + threadIdx.x;
  if (idx < O*K){
    int o = idx % O, k = idx / O;
    if (*flag) out[idx] = ((const float*)in)[o*K + k];
    else       out[idx] = b2f_u((u32)((const u16*)in)[o*K + k]);
  }
}

// ---------- K0b: vector convert -> fp32 (straight copy) ----------
__global__ void k_cvtvec(const void* __restrict__ in, float* __restrict__ out, int n,
                         const int* __restrict__ flag){
  int i = blockIdx.x*256 + threadIdx.x;
  if (i < n){
    if (*flag) out[i] = ((const float*)in)[i];
    else       out[i] = b2f_u((u32)((const u16*)in)[i]);
  }
}

// ---------- K0c: convert -> bf16 (layout-preserving; copy when already bf16) ----------
__global__ void k_cvtb16(const void* __restrict__ in, u16* __restrict__ out, int n,
                         const int* __restrict__ flag){
  int i = blockIdx.x*256 + threadIdx.x;
  if (i < n){
    if (*flag) out[i] = f2b_u(((const float*)in)[i]);
    else       out[i] = ((const u16*)in)[i];
  }
}

// ---------- K1: conv 2x2 stride 2 + window partition via MFMA -> bufA [b][g][l][c] ----------
// Per-window block. A[16 tok][K=512] staged bf16 in fragment layout (k = ci*4+ky*2+kx);
// weights bf16 in NATIVE [co][ci][ky][kx] = [co][512] layout (k-order matches).
// XCD-aware bijective swizzle: the 4 x-neighbor windows sharing each 64B line land on
// the same XCD (bid%8), so each line is fetched from HBM exactly once.
__global__ __launch_bounds__(256) void k_conv(const void* __restrict__ x_raw,
                                              const u16* __restrict__ wB,
                                              const float* __restrict__ bias, u16* __restrict__ outA,
                                              const int* __restrict__ flag){
  __shared__ u16 Xa[16*520];     // A: [tok][520-pad k], 16.6 KB
  __shared__ u16 Ys[16*136];     // output staging, 4.3 KB
  int t = threadIdx.x, bid = blockIdx.x;
  int xcd = bid & 7, slot = bid >> 3;
  int gIn = slot >> 2, sub = slot & 3;
  int group = gIn*8 + xcd;               // 0..1023, bijective
  int b = group >> 6, yg = (group >> 2) & 15, xgHi = group & 3;
  int xg = xgHi*4 + sub;
  int g = yg*16 + xg;
  size_t base = (size_t)b*2097152 + (size_t)(yg*8)*128 + (size_t)xg*8;
  if (*flag){
    const float* xb = (const float*)x_raw + base;
    #pragma unroll
    for (int i=0;i<4;i++){
      int idx = i*256 + t;
      int ci = idx >> 3, py = idx & 7;
      const float4* s4 = reinterpret_cast<const float4*>(xb + (size_t)ci*16384 + py*128);
      float4 v0 = s4[0], v1 = s4[1];
      int l0 = (py>>1)*4, k0 = ci*4 + (py&1)*2;
      *reinterpret_cast<u32*>(&Xa[(l0+0)*520 + k0]) = (u32)f2b_u(v0.x) | ((u32)f2b_u(v0.y)<<16);
      *reinterpret_cast<u32*>(&Xa[(l0+1)*520 + k0]) = (u32)f2b_u(v0.z) | ((u32)f2b_u(v0.w)<<16);
      *reinterpret_cast<u32*>(&Xa[(l0+2)*520 + k0]) = (u32)f2b_u(v1.x) | ((u32)f2b_u(v1.y)<<16);
      *reinterpret_cast<u32*>(&Xa[(l0+3)*520 + k0]) = (u32)f2b_u(v1.z) | ((u32)f2b_u(v1.w)<<16);
    }
  } else {
    const u16* xb = (const u16*)x_raw + base;
    #pragma unroll
    for (int i=0;i<4;i++){
      int idx = i*256 + t;
      int ci = idx >> 3, py = idx & 7;
      uint4 v = *reinterpret_cast<const uint4*>(xb + (size_t)ci*16384 + py*128);
      int l0 = (py>>1)*4, k0 = ci*4 + (py&1)*2;
      *reinterpret_cast<u32*>(&Xa[(l0+0)*520 + k0]) = v.x;
      *reinterpret_cast<u32*>(&Xa[(l0+1)*520 + k0]) = v.y;
      *reinterpret_cast<u32*>(&Xa[(l0+2)*520 + k0]) = v.z;
      *reinterpret_cast<u32*>(&Xa[(l0+3)*520 + k0]) = v.w;
    }
  }
  __syncthreads();
  int w = t >> 6, lane = t & 63, fr = lane & 15, fg = lane >> 4;
  bf16x8 a[16];
  #pragma unroll
  for (int c=0;c<16;c++) a[c] = *reinterpret_cast<const bf16x8*>(&Xa[fr*520 + c*32 + fg*8]);
  #pragma unroll
  for (int j=0;j<2;j++){
    int o = w*32 + j*16 + fr;          // 0..127
    float bv = bias[o];
    f32x4 d = {bv,bv,bv,bv};
    const u16* wp = wB + (size_t)o*512 + fg*8;
    #pragma unroll
    for (int c=0;c<16;c++){
      bf16x8 bb = *reinterpret_cast<const bf16x8*>(wp + c*32);
      d = __builtin_amdgcn_mfma_f32_16x16x32_bf16(a[c], bb, d, 0, 0, 0);
    }
    #pragma unroll
    for (int r=0;r<4;r++) Ys[(fg*4+r)*136 + o] = f2b_u(d[r]);
  }
  __syncthreads();
  {
    int tok = t >> 4, c0 = (t & 15)*8;
    uint4 v = *reinterpret_cast<const uint4*>(&Ys[tok*136 + c0]);
    size_t T = ((size_t)(b*256 + g)*16 + tok);
    *reinterpret_cast<uint4*>(outA + T*128 + c0) = v;
  }
}

// ---------- K2: LocalMSA (L=16) + residual: bufA -> bufB (same layout) ----------
// Projection via MFMA: A = X rows (bf16 LDS), B = qkv weight rows (bf16, original [o][k], L2).
__global__ __launch_bounds__(256) void k_msa1(const u16* __restrict__ A, const u16* __restrict__ wB,
                                              const float* __restrict__ qbias, u16* __restrict__ B){
  __shared__ u16 Xs[16*136];        // bf16, row stride 272 B
  __shared__ float QKV[16*388];
  __shared__ float S[512];          // [h][l][m]
  int t = threadIdx.x, bid = blockIdx.x;
  {
    int l = t >> 4, c0 = (t & 15)*8;
    *reinterpret_cast<uint4*>(&Xs[l*136 + c0]) =
      *reinterpret_cast<const uint4*>(A + (size_t)bid*2048 + l*128 + c0);
  }
  __syncthreads();
  {
    int w = t >> 6, lane = t & 63, fr = lane & 15, fg = lane >> 4;
    bf16x8 a[4];
    #pragma unroll
    for (int k=0;k<4;k++) a[k] = *reinterpret_cast<const bf16x8*>(&Xs[fr*136 + k*32 + fg*8]);
    #pragma unroll
    for (int j=0;j<6;j++){
      int o = w*96 + j*16 + fr;          // 0..383
      float bv = qbias[o];
      f32x4 d = {bv,bv,bv,bv};
      const u16* wp = wB + (size_t)o*128 + fg*8;
      #pragma unroll
      for (int k=0;k<4;k++){
        bf16x8 b = *reinterpret_cast<const bf16x8*>(wp + k*32);
        d = __builtin_amdgcn_mfma_f32_16x16x32_bf16(a[k], b, d, 0, 0, 0);
      }
      #pragma unroll
      for (int r=0;r<4;r++) QKV[(fg*4+r)*388 + o] = d[r];
    }
  }
  __syncthreads();
  const float scale = 0.08838834764831845f;   // 1/sqrt(128)
  for (int e = t; e < 512; e += 256){
    int h = e >> 8, l = (e>>4)&15, m = e&15;
    const float* q = &QKV[l*388 + h*64];
    const float* kk = &QKV[m*388 + 128 + h*64];
    float s = 0.f;
    #pragma unroll
    for (int d=0; d<64; d++) s += q[d]*kk[d];
    S[(h*16+l)*16 + m] = s*scale;
  }
  __syncthreads();
  if (t < 32){
    float* row = &S[t*16];
    float mx = row[0];
    #pragma unroll
    for (int m=1;m<16;m++) mx = fmaxf(mx,row[m]);
    float sum = 0.f;
    #pragma unroll
    for (int m=0;m<16;m++){ float e = expf(row[m]-mx); row[m]=e; sum+=e; }
    float inv = 1.0f/sum;
    #pragma unroll
    for (int m=0;m<16;m++) row[m] *= inv;
  }
  __syncthreads();
  {
    int l = t >> 4, og = t & 15, o0 = og*8;
    int h = o0 >> 6;
    const float* p = &S[(h*16+l)*16];
    float out8[8];
    #pragma unroll
    for (int j=0;j<8;j++){
      int o = o0+j, d = o & 63;
      float s = 0.f;
      #pragma unroll
      for (int m=0;m<16;m++) s += p[m]*QKV[m*388 + 256 + h*64 + d];
      out8[j] = s + b2f_u((u32)Xs[l*136 + o]);
    }
    st8b(B + (size_t)bid*2048 + l*128 + o0, out8);
  }
}

// ---------- K3/K5: MLP (+residual) via MFMA (bf16 in/weights, fp32 accum). ----------
//            MODE1: bufB [b][g][l][c] -> bufC [b][l][g][c].
//            MODE2: y [b][l][g][c] -> bufD [n][pix][c] (window reverse).
template<int MODE>
__global__ __launch_bounds__(256) void k_mlp(const u16* __restrict__ in,
    const u16* __restrict__ w1B, const float* __restrict__ b1,
    const u16* __restrict__ w2B, const float* __restrict__ b2,
    u16* __restrict__ out){
  __shared__ u16 Xs[16*136];        // bf16 input (also residual), 272 B rows
  __shared__ u16 Hs[16*520];        // bf16 hidden, 1040 B rows
  __shared__ u16 Ys[16*136];        // bf16 output staging
  int t = threadIdx.x, bid = blockIdx.x;
  {
    int l = t >> 4, c0 = (t & 15)*8;
    *reinterpret_cast<uint4*>(&Xs[l*136 + c0]) =
      *reinterpret_cast<const uint4*>(in + (size_t)bid*2048 + l*128 + c0);
  }
  __syncthreads();
  int w = t >> 6, lane = t & 63, fr = lane & 15, fg = lane >> 4;

  // ---- GEMM1: H = gelu(X @ W1^T + b1); wave handles 8 n-tiles of 16 ----
  {
    bf16x8 a[4];
    #pragma unroll
    for (int k=0;k<4;k++) a[k] = *reinterpret_cast<const bf16x8*>(&Xs[fr*136 + k*32 + fg*8]);
    #pragma unroll
    for (int j=0;j<8;j++){
      int o = w*128 + j*16 + fr;        // 0..511
      float bv = b1[o];
      f32x4 d = {bv,bv,bv,bv};
      const u16* wp = w1B + (size_t)o*128 + fg*8;
      #pragma unroll
      for (int k=0;k<4;k++){
        bf16x8 b = *reinterpret_cast<const bf16x8*>(wp + k*32);
        d = __builtin_amdgcn_mfma_f32_16x16x32_bf16(a[k], b, d, 0, 0, 0);
      }
      #pragma unroll
      for (int r=0;r<4;r++){
        float v = d[r];
        float g = 0.5f*v*(1.0f + erff(v*0.70710678118654752f));
        Hs[(fg*4+r)*520 + o] = f2b_u(g);
      }
    }
  }
  __syncthreads();

  // ---- GEMM2: Y = H @ W2^T + b2 + X; wave handles 2 n-tiles of 16 ----
  {
    int na = w*32 + fr, nb = na + 16;   // 0..127
    float ba = b2[na], bb = b2[nb];
    f32x4 d0 = {ba,ba,ba,ba}, d1 = {bb,bb,bb,bb};
    const u16* wpa = w2B + (size_t)na*512 + fg*8;
    const u16* wpb = w2B + (size_t)nb*512 + fg*8;
    #pragma unroll
    for (int k=0;k<16;k++){
      bf16x8 a = *reinterpret_cast<const bf16x8*>(&Hs[fr*520 + k*32 + fg*8]);
      bf16x8 bA = *reinterpret_cast<const bf16x8*>(wpa + k*32);
      bf16x8 bBv = *reinterpret_cast<const bf16x8*>(wpb + k*32);
      d0 = __builtin_amdgcn_mfma_f32_16x16x32_bf16(a, bA, d0, 0, 0, 0);
      d1 = __builtin_amdgcn_mfma_f32_16x16x32_bf16(a, bBv, d1, 0, 0, 0);
    }
    #pragma unroll
    for (int r=0;r<4;r++){
      int tok = fg*4 + r;
      float y0 = d0[r] + b2f_u((u32)Xs[tok*136 + na]);
      float y1 = d1[r] + b2f_u((u32)Xs[tok*136 + nb]);
      Ys[tok*136 + na] = f2b_u(y0);
      Ys[tok*136 + nb] = f2b_u(y1);
    }
  }
  __syncthreads();

  // ---- coalesced store with layout mapping ----
  {
    int tok = t >> 4, oc = (t & 15)*8;
    uint4 v = *reinterpret_cast<const uint4*>(&Ys[tok*136 + oc]);
    int T = bid*16 + tok;
    size_t addr;
    if (MODE == 1){
      int b = T >> 12, g = (T >> 4) & 255, ll = T & 15;
      addr = ((size_t)((b*16 + ll)*256 + g))*128 + oc;
    } else {
      int b = T >> 12, ll = (T >> 8) & 15, g = T & 255;
      int pcoord = ((g >> 4)*4 + (ll >> 2))*64 + ((g & 15)*4 + (ll & 3));
      addr = ((size_t)(b*4096 + pcoord))*128 + oc;
    }
    *reinterpret_cast<uint4*>(out + addr) = v;
  }
}

// ---------- K4a: QKV projection for DilatedMSA via MFMA ----------
__global__ __launch_bounds__(256) void k_qkv2(const u16* __restrict__ in, const u16* __restrict__ wB,
                                              const float* __restrict__ bias,
                                              u16* __restrict__ qbuf, u16* __restrict__ kvbuf){
  __shared__ u16 Xs[16*136];
  __shared__ u16 Qs[16*392];        // bf16 [tok][384+pad]
  int t = threadIdx.x, bid = blockIdx.x;
  {
    int l = t >> 4, c0 = (t & 15)*8;
    *reinterpret_cast<uint4*>(&Xs[l*136 + c0]) =
      *reinterpret_cast<const uint4*>(in + (size_t)bid*2048 + l*128 + c0);
  }
  __syncthreads();
  {
    int w = t >> 6, lane = t & 63, fr = lane & 15, fg = lane >> 4;
    bf16x8 a[4];
    #pragma unroll
    for (int k=0;k<4;k++) a[k] = *reinterpret_cast<const bf16x8*>(&Xs[fr*136 + k*32 + fg*8]);
    #pragma unroll
    for (int j=0;j<6;j++){
      int o = w*96 + j*16 + fr;          // 0..383
      float bv = bias[o];
      f32x4 d = {bv,bv,bv,bv};
      const u16* wp = wB + (size_t)o*128 + fg*8;
      #pragma unroll
      for (int k=0;k<4;k++){
        bf16x8 b = *reinterpret_cast<const bf16x8*>(wp + k*32);
        d = __builtin_amdgcn_mfma_f32_16x16x32_bf16(a[k], b, d, 0, 0, 0);
      }
      #pragma unroll
      for (int r=0;r<4;r++) Qs[(fg*4+r)*392 + o] = f2b_u(d[r]);
    }
  }
  __syncthreads();
  {
    int l = t >> 4, og = t & 15, o0 = og*24;
    size_t tok = (size_t)bid*16 + l;
    #pragma unroll
    for (int m=0; m<3; m++){
      int oc = o0 + m*8;
      uint4 v = *reinterpret_cast<const uint4*>(&Qs[l*392 + oc]);
      if (oc < 128) *reinterpret_cast<uint4*>(qbuf + tok*128 + oc) = v;
      else          *reinterpret_cast<uint4*>(kvbuf + tok*256 + (oc-128)) = v;
    }
  }
}

// ---------- K4b: DilatedMSA flash attention (L=256); y = x + attn IN PLACE over bufC ----------
__global__ __launch_bounds__(256) void k_attn2(const u16* __restrict__ qbuf, const u16* __restrict__ kvbuf,
                                               u16* __restrict__ y){
  __shared__ u16 Qb[64*72];        // bf16 [qrow][72-padded d]
  __shared__ u16 Kb[32*72];        // bf16 [krow][72-padded d]
  __shared__ float Vs[32*64];
  __shared__ float Ss[64*33];
  __shared__ float mrow[64], lrow[64], crow[64];
  int t = threadIdx.x, bid = blockIdx.x;
  int qt = bid & 3, h = (bid >> 2) & 1, bl = bid >> 3;
  size_t tokbase = (size_t)bl * 256;
  {
    int r = t >> 2, seg = t & 3;
    const u16* src = qbuf + (tokbase + qt*64 + r)*128 + h*64 + seg*16;
    uint4 v0 = *reinterpret_cast<const uint4*>(src);
    uint4 v1 = *reinterpret_cast<const uint4*>(src + 8);
    *reinterpret_cast<uint4*>(&Qb[r*72 + seg*16])     = v0;
    *reinterpret_cast<uint4*>(&Qb[r*72 + seg*16 + 8]) = v1;
  }
  if (t < 64){ mrow[t] = -1e30f; lrow[t] = 0.0f; }
  float Oacc[16];
  #pragma unroll
  for (int j=0;j<16;j++) Oacc[j] = 0.0f;
  int lq = t & 63, grp = t >> 6;
  int fc = lq & 15, fg = lq >> 4;     // MFMA lane coords
  __syncthreads();
  for (int kt=0; kt<8; kt++){
    {
      int r = t >> 3, seg = t & 7;
      const u16* base = kvbuf + (tokbase + kt*32 + r)*256 + h*64;
      *reinterpret_cast<uint4*>(&Kb[r*72 + seg*8]) = *reinterpret_cast<const uint4*>(base + seg*8);
      float v[8];
      ld8b(base + 128 + seg*8, v);
      #pragma unroll
      for (int j=0;j<8;j++) Vs[r*64 + seg*8 + j] = v[j];
    }
    __syncthreads();
    {
      f32x4 s0 = {0.f,0.f,0.f,0.f}, s1 = {0.f,0.f,0.f,0.f};
      bf16x8 a0  = *reinterpret_cast<const bf16x8*>(&Qb[(grp*16+fc)*72 + fg*8]);
      bf16x8 a1  = *reinterpret_cast<const bf16x8*>(&Qb[(grp*16+fc)*72 + 32 + fg*8]);
      bf16x8 b00 = *reinterpret_cast<const bf16x8*>(&Kb[fc*72 + fg*8]);
      bf16x8 b01 = *reinterpret_cast<const bf16x8*>(&Kb[fc*72 + 32 + fg*8]);
      bf16x8 b10 = *reinterpret_cast<const bf16x8*>(&Kb[(16+fc)*72 + fg*8]);
      bf16x8 b11 = *reinterpret_cast<const bf16x8*>(&Kb[(16+fc)*72 + 32 + fg*8]);
      s0 = __builtin_amdgcn_mfma_f32_16x16x32_bf16(a0, b00, s0, 0, 0, 0);
      s0 = __builtin_amdgcn_mfma_f32_16x16x32_bf16(a1, b01, s0, 0, 0, 0);
      s1 = __builtin_amdgcn_mfma_f32_16x16x32_bf16(a0, b10, s1, 0, 0, 0);
      s1 = __builtin_amdgcn_mfma_f32_16x16x32_bf16(a1, b11, s1, 0, 0, 0);
      #pragma unroll
      for (int r2=0;r2<4;r2++){
        int row = grp*16 + fg*4 + r2;
        Ss[row*33 + fc]      = s0[r2] * 0.08838834764831845f;
        Ss[row*33 + 16 + fc] = s1[r2] * 0.08838834764831845f;
      }
    }
    __syncthreads();
    if (t < 64){
      float* row = &Ss[t*33];
      float m = mrow[t];
      #pragma unroll
      for (int i=0;i<32;i++) m = fmaxf(m, row[i]);
      float corr = expf(mrow[t] - m);
      float s = lrow[t] * corr;
      #pragma unroll
      for (int i=0;i<32;i++){ float e = expf(row[i]-m); row[i] = e; s += e; }
      mrow[t] = m; lrow[t] = s; crow[t] = corr;
    }
    __syncthreads();
    {
      float corr = crow[lq];
      #pragma unroll
      for (int j=0;j<16;j++) Oacc[j] *= corr;
      for (int m=0;m<32;m++){
        float pp = Ss[lq*33 + m];
        const float4* vp = reinterpret_cast<const float4*>(&Vs[m*64 + grp*16]);
        float4 v0 = vp[0], v1 = vp[1], v2 = vp[2], v3 = vp[3];
        Oacc[0]+=pp*v0.x; Oacc[1]+=pp*v0.y; Oacc[2]+=pp*v0.z; Oacc[3]+=pp*v0.w;
        Oacc[4]+=pp*v1.x; Oacc[5]+=pp*v1.y; Oacc[6]+=pp*v1.z; Oacc[7]+=pp*v1.w;
        Oacc[8]+=pp*v2.x; Oacc[9]+=pp*v2.y; Oacc[10]+=pp*v2.z; Oacc[11]+=pp*v2.w;
        Oacc[12]+=pp*v3.x; Oacc[13]+=pp*v3.y; Oacc[14]+=pp*v3.z; Oacc[15]+=pp*v3.w;
      }
    }
    __syncthreads();
  }
  float inv = 1.0f / lrow[lq];
  u16* dst = y + (tokbase + qt*64 + lq)*128 + h*64 + grp*16;
  float res[16]; ld8b(dst, res); ld8b(dst+8, res+8);
  float o16[16];
  #pragma unroll
  for (int j=0;j<16;j++) o16[j] = Oacc[j]*inv + res[j];
  st8b(dst, o16); st8b(dst+8, o16+8);
}

// ---------- K_tr: h0/c0 [c][4096] -> hws/Cst [pix][128] fp32 (LDS-tiled transpose) ----------
__global__ __launch_bounds__(256) void k_tr_pc(const void* __restrict__ h0, const void* __restrict__ c0,
                                               float* __restrict__ hws, float* __restrict__ Cst,
                                               const int* __restrict__ flag){
  __shared__ float lds[32][33];
  int t = threadIdx.x, bid = blockIdx.x;
  int sel = bid >> 9, tile = bid & 511;
  int pt2 = tile >> 2, ct = tile & 3;
  const void* src = sel ? c0 : h0;
  float* dst = sel ? Cst : hws;
  int r = t >> 3, q = t & 7;
  {
    int c = ct*32 + r;
    int px = pt2*32 + q*4;
    if (*flag){
      float4 v = *reinterpret_cast<const float4*>((const float*)src + (size_t)c*4096 + px);
      lds[r][q*4+0]=v.x; lds[r][q*4+1]=v.y; lds[r][q*4+2]=v.z; lds[r][q*4+3]=v.w;
    } else {
      uint2 u = *reinterpret_cast<const uint2*>((const u16*)src + (size_t)c*4096 + px);
      lds[r][q*4+0]=b2f_u(u.x & 0xffffu); lds[r][q*4+1]=b2f_u(u.x >> 16);
      lds[r][q*4+2]=b2f_u(u.y & 0xffffu); lds[r][q*4+3]=b2f_u(u.y >> 16);
    }
  }
  __syncthreads();
  {
    int px = pt2*32 + r;
    int c = ct*32 + q*4;
    float4 o;
    o.x = lds[q*4+0][r]; o.y = lds[q*4+1][r]; o.z = lds[q*4+2][r]; o.w = lds[q*4+3][r];
    *reinterpret_cast<float4*>(dst + (size_t)px*128 + c) = o;
  }
}

// ---------- K6: fused LSTM step, register-tiled GEMM + wave softmax ----------
__global__ __launch_bounds__(256) void k_lstm_step(const u16* __restrict__ xD,
    float* __restrict__ hws, float* __restrict__ Cst,
    const float* __restrict__ wx, const float* __restrict__ wh, const float* __restrict__ bh,
    void* __restrict__ dout, int n, const int* __restrict__ flag){
  __shared__ float tile[256*8];      // [k][px]; k<128: x ch, k>=128: h ch
  __shared__ float glds[4*8*132];    // [gate][px][132-padded ch]
  int t = threadIdx.x, bid = blockIdx.x;
  int pix0 = bid*8;
  if (t < 128){
    int px = t >> 4, cg = t & 15;
    float v[8]; ld8b(xD + ((size_t)n*4096 + pix0 + px)*128 + cg*8, v);
    #pragma unroll
    for (int j=0;j<8;j++) tile[(cg*8+j)*8 + px] = v[j];
  } else {
    int t2 = t - 128;
    int px = t2 >> 4, cg = t2 & 15;
    const float4* hp = reinterpret_cast<const float4*>(hws + (size_t)(pix0+px)*128 + cg*8);
    float4 a = hp[0], b = hp[1];
    tile[(128+cg*8+0)*8+px]=a.x; tile[(128+cg*8+1)*8+px]=a.y;
    tile[(128+cg*8+2)*8+px]=a.z; tile[(128+cg*8+3)*8+px]=a.w;
    tile[(128+cg*8+4)*8+px]=b.x; tile[(128+cg*8+5)*8+px]=b.y;
    tile[(128+cg*8+6)*8+px]=b.z; tile[(128+cg*8+7)*8+px]=b.w;
  }
  __syncthreads();
  int w = t >> 6, l = t & 63;
  int ch = l*2;
  float acc[8][2];
  {
    float b0 = bh[w*128 + ch], b1 = bh[w*128 + ch + 1];
    #pragma unroll
    for (int p=0;p<8;p++){ acc[p][0]=b0; acc[p][1]=b1; }
  }
  const float* wxp = wx + w*128 + ch;
  const float* whp = wh + w*128 + ch;
  for (int k=0;k<128;k+=2){
    float2 wa = *reinterpret_cast<const float2*>(wxp + (size_t)k*512);
    float2 wb = *reinterpret_cast<const float2*>(wxp + (size_t)k*512 + 512);
    const float* xr0 = &tile[k*8];
    const float* xr1 = &tile[k*8 + 8];
    #pragma unroll
    for (int p=0;p<8;p++){
      float x0 = xr0[p], x1 = xr1[p];
      acc[p][0] += x0*wa.x; acc[p][1] += x0*wa.y;
      acc[p][0] += x1*wb.x; acc[p][1] += x1*wb.y;
    }
  }
  for (int k=0;k<128;k+=2){
    float2 wa = *reinterpret_cast<const float2*>(whp + (size_t)k*512);
    float2 wb = *reinterpret_cast<const float2*>(whp + (size_t)k*512 + 512);
    const float* xr0 = &tile[(128+k)*8];
    const float* xr1 = &tile[(128+k)*8 + 8];
    #pragma unroll
    for (int p=0;p<8;p++){
      float x0 = xr0[p], x1 = xr1[p];
      acc[p][0] += x0*wa.x; acc[p][1] += x0*wa.y;
      acc[p][0] += x1*wb.x; acc[p][1] += x1*wb.y;
    }
  }
  if (w == 2){
    #pragma unroll
    for (int p=0;p<8;p++){
      float v0 = tanhf(acc[p][0]), v1 = tanhf(acc[p][1]);
      *reinterpret_cast<float2*>(&glds[(w*8+p)*132 + ch]) = make_float2(v0, v1);
    }
  } else {
    #pragma unroll
    for (int p=0;p<8;p++){
      float m2 = fmaxf(acc[p][0], acc[p][1]);
      #pragma unroll
      for (int sft=1; sft<64; sft<<=1) m2 = fmaxf(m2, __shfl_xor(m2, sft));
      float e0 = expf(acc[p][0]-m2), e1 = expf(acc[p][1]-m2);
      float sm = e0 + e1;
      #pragma unroll
      for (int sft=1; sft<64; sft<<=1) sm += __shfl_xor(sm, sft);
      float inv = 1.0f/sm;
      *reinterpret_cast<float2*>(&glds[(w*8+p)*132 + ch]) = make_float2(e0*inv, e1*inv);
    }
  }
  __syncthreads();
  {
    int px = t & 7, ch0 = (t >> 3)*4;
    float4 fv = *reinterpret_cast<const float4*>(&glds[(0*8+px)*132 + ch0]);
    float4 iv = *reinterpret_cast<const float4*>(&glds[(1*8+px)*132 + ch0]);
    float4 sv = *reinterpret_cast<const float4*>(&glds[(2*8+px)*132 + ch0]);
    float4 ov = *reinterpret_cast<const float4*>(&glds[(3*8+px)*132 + ch0]);
    int pix = pix0 + px;
    float4 cold = *reinterpret_cast<const float4*>(Cst + (size_t)pix*128 + ch0);
    float cn[4], hn[4];
    cn[0] = fv.x*cold.x + iv.x*sv.x; hn[0] = ov.x*tanhf(cn[0]);
    cn[1] = fv.y*cold.y + iv.y*sv.y; hn[1] = ov.y*tanhf(cn[1]);
    cn[2] = fv.z*cold.z + iv.z*sv.z; hn[2] = ov.z*tanhf(cn[2]);
    cn[3] = fv.w*cold.w + iv.w*sv.w; hn[3] = ov.w*tanhf(cn[3]);
    *reinterpret_cast<float4*>(Cst + (size_t)pix*128 + ch0) = make_float4(cn[0],cn[1],cn[2],cn[3]);
    *reinterpret_cast<float4*>(hws + (size_t)pix*128 + ch0) = make_float4(hn[0],hn[1],hn[2],hn[3]);
    size_t ob = (size_t)n*524288;
    if (*flag){
      float* df = (float*)dout;
      #pragma unroll
      for (int j=0;j<4;j++) df[ob + (size_t)(ch0+j)*4096 + pix] = hn[j];
    } else {
      u16* db = (u16*)dout;
      #pragma unroll
      for (int j=0;j<4;j++) db[ob + (size_t)(ch0+j)*4096 + pix] = f2b_u(hn[j]);
    }
  }
}

// ---------- K7: final hf, Cf: [pix][128] fp32 -> d_out [c][4096] (tiled transpose, dtype) ----------
__global__ __launch_bounds__(256) void k_final_t(const float* __restrict__ hws, const float* __restrict__ Cst,
                                                 void* __restrict__ dout, const int* __restrict__ flag){
  __shared__ float lds[32][33];
  int t = threadIdx.x, bid = blockIdx.x;
  int sel = bid >> 9, tile = bid & 511;
  int pt2 = tile >> 2, ct = tile & 3;
  const float* src = sel ? Cst : hws;
  size_t base = sel ? 8912896u : 8388608u;
  int r = t >> 3, q = t & 7;
  {
    int px = pt2*32 + r, c = ct*32 + q*4;
    float4 v = *reinterpret_cast<const float4*>(src + (size_t)px*128 + c);
    lds[r][q*4+0]=v.x; lds[r][q*4+1]=v.y; lds[r][q*4+2]=v.z; lds[r][q*4+3]=v.w;
  }
  __syncthreads();
  {
    int c = ct*32 + r, px = pt2*32 + q*4;
    float v0 = lds[q*4+0][r], v1 = lds[q*4+1][r], v2 = lds[q*4+2][r], v3 = lds[q*4+3][r];
    if (*flag){
      *reinterpret_cast<float4*>((float*)dout + base + (size_t)c*4096 + px) = make_float4(v0,v1,v2,v3);
    } else {
      uint2 pk;
      pk.x = (u32)f2b_u(v0) | ((u32)f2b_u(v1) << 16);
      pk.y = (u32)f2b_u(v2) | ((u32)f2b_u(v3) << 16);
      *reinterpret_cast<uint2*>((u16*)dout + base + (size_t)c*4096 + px) = pk;
    }
  }
}

extern "C" void kernel_launch(void* const* d_in, const int* in_sizes, int n_in,
                              void* d_out, int out_size, void* d_ws, size_t ws_size,
                              hipStream_t stream) {
  const void* x      = d_in[0];
  const void* h0     = d_in[1];
  const void* c0     = d_in[2];
  const void* conv_w = d_in[3];
  const void* conv_b = d_in[4];
  const void* qkv1_w = d_in[5];
  const void* qkv1_b = d_in[6];
  const void* m1w1   = d_in[7];
  const void* m1b1   = d_in[8];
  const void* m1w2   = d_in[9];
  const void* m1b2   = d_in[10];
  const void* qkv2_w = d_in[11];
  const void* qkv2_b = d_in[12];
  const void* m2w1   = d_in[13];
  const void* m2b1   = d_in[14];
  const void* m2w2   = d_in[15];
  const void* m2b2   = d_in[16];
  const void* lwx    = d_in[17];
  const void* lwh    = d_in[18];
  const void* lbh    = d_in[19];

  char* p = (char*)d_ws;
  auto alloc = [&](size_t bytes)->void*{
    void* r = (void*)p; p += (bytes + 255) & ~(size_t)255; return r;
  };
  int*   flag    = (int*)alloc(256);
  u16* wB_conv = (u16*)alloc(128*512*2);       // bf16, native [co][ci*4+ky*2+kx]
  u16* wB_qkv1 = (u16*)alloc(384*128*2);       // bf16, original [o][k]
  u16* wB_m1a  = (u16*)alloc(512*128*2);
  u16* wB_m1b  = (u16*)alloc(128*512*2);
  u16* wB_qkv2 = (u16*)alloc(384*128*2);
  u16* wB_m2a  = (u16*)alloc(512*128*2);
  u16* wB_m2b  = (u16*)alloc(128*512*2);
  float* wT_lx   = (float*)alloc(128*512*4);   // transposed [k][512] fp32
  float* wT_lh   = (float*)alloc(128*512*4);
  float* bf_conv = (float*)alloc(128*4);
  float* bf_qkv1 = (float*)alloc(384*4);
  float* bf_m1b1 = (float*)alloc(512*4);
  float* bf_m1b2 = (float*)alloc(128*4);
  float* bf_qkv2 = (float*)alloc(384*4);
  float* bf_m2b1 = (float*)alloc(512*4);
  float* bf_m2b2 = (float*)alloc(128*4);
  float* bf_lbh  = (float*)alloc(512*4);
  u16* R0   = (u16*)alloc(16777216);   // bufA -> bufC/y -> (hws, Cst)
  u16* Rbig = (u16*)alloc(33554432);   // bufB (front) -> kvbuf -> bufD (front)

  u16* bufA = R0;
  u16* bufB = Rbig;
  u16* bufC = R0;          // also y (attn writes in place)
  u16* qbuf = (u16*)d_out; // hs region used as scratch; dead before first LSTM write
  u16* kvbuf = Rbig;
  u16* bufD = Rbig;
  float* hws = (float*)((char*)R0 + 8388608);         // 2 MB, [pix][128]
  float* Cst = (float*)((char*)R0 + 10485760);        // 2 MB, [pix][128]

  k_detect<<<1, 256, 0, stream>>>((const u32*)x, flag);

  auto T = [&](const void* in, float* o, int O, int K){
    int n = O*K;
    k_transpose<<<(n+255)/256, 256, 0, stream>>>(in, o, O, K, flag);
  };
  T(lwx,    wT_lx,   512, 128);
  T(lwh,    wT_lh,   512, 128);

  auto V = [&](const void* in, float* o, int n){
    k_cvtvec<<<(n+255)/256, 256, 0, stream>>>(in, o, n, flag);
  };
  V(conv_b, bf_conv, 128);
  V(qkv1_b, bf_qkv1, 384);
  V(m1b1,   bf_m1b1, 512);
  V(m1b2,   bf_m1b2, 128);
  V(qkv2_b, bf_qkv2, 384);
  V(m2b1,   bf_m2b1, 512);
  V(m2b2,   bf_m2b2, 128);
  V(lbh,    bf_lbh,  512);

  auto Wb = [&](const void* in, u16* o, int n){
    k_cvtb16<<<(n+255)/256, 256, 0, stream>>>(in, o, n, flag);
  };
  Wb(conv_w, wB_conv, 128*512);
  Wb(qkv1_w, wB_qkv1, 384*128);
  Wb(m1w1,   wB_m1a,  512*128);
  Wb(m1w2,   wB_m1b,  128*512);
  Wb(qkv2_w, wB_qkv2, 384*128);
  Wb(m2w1,   wB_m2a,  512*128);
  Wb(m2w2,   wB_m2b,  128*512);

  k_conv<<<4096, 256, 0, stream>>>(x, wB_conv, bf_conv, bufA, flag);
  k_msa1<<<4096, 256, 0, stream>>>(bufA, wB_qkv1, bf_qkv1, bufB);
  k_mlp<1><<<4096, 256, 0, stream>>>(bufB, wB_m1a, bf_m1b1, wB_m1b, bf_m1b2, bufC);
  k_qkv2<<<4096, 256, 0, stream>>>(bufC, wB_qkv2, bf_qkv2, qbuf, kvbuf);
  k_attn2<<<2048, 256, 0, stream>>>(qbuf, kvbuf, bufC);          // y = x + attn, in place
  k_mlp<2><<<4096, 256, 0, stream>>>(bufC, wB_m2a, bf_m2b1, wB_m2b, bf_m2b2, bufD);

  k_tr_pc<<<1024, 256, 0, stream>>>(h0, c0, hws, Cst, flag);
  for (int n = 0; n < 16; n++){
    k_lstm_step<<<512, 256, 0, stream>>>(bufD, hws, Cst, wT_lx, wT_lh, bf_lbh, d_out, n, flag);
  }
  k_final_t<<<1024, 256, 0, stream>>>(hws, Cst, d_out, flag);
}

// Round 7
// 1126.111 us; speedup vs baseline: 6.6265x; 1.0822x over previous
//
#include <hip/hip_runtime.h>
#include <hip/hip_bf16.h>

typedef unsigned int u32;
typedef unsigned short u16;

#define DI __device__ __forceinline__

typedef __attribute__((ext_vector_type(8))) __bf16 bf16x8;
typedef __attribute__((ext_vector_type(4))) float f32x4;

// ---------- bf16 helpers (bf16 == fp32 high 16 bits; RNE on store) ----------
DI float b2f_u(u32 u){ return __uint_as_float(u << 16); }
DI u16 f2b_u(float f){
  u32 x = __float_as_uint(f);
  x += 0x7fffu + ((x >> 16) & 1u);
  return (u16)(x >> 16);
}
DI void ld8b(const u16* p, float* o){
  uint4 v = *reinterpret_cast<const uint4*>(p);
  o[0] = b2f_u(v.x & 0xffffu); o[1] = b2f_u(v.x >> 16);
  o[2] = b2f_u(v.y & 0xffffu); o[3] = b2f_u(v.y >> 16);
  o[4] = b2f_u(v.z & 0xffffu); o[5] = b2f_u(v.z >> 16);
  o[6] = b2f_u(v.w & 0xffffu); o[7] = b2f_u(v.w >> 16);
}
DI void st8b(u16* p, const float* i){
  uint4 v;
  v.x = (u32)f2b_u(i[0]) | ((u32)f2b_u(i[1]) << 16);
  v.y = (u32)f2b_u(i[2]) | ((u32)f2b_u(i[3]) << 16);
  v.z = (u32)f2b_u(i[4]) | ((u32)f2b_u(i[5]) << 16);
  v.w = (u32)f2b_u(i[6]) | ((u32)f2b_u(i[7]) << 16);
  *reinterpret_cast<uint4*>(p) = v;
}

// ---------- K_detect: is d_in fp32 (flag=1) or packed bf16 (flag=0)? ----------
__global__ void k_detect(const u32* __restrict__ xw, int* __restrict__ flag){
  __shared__ int cnt;
  int t = threadIdx.x;
  if (t == 0) cnt = 0;
  __syncthreads();
  int c = 0;
  for (int i = t; i < 2048; i += 256){
    u32 lo = xw[i] & 0xffffu;
    u32 e = (lo >> 7) & 0xffu;
    if (e < 100u || e > 140u) c++;
  }
  atomicAdd(&cnt, c);
  __syncthreads();
  if (t == 0) *flag = (cnt > 200) ? 1 : 0;
}

// ---------- K_prep: ALL weight/bias conversions in ONE launch ----------
// [0,256)    conv_w  -> wB_conv  bf16 copy (65536)
// [256,448)  qkv1_w  -> wB_qkv1  (49152)
// [448,704)  m1w1    -> wB_m1a   (65536)
// [704,960)  m1w2    -> wB_m1b   (65536)
// [960,1152) qkv2_w  -> wB_qkv2  (49152)
// [1152,1408) m2w1   -> wB_m2a   (65536)
// [1408,1664) m2w2   -> wB_m2b   (65536)
// [1664,1920) lwx    -> wT_lx  fp32 transpose O=512 K=128 (65536)
// [1920,2176) lwh    -> wT_lh  (65536)
// [2176,2187) biases concatenated (2688)
__global__ void k_prep(
  const void* __restrict__ conv_w, const void* __restrict__ qkv1_w,
  const void* __restrict__ m1w1, const void* __restrict__ m1w2,
  const void* __restrict__ qkv2_w, const void* __restrict__ m2w1, const void* __restrict__ m2w2,
  const void* __restrict__ lwx, const void* __restrict__ lwh,
  const void* __restrict__ conv_b, const void* __restrict__ qkv1_b,
  const void* __restrict__ m1b1, const void* __restrict__ m1b2,
  const void* __restrict__ qkv2_b, const void* __restrict__ m2b1, const void* __restrict__ m2b2,
  const void* __restrict__ lbh,
  u16* __restrict__ wB_conv, u16* __restrict__ wB_qkv1, u16* __restrict__ wB_m1a,
  u16* __restrict__ wB_m1b, u16* __restrict__ wB_qkv2, u16* __restrict__ wB_m2a,
  u16* __restrict__ wB_m2b,
  float* __restrict__ wT_lx, float* __restrict__ wT_lh,
  float* __restrict__ bf_conv, float* __restrict__ bf_qkv1, float* __restrict__ bf_m1b1,
  float* __restrict__ bf_m1b2, float* __restrict__ bf_qkv2, float* __restrict__ bf_m2b1,
  float* __restrict__ bf_m2b2, float* __restrict__ bf_lbh,
  const int* __restrict__ flag){
  int bid = blockIdx.x, t = threadIdx.x;
  int fl = *flag;
  auto cvb = [&](const void* s, u16* d, int base, int n){
    int i = (bid - base)*256 + t;
    if (i < n) d[i] = fl ? f2b_u(((const float*)s)[i]) : ((const u16*)s)[i];
  };
  auto ldf = [&](const void* s, int i)->float{
    return fl ? ((const float*)s)[i] : b2f_u((u32)((const u16*)s)[i]);
  };
  if (bid < 256)       cvb(conv_w, wB_conv, 0,    65536);
  else if (bid < 448)  cvb(qkv1_w, wB_qkv1, 256,  49152);
  else if (bid < 704)  cvb(m1w1,   wB_m1a,  448,  65536);
  else if (bid < 960)  cvb(m1w2,   wB_m1b,  704,  65536);
  else if (bid < 1152) cvb(qkv2_w, wB_qkv2, 960,  49152);
  else if (bid < 1408) cvb(m2w1,   wB_m2a,  1152, 65536);
  else if (bid < 1664) cvb(m2w2,   wB_m2b,  1408, 65536);
  else if (bid < 1920){
    int idx = (bid - 1664)*256 + t;       // out [k][512]
    int o = idx & 511, k = idx >> 9;
    wT_lx[idx] = ldf(lwx, o*128 + k);
  } else if (bid < 2176){
    int idx = (bid - 1920)*256 + t;
    int o = idx & 511, k = idx >> 9;
    wT_lh[idx] = ldf(lwh, o*128 + k);
  } else {
    int i = (bid - 2176)*256 + t;
    if (i < 128)       bf_conv[i]        = ldf(conv_b, i);
    else if (i < 512)  bf_qkv1[i-128]    = ldf(qkv1_b, i-128);
    else if (i < 1024) bf_m1b1[i-512]    = ldf(m1b1,   i-512);
    else if (i < 1152) bf_m1b2[i-1024]   = ldf(m1b2,   i-1024);
    else if (i < 1536) bf_qkv2[i-1152]   = ldf(qkv2_b, i-1152);
    else if (i < 2048) bf_m2b1[i-1536]   = ldf(m2b1,   i-1536);
    else if (i < 2176) bf_m2b2[i-2048]   = ldf(m2b2,   i-2048);
    else if (i < 2688) bf_lbh[i-2176]    = ldf(lbh,    i-2176);
  }
}

// ---------- K1: conv 2x2 stride 2 + window partition via MFMA -> bufA [b][g][l][c] ----------
__global__ __launch_bounds__(256) void k_conv(const void* __restrict__ x_raw,
                                              const u16* __restrict__ wB,
                                              const float* __restrict__ bias, u16* __restrict__ outA,
                                              const int* __restrict__ flag){
  __shared__ u16 Xa[16*520];     // A: [tok][520-pad k], 16.6 KB
  __shared__ u16 Ys[16*136];     // output staging, 4.3 KB
  int t = threadIdx.x, bid = blockIdx.x;
  int xcd = bid & 7, slot = bid >> 3;
  int gIn = slot >> 2, sub = slot & 3;
  int group = gIn*8 + xcd;               // 0..1023, bijective
  int b = group >> 6, yg = (group >> 2) & 15, xgHi = group & 3;
  int xg = xgHi*4 + sub;
  int g = yg*16 + xg;
  size_t base = (size_t)b*2097152 + (size_t)(yg*8)*128 + (size_t)xg*8;
  if (*flag){
    const float* xb = (const float*)x_raw + base;
    #pragma unroll
    for (int i=0;i<4;i++){
      int idx = i*256 + t;
      int ci = idx >> 3, py = idx & 7;
      const float4* s4 = reinterpret_cast<const float4*>(xb + (size_t)ci*16384 + py*128);
      float4 v0 = s4[0], v1 = s4[1];
      int l0 = (py>>1)*4, k0 = ci*4 + (py&1)*2;
      *reinterpret_cast<u32*>(&Xa[(l0+0)*520 + k0]) = (u32)f2b_u(v0.x) | ((u32)f2b_u(v0.y)<<16);
      *reinterpret_cast<u32*>(&Xa[(l0+1)*520 + k0]) = (u32)f2b_u(v0.z) | ((u32)f2b_u(v0.w)<<16);
      *reinterpret_cast<u32*>(&Xa[(l0+2)*520 + k0]) = (u32)f2b_u(v1.x) | ((u32)f2b_u(v1.y)<<16);
      *reinterpret_cast<u32*>(&Xa[(l0+3)*520 + k0]) = (u32)f2b_u(v1.z) | ((u32)f2b_u(v1.w)<<16);
    }
  } else {
    const u16* xb = (const u16*)x_raw + base;
    #pragma unroll
    for (int i=0;i<4;i++){
      int idx = i*256 + t;
      int ci = idx >> 3, py = idx & 7;
      uint4 v = *reinterpret_cast<const uint4*>(xb + (size_t)ci*16384 + py*128);
      int l0 = (py>>1)*4, k0 = ci*4 + (py&1)*2;
      *reinterpret_cast<u32*>(&Xa[(l0+0)*520 + k0]) = v.x;
      *reinterpret_cast<u32*>(&Xa[(l0+1)*520 + k0]) = v.y;
      *reinterpret_cast<u32*>(&Xa[(l0+2)*520 + k0]) = v.z;
      *reinterpret_cast<u32*>(&Xa[(l0+3)*520 + k0]) = v.w;
    }
  }
  __syncthreads();
  int w = t >> 6, lane = t & 63, fr = lane & 15, fg = lane >> 4;
  bf16x8 a[16];
  #pragma unroll
  for (int c=0;c<16;c++) a[c] = *reinterpret_cast<const bf16x8*>(&Xa[fr*520 + c*32 + fg*8]);
  #pragma unroll
  for (int j=0;j<2;j++){
    int o = w*32 + j*16 + fr;          // 0..127
    float bv = bias[o];
    f32x4 d = {bv,bv,bv,bv};
    const u16* wp = wB + (size_t)o*512 + fg*8;
    #pragma unroll
    for (int c=0;c<16;c++){
      bf16x8 bb = *reinterpret_cast<const bf16x8*>(wp + c*32);
      d = __builtin_amdgcn_mfma_f32_16x16x32_bf16(a[c], bb, d, 0, 0, 0);
    }
    #pragma unroll
    for (int r=0;r<4;r++) Ys[(fg*4+r)*136 + o] = f2b_u(d[r]);
  }
  __syncthreads();
  {
    int tok = t >> 4, c0 = (t & 15)*8;
    uint4 v = *reinterpret_cast<const uint4*>(&Ys[tok*136 + c0]);
    size_t T = ((size_t)(b*256 + g)*16 + tok);
    *reinterpret_cast<uint4*>(outA + T*128 + c0) = v;
  }
}

// ---------- K2: LocalMSA (L=16) + residual: bufA -> bufB (same layout) ----------
__global__ __launch_bounds__(256) void k_msa1(const u16* __restrict__ A, const u16* __restrict__ wB,
                                              const float* __restrict__ qbias, u16* __restrict__ B){
  __shared__ u16 Xs[16*136];        // bf16, row stride 272 B
  __shared__ float QKV[16*388];
  __shared__ float S[512];          // [h][l][m]
  int t = threadIdx.x, bid = blockIdx.x;
  {
    int l = t >> 4, c0 = (t & 15)*8;
    *reinterpret_cast<uint4*>(&Xs[l*136 + c0]) =
      *reinterpret_cast<const uint4*>(A + (size_t)bid*2048 + l*128 + c0);
  }
  __syncthreads();
  {
    int w = t >> 6, lane = t & 63, fr = lane & 15, fg = lane >> 4;
    bf16x8 a[4];
    #pragma unroll
    for (int k=0;k<4;k++) a[k] = *reinterpret_cast<const bf16x8*>(&Xs[fr*136 + k*32 + fg*8]);
    #pragma unroll
    for (int j=0;j<6;j++){
      int o = w*96 + j*16 + fr;          // 0..383
      float bv = qbias[o];
      f32x4 d = {bv,bv,bv,bv};
      const u16* wp = wB + (size_t)o*128 + fg*8;
      #pragma unroll
      for (int k=0;k<4;k++){
        bf16x8 b = *reinterpret_cast<const bf16x8*>(wp + k*32);
        d = __builtin_amdgcn_mfma_f32_16x16x32_bf16(a[k], b, d, 0, 0, 0);
      }
      #pragma unroll
      for (int r=0;r<4;r++) QKV[(fg*4+r)*388 + o] = d[r];
    }
  }
  __syncthreads();
  const float scale = 0.08838834764831845f;   // 1/sqrt(128)
  for (int e = t; e < 512; e += 256){
    int h = e >> 8, l = (e>>4)&15, m = e&15;
    const float* q = &QKV[l*388 + h*64];
    const float* kk = &QKV[m*388 + 128 + h*64];
    float s = 0.f;
    #pragma unroll
    for (int d=0; d<64; d++) s += q[d]*kk[d];
    S[(h*16+l)*16 + m] = s*scale;
  }
  __syncthreads();
  if (t < 32){
    float* row = &S[t*16];
    float mx = row[0];
    #pragma unroll
    for (int m=1;m<16;m++) mx = fmaxf(mx,row[m]);
    float sum = 0.f;
    #pragma unroll
    for (int m=0;m<16;m++){ float e = expf(row[m]-mx); row[m]=e; sum+=e; }
    float inv = 1.0f/sum;
    #pragma unroll
    for (int m=0;m<16;m++) row[m] *= inv;
  }
  __syncthreads();
  {
    int l = t >> 4, og = t & 15, o0 = og*8;
    int h = o0 >> 6;
    const float* p = &S[(h*16+l)*16];
    float out8[8];
    #pragma unroll
    for (int j=0;j<8;j++){
      int o = o0+j, d = o & 63;
      float s = 0.f;
      #pragma unroll
      for (int m=0;m<16;m++) s += p[m]*QKV[m*388 + 256 + h*64 + d];
      out8[j] = s + b2f_u((u32)Xs[l*136 + o]);
    }
    st8b(B + (size_t)bid*2048 + l*128 + o0, out8);
  }
}

// ---------- K3/K5: MLP (+residual) via MFMA (bf16 in/weights, fp32 accum). ----------
template<int MODE>
__global__ __launch_bounds__(256) void k_mlp(const u16* __restrict__ in,
    const u16* __restrict__ w1B, const float* __restrict__ b1,
    const u16* __restrict__ w2B, const float* __restrict__ b2,
    u16* __restrict__ out){
  __shared__ u16 Xs[16*136];        // bf16 input (also residual), 272 B rows
  __shared__ u16 Hs[16*520];        // bf16 hidden, 1040 B rows
  __shared__ u16 Ys[16*136];        // bf16 output staging
  int t = threadIdx.x, bid = blockIdx.x;
  {
    int l = t >> 4, c0 = (t & 15)*8;
    *reinterpret_cast<uint4*>(&Xs[l*136 + c0]) =
      *reinterpret_cast<const uint4*>(in + (size_t)bid*2048 + l*128 + c0);
  }
  __syncthreads();
  int w = t >> 6, lane = t & 63, fr = lane & 15, fg = lane >> 4;

  // ---- GEMM1: H = gelu(X @ W1^T + b1); wave handles 8 n-tiles of 16 ----
  {
    bf16x8 a[4];
    #pragma unroll
    for (int k=0;k<4;k++) a[k] = *reinterpret_cast<const bf16x8*>(&Xs[fr*136 + k*32 + fg*8]);
    #pragma unroll
    for (int j=0;j<8;j++){
      int o = w*128 + j*16 + fr;        // 0..511
      float bv = b1[o];
      f32x4 d = {bv,bv,bv,bv};
      const u16* wp = w1B + (size_t)o*128 + fg*8;
      #pragma unroll
      for (int k=0;k<4;k++){
        bf16x8 b = *reinterpret_cast<const bf16x8*>(wp + k*32);
        d = __builtin_amdgcn_mfma_f32_16x16x32_bf16(a[k], b, d, 0, 0, 0);
      }
      #pragma unroll
      for (int r=0;r<4;r++){
        float v = d[r];
        float g = 0.5f*v*(1.0f + erff(v*0.70710678118654752f));
        Hs[(fg*4+r)*520 + o] = f2b_u(g);
      }
    }
  }
  __syncthreads();

  // ---- GEMM2: Y = H @ W2^T + b2 + X; wave handles 2 n-tiles of 16 ----
  {
    int na = w*32 + fr, nb = na + 16;   // 0..127
    float ba = b2[na], bb = b2[nb];
    f32x4 d0 = {ba,ba,ba,ba}, d1 = {bb,bb,bb,bb};
    const u16* wpa = w2B + (size_t)na*512 + fg*8;
    const u16* wpb = w2B + (size_t)nb*512 + fg*8;
    #pragma unroll
    for (int k=0;k<16;k++){
      bf16x8 a = *reinterpret_cast<const bf16x8*>(&Hs[fr*520 + k*32 + fg*8]);
      bf16x8 bA = *reinterpret_cast<const bf16x8*>(wpa + k*32);
      bf16x8 bBv = *reinterpret_cast<const bf16x8*>(wpb + k*32);
      d0 = __builtin_amdgcn_mfma_f32_16x16x32_bf16(a, bA, d0, 0, 0, 0);
      d1 = __builtin_amdgcn_mfma_f32_16x16x32_bf16(a, bBv, d1, 0, 0, 0);
    }
    #pragma unroll
    for (int r=0;r<4;r++){
      int tok = fg*4 + r;
      float y0 = d0[r] + b2f_u((u32)Xs[tok*136 + na]);
      float y1 = d1[r] + b2f_u((u32)Xs[tok*136 + nb]);
      Ys[tok*136 + na] = f2b_u(y0);
      Ys[tok*136 + nb] = f2b_u(y1);
    }
  }
  __syncthreads();

  // ---- coalesced store with layout mapping ----
  {
    int tok = t >> 4, oc = (t & 15)*8;
    uint4 v = *reinterpret_cast<const uint4*>(&Ys[tok*136 + oc]);
    int T = bid*16 + tok;
    size_t addr;
    if (MODE == 1){
      int b = T >> 12, g = (T >> 4) & 255, ll = T & 15;
      addr = ((size_t)((b*16 + ll)*256 + g))*128 + oc;
    } else {
      int b = T >> 12, ll = (T >> 8) & 15, g = T & 255;
      int pcoord = ((g >> 4)*4 + (ll >> 2))*64 + ((g & 15)*4 + (ll & 3));
      addr = ((size_t)(b*4096 + pcoord))*128 + oc;
    }
    *reinterpret_cast<uint4*>(out + addr) = v;
  }
}

// ---------- K4a: QKV projection for DilatedMSA via MFMA ----------
__global__ __launch_bounds__(256) void k_qkv2(const u16* __restrict__ in, const u16* __restrict__ wB,
                                              const float* __restrict__ bias,
                                              u16* __restrict__ qbuf, u16* __restrict__ kvbuf){
  __shared__ u16 Xs[16*136];
  __shared__ u16 Qs[16*392];        // bf16 [tok][384+pad]
  int t = threadIdx.x, bid = blockIdx.x;
  {
    int l = t >> 4, c0 = (t & 15)*8;
    *reinterpret_cast<uint4*>(&Xs[l*136 + c0]) =
      *reinterpret_cast<const uint4*>(in + (size_t)bid*2048 + l*128 + c0);
  }
  __syncthreads();
  {
    int w = t >> 6, lane = t & 63, fr = lane & 15, fg = lane >> 4;
    bf16x8 a[4];
    #pragma unroll
    for (int k=0;k<4;k++) a[k] = *reinterpret_cast<const bf16x8*>(&Xs[fr*136 + k*32 + fg*8]);
    #pragma unroll
    for (int j=0;j<6;j++){
      int o = w*96 + j*16 + fr;          // 0..383
      float bv = bias[o];
      f32x4 d = {bv,bv,bv,bv};
      const u16* wp = wB + (size_t)o*128 + fg*8;
      #pragma unroll
      for (int k=0;k<4;k++){
        bf16x8 b = *reinterpret_cast<const bf16x8*>(wp + k*32);
        d = __builtin_amdgcn_mfma_f32_16x16x32_bf16(a[k], b, d, 0, 0, 0);
      }
      #pragma unroll
      for (int r=0;r<4;r++) Qs[(fg*4+r)*392 + o] = f2b_u(d[r]);
    }
  }
  __syncthreads();
  {
    int l = t >> 4, og = t & 15, o0 = og*24;
    size_t tok = (size_t)bid*16 + l;
    #pragma unroll
    for (int m=0; m<3; m++){
      int oc = o0 + m*8;
      uint4 v = *reinterpret_cast<const uint4*>(&Qs[l*392 + oc]);
      if (oc < 128) *reinterpret_cast<uint4*>(qbuf + tok*128 + oc) = v;
      else          *reinterpret_cast<uint4*>(kvbuf + tok*256 + (oc-128)) = v;
    }
  }
}

// ---------- K4b: DilatedMSA flash attention, full-MFMA (QK^T and PV), in-register softmax ----------
// y = x + attn IN PLACE over bufC. Wave w owns q-tile w (16 q rows); m/l/corr live in
// registers (replicated across the 16 fc lanes via shfl_xor butterfly).
__global__ __launch_bounds__(256) void k_attn2(const u16* __restrict__ qbuf, const u16* __restrict__ kvbuf,
                                               u16* __restrict__ y){
  __shared__ __align__(16) char pool[24064];
  u16* Qb = (u16*)pool;              // [64][72] bf16
  u16* Kb = (u16*)(pool + 9216);     // [32][72] bf16
  u16* Vt = (u16*)(pool + 13824);    // [64 d][40 kt] bf16 (transposed V)
  u16* Pb = (u16*)(pool + 18944);    // [64 q][40 kt] bf16
  float* Os = (float*)pool;          // [64][68] f32, overlays Qb/Kb/Vt after loop

  int t = threadIdx.x, bid = blockIdx.x;
  int qt = bid & 3, h = (bid >> 2) & 1, bl = bid >> 3;
  size_t tokbase = (size_t)bl * 256;
  {
    int r = t >> 2, seg = t & 3;
    const u16* src = qbuf + (tokbase + qt*64 + r)*128 + h*64 + seg*16;
    uint4 v0 = *reinterpret_cast<const uint4*>(src);
    uint4 v1 = *reinterpret_cast<const uint4*>(src + 8);
    *reinterpret_cast<uint4*>(&Qb[r*72 + seg*16])     = v0;
    *reinterpret_cast<uint4*>(&Qb[r*72 + seg*16 + 8]) = v1;
  }
  int w = t >> 6, lane = t & 63;
  int fc = lane & 15, fg = lane >> 4;
  float m_reg[4], l_reg[4];
  #pragma unroll
  for (int r=0;r<4;r++){ m_reg[r] = -1e30f; l_reg[r] = 0.0f; }
  f32x4 o[4];
  #pragma unroll
  for (int j=0;j<4;j++) o[j] = {0.f,0.f,0.f,0.f};
  const float scale = 0.08838834764831845f;

  for (int kt=0; kt<8; kt++){
    {  // stage K rows (bf16)
      int r = t >> 3, seg = t & 7;
      const u16* base = kvbuf + (tokbase + kt*32 + r)*256 + h*64;
      *reinterpret_cast<uint4*>(&Kb[r*72 + seg*8]) = *reinterpret_cast<const uint4*>(base + seg*8);
    }
    {  // stage V transposed: thread = (token-pair pp, d-group dg)
      int pp = t >> 4, dg = t & 15, d0 = dg*4;
      const u16* b0 = kvbuf + (tokbase + kt*32 + 2*pp)*256 + h*64 + 128 + d0;
      uint2 v0 = *reinterpret_cast<const uint2*>(b0);
      uint2 v1 = *reinterpret_cast<const uint2*>(b0 + 256);
      *reinterpret_cast<u32*>(&Vt[(d0+0)*40 + 2*pp]) = (v0.x & 0xffffu) | (v1.x << 16);
      *reinterpret_cast<u32*>(&Vt[(d0+1)*40 + 2*pp]) = (v0.x >> 16) | (v1.x & 0xffff0000u);
      *reinterpret_cast<u32*>(&Vt[(d0+2)*40 + 2*pp]) = (v0.y & 0xffffu) | (v1.y << 16);
      *reinterpret_cast<u32*>(&Vt[(d0+3)*40 + 2*pp]) = (v0.y >> 16) | (v1.y & 0xffff0000u);
    }
    __syncthreads();
    // QK^T mfma: S[q = w*16 + fg*4 + r][kt-col = fc (s0) / 16+fc (s1)]
    f32x4 s0 = {0.f,0.f,0.f,0.f}, s1 = {0.f,0.f,0.f,0.f};
    {
      bf16x8 a0  = *reinterpret_cast<const bf16x8*>(&Qb[(w*16+fc)*72 + fg*8]);
      bf16x8 a1  = *reinterpret_cast<const bf16x8*>(&Qb[(w*16+fc)*72 + 32 + fg*8]);
      bf16x8 b00 = *reinterpret_cast<const bf16x8*>(&Kb[fc*72 + fg*8]);
      bf16x8 b01 = *reinterpret_cast<const bf16x8*>(&Kb[fc*72 + 32 + fg*8]);
      bf16x8 b10 = *reinterpret_cast<const bf16x8*>(&Kb[(16+fc)*72 + fg*8]);
      bf16x8 b11 = *reinterpret_cast<const bf16x8*>(&Kb[(16+fc)*72 + 32 + fg*8]);
      s0 = __builtin_amdgcn_mfma_f32_16x16x32_bf16(a0, b00, s0, 0, 0, 0);
      s0 = __builtin_amdgcn_mfma_f32_16x16x32_bf16(a1, b01, s0, 0, 0, 0);
      s1 = __builtin_amdgcn_mfma_f32_16x16x32_bf16(a0, b10, s1, 0, 0, 0);
      s1 = __builtin_amdgcn_mfma_f32_16x16x32_bf16(a1, b11, s1, 0, 0, 0);
    }
    // in-register online softmax (butterfly over the 16 fc lanes)
    float corr[4];
    #pragma unroll
    for (int r=0;r<4;r++){
      float v0 = s0[r]*scale, v1 = s1[r]*scale;
      float mx = fmaxf(v0, v1);
      mx = fmaxf(mx, __shfl_xor(mx, 1));
      mx = fmaxf(mx, __shfl_xor(mx, 2));
      mx = fmaxf(mx, __shfl_xor(mx, 4));
      mx = fmaxf(mx, __shfl_xor(mx, 8));
      float mnew = fmaxf(m_reg[r], mx);
      corr[r] = expf(m_reg[r] - mnew);
      m_reg[r] = mnew;
      float p0 = expf(v0 - mnew), p1 = expf(v1 - mnew);
      float sum = p0 + p1;
      sum += __shfl_xor(sum, 1);
      sum += __shfl_xor(sum, 2);
      sum += __shfl_xor(sum, 4);
      sum += __shfl_xor(sum, 8);
      l_reg[r] = l_reg[r]*corr[r] + sum;
      int row = w*16 + fg*4 + r;
      Pb[row*40 + fc]      = f2b_u(p0);
      Pb[row*40 + 16 + fc] = f2b_u(p1);
    }
    // PV mfma: O[q][d] += P[q][kt] V[kt][d]; A = Pb (own wave rows), B = Vt
    {
      bf16x8 pa = *reinterpret_cast<const bf16x8*>(&Pb[(w*16+fc)*40 + fg*8]);
      #pragma unroll
      for (int jt=0;jt<4;jt++){
        bf16x8 vb = *reinterpret_cast<const bf16x8*>(&Vt[(jt*16+fc)*40 + fg*8]);
        f32x4 oo = o[jt];
        oo[0] *= corr[0]; oo[1] *= corr[1]; oo[2] *= corr[2]; oo[3] *= corr[3];
        o[jt] = __builtin_amdgcn_mfma_f32_16x16x32_bf16(pa, vb, oo, 0, 0, 0);
      }
    }
    __syncthreads();
  }
  // normalize + stage O (overlays Qb/Kb/Vt; safe after final barrier)
  float inv[4];
  #pragma unroll
  for (int r=0;r<4;r++) inv[r] = 1.0f / l_reg[r];
  #pragma unroll
  for (int jt=0;jt<4;jt++){
    #pragma unroll
    for (int r=0;r<4;r++)
      Os[(w*16 + fg*4 + r)*68 + jt*16 + fc] = o[jt][r] * inv[r];
  }
  __syncthreads();
  // coalesced readout + residual
  {
    int row = t >> 2, seg = t & 3;
    float ov[16];
    #pragma unroll
    for (int j=0;j<16;j++) ov[j] = Os[row*68 + seg*16 + j];
    u16* dst = y + (tokbase + qt*64 + row)*128 + h*64 + seg*16;
    float res[16]; ld8b(dst, res); ld8b(dst+8, res+8);
    float o16[16];
    #pragma unroll
    for (int j=0;j<16;j++) o16[j] = ov[j] + res[j];
    st8b(dst, o16); st8b(dst+8, o16+8);
  }
}

// ---------- K_tr: h0/c0 [c][4096] -> hws/Cst [pix][128] fp32 (LDS-tiled transpose) ----------
__global__ __launch_bounds__(256) void k_tr_pc(const void* __restrict__ h0, const void* __restrict__ c0,
                                               float* __restrict__ hws, float* __restrict__ Cst,
                                               const int* __restrict__ flag){
  __shared__ float lds[32][33];
  int t = threadIdx.x, bid = blockIdx.x;
  int sel = bid >> 9, tile = bid & 511;
  int pt2 = tile >> 2, ct = tile & 3;
  const void* src = sel ? c0 : h0;
  float* dst = sel ? Cst : hws;
  int r = t >> 3, q = t & 7;
  {
    int c = ct*32 + r;
    int px = pt2*32 + q*4;
    if (*flag){
      float4 v = *reinterpret_cast<const float4*>((const float*)src + (size_t)c*4096 + px);
      lds[r][q*4+0]=v.x; lds[r][q*4+1]=v.y; lds[r][q*4+2]=v.z; lds[r][q*4+3]=v.w;
    } else {
      uint2 u = *reinterpret_cast<const uint2*>((const u16*)src + (size_t)c*4096 + px);
      lds[r][q*4+0]=b2f_u(u.x & 0xffffu); lds[r][q*4+1]=b2f_u(u.x >> 16);
      lds[r][q*4+2]=b2f_u(u.y & 0xffffu); lds[r][q*4+3]=b2f_u(u.y >> 16);
    }
  }
  __syncthreads();
  {
    int px = pt2*32 + r;
    int c = ct*32 + q*4;
    float4 o;
    o.x = lds[q*4+0][r]; o.y = lds[q*4+1][r]; o.z = lds[q*4+2][r]; o.w = lds[q*4+3][r];
    *reinterpret_cast<float4*>(dst + (size_t)px*128 + c) = o;
  }
}

// ---------- K6: fused LSTM step, register-tiled GEMM + wave softmax ----------
__global__ __launch_bounds__(256) void k_lstm_step(const u16* __restrict__ xD,
    float* __restrict__ hws, float* __restrict__ Cst,
    const float* __restrict__ wx, const float* __restrict__ wh, const float* __restrict__ bh,
    void* __restrict__ dout, int n, const int* __restrict__ flag){
  __shared__ float tile[256*8];      // [k][px]; k<128: x ch, k>=128: h ch
  __shared__ float glds[4*8*132];    // [gate][px][132-padded ch]
  int t = threadIdx.x, bid = blockIdx.x;
  int pix0 = bid*8;
  if (t < 128){
    int px = t >> 4, cg = t & 15;
    float v[8]; ld8b(xD + ((size_t)n*4096 + pix0 + px)*128 + cg*8, v);
    #pragma unroll
    for (int j=0;j<8;j++) tile[(cg*8+j)*8 + px] = v[j];
  } else {
    int t2 = t - 128;
    int px = t2 >> 4, cg = t2 & 15;
    const float4* hp = reinterpret_cast<const float4*>(hws + (size_t)(pix0+px)*128 + cg*8);
    float4 a = hp[0], b = hp[1];
    tile[(128+cg*8+0)*8+px]=a.x; tile[(128+cg*8+1)*8+px]=a.y;
    tile[(128+cg*8+2)*8+px]=a.z; tile[(128+cg*8+3)*8+px]=a.w;
    tile[(128+cg*8+4)*8+px]=b.x; tile[(128+cg*8+5)*8+px]=b.y;
    tile[(128+cg*8+6)*8+px]=b.z; tile[(128+cg*8+7)*8+px]=b.w;
  }
  __syncthreads();
  int w = t >> 6, l = t & 63;
  int ch = l*2;
  float acc[8][2];
  {
    float b0 = bh[w*128 + ch], b1 = bh[w*128 + ch + 1];
    #pragma unroll
    for (int p=0;p<8;p++){ acc[p][0]=b0; acc[p][1]=b1; }
  }
  const float* wxp = wx + w*128 + ch;
  const float* whp = wh + w*128 + ch;
  for (int k=0;k<128;k+=2){
    float2 wa = *reinterpret_cast<const float2*>(wxp + (size_t)k*512);
    float2 wb = *reinterpret_cast<const float2*>(wxp + (size_t)k*512 + 512);
    const float* xr0 = &tile[k*8];
    const float* xr1 = &tile[k*8 + 8];
    #pragma unroll
    for (int p=0;p<8;p++){
      float x0 = xr0[p], x1 = xr1[p];
      acc[p][0] += x0*wa.x; acc[p][1] += x0*wa.y;
      acc[p][0] += x1*wb.x; acc[p][1] += x1*wb.y;
    }
  }
  for (int k=0;k<128;k+=2){
    float2 wa = *reinterpret_cast<const float2*>(whp + (size_t)k*512);
    float2 wb = *reinterpret_cast<const float2*>(whp + (size_t)k*512 + 512);
    const float* xr0 = &tile[(128+k)*8];
    const float* xr1 = &tile[(128+k)*8 + 8];
    #pragma unroll
    for (int p=0;p<8;p++){
      float x0 = xr0[p], x1 = xr1[p];
      acc[p][0] += x0*wa.x; acc[p][1] += x0*wa.y;
      acc[p][0] += x1*wb.x; acc[p][1] += x1*wb.y;
    }
  }
  if (w == 2){
    #pragma unroll
    for (int p=0;p<8;p++){
      float v0 = tanhf(acc[p][0]), v1 = tanhf(acc[p][1]);
      *reinterpret_cast<float2*>(&glds[(w*8+p)*132 + ch]) = make_float2(v0, v1);
    }
  } else {
    #pragma unroll
    for (int p=0;p<8;p++){
      float m2 = fmaxf(acc[p][0], acc[p][1]);
      #pragma unroll
      for (int sft=1; sft<64; sft<<=1) m2 = fmaxf(m2, __shfl_xor(m2, sft));
      float e0 = expf(acc[p][0]-m2), e1 = expf(acc[p][1]-m2);
      float sm = e0 + e1;
      #pragma unroll
      for (int sft=1; sft<64; sft<<=1) sm += __shfl_xor(sm, sft);
      float inv = 1.0f/sm;
      *reinterpret_cast<float2*>(&glds[(w*8+p)*132 + ch]) = make_float2(e0*inv, e1*inv);
    }
  }
  __syncthreads();
  {
    int px = t & 7, ch0 = (t >> 3)*4;
    float4 fv = *reinterpret_cast<const float4*>(&glds[(0*8+px)*132 + ch0]);
    float4 iv = *reinterpret_cast<const float4*>(&glds[(1*8+px)*132 + ch0]);
    float4 sv = *reinterpret_cast<const float4*>(&glds[(2*8+px)*132 + ch0]);
    float4 ov = *reinterpret_cast<const float4*>(&glds[(3*8+px)*132 + ch0]);
    int pix = pix0 + px;
    float4 cold = *reinterpret_cast<const float4*>(Cst + (size_t)pix*128 + ch0);
    float cn[4], hn[4];
    cn[0] = fv.x*cold.x + iv.x*sv.x; hn[0] = ov.x*tanhf(cn[0]);
    cn[1] = fv.y*cold.y + iv.y*sv.y; hn[1] = ov.y*tanhf(cn[1]);
    cn[2] = fv.z*cold.z + iv.z*sv.z; hn[2] = ov.z*tanhf(cn[2]);
    cn[3] = fv.w*cold.w + iv.w*sv.w; hn[3] = ov.w*tanhf(cn[3]);
    *reinterpret_cast<float4*>(Cst + (size_t)pix*128 + ch0) = make_float4(cn[0],cn[1],cn[2],cn[3]);
    *reinterpret_cast<float4*>(hws + (size_t)pix*128 + ch0) = make_float4(hn[0],hn[1],hn[2],hn[3]);
    size_t ob = (size_t)n*524288;
    if (*flag){
      float* df = (float*)dout;
      #pragma unroll
      for (int j=0;j<4;j++) df[ob + (size_t)(ch0+j)*4096 + pix] = hn[j];
    } else {
      u16* db = (u16*)dout;
      #pragma unroll
      for (int j=0;j<4;j++) db[ob + (size_t)(ch0+j)*4096 + pix] = f2b_u(hn[j]);
    }
  }
}

// ---------- K7: final hf, Cf: [pix][128] fp32 -> d_out [c][4096] (tiled transpose, dtype) ----------
__global__ __launch_bounds__(256) void k_final_t(const float* __restrict__ hws, const float* __restrict__ Cst,
                                                 void* __restrict__ dout, const int* __restrict__ flag){
  __shared__ float lds[32][33];
  int t = threadIdx.x, bid = blockIdx.x;
  int sel = bid >> 9, tile = bid & 511;
  int pt2 = tile >> 2, ct = tile & 3;
  const float* src = sel ? Cst : hws;
  size_t base = sel ? 8912896u : 8388608u;
  int r = t >> 3, q = t & 7;
  {
    int px = pt2*32 + r, c = ct*32 + q*4;
    float4 v = *reinterpret_cast<const float4*>(src + (size_t)px*128 + c);
    lds[r][q*4+0]=v.x; lds[r][q*4+1]=v.y; lds[r][q*4+2]=v.z; lds[r][q*4+3]=v.w;
  }
  __syncthreads();
  {
    int c = ct*32 + r, px = pt2*32 + q*4;
    float v0 = lds[q*4+0][r], v1 = lds[q*4+1][r], v2 = lds[q*4+2][r], v3 = lds[q*4+3][r];
    if (*flag){
      *reinterpret_cast<float4*>((float*)dout + base + (size_t)c*4096 + px) = make_float4(v0,v1,v2,v3);
    } else {
      uint2 pk;
      pk.x = (u32)f2b_u(v0) | ((u32)f2b_u(v1) << 16);
      pk.y = (u32)f2b_u(v2) | ((u32)f2b_u(v3) << 16);
      *reinterpret_cast<uint2*>((u16*)dout + base + (size_t)c*4096 + px) = pk;
    }
  }
}

extern "C" void kernel_launch(void* const* d_in, const int* in_sizes, int n_in,
                              void* d_out, int out_size, void* d_ws, size_t ws_size,
                              hipStream_t stream) {
  const void* x      = d_in[0];
  const void* h0     = d_in[1];
  const void* c0     = d_in[2];
  const void* conv_w = d_in[3];
  const void* conv_b = d_in[4];
  const void* qkv1_w = d_in[5];
  const void* qkv1_b = d_in[6];
  const void* m1w1   = d_in[7];
  const void* m1b1   = d_in[8];
  const void* m1w2   = d_in[9];
  const void* m1b2   = d_in[10];
  const void* qkv2_w = d_in[11];
  const void* qkv2_b = d_in[12];
  const void* m2w1   = d_in[13];
  const void* m2b1   = d_in[14];
  const void* m2w2   = d_in[15];
  const void* m2b2   = d_in[16];
  const void* lwx    = d_in[17];
  const void* lwh    = d_in[18];
  const void* lbh    = d_in[19];

  char* p = (char*)d_ws;
  auto alloc = [&](size_t bytes)->void*{
    void* r = (void*)p; p += (bytes + 255) & ~(size_t)255; return r;
  };
  int*   flag    = (int*)alloc(256);
  u16* wB_conv = (u16*)alloc(128*512*2);       // bf16, native [co][ci*4+ky*2+kx]
  u16* wB_qkv1 = (u16*)alloc(384*128*2);       // bf16, original [o][k]
  u16* wB_m1a  = (u16*)alloc(512*128*2);
  u16* wB_m1b  = (u16*)alloc(128*512*2);
  u16* wB_qkv2 = (u16*)alloc(384*128*2);
  u16* wB_m2a  = (u16*)alloc(512*128*2);
  u16* wB_m2b  = (u16*)alloc(128*512*2);
  float* wT_lx   = (float*)alloc(128*512*4);   // transposed [k][512] fp32
  float* wT_lh   = (float*)alloc(128*512*4);
  float* bf_conv = (float*)alloc(128*4);
  float* bf_qkv1 = (float*)alloc(384*4);
  float* bf_m1b1 = (float*)alloc(512*4);
  float* bf_m1b2 = (float*)alloc(128*4);
  float* bf_qkv2 = (float*)alloc(384*4);
  float* bf_m2b1 = (float*)alloc(512*4);
  float* bf_m2b2 = (float*)alloc(128*4);
  float* bf_lbh  = (float*)alloc(512*4);
  u16* R0   = (u16*)alloc(16777216);   // bufA -> bufC/y -> (hws, Cst)
  u16* Rbig = (u16*)alloc(33554432);   // bufB (front) -> kvbuf -> bufD (front)

  u16* bufA = R0;
  u16* bufB = Rbig;
  u16* bufC = R0;          // also y (attn writes in place)
  u16* qbuf = (u16*)d_out; // hs region used as scratch; dead before first LSTM write
  u16* kvbuf = Rbig;
  u16* bufD = Rbig;
  float* hws = (float*)((char*)R0 + 8388608);         // 2 MB, [pix][128]
  float* Cst = (float*)((char*)R0 + 10485760);        // 2 MB, [pix][128]

  k_detect<<<1, 256, 0, stream>>>((const u32*)x, flag);

  k_prep<<<2187, 256, 0, stream>>>(
      conv_w, qkv1_w, m1w1, m1w2, qkv2_w, m2w1, m2w2, lwx, lwh,
      conv_b, qkv1_b, m1b1, m1b2, qkv2_b, m2b1, m2b2, lbh,
      wB_conv, wB_qkv1, wB_m1a, wB_m1b, wB_qkv2, wB_m2a, wB_m2b,
      wT_lx, wT_lh,
      bf_conv, bf_qkv1, bf_m1b1, bf_m1b2, bf_qkv2, bf_m2b1, bf_m2b2, bf_lbh,
      flag);

  k_conv<<<4096, 256, 0, stream>>>(x, wB_conv, bf_conv, bufA, flag);
  k_msa1<<<4096, 256, 0, stream>>>(bufA, wB_qkv1, bf_qkv1, bufB);
  k_mlp<1><<<4096, 256, 0, stream>>>(bufB, wB_m1a, bf_m1b1, wB_m1b, bf_m1b2, bufC);
  k_qkv2<<<4096, 256, 0, stream>>>(bufC, wB_qkv2, bf_qkv2, qbuf, kvbuf);
  k_attn2<<<2048, 256, 0, stream>>>(qbuf, kvbuf, bufC);          // y = x + attn, in place
  k_mlp<2><<<4096, 256, 0, stream>>>(bufC, wB_m2a, bf_m2b1, wB_m2b, bf_m2b2, bufD);

  k_tr_pc<<<1024, 256, 0, stream>>>(h0, c0, hws, Cst, flag);
  for (int n = 0; n < 16; n++){
    k_lstm_step<<<512, 256, 0, stream>>>(bufD, hws, Cst, wT_lx, wT_lh, bf_lbh, d_out, n, flag);
  }
  k_final_t<<<1024, 256, 0, stream>>>(hws, Cst, d_out, flag);
}

// Round 8
// 829.562 us; speedup vs baseline: 8.9953x; 1.3575x over previous
//
#include <hip/hip_runtime.h>
#include <hip/hip_bf16.h>

typedef unsigned int u32;
typedef unsigned short u16;

#define DI __device__ __forceinline__

typedef __attribute__((ext_vector_type(8))) __bf16 bf16x8;
typedef __attribute__((ext_vector_type(4))) float f32x4;

// ---------- bf16 helpers (bf16 == fp32 high 16 bits; RNE on store) ----------
DI float b2f_u(u32 u){ return __uint_as_float(u << 16); }
DI u16 f2b_u(float f){
  u32 x = __float_as_uint(f);
  x += 0x7fffu + ((x >> 16) & 1u);
  return (u16)(x >> 16);
}
DI void ld8b(const u16* p, float* o){
  uint4 v = *reinterpret_cast<const uint4*>(p);
  o[0] = b2f_u(v.x & 0xffffu); o[1] = b2f_u(v.x >> 16);
  o[2] = b2f_u(v.y & 0xffffu); o[3] = b2f_u(v.y >> 16);
  o[4] = b2f_u(v.z & 0xffffu); o[5] = b2f_u(v.z >> 16);
  o[6] = b2f_u(v.w & 0xffffu); o[7] = b2f_u(v.w >> 16);
}
DI void st8b(u16* p, const float* i){
  uint4 v;
  v.x = (u32)f2b_u(i[0]) | ((u32)f2b_u(i[1]) << 16);
  v.y = (u32)f2b_u(i[2]) | ((u32)f2b_u(i[3]) << 16);
  v.z = (u32)f2b_u(i[4]) | ((u32)f2b_u(i[5]) << 16);
  v.w = (u32)f2b_u(i[6]) | ((u32)f2b_u(i[7]) << 16);
  *reinterpret_cast<uint4*>(p) = v;
}

// ---------- K_detect: is d_in fp32 (flag=1) or packed bf16 (flag=0)? ----------
__global__ void k_detect(const u32* __restrict__ xw, int* __restrict__ flag){
  __shared__ int cnt;
  int t = threadIdx.x;
  if (t == 0) cnt = 0;
  __syncthreads();
  int c = 0;
  for (int i = t; i < 2048; i += 256){
    u32 lo = xw[i] & 0xffffu;
    u32 e = (lo >> 7) & 0xffu;
    if (e < 100u || e > 140u) c++;
  }
  atomicAdd(&cnt, c);
  __syncthreads();
  if (t == 0) *flag = (cnt > 200) ? 1 : 0;
}

// ---------- K_prep: ALL weight/bias conversions in ONE launch ----------
// Weights -> bf16 layout-preserving copies; lwx/lwh also bf16 (for LSTM MFMA); biases fp32.
__global__ void k_prep(
  const void* __restrict__ conv_w, const void* __restrict__ qkv1_w,
  const void* __restrict__ m1w1, const void* __restrict__ m1w2,
  const void* __restrict__ qkv2_w, const void* __restrict__ m2w1, const void* __restrict__ m2w2,
  const void* __restrict__ lwx, const void* __restrict__ lwh,
  const void* __restrict__ conv_b, const void* __restrict__ qkv1_b,
  const void* __restrict__ m1b1, const void* __restrict__ m1b2,
  const void* __restrict__ qkv2_b, const void* __restrict__ m2b1, const void* __restrict__ m2b2,
  const void* __restrict__ lbh,
  u16* __restrict__ wB_conv, u16* __restrict__ wB_qkv1, u16* __restrict__ wB_m1a,
  u16* __restrict__ wB_m1b, u16* __restrict__ wB_qkv2, u16* __restrict__ wB_m2a,
  u16* __restrict__ wB_m2b, u16* __restrict__ wBx, u16* __restrict__ wBh,
  float* __restrict__ bf_conv, float* __restrict__ bf_qkv1, float* __restrict__ bf_m1b1,
  float* __restrict__ bf_m1b2, float* __restrict__ bf_qkv2, float* __restrict__ bf_m2b1,
  float* __restrict__ bf_m2b2, float* __restrict__ bf_lbh,
  const int* __restrict__ flag){
  int bid = blockIdx.x, t = threadIdx.x;
  int fl = *flag;
  auto cvb = [&](const void* s, u16* d, int base, int n){
    int i = (bid - base)*256 + t;
    if (i < n) d[i] = fl ? f2b_u(((const float*)s)[i]) : ((const u16*)s)[i];
  };
  auto ldf = [&](const void* s, int i)->float{
    return fl ? ((const float*)s)[i] : b2f_u((u32)((const u16*)s)[i]);
  };
  if (bid < 256)       cvb(conv_w, wB_conv, 0,    65536);
  else if (bid < 448)  cvb(qkv1_w, wB_qkv1, 256,  49152);
  else if (bid < 704)  cvb(m1w1,   wB_m1a,  448,  65536);
  else if (bid < 960)  cvb(m1w2,   wB_m1b,  704,  65536);
  else if (bid < 1152) cvb(qkv2_w, wB_qkv2, 960,  49152);
  else if (bid < 1408) cvb(m2w1,   wB_m2a,  1152, 65536);
  else if (bid < 1664) cvb(m2w2,   wB_m2b,  1408, 65536);
  else if (bid < 1920) cvb(lwx,    wBx,     1664, 65536);
  else if (bid < 2176) cvb(lwh,    wBh,     1920, 65536);
  else {
    int i = (bid - 2176)*256 + t;
    if (i < 128)       bf_conv[i]        = ldf(conv_b, i);
    else if (i < 512)  bf_qkv1[i-128]    = ldf(qkv1_b, i-128);
    else if (i < 1024) bf_m1b1[i-512]    = ldf(m1b1,   i-512);
    else if (i < 1152) bf_m1b2[i-1024]   = ldf(m1b2,   i-1024);
    else if (i < 1536) bf_qkv2[i-1152]   = ldf(qkv2_b, i-1152);
    else if (i < 2048) bf_m2b1[i-1536]   = ldf(m2b1,   i-1536);
    else if (i < 2176) bf_m2b2[i-2048]   = ldf(m2b2,   i-2048);
    else if (i < 2688) bf_lbh[i-2176]    = ldf(lbh,    i-2176);
  }
}

// ---------- K1: conv 2x2 stride 2 + window partition via MFMA -> bufA [b][g][l][c] ----------
__global__ __launch_bounds__(256) void k_conv(const void* __restrict__ x_raw,
                                              const u16* __restrict__ wB,
                                              const float* __restrict__ bias, u16* __restrict__ outA,
                                              const int* __restrict__ flag){
  __shared__ u16 Xa[16*520];     // A: [tok][520-pad k], 16.6 KB
  __shared__ u16 Ys[16*136];     // output staging, 4.3 KB
  int t = threadIdx.x, bid = blockIdx.x;
  int xcd = bid & 7, slot = bid >> 3;
  int gIn = slot >> 2, sub = slot & 3;
  int group = gIn*8 + xcd;               // 0..1023, bijective
  int b = group >> 6, yg = (group >> 2) & 15, xgHi = group & 3;
  int xg = xgHi*4 + sub;
  int g = yg*16 + xg;
  size_t base = (size_t)b*2097152 + (size_t)(yg*8)*128 + (size_t)xg*8;
  if (*flag){
    const float* xb = (const float*)x_raw + base;
    #pragma unroll
    for (int i=0;i<4;i++){
      int idx = i*256 + t;
      int ci = idx >> 3, py = idx & 7;
      const float4* s4 = reinterpret_cast<const float4*>(xb + (size_t)ci*16384 + py*128);
      float4 v0 = s4[0], v1 = s4[1];
      int l0 = (py>>1)*4, k0 = ci*4 + (py&1)*2;
      *reinterpret_cast<u32*>(&Xa[(l0+0)*520 + k0]) = (u32)f2b_u(v0.x) | ((u32)f2b_u(v0.y)<<16);
      *reinterpret_cast<u32*>(&Xa[(l0+1)*520 + k0]) = (u32)f2b_u(v0.z) | ((u32)f2b_u(v0.w)<<16);
      *reinterpret_cast<u32*>(&Xa[(l0+2)*520 + k0]) = (u32)f2b_u(v1.x) | ((u32)f2b_u(v1.y)<<16);
      *reinterpret_cast<u32*>(&Xa[(l0+3)*520 + k0]) = (u32)f2b_u(v1.z) | ((u32)f2b_u(v1.w)<<16);
    }
  } else {
    const u16* xb = (const u16*)x_raw + base;
    #pragma unroll
    for (int i=0;i<4;i++){
      int idx = i*256 + t;
      int ci = idx >> 3, py = idx & 7;
      uint4 v = *reinterpret_cast<const uint4*>(xb + (size_t)ci*16384 + py*128);
      int l0 = (py>>1)*4, k0 = ci*4 + (py&1)*2;
      *reinterpret_cast<u32*>(&Xa[(l0+0)*520 + k0]) = v.x;
      *reinterpret_cast<u32*>(&Xa[(l0+1)*520 + k0]) = v.y;
      *reinterpret_cast<u32*>(&Xa[(l0+2)*520 + k0]) = v.z;
      *reinterpret_cast<u32*>(&Xa[(l0+3)*520 + k0]) = v.w;
    }
  }
  __syncthreads();
  int w = t >> 6, lane = t & 63, fr = lane & 15, fg = lane >> 4;
  bf16x8 a[16];
  #pragma unroll
  for (int c=0;c<16;c++) a[c] = *reinterpret_cast<const bf16x8*>(&Xa[fr*520 + c*32 + fg*8]);
  #pragma unroll
  for (int j=0;j<2;j++){
    int o = w*32 + j*16 + fr;          // 0..127
    float bv = bias[o];
    f32x4 d = {bv,bv,bv,bv};
    const u16* wp = wB + (size_t)o*512 + fg*8;
    #pragma unroll
    for (int c=0;c<16;c++){
      bf16x8 bb = *reinterpret_cast<const bf16x8*>(wp + c*32);
      d = __builtin_amdgcn_mfma_f32_16x16x32_bf16(a[c], bb, d, 0, 0, 0);
    }
    #pragma unroll
    for (int r=0;r<4;r++) Ys[(fg*4+r)*136 + o] = f2b_u(d[r]);
  }
  __syncthreads();
  {
    int tok = t >> 4, c0 = (t & 15)*8;
    uint4 v = *reinterpret_cast<const uint4*>(&Ys[tok*136 + c0]);
    size_t T = ((size_t)(b*256 + g)*16 + tok);
    *reinterpret_cast<uint4*>(outA + T*128 + c0) = v;
  }
}

// ---------- K2: LocalMSA (L=16) + residual: bufA -> bufB (same layout) ----------
__global__ __launch_bounds__(256) void k_msa1(const u16* __restrict__ A, const u16* __restrict__ wB,
                                              const float* __restrict__ qbias, u16* __restrict__ B){
  __shared__ u16 Xs[16*136];        // bf16, row stride 272 B
  __shared__ float QKV[16*388];
  __shared__ float S[512];          // [h][l][m]
  int t = threadIdx.x, bid = blockIdx.x;
  {
    int l = t >> 4, c0 = (t & 15)*8;
    *reinterpret_cast<uint4*>(&Xs[l*136 + c0]) =
      *reinterpret_cast<const uint4*>(A + (size_t)bid*2048 + l*128 + c0);
  }
  __syncthreads();
  {
    int w = t >> 6, lane = t & 63, fr = lane & 15, fg = lane >> 4;
    bf16x8 a[4];
    #pragma unroll
    for (int k=0;k<4;k++) a[k] = *reinterpret_cast<const bf16x8*>(&Xs[fr*136 + k*32 + fg*8]);
    #pragma unroll
    for (int j=0;j<6;j++){
      int o = w*96 + j*16 + fr;          // 0..383
      float bv = qbias[o];
      f32x4 d = {bv,bv,bv,bv};
      const u16* wp = wB + (size_t)o*128 + fg*8;
      #pragma unroll
      for (int k=0;k<4;k++){
        bf16x8 b = *reinterpret_cast<const bf16x8*>(wp + k*32);
        d = __builtin_amdgcn_mfma_f32_16x16x32_bf16(a[k], b, d, 0, 0, 0);
      }
      #pragma unroll
      for (int r=0;r<4;r++) QKV[(fg*4+r)*388 + o] = d[r];
    }
  }
  __syncthreads();
  const float scale = 0.08838834764831845f;   // 1/sqrt(128)
  for (int e = t; e < 512; e += 256){
    int h = e >> 8, l = (e>>4)&15, m = e&15;
    const float* q = &QKV[l*388 + h*64];
    const float* kk = &QKV[m*388 + 128 + h*64];
    float s = 0.f;
    #pragma unroll
    for (int d=0; d<64; d++) s += q[d]*kk[d];
    S[(h*16+l)*16 + m] = s*scale;
  }
  __syncthreads();
  if (t < 32){
    float* row = &S[t*16];
    float mx = row[0];
    #pragma unroll
    for (int m=1;m<16;m++) mx = fmaxf(mx,row[m]);
    float sum = 0.f;
    #pragma unroll
    for (int m=0;m<16;m++){ float e = expf(row[m]-mx); row[m]=e; sum+=e; }
    float inv = 1.0f/sum;
    #pragma unroll
    for (int m=0;m<16;m++) row[m] *= inv;
  }
  __syncthreads();
  {
    int l = t >> 4, og = t & 15, o0 = og*8;
    int h = o0 >> 6;
    const float* p = &S[(h*16+l)*16];
    float out8[8];
    #pragma unroll
    for (int j=0;j<8;j++){
      int o = o0+j, d = o & 63;
      float s = 0.f;
      #pragma unroll
      for (int m=0;m<16;m++) s += p[m]*QKV[m*388 + 256 + h*64 + d];
      out8[j] = s + b2f_u((u32)Xs[l*136 + o]);
    }
    st8b(B + (size_t)bid*2048 + l*128 + o0, out8);
  }
}

// ---------- K3/K5: MLP (+residual) via MFMA, 32 tokens/block (2 tiles/wave). ----------
//            MODE1: bufB [b][g][l][c] -> bufC [b][l][g][c].
//            MODE2: y [b][l][g][c] -> bufD [n][pix][c] (window reverse).
template<int MODE>
__global__ __launch_bounds__(256) void k_mlp(const u16* __restrict__ in,
    const u16* __restrict__ w1B, const float* __restrict__ b1,
    const u16* __restrict__ w2B, const float* __restrict__ b2,
    u16* __restrict__ out){
  __shared__ u16 Xs[32*136];        // bf16 input (also residual)
  __shared__ u16 Hs[32*520];        // bf16 hidden
  __shared__ u16 Ys[32*136];        // bf16 output staging
  int t = threadIdx.x, bid = blockIdx.x;
  {
    int l = t >> 3, c0 = (t & 7)*16;
    const u16* src = in + (size_t)bid*4096 + l*128 + c0;
    *reinterpret_cast<uint4*>(&Xs[l*136 + c0])     = *reinterpret_cast<const uint4*>(src);
    *reinterpret_cast<uint4*>(&Xs[l*136 + c0 + 8]) = *reinterpret_cast<const uint4*>(src + 8);
  }
  __syncthreads();
  int w = t >> 6, lane = t & 63, fr = lane & 15, fg = lane >> 4;

  // ---- GEMM1: H = gelu(X @ W1^T + b1); wave = 8 n-tiles x 2 tok-tiles ----
  {
    bf16x8 a0[4], a1[4];
    #pragma unroll
    for (int k=0;k<4;k++){
      a0[k] = *reinterpret_cast<const bf16x8*>(&Xs[fr*136 + k*32 + fg*8]);
      a1[k] = *reinterpret_cast<const bf16x8*>(&Xs[(16+fr)*136 + k*32 + fg*8]);
    }
    #pragma unroll
    for (int j=0;j<8;j++){
      int o = w*128 + j*16 + fr;        // 0..511
      float bv = b1[o];
      f32x4 d0 = {bv,bv,bv,bv}, d1 = {bv,bv,bv,bv};
      const u16* wp = w1B + (size_t)o*128 + fg*8;
      #pragma unroll
      for (int k=0;k<4;k++){
        bf16x8 b = *reinterpret_cast<const bf16x8*>(wp + k*32);
        d0 = __builtin_amdgcn_mfma_f32_16x16x32_bf16(a0[k], b, d0, 0, 0, 0);
        d1 = __builtin_amdgcn_mfma_f32_16x16x32_bf16(a1[k], b, d1, 0, 0, 0);
      }
      #pragma unroll
      for (int r=0;r<4;r++){
        float v0 = d0[r], v1 = d1[r];
        Hs[(fg*4+r)*520 + o]      = f2b_u(0.5f*v0*(1.0f + erff(v0*0.70710678118654752f)));
        Hs[(16+fg*4+r)*520 + o]   = f2b_u(0.5f*v1*(1.0f + erff(v1*0.70710678118654752f)));
      }
    }
  }
  __syncthreads();

  // ---- GEMM2: Y = H @ W2^T + b2 + X; wave = 2 n-tiles x 2 tok-tiles ----
  {
    int na = w*32 + fr, nb = na + 16;   // 0..127
    float ba = b2[na], bb = b2[nb];
    f32x4 d00 = {ba,ba,ba,ba}, d01 = {bb,bb,bb,bb};
    f32x4 d10 = {ba,ba,ba,ba}, d11 = {bb,bb,bb,bb};
    const u16* wpa = w2B + (size_t)na*512 + fg*8;
    const u16* wpb = w2B + (size_t)nb*512 + fg*8;
    #pragma unroll
    for (int k=0;k<16;k++){
      bf16x8 aa = *reinterpret_cast<const bf16x8*>(&Hs[fr*520 + k*32 + fg*8]);
      bf16x8 ab = *reinterpret_cast<const bf16x8*>(&Hs[(16+fr)*520 + k*32 + fg*8]);
      bf16x8 bA = *reinterpret_cast<const bf16x8*>(wpa + k*32);
      bf16x8 bB = *reinterpret_cast<const bf16x8*>(wpb + k*32);
      d00 = __builtin_amdgcn_mfma_f32_16x16x32_bf16(aa, bA, d00, 0, 0, 0);
      d01 = __builtin_amdgcn_mfma_f32_16x16x32_bf16(aa, bB, d01, 0, 0, 0);
      d10 = __builtin_amdgcn_mfma_f32_16x16x32_bf16(ab, bA, d10, 0, 0, 0);
      d11 = __builtin_amdgcn_mfma_f32_16x16x32_bf16(ab, bB, d11, 0, 0, 0);
    }
    #pragma unroll
    for (int r=0;r<4;r++){
      int ta = fg*4 + r, tb = 16 + ta;
      Ys[ta*136 + na] = f2b_u(d00[r] + b2f_u((u32)Xs[ta*136 + na]));
      Ys[ta*136 + nb] = f2b_u(d01[r] + b2f_u((u32)Xs[ta*136 + nb]));
      Ys[tb*136 + na] = f2b_u(d10[r] + b2f_u((u32)Xs[tb*136 + na]));
      Ys[tb*136 + nb] = f2b_u(d11[r] + b2f_u((u32)Xs[tb*136 + nb]));
    }
  }
  __syncthreads();

  // ---- coalesced store with layout mapping ----
  {
    int tok = t >> 3, oc = (t & 7)*16;
    uint4 v0 = *reinterpret_cast<const uint4*>(&Ys[tok*136 + oc]);
    uint4 v1 = *reinterpret_cast<const uint4*>(&Ys[tok*136 + oc + 8]);
    int T = bid*32 + tok;
    size_t addr;
    if (MODE == 1){
      int b = T >> 12, g = (T >> 4) & 255, ll = T & 15;
      addr = ((size_t)((b*16 + ll)*256 + g))*128 + oc;
    } else {
      int b = T >> 12, ll = (T >> 8) & 15, g = T & 255;
      int pcoord = ((g >> 4)*4 + (ll >> 2))*64 + ((g & 15)*4 + (ll & 3));
      addr = ((size_t)(b*4096 + pcoord))*128 + oc;
    }
    *reinterpret_cast<uint4*>(out + addr)     = v0;
    *reinterpret_cast<uint4*>(out + addr + 8) = v1;
  }
}

// ---------- K4a: QKV projection for DilatedMSA via MFMA ----------
__global__ __launch_bounds__(256) void k_qkv2(const u16* __restrict__ in, const u16* __restrict__ wB,
                                              const float* __restrict__ bias,
                                              u16* __restrict__ qbuf, u16* __restrict__ kvbuf){
  __shared__ u16 Xs[16*136];
  __shared__ u16 Qs[16*392];        // bf16 [tok][384+pad]
  int t = threadIdx.x, bid = blockIdx.x;
  {
    int l = t >> 4, c0 = (t & 15)*8;
    *reinterpret_cast<uint4*>(&Xs[l*136 + c0]) =
      *reinterpret_cast<const uint4*>(in + (size_t)bid*2048 + l*128 + c0);
  }
  __syncthreads();
  {
    int w = t >> 6, lane = t & 63, fr = lane & 15, fg = lane >> 4;
    bf16x8 a[4];
    #pragma unroll
    for (int k=0;k<4;k++) a[k] = *reinterpret_cast<const bf16x8*>(&Xs[fr*136 + k*32 + fg*8]);
    #pragma unroll
    for (int j=0;j<6;j++){
      int o = w*96 + j*16 + fr;          // 0..383
      float bv = bias[o];
      f32x4 d = {bv,bv,bv,bv};
      const u16* wp = wB + (size_t)o*128 + fg*8;
      #pragma unroll
      for (int k=0;k<4;k++){
        bf16x8 b = *reinterpret_cast<const bf16x8*>(wp + k*32);
        d = __builtin_amdgcn_mfma_f32_16x16x32_bf16(a[k], b, d, 0, 0, 0);
      }
      #pragma unroll
      for (int r=0;r<4;r++) Qs[(fg*4+r)*392 + o] = f2b_u(d[r]);
    }
  }
  __syncthreads();
  {
    int l = t >> 4, og = t & 15, o0 = og*24;
    size_t tok = (size_t)bid*16 + l;
    #pragma unroll
    for (int m=0; m<3; m++){
      int oc = o0 + m*8;
      uint4 v = *reinterpret_cast<const uint4*>(&Qs[l*392 + oc]);
      if (oc < 128) *reinterpret_cast<uint4*>(qbuf + tok*128 + oc) = v;
      else          *reinterpret_cast<uint4*>(kvbuf + tok*256 + (oc-128)) = v;
    }
  }
}

// ---------- K4b: DilatedMSA flash attention, full-MFMA (QK^T and PV), in-register softmax ----------
__global__ __launch_bounds__(256) void k_attn2(const u16* __restrict__ qbuf, const u16* __restrict__ kvbuf,
                                               u16* __restrict__ y){
  __shared__ __align__(16) char pool[24064];
  u16* Qb = (u16*)pool;              // [64][72] bf16
  u16* Kb = (u16*)(pool + 9216);     // [32][72] bf16
  u16* Vt = (u16*)(pool + 13824);    // [64 d][40 kt] bf16 (transposed V)
  u16* Pb = (u16*)(pool + 18944);    // [64 q][40 kt] bf16
  float* Os = (float*)pool;          // [64][68] f32, overlays Qb/Kb/Vt after loop

  int t = threadIdx.x, bid = blockIdx.x;
  int qt = bid & 3, h = (bid >> 2) & 1, bl = bid >> 3;
  size_t tokbase = (size_t)bl * 256;
  {
    int r = t >> 2, seg = t & 3;
    const u16* src = qbuf + (tokbase + qt*64 + r)*128 + h*64 + seg*16;
    uint4 v0 = *reinterpret_cast<const uint4*>(src);
    uint4 v1 = *reinterpret_cast<const uint4*>(src + 8);
    *reinterpret_cast<uint4*>(&Qb[r*72 + seg*16])     = v0;
    *reinterpret_cast<uint4*>(&Qb[r*72 + seg*16 + 8]) = v1;
  }
  int w = t >> 6, lane = t & 63;
  int fc = lane & 15, fg = lane >> 4;
  float m_reg[4], l_reg[4];
  #pragma unroll
  for (int r=0;r<4;r++){ m_reg[r] = -1e30f; l_reg[r] = 0.0f; }
  f32x4 o[4];
  #pragma unroll
  for (int j=0;j<4;j++) o[j] = {0.f,0.f,0.f,0.f};
  const float scale = 0.08838834764831845f;

  for (int kt=0; kt<8; kt++){
    {  // stage K rows (bf16)
      int r = t >> 3, seg = t & 7;
      const u16* base = kvbuf + (tokbase + kt*32 + r)*256 + h*64;
      *reinterpret_cast<uint4*>(&Kb[r*72 + seg*8]) = *reinterpret_cast<const uint4*>(base + seg*8);
    }
    {  // stage V transposed: thread = (token-pair pp, d-group dg)
      int pp = t >> 4, dg = t & 15, d0 = dg*4;
      const u16* b0 = kvbuf + (tokbase + kt*32 + 2*pp)*256 + h*64 + 128 + d0;
      uint2 v0 = *reinterpret_cast<const uint2*>(b0);
      uint2 v1 = *reinterpret_cast<const uint2*>(b0 + 256);
      *reinterpret_cast<u32*>(&Vt[(d0+0)*40 + 2*pp]) = (v0.x & 0xffffu) | (v1.x << 16);
      *reinterpret_cast<u32*>(&Vt[(d0+1)*40 + 2*pp]) = (v0.x >> 16) | (v1.x & 0xffff0000u);
      *reinterpret_cast<u32*>(&Vt[(d0+2)*40 + 2*pp]) = (v0.y & 0xffffu) | (v1.y << 16);
      *reinterpret_cast<u32*>(&Vt[(d0+3)*40 + 2*pp]) = (v0.y >> 16) | (v1.y & 0xffff0000u);
    }
    __syncthreads();
    // QK^T mfma
    f32x4 s0 = {0.f,0.f,0.f,0.f}, s1 = {0.f,0.f,0.f,0.f};
    {
      bf16x8 a0  = *reinterpret_cast<const bf16x8*>(&Qb[(w*16+fc)*72 + fg*8]);
      bf16x8 a1  = *reinterpret_cast<const bf16x8*>(&Qb[(w*16+fc)*72 + 32 + fg*8]);
      bf16x8 b00 = *reinterpret_cast<const bf16x8*>(&Kb[fc*72 + fg*8]);
      bf16x8 b01 = *reinterpret_cast<const bf16x8*>(&Kb[fc*72 + 32 + fg*8]);
      bf16x8 b10 = *reinterpret_cast<const bf16x8*>(&Kb[(16+fc)*72 + fg*8]);
      bf16x8 b11 = *reinterpret_cast<const bf16x8*>(&Kb[(16+fc)*72 + 32 + fg*8]);
      s0 = __builtin_amdgcn_mfma_f32_16x16x32_bf16(a0, b00, s0, 0, 0, 0);
      s0 = __builtin_amdgcn_mfma_f32_16x16x32_bf16(a1, b01, s0, 0, 0, 0);
      s1 = __builtin_amdgcn_mfma_f32_16x16x32_bf16(a0, b10, s1, 0, 0, 0);
      s1 = __builtin_amdgcn_mfma_f32_16x16x32_bf16(a1, b11, s1, 0, 0, 0);
    }
    // in-register online softmax (butterfly over the 16 fc lanes)
    float corr[4];
    #pragma unroll
    for (int r=0;r<4;r++){
      float v0 = s0[r]*scale, v1 = s1[r]*scale;
      float mx = fmaxf(v0, v1);
      mx = fmaxf(mx, __shfl_xor(mx, 1));
      mx = fmaxf(mx, __shfl_xor(mx, 2));
      mx = fmaxf(mx, __shfl_xor(mx, 4));
      mx = fmaxf(mx, __shfl_xor(mx, 8));
      float mnew = fmaxf(m_reg[r], mx);
      corr[r] = expf(m_reg[r] - mnew);
      m_reg[r] = mnew;
      float p0 = expf(v0 - mnew), p1 = expf(v1 - mnew);
      float sum = p0 + p1;
      sum += __shfl_xor(sum, 1);
      sum += __shfl_xor(sum, 2);
      sum += __shfl_xor(sum, 4);
      sum += __shfl_xor(sum, 8);
      l_reg[r] = l_reg[r]*corr[r] + sum;
      int row = w*16 + fg*4 + r;
      Pb[row*40 + fc]      = f2b_u(p0);
      Pb[row*40 + 16 + fc] = f2b_u(p1);
    }
    // PV mfma
    {
      bf16x8 pa = *reinterpret_cast<const bf16x8*>(&Pb[(w*16+fc)*40 + fg*8]);
      #pragma unroll
      for (int jt=0;jt<4;jt++){
        bf16x8 vb = *reinterpret_cast<const bf16x8*>(&Vt[(jt*16+fc)*40 + fg*8]);
        f32x4 oo = o[jt];
        oo[0] *= corr[0]; oo[1] *= corr[1]; oo[2] *= corr[2]; oo[3] *= corr[3];
        o[jt] = __builtin_amdgcn_mfma_f32_16x16x32_bf16(pa, vb, oo, 0, 0, 0);
      }
    }
    __syncthreads();
  }
  float inv[4];
  #pragma unroll
  for (int r=0;r<4;r++) inv[r] = 1.0f / l_reg[r];
  #pragma unroll
  for (int jt=0;jt<4;jt++){
    #pragma unroll
    for (int r=0;r<4;r++)
      Os[(w*16 + fg*4 + r)*68 + jt*16 + fc] = o[jt][r] * inv[r];
  }
  __syncthreads();
  {
    int row = t >> 2, seg = t & 3;
    float ov[16];
    #pragma unroll
    for (int j=0;j<16;j++) ov[j] = Os[row*68 + seg*16 + j];
    u16* dst = y + (tokbase + qt*64 + row)*128 + h*64 + seg*16;
    float res[16]; ld8b(dst, res); ld8b(dst+8, res+8);
    float o16[16];
    #pragma unroll
    for (int j=0;j<16;j++) o16[j] = ov[j] + res[j];
    st8b(dst, o16); st8b(dst+8, o16+8);
  }
}

// ---------- K_tr: h0/c0 [c][4096] -> hws/Cst [pix][128] fp32 + hbf bf16 ----------
__global__ __launch_bounds__(256) void k_tr_pc(const void* __restrict__ h0, const void* __restrict__ c0,
                                               float* __restrict__ hws, float* __restrict__ Cst,
                                               u16* __restrict__ hbf,
                                               const int* __restrict__ flag){
  __shared__ float lds[32][33];
  int t = threadIdx.x, bid = blockIdx.x;
  int sel = bid >> 9, tile = bid & 511;
  int pt2 = tile >> 2, ct = tile & 3;
  const void* src = sel ? c0 : h0;
  float* dst = sel ? Cst : hws;
  int r = t >> 3, q = t & 7;
  {
    int c = ct*32 + r;
    int px = pt2*32 + q*4;
    if (*flag){
      float4 v = *reinterpret_cast<const float4*>((const float*)src + (size_t)c*4096 + px);
      lds[r][q*4+0]=v.x; lds[r][q*4+1]=v.y; lds[r][q*4+2]=v.z; lds[r][q*4+3]=v.w;
    } else {
      uint2 u = *reinterpret_cast<const uint2*>((const u16*)src + (size_t)c*4096 + px);
      lds[r][q*4+0]=b2f_u(u.x & 0xffffu); lds[r][q*4+1]=b2f_u(u.x >> 16);
      lds[r][q*4+2]=b2f_u(u.y & 0xffffu); lds[r][q*4+3]=b2f_u(u.y >> 16);
    }
  }
  __syncthreads();
  {
    int px = pt2*32 + r;
    int c = ct*32 + q*4;
    float4 o;
    o.x = lds[q*4+0][r]; o.y = lds[q*4+1][r]; o.z = lds[q*4+2][r]; o.w = lds[q*4+3][r];
    *reinterpret_cast<float4*>(dst + (size_t)px*128 + c) = o;
    if (sel == 0){
      uint2 pk;
      pk.x = (u32)f2b_u(o.x) | ((u32)f2b_u(o.y) << 16);
      pk.y = (u32)f2b_u(o.z) | ((u32)f2b_u(o.w) << 16);
      *reinterpret_cast<uint2*>(hbf + (size_t)px*128 + c) = pk;
    }
  }
}

// ---------- K6: fused LSTM step via MFMA; block = 16 px, wave = gate ----------
// A = [x bf16 | h bf16] (K=256), B = lwx/lwh bf16 native [o][k]. Channel softmax
// fully in registers (shfl_xor over fc lanes). Gate exchange through LDS.
__global__ __launch_bounds__(256) void k_lstm_step(const u16* __restrict__ xD,
    u16* __restrict__ hbf, float* __restrict__ hws, float* __restrict__ Cst,
    const u16* __restrict__ wBx, const u16* __restrict__ wBh, const float* __restrict__ bh,
    void* __restrict__ dout, int n, const int* __restrict__ flag){
  __shared__ u16 Xa[16*136];         // x bf16
  __shared__ u16 Ha[16*136];         // h bf16
  __shared__ float glds[4*16*132];   // [gate][px][132-pad ch] f32
  __shared__ u16 hst[16*136];        // h-new bf16 staging for d_out
  int t = threadIdx.x, bid = blockIdx.x;
  int pix0 = bid*16;
  {
    int px = t >> 4, c0 = (t & 15)*8;
    *reinterpret_cast<uint4*>(&Xa[px*136 + c0]) =
      *reinterpret_cast<const uint4*>(xD + ((size_t)n*4096 + pix0 + px)*128 + c0);
    *reinterpret_cast<uint4*>(&Ha[px*136 + c0]) =
      *reinterpret_cast<const uint4*>(hbf + (size_t)(pix0 + px)*128 + c0);
  }
  __syncthreads();
  int w = t >> 6, lane = t & 63, fr = lane & 15, fg = lane >> 4;
  // gates GEMM: wave w computes gate w (128 channels), 8 n-tiles
  f32x4 acc[8];
  {
    bf16x8 ax[4], ah[4];
    #pragma unroll
    for (int k=0;k<4;k++){
      ax[k] = *reinterpret_cast<const bf16x8*>(&Xa[fr*136 + k*32 + fg*8]);
      ah[k] = *reinterpret_cast<const bf16x8*>(&Ha[fr*136 + k*32 + fg*8]);
    }
    #pragma unroll
    for (int j=0;j<8;j++){
      int o = w*128 + j*16 + fr;
      float bv = bh[o];
      f32x4 d = {bv,bv,bv,bv};
      const u16* wpx = wBx + (size_t)o*128 + fg*8;
      const u16* wph = wBh + (size_t)o*128 + fg*8;
      #pragma unroll
      for (int k=0;k<4;k++){
        bf16x8 b = *reinterpret_cast<const bf16x8*>(wpx + k*32);
        d = __builtin_amdgcn_mfma_f32_16x16x32_bf16(ax[k], b, d, 0, 0, 0);
      }
      #pragma unroll
      for (int k=0;k<4;k++){
        bf16x8 b = *reinterpret_cast<const bf16x8*>(wph + k*32);
        d = __builtin_amdgcn_mfma_f32_16x16x32_bf16(ah[k], b, d, 0, 0, 0);
      }
      acc[j] = d;
    }
  }
  // activation: w==2 -> tanh; else channel-softmax over 128 ch (8 j-regs x 16 fc lanes)
  if (w == 2){
    #pragma unroll
    for (int j=0;j<8;j++)
      #pragma unroll
      for (int r=0;r<4;r++)
        glds[(w*16 + fg*4 + r)*132 + j*16 + fr] = tanhf(acc[j][r]);
  } else {
    #pragma unroll
    for (int r=0;r<4;r++){
      float mx = acc[0][r];
      #pragma unroll
      for (int j=1;j<8;j++) mx = fmaxf(mx, acc[j][r]);
      mx = fmaxf(mx, __shfl_xor(mx, 1));
      mx = fmaxf(mx, __shfl_xor(mx, 2));
      mx = fmaxf(mx, __shfl_xor(mx, 4));
      mx = fmaxf(mx, __shfl_xor(mx, 8));
      float e[8], sum = 0.f;
      #pragma unroll
      for (int j=0;j<8;j++){ e[j] = expf(acc[j][r] - mx); sum += e[j]; }
      sum += __shfl_xor(sum, 1);
      sum += __shfl_xor(sum, 2);
      sum += __shfl_xor(sum, 4);
      sum += __shfl_xor(sum, 8);
      float inv = 1.0f/sum;
      #pragma unroll
      for (int j=0;j<8;j++)
        glds[(w*16 + fg*4 + r)*132 + j*16 + fr] = e[j]*inv;
    }
  }
  __syncthreads();
  // pointwise update: thread = (chg = t&15, px = t>>4)
  {
    int chg = t & 15, px = t >> 4;
    int ch0 = chg*8;
    int pix = pix0 + px;
    float fv[8], iv[8], sv[8], ov[8], cc[8];
    #pragma unroll
    for (int q2=0;q2<2;q2++){
      *reinterpret_cast<float4*>(&fv[q2*4]) = *reinterpret_cast<const float4*>(&glds[(0*16+px)*132 + ch0 + q2*4]);
      *reinterpret_cast<float4*>(&iv[q2*4]) = *reinterpret_cast<const float4*>(&glds[(1*16+px)*132 + ch0 + q2*4]);
      *reinterpret_cast<float4*>(&sv[q2*4]) = *reinterpret_cast<const float4*>(&glds[(2*16+px)*132 + ch0 + q2*4]);
      *reinterpret_cast<float4*>(&ov[q2*4]) = *reinterpret_cast<const float4*>(&glds[(3*16+px)*132 + ch0 + q2*4]);
      *reinterpret_cast<float4*>(&cc[q2*4]) = *reinterpret_cast<const float4*>(Cst + (size_t)pix*128 + ch0 + q2*4);
    }
    float cn[8], hn[8];
    #pragma unroll
    for (int j=0;j<8;j++){
      cn[j] = fv[j]*cc[j] + iv[j]*sv[j];
      hn[j] = ov[j]*tanhf(cn[j]);
    }
    #pragma unroll
    for (int q2=0;q2<2;q2++){
      *reinterpret_cast<float4*>(Cst + (size_t)pix*128 + ch0 + q2*4) = *reinterpret_cast<const float4*>(&cn[q2*4]);
      *reinterpret_cast<float4*>(hws + (size_t)pix*128 + ch0 + q2*4) = *reinterpret_cast<const float4*>(&hn[q2*4]);
    }
    uint4 pk;
    pk.x = (u32)f2b_u(hn[0]) | ((u32)f2b_u(hn[1]) << 16);
    pk.y = (u32)f2b_u(hn[2]) | ((u32)f2b_u(hn[3]) << 16);
    pk.z = (u32)f2b_u(hn[4]) | ((u32)f2b_u(hn[5]) << 16);
    pk.w = (u32)f2b_u(hn[6]) | ((u32)f2b_u(hn[7]) << 16);
    *reinterpret_cast<uint4*>(hbf + (size_t)pix*128 + ch0) = pk;
    *reinterpret_cast<uint4*>(&hst[px*136 + ch0]) = pk;
  }
  __syncthreads();
  // coalesced hs write (channel-major d_out)
  {
    int ch = t >> 1, ph = t & 1;
    size_t ob = (size_t)n*524288 + (size_t)ch*4096 + pix0 + ph*8;
    if (*flag){
      float* df = (float*)dout;
      float v[8];
      #pragma unroll
      for (int i=0;i<8;i++) v[i] = b2f_u((u32)hst[(ph*8+i)*136 + ch]);
      *reinterpret_cast<float4*>(df + ob)     = make_float4(v[0],v[1],v[2],v[3]);
      *reinterpret_cast<float4*>(df + ob + 4) = make_float4(v[4],v[5],v[6],v[7]);
    } else {
      u16* db = (u16*)dout;
      uint4 pk;
      pk.x = (u32)hst[(ph*8+0)*136 + ch] | ((u32)hst[(ph*8+1)*136 + ch] << 16);
      pk.y = (u32)hst[(ph*8+2)*136 + ch] | ((u32)hst[(ph*8+3)*136 + ch] << 16);
      pk.z = (u32)hst[(ph*8+4)*136 + ch] | ((u32)hst[(ph*8+5)*136 + ch] << 16);
      pk.w = (u32)hst[(ph*8+6)*136 + ch] | ((u32)hst[(ph*8+7)*136 + ch] << 16);
      *reinterpret_cast<uint4*>(db + ob) = pk;
    }
  }
}

// ---------- K7: final hf, Cf: [pix][128] fp32 -> d_out [c][4096] (tiled transpose, dtype) ----------
__global__ __launch_bounds__(256) void k_final_t(const float* __restrict__ hws, const float* __restrict__ Cst,
                                                 void* __restrict__ dout, const int* __restrict__ flag){
  __shared__ float lds[32][33];
  int t = threadIdx.x, bid = blockIdx.x;
  int sel = bid >> 9, tile = bid & 511;
  int pt2 = tile >> 2, ct = tile & 3;
  const float* src = sel ? Cst : hws;
  size_t base = sel ? 8912896u : 8388608u;
  int r = t >> 3, q = t & 7;
  {
    int px = pt2*32 + r, c = ct*32 + q*4;
    float4 v = *reinterpret_cast<const float4*>(src + (size_t)px*128 + c);
    lds[r][q*4+0]=v.x; lds[r][q*4+1]=v.y; lds[r][q*4+2]=v.z; lds[r][q*4+3]=v.w;
  }
  __syncthreads();
  {
    int c = ct*32 + r, px = pt2*32 + q*4;
    float v0 = lds[q*4+0][r], v1 = lds[q*4+1][r], v2 = lds[q*4+2][r], v3 = lds[q*4+3][r];
    if (*flag){
      *reinterpret_cast<float4*>((float*)dout + base + (size_t)c*4096 + px) = make_float4(v0,v1,v2,v3);
    } else {
      uint2 pk;
      pk.x = (u32)f2b_u(v0) | ((u32)f2b_u(v1) << 16);
      pk.y = (u32)f2b_u(v2) | ((u32)f2b_u(v3) << 16);
      *reinterpret_cast<uint2*>((u16*)dout + base + (size_t)c*4096 + px) = pk;
    }
  }
}

extern "C" void kernel_launch(void* const* d_in, const int* in_sizes, int n_in,
                              void* d_out, int out_size, void* d_ws, size_t ws_size,
                              hipStream_t stream) {
  const void* x      = d_in[0];
  const void* h0     = d_in[1];
  const void* c0     = d_in[2];
  const void* conv_w = d_in[3];
  const void* conv_b = d_in[4];
  const void* qkv1_w = d_in[5];
  const void* qkv1_b = d_in[6];
  const void* m1w1   = d_in[7];
  const void* m1b1   = d_in[8];
  const void* m1w2   = d_in[9];
  const void* m1b2   = d_in[10];
  const void* qkv2_w = d_in[11];
  const void* qkv2_b = d_in[12];
  const void* m2w1   = d_in[13];
  const void* m2b1   = d_in[14];
  const void* m2w2   = d_in[15];
  const void* m2b2   = d_in[16];
  const void* lwx    = d_in[17];
  const void* lwh    = d_in[18];
  const void* lbh    = d_in[19];

  char* p = (char*)d_ws;
  auto alloc = [&](size_t bytes)->void*{
    void* r = (void*)p; p += (bytes + 255) & ~(size_t)255; return r;
  };
  int*   flag    = (int*)alloc(256);
  u16* wB_conv = (u16*)alloc(128*512*2);       // bf16, native [co][ci*4+ky*2+kx]
  u16* wB_qkv1 = (u16*)alloc(384*128*2);       // bf16, original [o][k]
  u16* wB_m1a  = (u16*)alloc(512*128*2);
  u16* wB_m1b  = (u16*)alloc(128*512*2);
  u16* wB_qkv2 = (u16*)alloc(384*128*2);
  u16* wB_m2a  = (u16*)alloc(512*128*2);
  u16* wB_m2b  = (u16*)alloc(128*512*2);
  u16* wBx     = (u16*)alloc(512*128*2);       // bf16, original [o][k] (LSTM x)
  u16* wBh     = (u16*)alloc(512*128*2);       // bf16, original [o][k] (LSTM h)
  float* bf_conv = (float*)alloc(128*4);
  float* bf_qkv1 = (float*)alloc(384*4);
  float* bf_m1b1 = (float*)alloc(512*4);
  float* bf_m1b2 = (float*)alloc(128*4);
  float* bf_qkv2 = (float*)alloc(384*4);
  float* bf_m2b1 = (float*)alloc(512*4);
  float* bf_m2b2 = (float*)alloc(128*4);
  float* bf_lbh  = (float*)alloc(512*4);
  u16* R0   = (u16*)alloc(16777216);   // bufA -> bufC/y -> (hws, Cst, hbf)
  u16* Rbig = (u16*)alloc(33554432);   // bufB (front) -> kvbuf -> bufD (front)

  u16* bufA = R0;
  u16* bufB = Rbig;
  u16* bufC = R0;          // also y (attn writes in place)
  u16* qbuf = (u16*)d_out; // hs region used as scratch; dead before first LSTM write
  u16* kvbuf = Rbig;
  u16* bufD = Rbig;
  float* hws = (float*)((char*)R0 + 8388608);         // 2 MB, [pix][128] fp32
  float* Cst = (float*)((char*)R0 + 10485760);        // 2 MB, [pix][128] fp32
  u16*   hbf = (u16*)((char*)R0 + 12582912);          // 1 MB, [pix][128] bf16

  k_detect<<<1, 256, 0, stream>>>((const u32*)x, flag);

  k_prep<<<2187, 256, 0, stream>>>(
      conv_w, qkv1_w, m1w1, m1w2, qkv2_w, m2w1, m2w2, lwx, lwh,
      conv_b, qkv1_b, m1b1, m1b2, qkv2_b, m2b1, m2b2, lbh,
      wB_conv, wB_qkv1, wB_m1a, wB_m1b, wB_qkv2, wB_m2a, wB_m2b,
      wBx, wBh,
      bf_conv, bf_qkv1, bf_m1b1, bf_m1b2, bf_qkv2, bf_m2b1, bf_m2b2, bf_lbh,
      flag);

  k_conv<<<4096, 256, 0, stream>>>(x, wB_conv, bf_conv, bufA, flag);
  k_msa1<<<4096, 256, 0, stream>>>(bufA, wB_qkv1, bf_qkv1, bufB);
  k_mlp<1><<<2048, 256, 0, stream>>>(bufB, wB_m1a, bf_m1b1, wB_m1b, bf_m1b2, bufC);
  k_qkv2<<<4096, 256, 0, stream>>>(bufC, wB_qkv2, bf_qkv2, qbuf, kvbuf);
  k_attn2<<<2048, 256, 0, stream>>>(qbuf, kvbuf, bufC);          // y = x + attn, in place
  k_mlp<2><<<2048, 256, 0, stream>>>(bufC, wB_m2a, bf_m2b1, wB_m2b, bf_m2b2, bufD);

  k_tr_pc<<<1024, 256, 0, stream>>>(h0, c0, hws, Cst, hbf, flag);
  for (int n = 0; n < 16; n++){
    k_lstm_step<<<256, 256, 0, stream>>>(bufD, hbf, hws, Cst, wBx, wBh, bf_lbh, d_out, n, flag);
  }
  k_final_t<<<1024, 256, 0, stream>>>(hws, Cst, d_out, flag);
}

// Round 11
// 802.188 us; speedup vs baseline: 9.3022x; 1.0341x over previous
//
#include <hip/hip_runtime.h>
#include <hip/hip_bf16.h>

typedef unsigned int u32;
typedef unsigned short u16;

#define DI __device__ __forceinline__

typedef __attribute__((ext_vector_type(8))) __bf16 bf16x8;
typedef __attribute__((ext_vector_type(4))) float f32x4;

// ---------- bf16 helpers (bf16 == fp32 high 16 bits; RNE on store) ----------
DI float b2f_u(u32 u){ return __uint_as_float(u << 16); }
DI u16 f2b_u(float f){
  u32 x = __float_as_uint(f);
  x += 0x7fffu + ((x >> 16) & 1u);
  return (u16)(x >> 16);
}
DI void ld8b(const u16* p, float* o){
  uint4 v = *reinterpret_cast<const uint4*>(p);
  o[0] = b2f_u(v.x & 0xffffu); o[1] = b2f_u(v.x >> 16);
  o[2] = b2f_u(v.y & 0xffffu); o[3] = b2f_u(v.y >> 16);
  o[4] = b2f_u(v.z & 0xffffu); o[5] = b2f_u(v.z >> 16);
  o[6] = b2f_u(v.w & 0xffffu); o[7] = b2f_u(v.w >> 16);
}
DI void st8b(u16* p, const float* i){
  uint4 v;
  v.x = (u32)f2b_u(i[0]) | ((u32)f2b_u(i[1]) << 16);
  v.y = (u32)f2b_u(i[2]) | ((u32)f2b_u(i[3]) << 16);
  v.z = (u32)f2b_u(i[4]) | ((u32)f2b_u(i[5]) << 16);
  v.w = (u32)f2b_u(i[6]) | ((u32)f2b_u(i[7]) << 16);
  *reinterpret_cast<uint4*>(p) = v;
}

// ---------- K_detect: is d_in fp32 (flag=1) or packed bf16 (flag=0)? ----------
__global__ void k_detect(const u32* __restrict__ xw, int* __restrict__ flag){
  __shared__ int cnt;
  int t = threadIdx.x;
  if (t == 0) cnt = 0;
  __syncthreads();
  int c = 0;
  for (int i = t; i < 2048; i += 256){
    u32 lo = xw[i] & 0xffffu;
    u32 e = (lo >> 7) & 0xffu;
    if (e < 100u || e > 140u) c++;
  }
  atomicAdd(&cnt, c);
  __syncthreads();
  if (t == 0) *flag = (cnt > 200) ? 1 : 0;
}

// ---------- K_prep: ALL weight/bias conversions in ONE launch ----------
__global__ void k_prep(
  const void* __restrict__ conv_w, const void* __restrict__ qkv1_w,
  const void* __restrict__ m1w1, const void* __restrict__ m1w2,
  const void* __restrict__ qkv2_w, const void* __restrict__ m2w1, const void* __restrict__ m2w2,
  const void* __restrict__ lwx, const void* __restrict__ lwh,
  const void* __restrict__ conv_b, const void* __restrict__ qkv1_b,
  const void* __restrict__ m1b1, const void* __restrict__ m1b2,
  const void* __restrict__ qkv2_b, const void* __restrict__ m2b1, const void* __restrict__ m2b2,
  const void* __restrict__ lbh,
  u16* __restrict__ wB_conv, u16* __restrict__ wB_qkv1, u16* __restrict__ wB_m1a,
  u16* __restrict__ wB_m1b, u16* __restrict__ wB_qkv2, u16* __restrict__ wB_m2a,
  u16* __restrict__ wB_m2b, u16* __restrict__ wBx, u16* __restrict__ wBh,
  float* __restrict__ bf_conv, float* __restrict__ bf_qkv1, float* __restrict__ bf_m1b1,
  float* __restrict__ bf_m1b2, float* __restrict__ bf_qkv2, float* __restrict__ bf_m2b1,
  float* __restrict__ bf_m2b2, float* __restrict__ bf_lbh,
  const int* __restrict__ flag){
  int bid = blockIdx.x, t = threadIdx.x;
  int fl = *flag;
  auto cvb = [&](const void* s, u16* d, int base, int n){
    int i = (bid - base)*256 + t;
    if (i < n) d[i] = fl ? f2b_u(((const float*)s)[i]) : ((const u16*)s)[i];
  };
  auto ldf = [&](const void* s, int i)->float{
    return fl ? ((const float*)s)[i] : b2f_u((u32)((const u16*)s)[i]);
  };
  if (bid < 256)       cvb(conv_w, wB_conv, 0,    65536);
  else if (bid < 448)  cvb(qkv1_w, wB_qkv1, 256,  49152);
  else if (bid < 704)  cvb(m1w1,   wB_m1a,  448,  65536);
  else if (bid < 960)  cvb(m1w2,   wB_m1b,  704,  65536);
  else if (bid < 1152) cvb(qkv2_w, wB_qkv2, 960,  49152);
  else if (bid < 1408) cvb(m2w1,   wB_m2a,  1152, 65536);
  else if (bid < 1664) cvb(m2w2,   wB_m2b,  1408, 65536);
  else if (bid < 1920) cvb(lwx,    wBx,     1664, 65536);
  else if (bid < 2176) cvb(lwh,    wBh,     1920, 65536);
  else {
    int i = (bid - 2176)*256 + t;
    if (i < 128)       bf_conv[i]        = ldf(conv_b, i);
    else if (i < 512)  bf_qkv1[i-128]    = ldf(qkv1_b, i-128);
    else if (i < 1024) bf_m1b1[i-512]    = ldf(m1b1,   i-512);
    else if (i < 1152) bf_m1b2[i-1024]   = ldf(m1b2,   i-1024);
    else if (i < 1536) bf_qkv2[i-1152]   = ldf(qkv2_b, i-1152);
    else if (i < 2048) bf_m2b1[i-1536]   = ldf(m2b1,   i-1536);
    else if (i < 2176) bf_m2b2[i-2048]   = ldf(m2b2,   i-2048);
    else if (i < 2688) bf_lbh[i-2176]    = ldf(lbh,    i-2176);
  }
}

// ---------- K1: conv 2x2 s2 + window partition via MFMA, strip-blocked ----------
// Block = (b, yg, xh): 8 input rows x 64 cols x 128 ci -> 128 tokens x 128 co.
// ci streamed in 16-chunks; loads are 128B-contiguous row segments (fully coalesced,
// strips disjoint across blocks). Wave = 2 tok-tiles x 8 co-tiles (weights reused x2).
__global__ __launch_bounds__(256) void k_conv(const void* __restrict__ x_raw,
                                              const u16* __restrict__ wB,
                                              const float* __restrict__ bias, u16* __restrict__ outA,
                                              const int* __restrict__ flag){
  __shared__ __align__(16) u16 pool[128*136];   // Aa [128][72] (first 18.4KB); Ys [128][136] overlay
  u16* Aa = pool;
  u16* Ys = pool;
  int t = threadIdx.x, bid = blockIdx.x;
  int xh = bid & 1, yg = (bid >> 1) & 15, b = bid >> 5;
  size_t slab = (size_t)b*2097152 + (size_t)(yg*8)*128 + (size_t)xh*64;
  int w = t >> 6, lane = t & 63, fr = lane & 15, fg = lane >> 4;
  f32x4 acc[2][8];
  #pragma unroll
  for (int j=0;j<8;j++){
    float bv = bias[j*16 + fr];
    acc[0][j] = {bv,bv,bv,bv};
    acc[1][j] = {bv,bv,bv,bv};
  }
  for (int ci0 = 0; ci0 < 128; ci0 += 16){
    if (ci0) __syncthreads();
    if (*flag){
      const float* xb = (const float*)x_raw + slab + (size_t)ci0*16384;
      #pragma unroll
      for (int i=0;i<4;i++){
        int idx = i*256 + t;            // 0..1023
        int row = idx >> 3, seg = idx & 7;   // row = cr*8+py (0..127), seg = 8-px group
        int cr = row >> 3, py = row & 7;
        const float* sp = xb + (size_t)cr*16384 + py*128 + seg*8;
        float4 v0 = *reinterpret_cast<const float4*>(sp);
        float4 v1 = *reinterpret_cast<const float4*>(sp + 4);
        int tok0 = seg*16 + (py>>1)*4;
        int k0 = cr*4 + (py&1)*2;
        *reinterpret_cast<u32*>(&Aa[(tok0+0)*72 + k0]) = (u32)f2b_u(v0.x) | ((u32)f2b_u(v0.y)<<16);
        *reinterpret_cast<u32*>(&Aa[(tok0+1)*72 + k0]) = (u32)f2b_u(v0.z) | ((u32)f2b_u(v0.w)<<16);
        *reinterpret_cast<u32*>(&Aa[(tok0+2)*72 + k0]) = (u32)f2b_u(v1.x) | ((u32)f2b_u(v1.y)<<16);
        *reinterpret_cast<u32*>(&Aa[(tok0+3)*72 + k0]) = (u32)f2b_u(v1.z) | ((u32)f2b_u(v1.w)<<16);
      }
    } else {
      const u16* xb = (const u16*)x_raw + slab + (size_t)ci0*16384;
      #pragma unroll
      for (int i=0;i<4;i++){
        int idx = i*256 + t;
        int row = idx >> 3, seg = idx & 7;
        int cr = row >> 3, py = row & 7;
        uint4 v = *reinterpret_cast<const uint4*>(xb + (size_t)cr*16384 + py*128 + seg*8);
        int tok0 = seg*16 + (py>>1)*4;
        int k0 = cr*4 + (py&1)*2;
        *reinterpret_cast<u32*>(&Aa[(tok0+0)*72 + k0]) = v.x;
        *reinterpret_cast<u32*>(&Aa[(tok0+1)*72 + k0]) = v.y;
        *reinterpret_cast<u32*>(&Aa[(tok0+2)*72 + k0]) = v.z;
        *reinterpret_cast<u32*>(&Aa[(tok0+3)*72 + k0]) = v.w;
      }
    }
    __syncthreads();
    bf16x8 a0[2], a1[2];
    #pragma unroll
    for (int kk=0;kk<2;kk++){
      a0[kk] = *reinterpret_cast<const bf16x8*>(&Aa[(w*16+fr)*72 + kk*32 + fg*8]);
      a1[kk] = *reinterpret_cast<const bf16x8*>(&Aa[((w+4)*16+fr)*72 + kk*32 + fg*8]);
    }
    #pragma unroll
    for (int j=0;j<8;j++){
      const u16* wp = wB + (size_t)(j*16+fr)*512 + ci0*4 + fg*8;
      bf16x8 b0 = *reinterpret_cast<const bf16x8*>(wp);
      bf16x8 b1 = *reinterpret_cast<const bf16x8*>(wp + 32);
      acc[0][j] = __builtin_amdgcn_mfma_f32_16x16x32_bf16(a0[0], b0, acc[0][j], 0, 0, 0);
      acc[0][j] = __builtin_amdgcn_mfma_f32_16x16x32_bf16(a0[1], b1, acc[0][j], 0, 0, 0);
      acc[1][j] = __builtin_amdgcn_mfma_f32_16x16x32_bf16(a1[0], b0, acc[1][j], 0, 0, 0);
      acc[1][j] = __builtin_amdgcn_mfma_f32_16x16x32_bf16(a1[1], b1, acc[1][j], 0, 0, 0);
    }
  }
  __syncthreads();
  #pragma unroll
  for (int tt=0;tt<2;tt++){
    int tokbase = (w + tt*4)*16;
    #pragma unroll
    for (int j=0;j<8;j++){
      #pragma unroll
      for (int r=0;r<4;r++)
        Ys[(tokbase + fg*4 + r)*136 + j*16 + fr] = f2b_u(acc[tt][j][r]);
    }
  }
  __syncthreads();
  {
    int tok = t >> 1, half = t & 1;
    int gl = yg*16 + xh*8 + (tok >> 4);
    int l = tok & 15;
    u16* dst = outA + ((size_t)(b*256 + gl)*16 + l)*128 + half*64;
    const u16* src = &Ys[tok*136 + half*64];
    #pragma unroll
    for (int q2=0;q2<8;q2++)    // FIX: 8 x uint4 = 64 u16 = full half-row (was 4 -> half dropped)
      *reinterpret_cast<uint4*>(dst + q2*8) = *reinterpret_cast<const uint4*>(src + q2*8);
  }
}

// ---------- K2: LocalMSA (L=16) + residual: bufA -> bufB (same layout) ----------
__global__ __launch_bounds__(256) void k_msa1(const u16* __restrict__ A, const u16* __restrict__ wB,
                                              const float* __restrict__ qbias, u16* __restrict__ B){
  __shared__ u16 Xs[16*136];        // bf16, row stride 272 B
  __shared__ float QKV[16*388];
  __shared__ float S[512];          // [h][l][m]
  int t = threadIdx.x, bid = blockIdx.x;
  {
    int l = t >> 4, c0 = (t & 15)*8;
    *reinterpret_cast<uint4*>(&Xs[l*136 + c0]) =
      *reinterpret_cast<const uint4*>(A + (size_t)bid*2048 + l*128 + c0);
  }
  __syncthreads();
  {
    int w = t >> 6, lane = t & 63, fr = lane & 15, fg = lane >> 4;
    bf16x8 a[4];
    #pragma unroll
    for (int k=0;k<4;k++) a[k] = *reinterpret_cast<const bf16x8*>(&Xs[fr*136 + k*32 + fg*8]);
    #pragma unroll
    for (int j=0;j<6;j++){
      int o = w*96 + j*16 + fr;          // 0..383
      float bv = qbias[o];
      f32x4 d = {bv,bv,bv,bv};
      const u16* wp = wB + (size_t)o*128 + fg*8;
      #pragma unroll
      for (int k=0;k<4;k++){
        bf16x8 b = *reinterpret_cast<const bf16x8*>(wp + k*32);
        d = __builtin_amdgcn_mfma_f32_16x16x32_bf16(a[k], b, d, 0, 0, 0);
      }
      #pragma unroll
      for (int r=0;r<4;r++) QKV[(fg*4+r)*388 + o] = d[r];
    }
  }
  __syncthreads();
  const float scale = 0.08838834764831845f;   // 1/sqrt(128)
  for (int e = t; e < 512; e += 256){
    int h = e >> 8, l = (e>>4)&15, m = e&15;
    const float* q = &QKV[l*388 + h*64];
    const float* kk = &QKV[m*388 + 128 + h*64];
    float s = 0.f;
    #pragma unroll
    for (int d=0; d<64; d++) s += q[d]*kk[d];
    S[(h*16+l)*16 + m] = s*scale;
  }
  __syncthreads();
  if (t < 32){
    float* row = &S[t*16];
    float mx = row[0];
    #pragma unroll
    for (int m=1;m<16;m++) mx = fmaxf(mx,row[m]);
    float sum = 0.f;
    #pragma unroll
    for (int m=0;m<16;m++){ float e = expf(row[m]-mx); row[m]=e; sum+=e; }
    float inv = 1.0f/sum;
    #pragma unroll
    for (int m=0;m<16;m++) row[m] *= inv;
  }
  __syncthreads();
  {
    int l = t >> 4, og = t & 15, o0 = og*8;
    int h = o0 >> 6;
    const float* p = &S[(h*16+l)*16];
    float out8[8];
    #pragma unroll
    for (int j=0;j<8;j++){
      int o = o0+j, d = o & 63;
      float s = 0.f;
      #pragma unroll
      for (int m=0;m<16;m++) s += p[m]*QKV[m*388 + 256 + h*64 + d];
      out8[j] = s + b2f_u((u32)Xs[l*136 + o]);
    }
    st8b(B + (size_t)bid*2048 + l*128 + o0, out8);
  }
}

// ---------- K3/K5: MLP (+residual) via MFMA, 32 tokens/block (2 tiles/wave). ----------
template<int MODE>
__global__ __launch_bounds__(256) void k_mlp(const u16* __restrict__ in,
    const u16* __restrict__ w1B, const float* __restrict__ b1,
    const u16* __restrict__ w2B, const float* __restrict__ b2,
    u16* __restrict__ out){
  __shared__ u16 Xs[32*136];        // bf16 input (also residual)
  __shared__ u16 Hs[32*520];        // bf16 hidden
  __shared__ u16 Ys[32*136];        // bf16 output staging
  int t = threadIdx.x, bid = blockIdx.x;
  {
    int l = t >> 3, c0 = (t & 7)*16;
    const u16* src = in + (size_t)bid*4096 + l*128 + c0;
    *reinterpret_cast<uint4*>(&Xs[l*136 + c0])     = *reinterpret_cast<const uint4*>(src);
    *reinterpret_cast<uint4*>(&Xs[l*136 + c0 + 8]) = *reinterpret_cast<const uint4*>(src + 8);
  }
  __syncthreads();
  int w = t >> 6, lane = t & 63, fr = lane & 15, fg = lane >> 4;

  // ---- GEMM1: H = gelu(X @ W1^T + b1); wave = 8 n-tiles x 2 tok-tiles ----
  {
    bf16x8 a0[4], a1[4];
    #pragma unroll
    for (int k=0;k<4;k++){
      a0[k] = *reinterpret_cast<const bf16x8*>(&Xs[fr*136 + k*32 + fg*8]);
      a1[k] = *reinterpret_cast<const bf16x8*>(&Xs[(16+fr)*136 + k*32 + fg*8]);
    }
    #pragma unroll
    for (int j=0;j<8;j++){
      int o = w*128 + j*16 + fr;        // 0..511
      float bv = b1[o];
      f32x4 d0 = {bv,bv,bv,bv}, d1 = {bv,bv,bv,bv};
      const u16* wp = w1B + (size_t)o*128 + fg*8;
      #pragma unroll
      for (int k=0;k<4;k++){
        bf16x8 b = *reinterpret_cast<const bf16x8*>(wp + k*32);
        d0 = __builtin_amdgcn_mfma_f32_16x16x32_bf16(a0[k], b, d0, 0, 0, 0);
        d1 = __builtin_amdgcn_mfma_f32_16x16x32_bf16(a1[k], b, d1, 0, 0, 0);
      }
      #pragma unroll
      for (int r=0;r<4;r++){
        float v0 = d0[r], v1 = d1[r];
        Hs[(fg*4+r)*520 + o]      = f2b_u(0.5f*v0*(1.0f + erff(v0*0.70710678118654752f)));
        Hs[(16+fg*4+r)*520 + o]   = f2b_u(0.5f*v1*(1.0f + erff(v1*0.70710678118654752f)));
      }
    }
  }
  __syncthreads();

  // ---- GEMM2: Y = H @ W2^T + b2 + X; wave = 2 n-tiles x 2 tok-tiles ----
  {
    int na = w*32 + fr, nb = na + 16;   // 0..127
    float ba = b2[na], bb = b2[nb];
    f32x4 d00 = {ba,ba,ba,ba}, d01 = {bb,bb,bb,bb};
    f32x4 d10 = {ba,ba,ba,ba}, d11 = {bb,bb,bb,bb};
    const u16* wpa = w2B + (size_t)na*512 + fg*8;
    const u16* wpb = w2B + (size_t)nb*512 + fg*8;
    #pragma unroll
    for (int k=0;k<16;k++){
      bf16x8 aa = *reinterpret_cast<const bf16x8*>(&Hs[fr*520 + k*32 + fg*8]);
      bf16x8 ab = *reinterpret_cast<const bf16x8*>(&Hs[(16+fr)*520 + k*32 + fg*8]);
      bf16x8 bA = *reinterpret_cast<const bf16x8*>(wpa + k*32);
      bf16x8 bB = *reinterpret_cast<const bf16x8*>(wpb + k*32);
      d00 = __builtin_amdgcn_mfma_f32_16x16x32_bf16(aa, bA, d00, 0, 0, 0);
      d01 = __builtin_amdgcn_mfma_f32_16x16x32_bf16(aa, bB, d01, 0, 0, 0);
      d10 = __builtin_amdgcn_mfma_f32_16x16x32_bf16(ab, bA, d10, 0, 0, 0);
      d11 = __builtin_amdgcn_mfma_f32_16x16x32_bf16(ab, bB, d11, 0, 0, 0);
    }
    #pragma unroll
    for (int r=0;r<4;r++){
      int ta = fg*4 + r, tb = 16 + ta;
      Ys[ta*136 + na] = f2b_u(d00[r] + b2f_u((u32)Xs[ta*136 + na]));
      Ys[ta*136 + nb] = f2b_u(d01[r] + b2f_u((u32)Xs[ta*136 + nb]));
      Ys[tb*136 + na] = f2b_u(d10[r] + b2f_u((u32)Xs[tb*136 + na]));
      Ys[tb*136 + nb] = f2b_u(d11[r] + b2f_u((u32)Xs[tb*136 + nb]));
    }
  }
  __syncthreads();

  // ---- coalesced store with layout mapping ----
  {
    int tok = t >> 3, oc = (t & 7)*16;
    uint4 v0 = *reinterpret_cast<const uint4*>(&Ys[tok*136 + oc]);
    uint4 v1 = *reinterpret_cast<const uint4*>(&Ys[tok*136 + oc + 8]);
    int T = bid*32 + tok;
    size_t addr;
    if (MODE == 1){
      int b = T >> 12, g = (T >> 4) & 255, ll = T & 15;
      addr = ((size_t)((b*16 + ll)*256 + g))*128 + oc;
    } else {
      int b = T >> 12, ll = (T >> 8) & 15, g = T & 255;
      int pcoord = ((g >> 4)*4 + (ll >> 2))*64 + ((g & 15)*4 + (ll & 3));
      addr = ((size_t)(b*4096 + pcoord))*128 + oc;
    }
    *reinterpret_cast<uint4*>(out + addr)     = v0;
    *reinterpret_cast<uint4*>(out + addr + 8) = v1;
  }
}

// ---------- K4a: QKV projection for DilatedMSA via MFMA ----------
__global__ __launch_bounds__(256) void k_qkv2(const u16* __restrict__ in, const u16* __restrict__ wB,
                                              const float* __restrict__ bias,
                                              u16* __restrict__ qbuf, u16* __restrict__ kvbuf){
  __shared__ u16 Xs[16*136];
  __shared__ u16 Qs[16*392];        // bf16 [tok][384+pad]
  int t = threadIdx.x, bid = blockIdx.x;
  {
    int l = t >> 4, c0 = (t & 15)*8;
    *reinterpret_cast<uint4*>(&Xs[l*136 + c0]) =
      *reinterpret_cast<const uint4*>(in + (size_t)bid*2048 + l*128 + c0);
  }
  __syncthreads();
  {
    int w = t >> 6, lane = t & 63, fr = lane & 15, fg = lane >> 4;
    bf16x8 a[4];
    #pragma unroll
    for (int k=0;k<4;k++) a[k] = *reinterpret_cast<const bf16x8*>(&Xs[fr*136 + k*32 + fg*8]);
    #pragma unroll
    for (int j=0;j<6;j++){
      int o = w*96 + j*16 + fr;          // 0..383
      float bv = bias[o];
      f32x4 d = {bv,bv,bv,bv};
      const u16* wp = wB + (size_t)o*128 + fg*8;
      #pragma unroll
      for (int k=0;k<4;k++){
        bf16x8 b = *reinterpret_cast<const bf16x8*>(wp + k*32);
        d = __builtin_amdgcn_mfma_f32_16x16x32_bf16(a[k], b, d, 0, 0, 0);
      }
      #pragma unroll
      for (int r=0;r<4;r++) Qs[(fg*4+r)*392 + o] = f2b_u(d[r]);
    }
  }
  __syncthreads();
  {
    int l = t >> 4, og = t & 15, o0 = og*24;
    size_t tok = (size_t)bid*16 + l;
    #pragma unroll
    for (int m=0; m<3; m++){
      int oc = o0 + m*8;
      uint4 v = *reinterpret_cast<const uint4*>(&Qs[l*392 + oc]);
      if (oc < 128) *reinterpret_cast<uint4*>(qbuf + tok*128 + oc) = v;
      else          *reinterpret_cast<uint4*>(kvbuf + tok*256 + (oc-128)) = v;
    }
  }
}

// ---------- K4b: DilatedMSA flash attention, full-MFMA (QK^T and PV), in-register softmax ----------
__global__ __launch_bounds__(256) void k_attn2(const u16* __restrict__ qbuf, const u16* __restrict__ kvbuf,
                                               u16* __restrict__ y){
  __shared__ __align__(16) char pool[24064];
  u16* Qb = (u16*)pool;              // [64][72] bf16
  u16* Kb = (u16*)(pool + 9216);     // [32][72] bf16
  u16* Vt = (u16*)(pool + 13824);    // [64 d][40 kt] bf16 (transposed V)
  u16* Pb = (u16*)(pool + 18944);    // [64 q][40 kt] bf16
  float* Os = (float*)pool;          // [64][68] f32, overlays Qb/Kb/Vt after loop

  int t = threadIdx.x, bid = blockIdx.x;
  int qt = bid & 3, h = (bid >> 2) & 1, bl = bid >> 3;
  size_t tokbase = (size_t)bl * 256;
  {
    int r = t >> 2, seg = t & 3;
    const u16* src = qbuf + (tokbase + qt*64 + r)*128 + h*64 + seg*16;
    uint4 v0 = *reinterpret_cast<const uint4*>(src);
    uint4 v1 = *reinterpret_cast<const uint4*>(src + 8);
    *reinterpret_cast<uint4*>(&Qb[r*72 + seg*16])     = v0;
    *reinterpret_cast<uint4*>(&Qb[r*72 + seg*16 + 8]) = v1;
  }
  int w = t >> 6, lane = t & 63;
  int fc = lane & 15, fg = lane >> 4;
  float m_reg[4], l_reg[4];
  #pragma unroll
  for (int r=0;r<4;r++){ m_reg[r] = -1e30f; l_reg[r] = 0.0f; }
  f32x4 o[4];
  #pragma unroll
  for (int j=0;j<4;j++) o[j] = {0.f,0.f,0.f,0.f};
  const float scale = 0.08838834764831845f;

  for (int kt=0; kt<8; kt++){
    {  // stage K rows (bf16)
      int r = t >> 3, seg = t & 7;
      const u16* base = kvbuf + (tokbase + kt*32 + r)*256 + h*64;
      *reinterpret_cast<uint4*>(&Kb[r*72 + seg*8]) = *reinterpret_cast<const uint4*>(base + seg*8);
    }
    {  // stage V transposed
      int pp = t >> 4, dg = t & 15, d0 = dg*4;
      const u16* b0 = kvbuf + (tokbase + kt*32 + 2*pp)*256 + h*64 + 128 + d0;
      uint2 v0 = *reinterpret_cast<const uint2*>(b0);
      uint2 v1 = *reinterpret_cast<const uint2*>(b0 + 256);
      *reinterpret_cast<u32*>(&Vt[(d0+0)*40 + 2*pp]) = (v0.x & 0xffffu) | (v1.x << 16);
      *reinterpret_cast<u32*>(&Vt[(d0+1)*40 + 2*pp]) = (v0.x >> 16) | (v1.x & 0xffff0000u);
      *reinterpret_cast<u32*>(&Vt[(d0+2)*40 + 2*pp]) = (v0.y & 0xffffu) | (v1.y << 16);
      *reinterpret_cast<u32*>(&Vt[(d0+3)*40 + 2*pp]) = (v0.y >> 16) | (v1.y & 0xffff0000u);
    }
    __syncthreads();
    f32x4 s0 = {0.f,0.f,0.f,0.f}, s1 = {0.f,0.f,0.f,0.f};
    {
      bf16x8 a0  = *reinterpret_cast<const bf16x8*>(&Qb[(w*16+fc)*72 + fg*8]);
      bf16x8 a1  = *reinterpret_cast<const bf16x8*>(&Qb[(w*16+fc)*72 + 32 + fg*8]);
      bf16x8 b00 = *reinterpret_cast<const bf16x8*>(&Kb[fc*72 + fg*8]);
      bf16x8 b01 = *reinterpret_cast<const bf16x8*>(&Kb[fc*72 + 32 + fg*8]);
      bf16x8 b10 = *reinterpret_cast<const bf16x8*>(&Kb[(16+fc)*72 + fg*8]);
      bf16x8 b11 = *reinterpret_cast<const bf16x8*>(&Kb[(16+fc)*72 + 32 + fg*8]);
      s0 = __builtin_amdgcn_mfma_f32_16x16x32_bf16(a0, b00, s0, 0, 0, 0);
      s0 = __builtin_amdgcn_mfma_f32_16x16x32_bf16(a1, b01, s0, 0, 0, 0);
      s1 = __builtin_amdgcn_mfma_f32_16x16x32_bf16(a0, b10, s1, 0, 0, 0);
      s1 = __builtin_amdgcn_mfma_f32_16x16x32_bf16(a1, b11, s1, 0, 0, 0);
    }
    float corr[4];
    #pragma unroll
    for (int r=0;r<4;r++){
      float v0 = s0[r]*scale, v1 = s1[r]*scale;
      float mx = fmaxf(v0, v1);
      mx = fmaxf(mx, __shfl_xor(mx, 1));
      mx = fmaxf(mx, __shfl_xor(mx, 2));
      mx = fmaxf(mx, __shfl_xor(mx, 4));
      mx = fmaxf(mx, __shfl_xor(mx, 8));
      float mnew = fmaxf(m_reg[r], mx);
      corr[r] = expf(m_reg[r] - mnew);
      m_reg[r] = mnew;
      float p0 = expf(v0 - mnew), p1 = expf(v1 - mnew);
      float sum = p0 + p1;
      sum += __shfl_xor(sum, 1);
      sum += __shfl_xor(sum, 2);
      sum += __shfl_xor(sum, 4);
      sum += __shfl_xor(sum, 8);
      l_reg[r] = l_reg[r]*corr[r] + sum;
      int row = w*16 + fg*4 + r;
      Pb[row*40 + fc]      = f2b_u(p0);
      Pb[row*40 + 16 + fc] = f2b_u(p1);
    }
    {
      bf16x8 pa = *reinterpret_cast<const bf16x8*>(&Pb[(w*16+fc)*40 + fg*8]);
      #pragma unroll
      for (int jt=0;jt<4;jt++){
        bf16x8 vb = *reinterpret_cast<const bf16x8*>(&Vt[(jt*16+fc)*40 + fg*8]);
        f32x4 oo = o[jt];
        oo[0] *= corr[0]; oo[1] *= corr[1]; oo[2] *= corr[2]; oo[3] *= corr[3];
        o[jt] = __builtin_amdgcn_mfma_f32_16x16x32_bf16(pa, vb, oo, 0, 0, 0);
      }
    }
    __syncthreads();
  }
  float inv[4];
  #pragma unroll
  for (int r=0;r<4;r++) inv[r] = 1.0f / l_reg[r];
  #pragma unroll
  for (int jt=0;jt<4;jt++){
    #pragma unroll
    for (int r=0;r<4;r++)
      Os[(w*16 + fg*4 + r)*68 + jt*16 + fc] = o[jt][r] * inv[r];
  }
  __syncthreads();
  {
    int row = t >> 2, seg = t & 3;
    float ov[16];
    #pragma unroll
    for (int j=0;j<16;j++) ov[j] = Os[row*68 + seg*16 + j];
    u16* dst = y + (tokbase + qt*64 + row)*128 + h*64 + seg*16;
    float res[16]; ld8b(dst, res); ld8b(dst+8, res+8);
    float o16[16];
    #pragma unroll
    for (int j=0;j<16;j++) o16[j] = ov[j] + res[j];
    st8b(dst, o16); st8b(dst+8, o16+8);
  }
}

// ---------- K_tr: h0/c0 [c][4096] -> hws/Cst [pix][128] fp32 + hbf bf16 ----------
__global__ __launch_bounds__(256) void k_tr_pc(const void* __restrict__ h0, const void* __restrict__ c0,
                                               float* __restrict__ hws, float* __restrict__ Cst,
                                               u16* __restrict__ hbf,
                                               const int* __restrict__ flag){
  __shared__ float lds[32][33];
  int t = threadIdx.x, bid = blockIdx.x;
  int sel = bid >> 9, tile = bid & 511;
  int pt2 = tile >> 2, ct = tile & 3;
  const void* src = sel ? c0 : h0;
  float* dst = sel ? Cst : hws;
  int r = t >> 3, q = t & 7;
  {
    int c = ct*32 + r;
    int px = pt2*32 + q*4;
    if (*flag){
      float4 v = *reinterpret_cast<const float4*>((const float*)src + (size_t)c*4096 + px);
      lds[r][q*4+0]=v.x; lds[r][q*4+1]=v.y; lds[r][q*4+2]=v.z; lds[r][q*4+3]=v.w;
    } else {
      uint2 u = *reinterpret_cast<const uint2*>((const u16*)src + (size_t)c*4096 + px);
      lds[r][q*4+0]=b2f_u(u.x & 0xffffu); lds[r][q*4+1]=b2f_u(u.x >> 16);
      lds[r][q*4+2]=b2f_u(u.y & 0xffffu); lds[r][q*4+3]=b2f_u(u.y >> 16);
    }
  }
  __syncthreads();
  {
    int px = pt2*32 + r;
    int c = ct*32 + q*4;
    float4 o;
    o.x = lds[q*4+0][r]; o.y = lds[q*4+1][r]; o.z = lds[q*4+2][r]; o.w = lds[q*4+3][r];
    *reinterpret_cast<float4*>(dst + (size_t)px*128 + c) = o;
    if (sel == 0){
      uint2 pk;
      pk.x = (u32)f2b_u(o.x) | ((u32)f2b_u(o.y) << 16);
      pk.y = (u32)f2b_u(o.z) | ((u32)f2b_u(o.w) << 16);
      *reinterpret_cast<uint2*>(hbf + (size_t)px*128 + c) = pk;
    }
  }
}

// ---------- K6: fused LSTM step via MFMA; block = 16 px, wave = gate ----------
__global__ __launch_bounds__(256) void k_lstm_step(const u16* __restrict__ xD,
    u16* __restrict__ hbf, float* __restrict__ hws, float* __restrict__ Cst,
    const u16* __restrict__ wBx, const u16* __restrict__ wBh, const float* __restrict__ bh,
    void* __restrict__ dout, int n, const int* __restrict__ flag){
  __shared__ u16 Xa[16*136];         // x bf16
  __shared__ u16 Ha[16*136];         // h bf16
  __shared__ float glds[4*16*132];   // [gate][px][132-pad ch] f32
  __shared__ u16 hst[16*136];        // h-new bf16 staging for d_out
  int t = threadIdx.x, bid = blockIdx.x;
  int pix0 = bid*16;
  {
    int px = t >> 4, c0 = (t & 15)*8;
    *reinterpret_cast<uint4*>(&Xa[px*136 + c0]) =
      *reinterpret_cast<const uint4*>(xD + ((size_t)n*4096 + pix0 + px)*128 + c0);
    *reinterpret_cast<uint4*>(&Ha[px*136 + c0]) =
      *reinterpret_cast<const uint4*>(hbf + (size_t)(pix0 + px)*128 + c0);
  }
  __syncthreads();
  int w = t >> 6, lane = t & 63, fr = lane & 15, fg = lane >> 4;
  f32x4 acc[8];
  {
    bf16x8 ax[4], ah[4];
    #pragma unroll
    for (int k=0;k<4;k++){
      ax[k] = *reinterpret_cast<const bf16x8*>(&Xa[fr*136 + k*32 + fg*8]);
      ah[k] = *reinterpret_cast<const bf16x8*>(&Ha[fr*136 + k*32 + fg*8]);
    }
    #pragma unroll
    for (int j=0;j<8;j++){
      int o = w*128 + j*16 + fr;
      float bv = bh[o];
      f32x4 d = {bv,bv,bv,bv};
      const u16* wpx = wBx + (size_t)o*128 + fg*8;
      const u16* wph = wBh + (size_t)o*128 + fg*8;
      #pragma unroll
      for (int k=0;k<4;k++){
        bf16x8 b = *reinterpret_cast<const bf16x8*>(wpx + k*32);
        d = __builtin_amdgcn_mfma_f32_16x16x32_bf16(ax[k], b, d, 0, 0, 0);
      }
      #pragma unroll
      for (int k=0;k<4;k++){
        bf16x8 b = *reinterpret_cast<const bf16x8*>(wph + k*32);
        d = __builtin_amdgcn_mfma_f32_16x16x32_bf16(ah[k], b, d, 0, 0, 0);
      }
      acc[j] = d;
    }
  }
  if (w == 2){
    #pragma unroll
    for (int j=0;j<8;j++)
      #pragma unroll
      for (int r=0;r<4;r++)
        glds[(w*16 + fg*4 + r)*132 + j*16 + fr] = tanhf(acc[j][r]);
  } else {
    #pragma unroll
    for (int r=0;r<4;r++){
      float mx = acc[0][r];
      #pragma unroll
      for (int j=1;j<8;j++) mx = fmaxf(mx, acc[j][r]);
      mx = fmaxf(mx, __shfl_xor(mx, 1));
      mx = fmaxf(mx, __shfl_xor(mx, 2));
      mx = fmaxf(mx, __shfl_xor(mx, 4));
      mx = fmaxf(mx, __shfl_xor(mx, 8));
      float e[8], sum = 0.f;
      #pragma unroll
      for (int j=0;j<8;j++){ e[j] = expf(acc[j][r] - mx); sum += e[j]; }
      sum += __shfl_xor(sum, 1);
      sum += __shfl_xor(sum, 2);
      sum += __shfl_xor(sum, 4);
      sum += __shfl_xor(sum, 8);
      float inv = 1.0f/sum;
      #pragma unroll
      for (int j=0;j<8;j++)
        glds[(w*16 + fg*4 + r)*132 + j*16 + fr] = e[j]*inv;
    }
  }
  __syncthreads();
  {
    int chg = t & 15, px = t >> 4;
    int ch0 = chg*8;
    int pix = pix0 + px;
    float fv[8], iv[8], sv[8], ov[8], cc[8];
    #pragma unroll
    for (int q2=0;q2<2;q2++){
      *reinterpret_cast<float4*>(&fv[q2*4]) = *reinterpret_cast<const float4*>(&glds[(0*16+px)*132 + ch0 + q2*4]);
      *reinterpret_cast<float4*>(&iv[q2*4]) = *reinterpret_cast<const float4*>(&glds[(1*16+px)*132 + ch0 + q2*4]);
      *reinterpret_cast<float4*>(&sv[q2*4]) = *reinterpret_cast<const float4*>(&glds[(2*16+px)*132 + ch0 + q2*4]);
      *reinterpret_cast<float4*>(&ov[q2*4]) = *reinterpret_cast<const float4*>(&glds[(3*16+px)*132 + ch0 + q2*4]);
      *reinterpret_cast<float4*>(&cc[q2*4]) = *reinterpret_cast<const float4*>(Cst + (size_t)pix*128 + ch0 + q2*4);
    }
    float cn[8], hn[8];
    #pragma unroll
    for (int j=0;j<8;j++){
      cn[j] = fv[j]*cc[j] + iv[j]*sv[j];
      hn[j] = ov[j]*tanhf(cn[j]);
    }
    #pragma unroll
    for (int q2=0;q2<2;q2++){
      *reinterpret_cast<float4*>(Cst + (size_t)pix*128 + ch0 + q2*4) = *reinterpret_cast<const float4*>(&cn[q2*4]);
      *reinterpret_cast<float4*>(hws + (size_t)pix*128 + ch0 + q2*4) = *reinterpret_cast<const float4*>(&hn[q2*4]);
    }
    uint4 pk;
    pk.x = (u32)f2b_u(hn[0]) | ((u32)f2b_u(hn[1]) << 16);
    pk.y = (u32)f2b_u(hn[2]) | ((u32)f2b_u(hn[3]) << 16);
    pk.z = (u32)f2b_u(hn[4]) | ((u32)f2b_u(hn[5]) << 16);
    pk.w = (u32)f2b_u(hn[6]) | ((u32)f2b_u(hn[7]) << 16);
    *reinterpret_cast<uint4*>(hbf + (size_t)pix*128 + ch0) = pk;
    *reinterpret_cast<uint4*>(&hst[px*136 + ch0]) = pk;
  }
  __syncthreads();
  {
    int ch = t >> 1, ph = t & 1;
    size_t ob = (size_t)n*524288 + (size_t)ch*4096 + pix0 + ph*8;
    if (*flag){
      float* df = (float*)dout;
      float v[8];
      #pragma unroll
      for (int i=0;i<8;i++) v[i] = b2f_u((u32)hst[(ph*8+i)*136 + ch]);
      *reinterpret_cast<float4*>(df + ob)     = make_float4(v[0],v[1],v[2],v[3]);
      *reinterpret_cast<float4*>(df + ob + 4) = make_float4(v[4],v[5],v[6],v[7]);
    } else {
      u16* db = (u16*)dout;
      uint4 pk;
      pk.x = (u32)hst[(ph*8+0)*136 + ch] | ((u32)hst[(ph*8+1)*136 + ch] << 16);
      pk.y = (u32)hst[(ph*8+2)*136 + ch] | ((u32)hst[(ph*8+3)*136 + ch] << 16);
      pk.z = (u32)hst[(ph*8+4)*136 + ch] | ((u32)hst[(ph*8+5)*136 + ch] << 16);
      pk.w = (u32)hst[(ph*8+6)*136 + ch] | ((u32)hst[(ph*8+7)*136 + ch] << 16);
      *reinterpret_cast<uint4*>(db + ob) = pk;
    }
  }
}

// ---------- K7: final hf, Cf: [pix][128] fp32 -> d_out [c][4096] (tiled transpose, dtype) ----------
__global__ __launch_bounds__(256) void k_final_t(const float* __restrict__ hws, const float* __restrict__ Cst,
                                                 void* __restrict__ dout, const int* __restrict__ flag){
  __shared__ float lds[32][33];
  int t = threadIdx.x, bid = blockIdx.x;
  int sel = bid >> 9, tile = bid & 511;
  int pt2 = tile >> 2, ct = tile & 3;
  const float* src = sel ? Cst : hws;
  size_t base = sel ? 8912896u : 8388608u;
  int r = t >> 3, q = t & 7;
  {
    int px = pt2*32 + r, c = ct*32 + q*4;
    float4 v = *reinterpret_cast<const float4*>(src + (size_t)px*128 + c);
    lds[r][q*4+0]=v.x; lds[r][q*4+1]=v.y; lds[r][q*4+2]=v.z; lds[r][q*4+3]=v.w;
  }
  __syncthreads();
  {
    int c = ct*32 + r, px = pt2*32 + q*4;
    float v0 = lds[q*4+0][r], v1 = lds[q*4+1][r], v2 = lds[q*4+2][r], v3 = lds[q*4+3][r];
    if (*flag){
      *reinterpret_cast<float4*>((float*)dout + base + (size_t)c*4096 + px) = make_float4(v0,v1,v2,v3);
    } else {
      uint2 pk;
      pk.x = (u32)f2b_u(v0) | ((u32)f2b_u(v1) << 16);
      pk.y = (u32)f2b_u(v2) | ((u32)f2b_u(v3) << 16);
      *reinterpret_cast<uint2*>((u16*)dout + base + (size_t)c*4096 + px) = pk;
    }
  }
}

extern "C" void kernel_launch(void* const* d_in, const int* in_sizes, int n_in,
                              void* d_out, int out_size, void* d_ws, size_t ws_size,
                              hipStream_t stream) {
  const void* x      = d_in[0];
  const void* h0     = d_in[1];
  const void* c0     = d_in[2];
  const void* conv_w = d_in[3];
  const void* conv_b = d_in[4];
  const void* qkv1_w = d_in[5];
  const void* qkv1_b = d_in[6];
  const void* m1w1   = d_in[7];
  const void* m1b1   = d_in[8];
  const void* m1w2   = d_in[9];
  const void* m1b2   = d_in[10];
  const void* qkv2_w = d_in[11];
  const void* qkv2_b = d_in[12];
  const void* m2w1   = d_in[13];
  const void* m2b1   = d_in[14];
  const void* m2w2   = d_in[15];
  const void* m2b2   = d_in[16];
  const void* lwx    = d_in[17];
  const void* lwh    = d_in[18];
  const void* lbh    = d_in[19];

  char* p = (char*)d_ws;
  auto alloc = [&](size_t bytes)->void*{
    void* r = (void*)p; p += (bytes + 255) & ~(size_t)255; return r;
  };
  int*   flag    = (int*)alloc(256);
  u16* wB_conv = (u16*)alloc(128*512*2);       // bf16, native [co][ci*4+ky*2+kx]
  u16* wB_qkv1 = (u16*)alloc(384*128*2);       // bf16, original [o][k]
  u16* wB_m1a  = (u16*)alloc(512*128*2);
  u16* wB_m1b  = (u16*)alloc(128*512*2);
  u16* wB_qkv2 = (u16*)alloc(384*128*2);
  u16* wB_m2a  = (u16*)alloc(512*128*2);
  u16* wB_m2b  = (u16*)alloc(128*512*2);
  u16* wBx     = (u16*)alloc(512*128*2);       // bf16, original [o][k] (LSTM x)
  u16* wBh     = (u16*)alloc(512*128*2);       // bf16, original [o][k] (LSTM h)
  float* bf_conv = (float*)alloc(128*4);
  float* bf_qkv1 = (float*)alloc(384*4);
  float* bf_m1b1 = (float*)alloc(512*4);
  float* bf_m1b2 = (float*)alloc(128*4);
  float* bf_qkv2 = (float*)alloc(384*4);
  float* bf_m2b1 = (float*)alloc(512*4);
  float* bf_m2b2 = (float*)alloc(128*4);
  float* bf_lbh  = (float*)alloc(512*4);
  u16* R0   = (u16*)alloc(16777216);   // bufA -> bufC/y -> (hws, Cst, hbf)
  u16* Rbig = (u16*)alloc(33554432);   // bufB (front) -> kvbuf -> bufD (front)

  u16* bufA = R0;
  u16* bufB = Rbig;
  u16* bufC = R0;          // also y (attn writes in place)
  u16* qbuf = (u16*)d_out; // hs region used as scratch; dead before first LSTM write
  u16* kvbuf = Rbig;
  u16* bufD = Rbig;
  float* hws = (float*)((char*)R0 + 8388608);         // 2 MB, [pix][128] fp32
  float* Cst = (float*)((char*)R0 + 10485760);        // 2 MB, [pix][128] fp32
  u16*   hbf = (u16*)((char*)R0 + 12582912);          // 1 MB, [pix][128] bf16

  k_detect<<<1, 256, 0, stream>>>((const u32*)x, flag);

  k_prep<<<2187, 256, 0, stream>>>(
      conv_w, qkv1_w, m1w1, m1w2, qkv2_w, m2w1, m2w2, lwx, lwh,
      conv_b, qkv1_b, m1b1, m1b2, qkv2_b, m2b1, m2b2, lbh,
      wB_conv, wB_qkv1, wB_m1a, wB_m1b, wB_qkv2, wB_m2a, wB_m2b,
      wBx, wBh,
      bf_conv, bf_qkv1, bf_m1b1, bf_m1b2, bf_qkv2, bf_m2b1, bf_m2b2, bf_lbh,
      flag);

  k_conv<<<512, 256, 0, stream>>>(x, wB_conv, bf_conv, bufA, flag);
  k_msa1<<<4096, 256, 0, stream>>>(bufA, wB_qkv1, bf_qkv1, bufB);
  k_mlp<1><<<2048, 256, 0, stream>>>(bufB, wB_m1a, bf_m1b1, wB_m1b, bf_m1b2, bufC);
  k_qkv2<<<4096, 256, 0, stream>>>(bufC, wB_qkv2, bf_qkv2, qbuf, kvbuf);
  k_attn2<<<2048, 256, 0, stream>>>(qbuf, kvbuf, bufC);          // y = x + attn, in place
  k_mlp<2><<<2048, 256, 0, stream>>>(bufC, wB_m2a, bf_m2b1, wB_m2b, bf_m2b2, bufD);

  k_tr_pc<<<1024, 256, 0, stream>>>(h0, c0, hws, Cst, hbf, flag);
  for (int n = 0; n < 16; n++){
    k_lstm_step<<<256, 256, 0, stream>>>(bufD, hbf, hws, Cst, wBx, wBh, bf_lbh, d_out, n, flag);
  }
  k_final_t<<<1024, 256, 0, stream>>>(hws, Cst, d_out, flag);
}

// Round 12
// 663.948 us; speedup vs baseline: 11.2390x; 1.2082x over previous
//
#include <hip/hip_runtime.h>
#include <hip/hip_bf16.h>

typedef unsigned int u32;
typedef unsigned short u16;

#define DI __device__ __forceinline__

typedef __attribute__((ext_vector_type(8))) __bf16 bf16x8;
typedef __attribute__((ext_vector_type(4))) float f32x4;

// ---------- bf16 helpers (bf16 == fp32 high 16 bits; RNE on store) ----------
DI float b2f_u(u32 u){ return __uint_as_float(u << 16); }
DI u16 f2b_u(float f){
  u32 x = __float_as_uint(f);
  x += 0x7fffu + ((x >> 16) & 1u);
  return (u16)(x >> 16);
}
DI void ld8b(const u16* p, float* o){
  uint4 v = *reinterpret_cast<const uint4*>(p);
  o[0] = b2f_u(v.x & 0xffffu); o[1] = b2f_u(v.x >> 16);
  o[2] = b2f_u(v.y & 0xffffu); o[3] = b2f_u(v.y >> 16);
  o[4] = b2f_u(v.z & 0xffffu); o[5] = b2f_u(v.z >> 16);
  o[6] = b2f_u(v.w & 0xffffu); o[7] = b2f_u(v.w >> 16);
}
DI void st8b(u16* p, const float* i){
  uint4 v;
  v.x = (u32)f2b_u(i[0]) | ((u32)f2b_u(i[1]) << 16);
  v.y = (u32)f2b_u(i[2]) | ((u32)f2b_u(i[3]) << 16);
  v.z = (u32)f2b_u(i[4]) | ((u32)f2b_u(i[5]) << 16);
  v.w = (u32)f2b_u(i[6]) | ((u32)f2b_u(i[7]) << 16);
  *reinterpret_cast<uint4*>(p) = v;
}

// ---------- K_detect: is d_in fp32 (flag=1) or packed bf16 (flag=0)? ----------
__global__ void k_detect(const u32* __restrict__ xw, int* __restrict__ flag){
  __shared__ int cnt;
  int t = threadIdx.x;
  if (t == 0) cnt = 0;
  __syncthreads();
  int c = 0;
  for (int i = t; i < 2048; i += 256){
    u32 lo = xw[i] & 0xffffu;
    u32 e = (lo >> 7) & 0xffu;
    if (e < 100u || e > 140u) c++;
  }
  atomicAdd(&cnt, c);
  __syncthreads();
  if (t == 0) *flag = (cnt > 200) ? 1 : 0;
}

// ---------- K_prep: ALL weight/bias conversions in ONE launch ----------
__global__ void k_prep(
  const void* __restrict__ conv_w, const void* __restrict__ qkv1_w,
  const void* __restrict__ m1w1, const void* __restrict__ m1w2,
  const void* __restrict__ qkv2_w, const void* __restrict__ m2w1, const void* __restrict__ m2w2,
  const void* __restrict__ lwx, const void* __restrict__ lwh,
  const void* __restrict__ conv_b, const void* __restrict__ qkv1_b,
  const void* __restrict__ m1b1, const void* __restrict__ m1b2,
  const void* __restrict__ qkv2_b, const void* __restrict__ m2b1, const void* __restrict__ m2b2,
  const void* __restrict__ lbh,
  u16* __restrict__ wB_conv, u16* __restrict__ wB_qkv1, u16* __restrict__ wB_m1a,
  u16* __restrict__ wB_m1b, u16* __restrict__ wB_qkv2, u16* __restrict__ wB_m2a,
  u16* __restrict__ wB_m2b, u16* __restrict__ wBx, u16* __restrict__ wBh,
  float* __restrict__ bf_conv, float* __restrict__ bf_qkv1, float* __restrict__ bf_m1b1,
  float* __restrict__ bf_m1b2, float* __restrict__ bf_qkv2, float* __restrict__ bf_m2b1,
  float* __restrict__ bf_m2b2, float* __restrict__ bf_lbh,
  const int* __restrict__ flag){
  int bid = blockIdx.x, t = threadIdx.x;
  int fl = *flag;
  auto cvb = [&](const void* s, u16* d, int base, int n){
    int i = (bid - base)*256 + t;
    if (i < n) d[i] = fl ? f2b_u(((const float*)s)[i]) : ((const u16*)s)[i];
  };
  auto ldf = [&](const void* s, int i)->float{
    return fl ? ((const float*)s)[i] : b2f_u((u32)((const u16*)s)[i]);
  };
  if (bid < 256)       cvb(conv_w, wB_conv, 0,    65536);
  else if (bid < 448)  cvb(qkv1_w, wB_qkv1, 256,  49152);
  else if (bid < 704)  cvb(m1w1,   wB_m1a,  448,  65536);
  else if (bid < 960)  cvb(m1w2,   wB_m1b,  704,  65536);
  else if (bid < 1152) cvb(qkv2_w, wB_qkv2, 960,  49152);
  else if (bid < 1408) cvb(m2w1,   wB_m2a,  1152, 65536);
  else if (bid < 1664) cvb(m2w2,   wB_m2b,  1408, 65536);
  else if (bid < 1920) cvb(lwx,    wBx,     1664, 65536);
  else if (bid < 2176) cvb(lwh,    wBh,     1920, 65536);
  else {
    int i = (bid - 2176)*256 + t;
    if (i < 128)       bf_conv[i]        = ldf(conv_b, i);
    else if (i < 512)  bf_qkv1[i-128]    = ldf(qkv1_b, i-128);
    else if (i < 1024) bf_m1b1[i-512]    = ldf(m1b1,   i-512);
    else if (i < 1152) bf_m1b2[i-1024]   = ldf(m1b2,   i-1024);
    else if (i < 1536) bf_qkv2[i-1152]   = ldf(qkv2_b, i-1152);
    else if (i < 2048) bf_m2b1[i-1536]   = ldf(m2b1,   i-1536);
    else if (i < 2176) bf_m2b2[i-2048]   = ldf(m2b2,   i-2048);
    else if (i < 2688) bf_lbh[i-2176]    = ldf(lbh,    i-2176);
  }
}

// ---------- K1: conv 2x2 s2 + window partition via MFMA, strip-blocked ----------
__global__ __launch_bounds__(256) void k_conv(const void* __restrict__ x_raw,
                                              const u16* __restrict__ wB,
                                              const float* __restrict__ bias, u16* __restrict__ outA,
                                              const int* __restrict__ flag){
  __shared__ __align__(16) u16 pool[128*136];   // Aa [128][72] (first 18.4KB); Ys [128][136] overlay
  u16* Aa = pool;
  u16* Ys = pool;
  int t = threadIdx.x, bid = blockIdx.x;
  int xh = bid & 1, yg = (bid >> 1) & 15, b = bid >> 5;
  size_t slab = (size_t)b*2097152 + (size_t)(yg*8)*128 + (size_t)xh*64;
  int w = t >> 6, lane = t & 63, fr = lane & 15, fg = lane >> 4;
  f32x4 acc[2][8];
  #pragma unroll
  for (int j=0;j<8;j++){
    float bv = bias[j*16 + fr];
    acc[0][j] = {bv,bv,bv,bv};
    acc[1][j] = {bv,bv,bv,bv};
  }
  for (int ci0 = 0; ci0 < 128; ci0 += 16){
    if (ci0) __syncthreads();
    if (*flag){
      const float* xb = (const float*)x_raw + slab + (size_t)ci0*16384;
      #pragma unroll
      for (int i=0;i<4;i++){
        int idx = i*256 + t;            // 0..1023
        int row = idx >> 3, seg = idx & 7;   // row = cr*8+py (0..127), seg = 8-px group
        int cr = row >> 3, py = row & 7;
        const float* sp = xb + (size_t)cr*16384 + py*128 + seg*8;
        float4 v0 = *reinterpret_cast<const float4*>(sp);
        float4 v1 = *reinterpret_cast<const float4*>(sp + 4);
        int tok0 = seg*16 + (py>>1)*4;
        int k0 = cr*4 + (py&1)*2;
        *reinterpret_cast<u32*>(&Aa[(tok0+0)*72 + k0]) = (u32)f2b_u(v0.x) | ((u32)f2b_u(v0.y)<<16);
        *reinterpret_cast<u32*>(&Aa[(tok0+1)*72 + k0]) = (u32)f2b_u(v0.z) | ((u32)f2b_u(v0.w)<<16);
        *reinterpret_cast<u32*>(&Aa[(tok0+2)*72 + k0]) = (u32)f2b_u(v1.x) | ((u32)f2b_u(v1.y)<<16);
        *reinterpret_cast<u32*>(&Aa[(tok0+3)*72 + k0]) = (u32)f2b_u(v1.z) | ((u32)f2b_u(v1.w)<<16);
      }
    } else {
      const u16* xb = (const u16*)x_raw + slab + (size_t)ci0*16384;
      #pragma unroll
      for (int i=0;i<4;i++){
        int idx = i*256 + t;
        int row = idx >> 3, seg = idx & 7;
        int cr = row >> 3, py = row & 7;
        uint4 v = *reinterpret_cast<const uint4*>(xb + (size_t)cr*16384 + py*128 + seg*8);
        int tok0 = seg*16 + (py>>1)*4;
        int k0 = cr*4 + (py&1)*2;
        *reinterpret_cast<u32*>(&Aa[(tok0+0)*72 + k0]) = v.x;
        *reinterpret_cast<u32*>(&Aa[(tok0+1)*72 + k0]) = v.y;
        *reinterpret_cast<u32*>(&Aa[(tok0+2)*72 + k0]) = v.z;
        *reinterpret_cast<u32*>(&Aa[(tok0+3)*72 + k0]) = v.w;
      }
    }
    __syncthreads();
    bf16x8 a0[2], a1[2];
    #pragma unroll
    for (int kk=0;kk<2;kk++){
      a0[kk] = *reinterpret_cast<const bf16x8*>(&Aa[(w*16+fr)*72 + kk*32 + fg*8]);
      a1[kk] = *reinterpret_cast<const bf16x8*>(&Aa[((w+4)*16+fr)*72 + kk*32 + fg*8]);
    }
    #pragma unroll
    for (int j=0;j<8;j++){
      const u16* wp = wB + (size_t)(j*16+fr)*512 + ci0*4 + fg*8;
      bf16x8 b0 = *reinterpret_cast<const bf16x8*>(wp);
      bf16x8 b1 = *reinterpret_cast<const bf16x8*>(wp + 32);
      acc[0][j] = __builtin_amdgcn_mfma_f32_16x16x32_bf16(a0[0], b0, acc[0][j], 0, 0, 0);
      acc[0][j] = __builtin_amdgcn_mfma_f32_16x16x32_bf16(a0[1], b1, acc[0][j], 0, 0, 0);
      acc[1][j] = __builtin_amdgcn_mfma_f32_16x16x32_bf16(a1[0], b0, acc[1][j], 0, 0, 0);
      acc[1][j] = __builtin_amdgcn_mfma_f32_16x16x32_bf16(a1[1], b1, acc[1][j], 0, 0, 0);
    }
  }
  __syncthreads();
  #pragma unroll
  for (int tt=0;tt<2;tt++){
    int tokbase = (w + tt*4)*16;
    #pragma unroll
    for (int j=0;j<8;j++){
      #pragma unroll
      for (int r=0;r<4;r++)
        Ys[(tokbase + fg*4 + r)*136 + j*16 + fr] = f2b_u(acc[tt][j][r]);
    }
  }
  __syncthreads();
  {
    int tok = t >> 1, half = t & 1;
    int gl = yg*16 + xh*8 + (tok >> 4);
    int l = tok & 15;
    u16* dst = outA + ((size_t)(b*256 + gl)*16 + l)*128 + half*64;
    const u16* src = &Ys[tok*136 + half*64];
    #pragma unroll
    for (int q2=0;q2<8;q2++)
      *reinterpret_cast<uint4*>(dst + q2*8) = *reinterpret_cast<const uint4*>(src + q2*8);
  }
}

// ---------- K2: LocalMSA (L=16) + residual: bufA -> bufB (same layout) ----------
__global__ __launch_bounds__(256) void k_msa1(const u16* __restrict__ A, const u16* __restrict__ wB,
                                              const float* __restrict__ qbias, u16* __restrict__ B){
  __shared__ u16 Xs[16*136];        // bf16, row stride 272 B
  __shared__ float QKV[16*388];
  __shared__ float S[512];          // [h][l][m]
  int t = threadIdx.x, bid = blockIdx.x;
  {
    int l = t >> 4, c0 = (t & 15)*8;
    *reinterpret_cast<uint4*>(&Xs[l*136 + c0]) =
      *reinterpret_cast<const uint4*>(A + (size_t)bid*2048 + l*128 + c0);
  }
  __syncthreads();
  {
    int w = t >> 6, lane = t & 63, fr = lane & 15, fg = lane >> 4;
    bf16x8 a[4];
    #pragma unroll
    for (int k=0;k<4;k++) a[k] = *reinterpret_cast<const bf16x8*>(&Xs[fr*136 + k*32 + fg*8]);
    #pragma unroll
    for (int j=0;j<6;j++){
      int o = w*96 + j*16 + fr;          // 0..383
      float bv = qbias[o];
      f32x4 d = {bv,bv,bv,bv};
      const u16* wp = wB + (size_t)o*128 + fg*8;
      #pragma unroll
      for (int k=0;k<4;k++){
        bf16x8 b = *reinterpret_cast<const bf16x8*>(wp + k*32);
        d = __builtin_amdgcn_mfma_f32_16x16x32_bf16(a[k], b, d, 0, 0, 0);
      }
      #pragma unroll
      for (int r=0;r<4;r++) QKV[(fg*4+r)*388 + o] = d[r];
    }
  }
  __syncthreads();
  const float scale = 0.08838834764831845f;   // 1/sqrt(128)
  for (int e = t; e < 512; e += 256){
    int h = e >> 8, l = (e>>4)&15, m = e&15;
    const float* q = &QKV[l*388 + h*64];
    const float* kk = &QKV[m*388 + 128 + h*64];
    float s = 0.f;
    #pragma unroll
    for (int d=0; d<64; d++) s += q[d]*kk[d];
    S[(h*16+l)*16 + m] = s*scale;
  }
  __syncthreads();
  if (t < 32){
    float* row = &S[t*16];
    float mx = row[0];
    #pragma unroll
    for (int m=1;m<16;m++) mx = fmaxf(mx,row[m]);
    float sum = 0.f;
    #pragma unroll
    for (int m=0;m<16;m++){ float e = expf(row[m]-mx); row[m]=e; sum+=e; }
    float inv = 1.0f/sum;
    #pragma unroll
    for (int m=0;m<16;m++) row[m] *= inv;
  }
  __syncthreads();
  {
    int l = t >> 4, og = t & 15, o0 = og*8;
    int h = o0 >> 6;
    const float* p = &S[(h*16+l)*16];
    float out8[8];
    #pragma unroll
    for (int j=0;j<8;j++){
      int o = o0+j, d = o & 63;
      float s = 0.f;
      #pragma unroll
      for (int m=0;m<16;m++) s += p[m]*QKV[m*388 + 256 + h*64 + d];
      out8[j] = s + b2f_u((u32)Xs[l*136 + o]);
    }
    st8b(B + (size_t)bid*2048 + l*128 + o0, out8);
  }
}

// ---------- K3/K5: MLP (+residual) via MFMA, 32 tokens/block (2 tiles/wave). ----------
template<int MODE>
__global__ __launch_bounds__(256) void k_mlp(const u16* __restrict__ in,
    const u16* __restrict__ w1B, const float* __restrict__ b1,
    const u16* __restrict__ w2B, const float* __restrict__ b2,
    u16* __restrict__ out){
  __shared__ u16 Xs[32*136];        // bf16 input (also residual)
  __shared__ u16 Hs[32*520];        // bf16 hidden
  __shared__ u16 Ys[32*136];        // bf16 output staging
  int t = threadIdx.x, bid = blockIdx.x;
  {
    int l = t >> 3, c0 = (t & 7)*16;
    const u16* src = in + (size_t)bid*4096 + l*128 + c0;
    *reinterpret_cast<uint4*>(&Xs[l*136 + c0])     = *reinterpret_cast<const uint4*>(src);
    *reinterpret_cast<uint4*>(&Xs[l*136 + c0 + 8]) = *reinterpret_cast<const uint4*>(src + 8);
  }
  __syncthreads();
  int w = t >> 6, lane = t & 63, fr = lane & 15, fg = lane >> 4;

  // ---- GEMM1: H = gelu(X @ W1^T + b1); wave = 8 n-tiles x 2 tok-tiles ----
  {
    bf16x8 a0[4], a1[4];
    #pragma unroll
    for (int k=0;k<4;k++){
      a0[k] = *reinterpret_cast<const bf16x8*>(&Xs[fr*136 + k*32 + fg*8]);
      a1[k] = *reinterpret_cast<const bf16x8*>(&Xs[(16+fr)*136 + k*32 + fg*8]);
    }
    #pragma unroll
    for (int j=0;j<8;j++){
      int o = w*128 + j*16 + fr;        // 0..511
      float bv = b1[o];
      f32x4 d0 = {bv,bv,bv,bv}, d1 = {bv,bv,bv,bv};
      const u16* wp = w1B + (size_t)o*128 + fg*8;
      #pragma unroll
      for (int k=0;k<4;k++){
        bf16x8 b = *reinterpret_cast<const bf16x8*>(wp + k*32);
        d0 = __builtin_amdgcn_mfma_f32_16x16x32_bf16(a0[k], b, d0, 0, 0, 0);
        d1 = __builtin_amdgcn_mfma_f32_16x16x32_bf16(a1[k], b, d1, 0, 0, 0);
      }
      #pragma unroll
      for (int r=0;r<4;r++){
        float v0 = d0[r], v1 = d1[r];
        Hs[(fg*4+r)*520 + o]      = f2b_u(0.5f*v0*(1.0f + erff(v0*0.70710678118654752f)));
        Hs[(16+fg*4+r)*520 + o]   = f2b_u(0.5f*v1*(1.0f + erff(v1*0.70710678118654752f)));
      }
    }
  }
  __syncthreads();

  // ---- GEMM2: Y = H @ W2^T + b2 + X; wave = 2 n-tiles x 2 tok-tiles ----
  {
    int na = w*32 + fr, nb = na + 16;   // 0..127
    float ba = b2[na], bb = b2[nb];
    f32x4 d00 = {ba,ba,ba,ba}, d01 = {bb,bb,bb,bb};
    f32x4 d10 = {ba,ba,ba,ba}, d11 = {bb,bb,bb,bb};
    const u16* wpa = w2B + (size_t)na*512 + fg*8;
    const u16* wpb = w2B + (size_t)nb*512 + fg*8;
    #pragma unroll
    for (int k=0;k<16;k++){
      bf16x8 aa = *reinterpret_cast<const bf16x8*>(&Hs[fr*520 + k*32 + fg*8]);
      bf16x8 ab = *reinterpret_cast<const bf16x8*>(&Hs[(16+fr)*520 + k*32 + fg*8]);
      bf16x8 bA = *reinterpret_cast<const bf16x8*>(wpa + k*32);
      bf16x8 bB = *reinterpret_cast<const bf16x8*>(wpb + k*32);
      d00 = __builtin_amdgcn_mfma_f32_16x16x32_bf16(aa, bA, d00, 0, 0, 0);
      d01 = __builtin_amdgcn_mfma_f32_16x16x32_bf16(aa, bB, d01, 0, 0, 0);
      d10 = __builtin_amdgcn_mfma_f32_16x16x32_bf16(ab, bA, d10, 0, 0, 0);
      d11 = __builtin_amdgcn_mfma_f32_16x16x32_bf16(ab, bB, d11, 0, 0, 0);
    }
    #pragma unroll
    for (int r=0;r<4;r++){
      int ta = fg*4 + r, tb = 16 + ta;
      Ys[ta*136 + na] = f2b_u(d00[r] + b2f_u((u32)Xs[ta*136 + na]));
      Ys[ta*136 + nb] = f2b_u(d01[r] + b2f_u((u32)Xs[ta*136 + nb]));
      Ys[tb*136 + na] = f2b_u(d10[r] + b2f_u((u32)Xs[tb*136 + na]));
      Ys[tb*136 + nb] = f2b_u(d11[r] + b2f_u((u32)Xs[tb*136 + nb]));
    }
  }
  __syncthreads();

  // ---- coalesced store with layout mapping ----
  {
    int tok = t >> 3, oc = (t & 7)*16;
    uint4 v0 = *reinterpret_cast<const uint4*>(&Ys[tok*136 + oc]);
    uint4 v1 = *reinterpret_cast<const uint4*>(&Ys[tok*136 + oc + 8]);
    int T = bid*32 + tok;
    size_t addr;
    if (MODE == 1){
      int b = T >> 12, g = (T >> 4) & 255, ll = T & 15;
      addr = ((size_t)((b*16 + ll)*256 + g))*128 + oc;
    } else {
      int b = T >> 12, ll = (T >> 8) & 15, g = T & 255;
      int pcoord = ((g >> 4)*4 + (ll >> 2))*64 + ((g & 15)*4 + (ll & 3));
      addr = ((size_t)(b*4096 + pcoord))*128 + oc;
    }
    *reinterpret_cast<uint4*>(out + addr)     = v0;
    *reinterpret_cast<uint4*>(out + addr + 8) = v1;
  }
}

// ---------- K4a: QKV projection for DilatedMSA via MFMA ----------
__global__ __launch_bounds__(256) void k_qkv2(const u16* __restrict__ in, const u16* __restrict__ wB,
                                              const float* __restrict__ bias,
                                              u16* __restrict__ qbuf, u16* __restrict__ kvbuf){
  __shared__ u16 Xs[16*136];
  __shared__ u16 Qs[16*392];        // bf16 [tok][384+pad]
  int t = threadIdx.x, bid = blockIdx.x;
  {
    int l = t >> 4, c0 = (t & 15)*8;
    *reinterpret_cast<uint4*>(&Xs[l*136 + c0]) =
      *reinterpret_cast<const uint4*>(in + (size_t)bid*2048 + l*128 + c0);
  }
  __syncthreads();
  {
    int w = t >> 6, lane = t & 63, fr = lane & 15, fg = lane >> 4;
    bf16x8 a[4];
    #pragma unroll
    for (int k=0;k<4;k++) a[k] = *reinterpret_cast<const bf16x8*>(&Xs[fr*136 + k*32 + fg*8]);
    #pragma unroll
    for (int j=0;j<6;j++){
      int o = w*96 + j*16 + fr;          // 0..383
      float bv = bias[o];
      f32x4 d = {bv,bv,bv,bv};
      const u16* wp = wB + (size_t)o*128 + fg*8;
      #pragma unroll
      for (int k=0;k<4;k++){
        bf16x8 b = *reinterpret_cast<const bf16x8*>(wp + k*32);
        d = __builtin_amdgcn_mfma_f32_16x16x32_bf16(a[k], b, d, 0, 0, 0);
      }
      #pragma unroll
      for (int r=0;r<4;r++) Qs[(fg*4+r)*392 + o] = f2b_u(d[r]);
    }
  }
  __syncthreads();
  {
    int l = t >> 4, og = t & 15, o0 = og*24;
    size_t tok = (size_t)bid*16 + l;
    #pragma unroll
    for (int m=0; m<3; m++){
      int oc = o0 + m*8;
      uint4 v = *reinterpret_cast<const uint4*>(&Qs[l*392 + oc]);
      if (oc < 128) *reinterpret_cast<uint4*>(qbuf + tok*128 + oc) = v;
      else          *reinterpret_cast<uint4*>(kvbuf + tok*256 + (oc-128)) = v;
    }
  }
}

// ---------- K4b: DilatedMSA flash attention, full-MFMA (QK^T and PV), in-register softmax ----------
__global__ __launch_bounds__(256) void k_attn2(const u16* __restrict__ qbuf, const u16* __restrict__ kvbuf,
                                               u16* __restrict__ y){
  __shared__ __align__(16) char pool[24064];
  u16* Qb = (u16*)pool;              // [64][72] bf16
  u16* Kb = (u16*)(pool + 9216);     // [32][72] bf16
  u16* Vt = (u16*)(pool + 13824);    // [64 d][40 kt] bf16 (transposed V)
  u16* Pb = (u16*)(pool + 18944);    // [64 q][40 kt] bf16
  float* Os = (float*)pool;          // [64][68] f32, overlays Qb/Kb/Vt after loop

  int t = threadIdx.x, bid = blockIdx.x;
  int qt = bid & 3, h = (bid >> 2) & 1, bl = bid >> 3;
  size_t tokbase = (size_t)bl * 256;
  {
    int r = t >> 2, seg = t & 3;
    const u16* src = qbuf + (tokbase + qt*64 + r)*128 + h*64 + seg*16;
    uint4 v0 = *reinterpret_cast<const uint4*>(src);
    uint4 v1 = *reinterpret_cast<const uint4*>(src + 8);
    *reinterpret_cast<uint4*>(&Qb[r*72 + seg*16])     = v0;
    *reinterpret_cast<uint4*>(&Qb[r*72 + seg*16 + 8]) = v1;
  }
  int w = t >> 6, lane = t & 63;
  int fc = lane & 15, fg = lane >> 4;
  float m_reg[4], l_reg[4];
  #pragma unroll
  for (int r=0;r<4;r++){ m_reg[r] = -1e30f; l_reg[r] = 0.0f; }
  f32x4 o[4];
  #pragma unroll
  for (int j=0;j<4;j++) o[j] = {0.f,0.f,0.f,0.f};
  const float scale = 0.08838834764831845f;

  for (int kt=0; kt<8; kt++){
    {  // stage K rows (bf16)
      int r = t >> 3, seg = t & 7;
      const u16* base = kvbuf + (tokbase + kt*32 + r)*256 + h*64;
      *reinterpret_cast<uint4*>(&Kb[r*72 + seg*8]) = *reinterpret_cast<const uint4*>(base + seg*8);
    }
    {  // stage V transposed
      int pp = t >> 4, dg = t & 15, d0 = dg*4;
      const u16* b0 = kvbuf + (tokbase + kt*32 + 2*pp)*256 + h*64 + 128 + d0;
      uint2 v0 = *reinterpret_cast<const uint2*>(b0);
      uint2 v1 = *reinterpret_cast<const uint2*>(b0 + 256);
      *reinterpret_cast<u32*>(&Vt[(d0+0)*40 + 2*pp]) = (v0.x & 0xffffu) | (v1.x << 16);
      *reinterpret_cast<u32*>(&Vt[(d0+1)*40 + 2*pp]) = (v0.x >> 16) | (v1.x & 0xffff0000u);
      *reinterpret_cast<u32*>(&Vt[(d0+2)*40 + 2*pp]) = (v0.y & 0xffffu) | (v1.y << 16);
      *reinterpret_cast<u32*>(&Vt[(d0+3)*40 + 2*pp]) = (v0.y >> 16) | (v1.y & 0xffff0000u);
    }
    __syncthreads();
    f32x4 s0 = {0.f,0.f,0.f,0.f}, s1 = {0.f,0.f,0.f,0.f};
    {
      bf16x8 a0  = *reinterpret_cast<const bf16x8*>(&Qb[(w*16+fc)*72 + fg*8]);
      bf16x8 a1  = *reinterpret_cast<const bf16x8*>(&Qb[(w*16+fc)*72 + 32 + fg*8]);
      bf16x8 b00 = *reinterpret_cast<const bf16x8*>(&Kb[fc*72 + fg*8]);
      bf16x8 b01 = *reinterpret_cast<const bf16x8*>(&Kb[fc*72 + 32 + fg*8]);
      bf16x8 b10 = *reinterpret_cast<const bf16x8*>(&Kb[(16+fc)*72 + fg*8]);
      bf16x8 b11 = *reinterpret_cast<const bf16x8*>(&Kb[(16+fc)*72 + 32 + fg*8]);
      s0 = __builtin_amdgcn_mfma_f32_16x16x32_bf16(a0, b00, s0, 0, 0, 0);
      s0 = __builtin_amdgcn_mfma_f32_16x16x32_bf16(a1, b01, s0, 0, 0, 0);
      s1 = __builtin_amdgcn_mfma_f32_16x16x32_bf16(a0, b10, s1, 0, 0, 0);
      s1 = __builtin_amdgcn_mfma_f32_16x16x32_bf16(a1, b11, s1, 0, 0, 0);
    }
    float corr[4];
    #pragma unroll
    for (int r=0;r<4;r++){
      float v0 = s0[r]*scale, v1 = s1[r]*scale;
      float mx = fmaxf(v0, v1);
      mx = fmaxf(mx, __shfl_xor(mx, 1));
      mx = fmaxf(mx, __shfl_xor(mx, 2));
      mx = fmaxf(mx, __shfl_xor(mx, 4));
      mx = fmaxf(mx, __shfl_xor(mx, 8));
      float mnew = fmaxf(m_reg[r], mx);
      corr[r] = expf(m_reg[r] - mnew);
      m_reg[r] = mnew;
      float p0 = expf(v0 - mnew), p1 = expf(v1 - mnew);
      float sum = p0 + p1;
      sum += __shfl_xor(sum, 1);
      sum += __shfl_xor(sum, 2);
      sum += __shfl_xor(sum, 4);
      sum += __shfl_xor(sum, 8);
      l_reg[r] = l_reg[r]*corr[r] + sum;
      int row = w*16 + fg*4 + r;
      Pb[row*40 + fc]      = f2b_u(p0);
      Pb[row*40 + 16 + fc] = f2b_u(p1);
    }
    {
      bf16x8 pa = *reinterpret_cast<const bf16x8*>(&Pb[(w*16+fc)*40 + fg*8]);
      #pragma unroll
      for (int jt=0;jt<4;jt++){
        bf16x8 vb = *reinterpret_cast<const bf16x8*>(&Vt[(jt*16+fc)*40 + fg*8]);
        f32x4 oo = o[jt];
        oo[0] *= corr[0]; oo[1] *= corr[1]; oo[2] *= corr[2]; oo[3] *= corr[3];
        o[jt] = __builtin_amdgcn_mfma_f32_16x16x32_bf16(pa, vb, oo, 0, 0, 0);
      }
    }
    __syncthreads();
  }
  float inv[4];
  #pragma unroll
  for (int r=0;r<4;r++) inv[r] = 1.0f / l_reg[r];
  #pragma unroll
  for (int jt=0;jt<4;jt++){
    #pragma unroll
    for (int r=0;r<4;r++)
      Os[(w*16 + fg*4 + r)*68 + jt*16 + fc] = o[jt][r] * inv[r];
  }
  __syncthreads();
  {
    int row = t >> 2, seg = t & 3;
    float ov[16];
    #pragma unroll
    for (int j=0;j<16;j++) ov[j] = Os[row*68 + seg*16 + j];
    u16* dst = y + (tokbase + qt*64 + row)*128 + h*64 + seg*16;
    float res[16]; ld8b(dst, res); ld8b(dst+8, res+8);
    float o16[16];
    #pragma unroll
    for (int j=0;j<16;j++) o16[j] = ov[j] + res[j];
    st8b(dst, o16); st8b(dst+8, o16+8);
  }
}

// ---------- K6: FUSED LSTM (all 16 steps): block owns 16 pixels; h/C live in LDS ----------
// Per-pixel recurrence is independent across pixels (channel softmax + pointwise update),
// so no cross-block traffic. Writes hs[n] per step; hf/Cf at end (fp32 path preserved).
__global__ __launch_bounds__(256) void k_lstm_all(const u16* __restrict__ xD,
    const void* __restrict__ h0, const void* __restrict__ c0,
    const u16* __restrict__ wBx, const u16* __restrict__ wBh, const float* __restrict__ bh,
    void* __restrict__ dout, const int* __restrict__ flag){
  __shared__ u16 Xa[16*136];         // x bf16
  __shared__ u16 Ha[16*136];         // h bf16
  __shared__ float glds[4*16*132];   // [gate][px][132-pad ch] f32 (gate0 reused for hn f32)
  __shared__ float Cls[16*132];      // C state f32
  __shared__ u16 hst[16*136];        // h-new bf16 staging
  int t = threadIdx.x, bid = blockIdx.x;
  int pix0 = bid*16;
  int fl = *flag;
  // ---- init h (bf16) and C (f32) from h0/c0 [c][4096] ----
  {
    int c = t >> 1, half = t & 1;
    int pxb = half*8;
    if (fl){
      const float* hp = (const float*)h0 + (size_t)c*4096 + pix0 + pxb;
      const float* cp = (const float*)c0 + (size_t)c*4096 + pix0 + pxb;
      #pragma unroll
      for (int i=0;i<8;i++){
        Ha[(pxb+i)*136 + c] = f2b_u(hp[i]);
        Cls[(pxb+i)*132 + c] = cp[i];
      }
    } else {
      const u16* hp = (const u16*)h0 + (size_t)c*4096 + pix0 + pxb;
      const u16* cp = (const u16*)c0 + (size_t)c*4096 + pix0 + pxb;
      #pragma unroll
      for (int i=0;i<8;i++){
        Ha[(pxb+i)*136 + c] = hp[i];
        Cls[(pxb+i)*132 + c] = b2f_u((u32)cp[i]);
      }
    }
  }
  int w = t >> 6, lane = t & 63, fr = lane & 15, fg = lane >> 4;
  for (int n = 0; n < 16; n++){
    { // load x tile
      int px = t >> 4, c0v = (t & 15)*8;
      *reinterpret_cast<uint4*>(&Xa[px*136 + c0v]) =
        *reinterpret_cast<const uint4*>(xD + ((size_t)n*4096 + pix0 + px)*128 + c0v);
    }
    __syncthreads();
    // gates GEMM: wave w = gate w, 8 n-tiles over 128 channels
    f32x4 acc[8];
    {
      bf16x8 ax[4], ah[4];
      #pragma unroll
      for (int k=0;k<4;k++){
        ax[k] = *reinterpret_cast<const bf16x8*>(&Xa[fr*136 + k*32 + fg*8]);
        ah[k] = *reinterpret_cast<const bf16x8*>(&Ha[fr*136 + k*32 + fg*8]);
      }
      #pragma unroll
      for (int j=0;j<8;j++){
        int o = w*128 + j*16 + fr;
        float bv = bh[o];
        f32x4 d = {bv,bv,bv,bv};
        const u16* wpx = wBx + (size_t)o*128 + fg*8;
        const u16* wph = wBh + (size_t)o*128 + fg*8;
        #pragma unroll
        for (int k=0;k<4;k++){
          bf16x8 b = *reinterpret_cast<const bf16x8*>(wpx + k*32);
          d = __builtin_amdgcn_mfma_f32_16x16x32_bf16(ax[k], b, d, 0, 0, 0);
        }
        #pragma unroll
        for (int k=0;k<4;k++){
          bf16x8 b = *reinterpret_cast<const bf16x8*>(wph + k*32);
          d = __builtin_amdgcn_mfma_f32_16x16x32_bf16(ah[k], b, d, 0, 0, 0);
        }
        acc[j] = d;
      }
    }
    // activation: w==2 -> tanh; else channel-softmax (register butterfly over fc lanes)
    if (w == 2){
      #pragma unroll
      for (int j=0;j<8;j++)
        #pragma unroll
        for (int r=0;r<4;r++)
          glds[(w*16 + fg*4 + r)*132 + j*16 + fr] = tanhf(acc[j][r]);
    } else {
      #pragma unroll
      for (int r=0;r<4;r++){
        float mx = acc[0][r];
        #pragma unroll
        for (int j=1;j<8;j++) mx = fmaxf(mx, acc[j][r]);
        mx = fmaxf(mx, __shfl_xor(mx, 1));
        mx = fmaxf(mx, __shfl_xor(mx, 2));
        mx = fmaxf(mx, __shfl_xor(mx, 4));
        mx = fmaxf(mx, __shfl_xor(mx, 8));
        float e[8], sum = 0.f;
        #pragma unroll
        for (int j=0;j<8;j++){ e[j] = expf(acc[j][r] - mx); sum += e[j]; }
        sum += __shfl_xor(sum, 1);
        sum += __shfl_xor(sum, 2);
        sum += __shfl_xor(sum, 4);
        sum += __shfl_xor(sum, 8);
        float inv = 1.0f/sum;
        #pragma unroll
        for (int j=0;j<8;j++)
          glds[(w*16 + fg*4 + r)*132 + j*16 + fr] = e[j]*inv;
      }
    }
    __syncthreads();
    // pointwise update: thread = (chg = t&15, px = t>>4); C in LDS
    {
      int chg = t & 15, px = t >> 4;
      int ch0 = chg*8;
      float fv[8], iv[8], sv[8], ov[8], cc[8];
      #pragma unroll
      for (int q2=0;q2<2;q2++){
        *reinterpret_cast<float4*>(&fv[q2*4]) = *reinterpret_cast<const float4*>(&glds[(0*16+px)*132 + ch0 + q2*4]);
        *reinterpret_cast<float4*>(&iv[q2*4]) = *reinterpret_cast<const float4*>(&glds[(1*16+px)*132 + ch0 + q2*4]);
        *reinterpret_cast<float4*>(&sv[q2*4]) = *reinterpret_cast<const float4*>(&glds[(2*16+px)*132 + ch0 + q2*4]);
        *reinterpret_cast<float4*>(&ov[q2*4]) = *reinterpret_cast<const float4*>(&glds[(3*16+px)*132 + ch0 + q2*4]);
        *reinterpret_cast<float4*>(&cc[q2*4]) = *reinterpret_cast<const float4*>(&Cls[px*132 + ch0 + q2*4]);
      }
      float cn[8], hn[8];
      #pragma unroll
      for (int j=0;j<8;j++){
        cn[j] = fv[j]*cc[j] + iv[j]*sv[j];
        hn[j] = ov[j]*tanhf(cn[j]);
      }
      #pragma unroll
      for (int q2=0;q2<2;q2++)
        *reinterpret_cast<float4*>(&Cls[px*132 + ch0 + q2*4]) = *reinterpret_cast<const float4*>(&cn[q2*4]);
      uint4 pk;
      pk.x = (u32)f2b_u(hn[0]) | ((u32)f2b_u(hn[1]) << 16);
      pk.y = (u32)f2b_u(hn[2]) | ((u32)f2b_u(hn[3]) << 16);
      pk.z = (u32)f2b_u(hn[4]) | ((u32)f2b_u(hn[5]) << 16);
      pk.w = (u32)f2b_u(hn[6]) | ((u32)f2b_u(hn[7]) << 16);
      *reinterpret_cast<uint4*>(&Ha[px*136 + ch0])  = pk;
      *reinterpret_cast<uint4*>(&hst[px*136 + ch0]) = pk;
      if (n == 15){
        // stash fp32 hn into glds gate-0 region (same cell this thread just read; no race)
        #pragma unroll
        for (int q2=0;q2<2;q2++)
          *reinterpret_cast<float4*>(&glds[px*132 + ch0 + q2*4]) = *reinterpret_cast<const float4*>(&hn[q2*4]);
      }
    }
    __syncthreads();
    // coalesced hs write (channel-major d_out)
    {
      int ch = t >> 1, ph = t & 1;
      size_t ob = (size_t)n*524288 + (size_t)ch*4096 + pix0 + ph*8;
      if (fl){
        float* df = (float*)dout;
        float v[8];
        #pragma unroll
        for (int i=0;i<8;i++) v[i] = b2f_u((u32)hst[(ph*8+i)*136 + ch]);
        *reinterpret_cast<float4*>(df + ob)     = make_float4(v[0],v[1],v[2],v[3]);
        *reinterpret_cast<float4*>(df + ob + 4) = make_float4(v[4],v[5],v[6],v[7]);
      } else {
        u16* db = (u16*)dout;
        uint4 pk;
        pk.x = (u32)hst[(ph*8+0)*136 + ch] | ((u32)hst[(ph*8+1)*136 + ch] << 16);
        pk.y = (u32)hst[(ph*8+2)*136 + ch] | ((u32)hst[(ph*8+3)*136 + ch] << 16);
        pk.z = (u32)hst[(ph*8+4)*136 + ch] | ((u32)hst[(ph*8+5)*136 + ch] << 16);
        pk.w = (u32)hst[(ph*8+6)*136 + ch] | ((u32)hst[(ph*8+7)*136 + ch] << 16);
        *reinterpret_cast<uint4*>(db + ob) = pk;
      }
    }
  }
  __syncthreads();
  // ---- final hf (fp32 from glds), Cf (fp32 from Cls) ----
  {
    int c = t >> 1, half = t & 1;
    int pxb = half*8;
    if (fl){
      float hv[8], cv[8];
      #pragma unroll
      for (int i=0;i<8;i++){ hv[i] = glds[(pxb+i)*132 + c]; cv[i] = Cls[(pxb+i)*132 + c]; }
      float* df = (float*)dout;
      size_t hb = 8388608u + (size_t)c*4096 + pix0 + pxb;
      size_t cb = 8912896u + (size_t)c*4096 + pix0 + pxb;
      *reinterpret_cast<float4*>(df + hb)     = make_float4(hv[0],hv[1],hv[2],hv[3]);
      *reinterpret_cast<float4*>(df + hb + 4) = make_float4(hv[4],hv[5],hv[6],hv[7]);
      *reinterpret_cast<float4*>(df + cb)     = make_float4(cv[0],cv[1],cv[2],cv[3]);
      *reinterpret_cast<float4*>(df + cb + 4) = make_float4(cv[4],cv[5],cv[6],cv[7]);
    } else {
      u16* db = (u16*)dout;
      uint4 hp, cp2;
      hp.x = (u32)hst[(pxb+0)*136 + c] | ((u32)hst[(pxb+1)*136 + c] << 16);
      hp.y = (u32)hst[(pxb+2)*136 + c] | ((u32)hst[(pxb+3)*136 + c] << 16);
      hp.z = (u32)hst[(pxb+4)*136 + c] | ((u32)hst[(pxb+5)*136 + c] << 16);
      hp.w = (u32)hst[(pxb+6)*136 + c] | ((u32)hst[(pxb+7)*136 + c] << 16);
      cp2.x = (u32)f2b_u(Cls[(pxb+0)*132 + c]) | ((u32)f2b_u(Cls[(pxb+1)*132 + c]) << 16);
      cp2.y = (u32)f2b_u(Cls[(pxb+2)*132 + c]) | ((u32)f2b_u(Cls[(pxb+3)*132 + c]) << 16);
      cp2.z = (u32)f2b_u(Cls[(pxb+4)*132 + c]) | ((u32)f2b_u(Cls[(pxb+5)*132 + c]) << 16);
      cp2.w = (u32)f2b_u(Cls[(pxb+6)*132 + c]) | ((u32)f2b_u(Cls[(pxb+7)*132 + c]) << 16);
      *reinterpret_cast<uint4*>(db + 8388608u + (size_t)c*4096 + pix0 + pxb) = hp;
      *reinterpret_cast<uint4*>(db + 8912896u + (size_t)c*4096 + pix0 + pxb) = cp2;
    }
  }
}

extern "C" void kernel_launch(void* const* d_in, const int* in_sizes, int n_in,
                              void* d_out, int out_size, void* d_ws, size_t ws_size,
                              hipStream_t stream) {
  const void* x      = d_in[0];
  const void* h0     = d_in[1];
  const void* c0     = d_in[2];
  const void* conv_w = d_in[3];
  const void* conv_b = d_in[4];
  const void* qkv1_w = d_in[5];
  const void* qkv1_b = d_in[6];
  const void* m1w1   = d_in[7];
  const void* m1b1   = d_in[8];
  const void* m1w2   = d_in[9];
  const void* m1b2   = d_in[10];
  const void* qkv2_w = d_in[11];
  const void* qkv2_b = d_in[12];
  const void* m2w1   = d_in[13];
  const void* m2b1   = d_in[14];
  const void* m2w2   = d_in[15];
  const void* m2b2   = d_in[16];
  const void* lwx    = d_in[17];
  const void* lwh    = d_in[18];
  const void* lbh    = d_in[19];

  char* p = (char*)d_ws;
  auto alloc = [&](size_t bytes)->void*{
    void* r = (void*)p; p += (bytes + 255) & ~(size_t)255; return r;
  };
  int*   flag    = (int*)alloc(256);
  u16* wB_conv = (u16*)alloc(128*512*2);       // bf16, native [co][ci*4+ky*2+kx]
  u16* wB_qkv1 = (u16*)alloc(384*128*2);       // bf16, original [o][k]
  u16* wB_m1a  = (u16*)alloc(512*128*2);
  u16* wB_m1b  = (u16*)alloc(128*512*2);
  u16* wB_qkv2 = (u16*)alloc(384*128*2);
  u16* wB_m2a  = (u16*)alloc(512*128*2);
  u16* wB_m2b  = (u16*)alloc(128*512*2);
  u16* wBx     = (u16*)alloc(512*128*2);       // bf16, original [o][k] (LSTM x)
  u16* wBh     = (u16*)alloc(512*128*2);       // bf16, original [o][k] (LSTM h)
  float* bf_conv = (float*)alloc(128*4);
  float* bf_qkv1 = (float*)alloc(384*4);
  float* bf_m1b1 = (float*)alloc(512*4);
  float* bf_m1b2 = (float*)alloc(128*4);
  float* bf_qkv2 = (float*)alloc(384*4);
  float* bf_m2b1 = (float*)alloc(512*4);
  float* bf_m2b2 = (float*)alloc(128*4);
  float* bf_lbh  = (float*)alloc(512*4);
  u16* R0   = (u16*)alloc(16777216);   // bufA -> bufC/y
  u16* Rbig = (u16*)alloc(33554432);   // bufB (front) -> kvbuf -> bufD (front)

  u16* bufA = R0;
  u16* bufB = Rbig;
  u16* bufC = R0;          // also y (attn writes in place)
  u16* qbuf = (u16*)d_out; // hs region used as scratch; dead before first LSTM write
  u16* kvbuf = Rbig;
  u16* bufD = Rbig;

  k_detect<<<1, 256, 0, stream>>>((const u32*)x, flag);

  k_prep<<<2187, 256, 0, stream>>>(
      conv_w, qkv1_w, m1w1, m1w2, qkv2_w, m2w1, m2w2, lwx, lwh,
      conv_b, qkv1_b, m1b1, m1b2, qkv2_b, m2b1, m2b2, lbh,
      wB_conv, wB_qkv1, wB_m1a, wB_m1b, wB_qkv2, wB_m2a, wB_m2b,
      wBx, wBh,
      bf_conv, bf_qkv1, bf_m1b1, bf_m1b2, bf_qkv2, bf_m2b1, bf_m2b2, bf_lbh,
      flag);

  k_conv<<<512, 256, 0, stream>>>(x, wB_conv, bf_conv, bufA, flag);
  k_msa1<<<4096, 256, 0, stream>>>(bufA, wB_qkv1, bf_qkv1, bufB);
  k_mlp<1><<<2048, 256, 0, stream>>>(bufB, wB_m1a, bf_m1b1, wB_m1b, bf_m1b2, bufC);
  k_qkv2<<<4096, 256, 0, stream>>>(bufC, wB_qkv2, bf_qkv2, qbuf, kvbuf);
  k_attn2<<<2048, 256, 0, stream>>>(qbuf, kvbuf, bufC);          // y = x + attn, in place
  k_mlp<2><<<2048, 256, 0, stream>>>(bufC, wB_m2a, bf_m2b1, wB_m2b, bf_m2b2, bufD);

  k_lstm_all<<<256, 256, 0, stream>>>(bufD, h0, c0, wBx, wBh, bf_lbh, d_out, flag);
}

// Round 13
// 657.605 us; speedup vs baseline: 11.3474x; 1.0096x over previous
//
#include <hip/hip_runtime.h>
#include <hip/hip_bf16.h>

typedef unsigned int u32;
typedef unsigned short u16;

#define DI __device__ __forceinline__

typedef __attribute__((ext_vector_type(8))) __bf16 bf16x8;
typedef __attribute__((ext_vector_type(4))) float f32x4;

// ---------- bf16 helpers (bf16 == fp32 high 16 bits; RNE on store) ----------
DI float b2f_u(u32 u){ return __uint_as_float(u << 16); }
DI u16 f2b_u(float f){
  u32 x = __float_as_uint(f);
  x += 0x7fffu + ((x >> 16) & 1u);
  return (u16)(x >> 16);
}
DI void ld8b(const u16* p, float* o){
  uint4 v = *reinterpret_cast<const uint4*>(p);
  o[0] = b2f_u(v.x & 0xffffu); o[1] = b2f_u(v.x >> 16);
  o[2] = b2f_u(v.y & 0xffffu); o[3] = b2f_u(v.y >> 16);
  o[4] = b2f_u(v.z & 0xffffu); o[5] = b2f_u(v.z >> 16);
  o[6] = b2f_u(v.w & 0xffffu); o[7] = b2f_u(v.w >> 16);
}
DI void st8b(u16* p, const float* i){
  uint4 v;
  v.x = (u32)f2b_u(i[0]) | ((u32)f2b_u(i[1]) << 16);
  v.y = (u32)f2b_u(i[2]) | ((u32)f2b_u(i[3]) << 16);
  v.z = (u32)f2b_u(i[4]) | ((u32)f2b_u(i[5]) << 16);
  v.w = (u32)f2b_u(i[6]) | ((u32)f2b_u(i[7]) << 16);
  *reinterpret_cast<uint4*>(p) = v;
}

// ---------- K_detect: is d_in fp32 (flag=1) or packed bf16 (flag=0)? ----------
__global__ void k_detect(const u32* __restrict__ xw, int* __restrict__ flag){
  __shared__ int cnt;
  int t = threadIdx.x;
  if (t == 0) cnt = 0;
  __syncthreads();
  int c = 0;
  for (int i = t; i < 2048; i += 256){
    u32 lo = xw[i] & 0xffffu;
    u32 e = (lo >> 7) & 0xffu;
    if (e < 100u || e > 140u) c++;
  }
  atomicAdd(&cnt, c);
  __syncthreads();
  if (t == 0) *flag = (cnt > 200) ? 1 : 0;
}

// ---------- K_prep: ALL weight/bias conversions in ONE launch ----------
__global__ void k_prep(
  const void* __restrict__ conv_w, const void* __restrict__ qkv1_w,
  const void* __restrict__ m1w1, const void* __restrict__ m1w2,
  const void* __restrict__ qkv2_w, const void* __restrict__ m2w1, const void* __restrict__ m2w2,
  const void* __restrict__ lwx, const void* __restrict__ lwh,
  const void* __restrict__ conv_b, const void* __restrict__ qkv1_b,
  const void* __restrict__ m1b1, const void* __restrict__ m1b2,
  const void* __restrict__ qkv2_b, const void* __restrict__ m2b1, const void* __restrict__ m2b2,
  const void* __restrict__ lbh,
  u16* __restrict__ wB_conv, u16* __restrict__ wB_qkv1, u16* __restrict__ wB_m1a,
  u16* __restrict__ wB_m1b, u16* __restrict__ wB_qkv2, u16* __restrict__ wB_m2a,
  u16* __restrict__ wB_m2b, u16* __restrict__ wBx, u16* __restrict__ wBh,
  float* __restrict__ bf_conv, float* __restrict__ bf_qkv1, float* __restrict__ bf_m1b1,
  float* __restrict__ bf_m1b2, float* __restrict__ bf_qkv2, float* __restrict__ bf_m2b1,
  float* __restrict__ bf_m2b2, float* __restrict__ bf_lbh,
  const int* __restrict__ flag){
  int bid = blockIdx.x, t = threadIdx.x;
  int fl = *flag;
  auto cvb = [&](const void* s, u16* d, int base, int n){
    int i = (bid - base)*256 + t;
    if (i < n) d[i] = fl ? f2b_u(((const float*)s)[i]) : ((const u16*)s)[i];
  };
  auto ldf = [&](const void* s, int i)->float{
    return fl ? ((const float*)s)[i] : b2f_u((u32)((const u16*)s)[i]);
  };
  if (bid < 256)       cvb(conv_w, wB_conv, 0,    65536);
  else if (bid < 448)  cvb(qkv1_w, wB_qkv1, 256,  49152);
  else if (bid < 704)  cvb(m1w1,   wB_m1a,  448,  65536);
  else if (bid < 960)  cvb(m1w2,   wB_m1b,  704,  65536);
  else if (bid < 1152) cvb(qkv2_w, wB_qkv2, 960,  49152);
  else if (bid < 1408) cvb(m2w1,   wB_m2a,  1152, 65536);
  else if (bid < 1664) cvb(m2w2,   wB_m2b,  1408, 65536);
  else if (bid < 1920) cvb(lwx,    wBx,     1664, 65536);
  else if (bid < 2176) cvb(lwh,    wBh,     1920, 65536);
  else {
    int i = (bid - 2176)*256 + t;
    if (i < 128)       bf_conv[i]        = ldf(conv_b, i);
    else if (i < 512)  bf_qkv1[i-128]    = ldf(qkv1_b, i-128);
    else if (i < 1024) bf_m1b1[i-512]    = ldf(m1b1,   i-512);
    else if (i < 1152) bf_m1b2[i-1024]   = ldf(m1b2,   i-1024);
    else if (i < 1536) bf_qkv2[i-1152]   = ldf(qkv2_b, i-1152);
    else if (i < 2048) bf_m2b1[i-1536]   = ldf(m2b1,   i-1536);
    else if (i < 2176) bf_m2b2[i-2048]   = ldf(m2b2,   i-2048);
    else if (i < 2688) bf_lbh[i-2176]    = ldf(lbh,    i-2176);
  }
}

// ---------- K1: conv 2x2 s2 + window partition via MFMA, strip-blocked ----------
__global__ __launch_bounds__(256) void k_conv(const void* __restrict__ x_raw,
                                              const u16* __restrict__ wB,
                                              const float* __restrict__ bias, u16* __restrict__ outA,
                                              const int* __restrict__ flag){
  __shared__ __align__(16) u16 pool[128*136];   // Aa [128][72] (first 18.4KB); Ys [128][136] overlay
  u16* Aa = pool;
  u16* Ys = pool;
  int t = threadIdx.x, bid = blockIdx.x;
  int xh = bid & 1, yg = (bid >> 1) & 15, b = bid >> 5;
  size_t slab = (size_t)b*2097152 + (size_t)(yg*8)*128 + (size_t)xh*64;
  int w = t >> 6, lane = t & 63, fr = lane & 15, fg = lane >> 4;
  f32x4 acc[2][8];
  #pragma unroll
  for (int j=0;j<8;j++){
    float bv = bias[j*16 + fr];
    acc[0][j] = {bv,bv,bv,bv};
    acc[1][j] = {bv,bv,bv,bv};
  }
  for (int ci0 = 0; ci0 < 128; ci0 += 16){
    if (ci0) __syncthreads();
    if (*flag){
      const float* xb = (const float*)x_raw + slab + (size_t)ci0*16384;
      #pragma unroll
      for (int i=0;i<4;i++){
        int idx = i*256 + t;            // 0..1023
        int row = idx >> 3, seg = idx & 7;   // row = cr*8+py (0..127), seg = 8-px group
        int cr = row >> 3, py = row & 7;
        const float* sp = xb + (size_t)cr*16384 + py*128 + seg*8;
        float4 v0 = *reinterpret_cast<const float4*>(sp);
        float4 v1 = *reinterpret_cast<const float4*>(sp + 4);
        int tok0 = seg*16 + (py>>1)*4;
        int k0 = cr*4 + (py&1)*2;
        *reinterpret_cast<u32*>(&Aa[(tok0+0)*72 + k0]) = (u32)f2b_u(v0.x) | ((u32)f2b_u(v0.y)<<16);
        *reinterpret_cast<u32*>(&Aa[(tok0+1)*72 + k0]) = (u32)f2b_u(v0.z) | ((u32)f2b_u(v0.w)<<16);
        *reinterpret_cast<u32*>(&Aa[(tok0+2)*72 + k0]) = (u32)f2b_u(v1.x) | ((u32)f2b_u(v1.y)<<16);
        *reinterpret_cast<u32*>(&Aa[(tok0+3)*72 + k0]) = (u32)f2b_u(v1.z) | ((u32)f2b_u(v1.w)<<16);
      }
    } else {
      const u16* xb = (const u16*)x_raw + slab + (size_t)ci0*16384;
      #pragma unroll
      for (int i=0;i<4;i++){
        int idx = i*256 + t;
        int row = idx >> 3, seg = idx & 7;
        int cr = row >> 3, py = row & 7;
        uint4 v = *reinterpret_cast<const uint4*>(xb + (size_t)cr*16384 + py*128 + seg*8);
        int tok0 = seg*16 + (py>>1)*4;
        int k0 = cr*4 + (py&1)*2;
        *reinterpret_cast<u32*>(&Aa[(tok0+0)*72 + k0]) = v.x;
        *reinterpret_cast<u32*>(&Aa[(tok0+1)*72 + k0]) = v.y;
        *reinterpret_cast<u32*>(&Aa[(tok0+2)*72 + k0]) = v.z;
        *reinterpret_cast<u32*>(&Aa[(tok0+3)*72 + k0]) = v.w;
      }
    }
    __syncthreads();
    bf16x8 a0[2], a1[2];
    #pragma unroll
    for (int kk=0;kk<2;kk++){
      a0[kk] = *reinterpret_cast<const bf16x8*>(&Aa[(w*16+fr)*72 + kk*32 + fg*8]);
      a1[kk] = *reinterpret_cast<const bf16x8*>(&Aa[((w+4)*16+fr)*72 + kk*32 + fg*8]);
    }
    #pragma unroll
    for (int j=0;j<8;j++){
      const u16* wp = wB + (size_t)(j*16+fr)*512 + ci0*4 + fg*8;
      bf16x8 b0 = *reinterpret_cast<const bf16x8*>(wp);
      bf16x8 b1 = *reinterpret_cast<const bf16x8*>(wp + 32);
      acc[0][j] = __builtin_amdgcn_mfma_f32_16x16x32_bf16(a0[0], b0, acc[0][j], 0, 0, 0);
      acc[0][j] = __builtin_amdgcn_mfma_f32_16x16x32_bf16(a0[1], b1, acc[0][j], 0, 0, 0);
      acc[1][j] = __builtin_amdgcn_mfma_f32_16x16x32_bf16(a1[0], b0, acc[1][j], 0, 0, 0);
      acc[1][j] = __builtin_amdgcn_mfma_f32_16x16x32_bf16(a1[1], b1, acc[1][j], 0, 0, 0);
    }
  }
  __syncthreads();
  #pragma unroll
  for (int tt=0;tt<2;tt++){
    int tokbase = (w + tt*4)*16;
    #pragma unroll
    for (int j=0;j<8;j++){
      #pragma unroll
      for (int r=0;r<4;r++)
        Ys[(tokbase + fg*4 + r)*136 + j*16 + fr] = f2b_u(acc[tt][j][r]);
    }
  }
  __syncthreads();
  {
    int tok = t >> 1, half = t & 1;
    int gl = yg*16 + xh*8 + (tok >> 4);
    int l = tok & 15;
    u16* dst = outA + ((size_t)(b*256 + gl)*16 + l)*128 + half*64;
    const u16* src = &Ys[tok*136 + half*64];
    #pragma unroll
    for (int q2=0;q2<8;q2++)
      *reinterpret_cast<uint4*>(dst + q2*8) = *reinterpret_cast<const uint4*>(src + q2*8);
  }
}

// ---------- K2: LocalMSA (L=16) + residual: bufA -> bufB (same layout) ----------
__global__ __launch_bounds__(256) void k_msa1(const u16* __restrict__ A, const u16* __restrict__ wB,
                                              const float* __restrict__ qbias, u16* __restrict__ B){
  __shared__ u16 Xs[16*136];        // bf16, row stride 272 B
  __shared__ float QKV[16*388];
  __shared__ float S[512];          // [h][l][m]
  int t = threadIdx.x, bid = blockIdx.x;
  {
    int l = t >> 4, c0 = (t & 15)*8;
    *reinterpret_cast<uint4*>(&Xs[l*136 + c0]) =
      *reinterpret_cast<const uint4*>(A + (size_t)bid*2048 + l*128 + c0);
  }
  __syncthreads();
  {
    int w = t >> 6, lane = t & 63, fr = lane & 15, fg = lane >> 4;
    bf16x8 a[4];
    #pragma unroll
    for (int k=0;k<4;k++) a[k] = *reinterpret_cast<const bf16x8*>(&Xs[fr*136 + k*32 + fg*8]);
    #pragma unroll
    for (int j=0;j<6;j++){
      int o = w*96 + j*16 + fr;          // 0..383
      float bv = qbias[o];
      f32x4 d = {bv,bv,bv,bv};
      const u16* wp = wB + (size_t)o*128 + fg*8;
      #pragma unroll
      for (int k=0;k<4;k++){
        bf16x8 b = *reinterpret_cast<const bf16x8*>(wp + k*32);
        d = __builtin_amdgcn_mfma_f32_16x16x32_bf16(a[k], b, d, 0, 0, 0);
      }
      #pragma unroll
      for (int r=0;r<4;r++) QKV[(fg*4+r)*388 + o] = d[r];
    }
  }
  __syncthreads();
  const float scale = 0.08838834764831845f;   // 1/sqrt(128)
  for (int e = t; e < 512; e += 256){
    int h = e >> 8, l = (e>>4)&15, m = e&15;
    const float* q = &QKV[l*388 + h*64];
    const float* kk = &QKV[m*388 + 128 + h*64];
    float s = 0.f;
    #pragma unroll
    for (int d=0; d<64; d++) s += q[d]*kk[d];
    S[(h*16+l)*16 + m] = s*scale;
  }
  __syncthreads();
  if (t < 32){
    float* row = &S[t*16];
    float mx = row[0];
    #pragma unroll
    for (int m=1;m<16;m++) mx = fmaxf(mx,row[m]);
    float sum = 0.f;
    #pragma unroll
    for (int m=0;m<16;m++){ float e = expf(row[m]-mx); row[m]=e; sum+=e; }
    float inv = 1.0f/sum;
    #pragma unroll
    for (int m=0;m<16;m++) row[m] *= inv;
  }
  __syncthreads();
  {
    int l = t >> 4, og = t & 15, o0 = og*8;
    int h = o0 >> 6;
    const float* p = &S[(h*16+l)*16];
    float out8[8];
    #pragma unroll
    for (int j=0;j<8;j++){
      int o = o0+j, d = o & 63;
      float s = 0.f;
      #pragma unroll
      for (int m=0;m<16;m++) s += p[m]*QKV[m*388 + 256 + h*64 + d];
      out8[j] = s + b2f_u((u32)Xs[l*136 + o]);
    }
    st8b(B + (size_t)bid*2048 + l*128 + o0, out8);
  }
}

// ---------- K3/K5: MLP (+residual) via MFMA, 32 tokens/block (2 tiles/wave). ----------
template<int MODE>
__global__ __launch_bounds__(256) void k_mlp(const u16* __restrict__ in,
    const u16* __restrict__ w1B, const float* __restrict__ b1,
    const u16* __restrict__ w2B, const float* __restrict__ b2,
    u16* __restrict__ out){
  __shared__ u16 Xs[32*136];        // bf16 input (also residual)
  __shared__ u16 Hs[32*520];        // bf16 hidden
  __shared__ u16 Ys[32*136];        // bf16 output staging
  int t = threadIdx.x, bid = blockIdx.x;
  {
    int l = t >> 3, c0 = (t & 7)*16;
    const u16* src = in + (size_t)bid*4096 + l*128 + c0;
    *reinterpret_cast<uint4*>(&Xs[l*136 + c0])     = *reinterpret_cast<const uint4*>(src);
    *reinterpret_cast<uint4*>(&Xs[l*136 + c0 + 8]) = *reinterpret_cast<const uint4*>(src + 8);
  }
  __syncthreads();
  int w = t >> 6, lane = t & 63, fr = lane & 15, fg = lane >> 4;

  // ---- GEMM1: H = gelu(X @ W1^T + b1); wave = 8 n-tiles x 2 tok-tiles ----
  {
    bf16x8 a0[4], a1[4];
    #pragma unroll
    for (int k=0;k<4;k++){
      a0[k] = *reinterpret_cast<const bf16x8*>(&Xs[fr*136 + k*32 + fg*8]);
      a1[k] = *reinterpret_cast<const bf16x8*>(&Xs[(16+fr)*136 + k*32 + fg*8]);
    }
    #pragma unroll
    for (int j=0;j<8;j++){
      int o = w*128 + j*16 + fr;        // 0..511
      float bv = b1[o];
      f32x4 d0 = {bv,bv,bv,bv}, d1 = {bv,bv,bv,bv};
      const u16* wp = w1B + (size_t)o*128 + fg*8;
      #pragma unroll
      for (int k=0;k<4;k++){
        bf16x8 b = *reinterpret_cast<const bf16x8*>(wp + k*32);
        d0 = __builtin_amdgcn_mfma_f32_16x16x32_bf16(a0[k], b, d0, 0, 0, 0);
        d1 = __builtin_amdgcn_mfma_f32_16x16x32_bf16(a1[k], b, d1, 0, 0, 0);
      }
      #pragma unroll
      for (int r=0;r<4;r++){
        float v0 = d0[r], v1 = d1[r];
        Hs[(fg*4+r)*520 + o]      = f2b_u(0.5f*v0*(1.0f + erff(v0*0.70710678118654752f)));
        Hs[(16+fg*4+r)*520 + o]   = f2b_u(0.5f*v1*(1.0f + erff(v1*0.70710678118654752f)));
      }
    }
  }
  __syncthreads();

  // ---- GEMM2: Y = H @ W2^T + b2 + X; wave = 2 n-tiles x 2 tok-tiles ----
  {
    int na = w*32 + fr, nb = na + 16;   // 0..127
    float ba = b2[na], bb = b2[nb];
    f32x4 d00 = {ba,ba,ba,ba}, d01 = {bb,bb,bb,bb};
    f32x4 d10 = {ba,ba,ba,ba}, d11 = {bb,bb,bb,bb};
    const u16* wpa = w2B + (size_t)na*512 + fg*8;
    const u16* wpb = w2B + (size_t)nb*512 + fg*8;
    #pragma unroll
    for (int k=0;k<16;k++){
      bf16x8 aa = *reinterpret_cast<const bf16x8*>(&Hs[fr*520 + k*32 + fg*8]);
      bf16x8 ab = *reinterpret_cast<const bf16x8*>(&Hs[(16+fr)*520 + k*32 + fg*8]);
      bf16x8 bA = *reinterpret_cast<const bf16x8*>(wpa + k*32);
      bf16x8 bB = *reinterpret_cast<const bf16x8*>(wpb + k*32);
      d00 = __builtin_amdgcn_mfma_f32_16x16x32_bf16(aa, bA, d00, 0, 0, 0);
      d01 = __builtin_amdgcn_mfma_f32_16x16x32_bf16(aa, bB, d01, 0, 0, 0);
      d10 = __builtin_amdgcn_mfma_f32_16x16x32_bf16(ab, bA, d10, 0, 0, 0);
      d11 = __builtin_amdgcn_mfma_f32_16x16x32_bf16(ab, bB, d11, 0, 0, 0);
    }
    #pragma unroll
    for (int r=0;r<4;r++){
      int ta = fg*4 + r, tb = 16 + ta;
      Ys[ta*136 + na] = f2b_u(d00[r] + b2f_u((u32)Xs[ta*136 + na]));
      Ys[ta*136 + nb] = f2b_u(d01[r] + b2f_u((u32)Xs[ta*136 + nb]));
      Ys[tb*136 + na] = f2b_u(d10[r] + b2f_u((u32)Xs[tb*136 + na]));
      Ys[tb*136 + nb] = f2b_u(d11[r] + b2f_u((u32)Xs[tb*136 + nb]));
    }
  }
  __syncthreads();

  // ---- coalesced store with layout mapping ----
  {
    int tok = t >> 3, oc = (t & 7)*16;
    uint4 v0 = *reinterpret_cast<const uint4*>(&Ys[tok*136 + oc]);
    uint4 v1 = *reinterpret_cast<const uint4*>(&Ys[tok*136 + oc + 8]);
    int T = bid*32 + tok;
    size_t addr;
    if (MODE == 1){
      int b = T >> 12, g = (T >> 4) & 255, ll = T & 15;
      addr = ((size_t)((b*16 + ll)*256 + g))*128 + oc;
    } else {
      int b = T >> 12, ll = (T >> 8) & 15, g = T & 255;
      int pcoord = ((g >> 4)*4 + (ll >> 2))*64 + ((g & 15)*4 + (ll & 3));
      addr = ((size_t)(b*4096 + pcoord))*128 + oc;
    }
    *reinterpret_cast<uint4*>(out + addr)     = v0;
    *reinterpret_cast<uint4*>(out + addr + 8) = v1;
  }
}

// ---------- K4a: QKV projection for DilatedMSA via MFMA ----------
__global__ __launch_bounds__(256) void k_qkv2(const u16* __restrict__ in, const u16* __restrict__ wB,
                                              const float* __restrict__ bias,
                                              u16* __restrict__ qbuf, u16* __restrict__ kvbuf){
  __shared__ u16 Xs[16*136];
  __shared__ u16 Qs[16*392];        // bf16 [tok][384+pad]
  int t = threadIdx.x, bid = blockIdx.x;
  {
    int l = t >> 4, c0 = (t & 15)*8;
    *reinterpret_cast<uint4*>(&Xs[l*136 + c0]) =
      *reinterpret_cast<const uint4*>(in + (size_t)bid*2048 + l*128 + c0);
  }
  __syncthreads();
  {
    int w = t >> 6, lane = t & 63, fr = lane & 15, fg = lane >> 4;
    bf16x8 a[4];
    #pragma unroll
    for (int k=0;k<4;k++) a[k] = *reinterpret_cast<const bf16x8*>(&Xs[fr*136 + k*32 + fg*8]);
    #pragma unroll
    for (int j=0;j<6;j++){
      int o = w*96 + j*16 + fr;          // 0..383
      float bv = bias[o];
      f32x4 d = {bv,bv,bv,bv};
      const u16* wp = wB + (size_t)o*128 + fg*8;
      #pragma unroll
      for (int k=0;k<4;k++){
        bf16x8 b = *reinterpret_cast<const bf16x8*>(wp + k*32);
        d = __builtin_amdgcn_mfma_f32_16x16x32_bf16(a[k], b, d, 0, 0, 0);
      }
      #pragma unroll
      for (int r=0;r<4;r++) Qs[(fg*4+r)*392 + o] = f2b_u(d[r]);
    }
  }
  __syncthreads();
  {
    int l = t >> 4, og = t & 15, o0 = og*24;
    size_t tok = (size_t)bid*16 + l;
    #pragma unroll
    for (int m=0; m<3; m++){
      int oc = o0 + m*8;
      uint4 v = *reinterpret_cast<const uint4*>(&Qs[l*392 + oc]);
      if (oc < 128) *reinterpret_cast<uint4*>(qbuf + tok*128 + oc) = v;
      else          *reinterpret_cast<uint4*>(kvbuf + tok*256 + (oc-128)) = v;
    }
  }
}

// ---------- K4b: DilatedMSA flash attention, full-MFMA (QK^T and PV), in-register softmax ----------
__global__ __launch_bounds__(256) void k_attn2(const u16* __restrict__ qbuf, const u16* __restrict__ kvbuf,
                                               u16* __restrict__ y){
  __shared__ __align__(16) char pool[24064];
  u16* Qb = (u16*)pool;              // [64][72] bf16
  u16* Kb = (u16*)(pool + 9216);     // [32][72] bf16
  u16* Vt = (u16*)(pool + 13824);    // [64 d][40 kt] bf16 (transposed V)
  u16* Pb = (u16*)(pool + 18944);    // [64 q][40 kt] bf16
  float* Os = (float*)pool;          // [64][68] f32, overlays Qb/Kb/Vt after loop

  int t = threadIdx.x, bid = blockIdx.x;
  int qt = bid & 3, h = (bid >> 2) & 1, bl = bid >> 3;
  size_t tokbase = (size_t)bl * 256;
  {
    int r = t >> 2, seg = t & 3;
    const u16* src = qbuf + (tokbase + qt*64 + r)*128 + h*64 + seg*16;
    uint4 v0 = *reinterpret_cast<const uint4*>(src);
    uint4 v1 = *reinterpret_cast<const uint4*>(src + 8);
    *reinterpret_cast<uint4*>(&Qb[r*72 + seg*16])     = v0;
    *reinterpret_cast<uint4*>(&Qb[r*72 + seg*16 + 8]) = v1;
  }
  int w = t >> 6, lane = t & 63;
  int fc = lane & 15, fg = lane >> 4;
  float m_reg[4], l_reg[4];
  #pragma unroll
  for (int r=0;r<4;r++){ m_reg[r] = -1e30f; l_reg[r] = 0.0f; }
  f32x4 o[4];
  #pragma unroll
  for (int j=0;j<4;j++) o[j] = {0.f,0.f,0.f,0.f};
  const float scale = 0.08838834764831845f;

  for (int kt=0; kt<8; kt++){
    {  // stage K rows (bf16)
      int r = t >> 3, seg = t & 7;
      const u16* base = kvbuf + (tokbase + kt*32 + r)*256 + h*64;
      *reinterpret_cast<uint4*>(&Kb[r*72 + seg*8]) = *reinterpret_cast<const uint4*>(base + seg*8);
    }
    {  // stage V transposed
      int pp = t >> 4, dg = t & 15, d0 = dg*4;
      const u16* b0 = kvbuf + (tokbase + kt*32 + 2*pp)*256 + h*64 + 128 + d0;
      uint2 v0 = *reinterpret_cast<const uint2*>(b0);
      uint2 v1 = *reinterpret_cast<const uint2*>(b0 + 256);
      *reinterpret_cast<u32*>(&Vt[(d0+0)*40 + 2*pp]) = (v0.x & 0xffffu) | (v1.x << 16);
      *reinterpret_cast<u32*>(&Vt[(d0+1)*40 + 2*pp]) = (v0.x >> 16) | (v1.x & 0xffff0000u);
      *reinterpret_cast<u32*>(&Vt[(d0+2)*40 + 2*pp]) = (v0.y & 0xffffu) | (v1.y << 16);
      *reinterpret_cast<u32*>(&Vt[(d0+3)*40 + 2*pp]) = (v0.y >> 16) | (v1.y & 0xffff0000u);
    }
    __syncthreads();
    f32x4 s0 = {0.f,0.f,0.f,0.f}, s1 = {0.f,0.f,0.f,0.f};
    {
      bf16x8 a0  = *reinterpret_cast<const bf16x8*>(&Qb[(w*16+fc)*72 + fg*8]);
      bf16x8 a1  = *reinterpret_cast<const bf16x8*>(&Qb[(w*16+fc)*72 + 32 + fg*8]);
      bf16x8 b00 = *reinterpret_cast<const bf16x8*>(&Kb[fc*72 + fg*8]);
      bf16x8 b01 = *reinterpret_cast<const bf16x8*>(&Kb[fc*72 + 32 + fg*8]);
      bf16x8 b10 = *reinterpret_cast<const bf16x8*>(&Kb[(16+fc)*72 + fg*8]);
      bf16x8 b11 = *reinterpret_cast<const bf16x8*>(&Kb[(16+fc)*72 + 32 + fg*8]);
      s0 = __builtin_amdgcn_mfma_f32_16x16x32_bf16(a0, b00, s0, 0, 0, 0);
      s0 = __builtin_amdgcn_mfma_f32_16x16x32_bf16(a1, b01, s0, 0, 0, 0);
      s1 = __builtin_amdgcn_mfma_f32_16x16x32_bf16(a0, b10, s1, 0, 0, 0);
      s1 = __builtin_amdgcn_mfma_f32_16x16x32_bf16(a1, b11, s1, 0, 0, 0);
    }
    float corr[4];
    #pragma unroll
    for (int r=0;r<4;r++){
      float v0 = s0[r]*scale, v1 = s1[r]*scale;
      float mx = fmaxf(v0, v1);
      mx = fmaxf(mx, __shfl_xor(mx, 1));
      mx = fmaxf(mx, __shfl_xor(mx, 2));
      mx = fmaxf(mx, __shfl_xor(mx, 4));
      mx = fmaxf(mx, __shfl_xor(mx, 8));
      float mnew = fmaxf(m_reg[r], mx);
      corr[r] = expf(m_reg[r] - mnew);
      m_reg[r] = mnew;
      float p0 = expf(v0 - mnew), p1 = expf(v1 - mnew);
      float sum = p0 + p1;
      sum += __shfl_xor(sum, 1);
      sum += __shfl_xor(sum, 2);
      sum += __shfl_xor(sum, 4);
      sum += __shfl_xor(sum, 8);
      l_reg[r] = l_reg[r]*corr[r] + sum;
      int row = w*16 + fg*4 + r;
      Pb[row*40 + fc]      = f2b_u(p0);
      Pb[row*40 + 16 + fc] = f2b_u(p1);
    }
    {
      bf16x8 pa = *reinterpret_cast<const bf16x8*>(&Pb[(w*16+fc)*40 + fg*8]);
      #pragma unroll
      for (int jt=0;jt<4;jt++){
        bf16x8 vb = *reinterpret_cast<const bf16x8*>(&Vt[(jt*16+fc)*40 + fg*8]);
        f32x4 oo = o[jt];
        oo[0] *= corr[0]; oo[1] *= corr[1]; oo[2] *= corr[2]; oo[3] *= corr[3];
        o[jt] = __builtin_amdgcn_mfma_f32_16x16x32_bf16(pa, vb, oo, 0, 0, 0);
      }
    }
    __syncthreads();
  }
  float inv[4];
  #pragma unroll
  for (int r=0;r<4;r++) inv[r] = 1.0f / l_reg[r];
  #pragma unroll
  for (int jt=0;jt<4;jt++){
    #pragma unroll
    for (int r=0;r<4;r++)
      Os[(w*16 + fg*4 + r)*68 + jt*16 + fc] = o[jt][r] * inv[r];
  }
  __syncthreads();
  {
    int row = t >> 2, seg = t & 3;
    float ov[16];
    #pragma unroll
    for (int j=0;j<16;j++) ov[j] = Os[row*68 + seg*16 + j];
    u16* dst = y + (tokbase + qt*64 + row)*128 + h*64 + seg*16;
    float res[16]; ld8b(dst, res); ld8b(dst+8, res+8);
    float o16[16];
    #pragma unroll
    for (int j=0;j<16;j++) o16[j] = ov[j] + res[j];
    st8b(dst, o16); st8b(dst+8, o16+8);
  }
}

// ---------- K6: FUSED LSTM (all 16 steps), 8 waves: K-split x/h + LDS combine ----------
// Waves 0-3: x-part (bias-seeded), gate = w. Waves 4-7: h-part (zero-seeded) -> partial LDS.
// Softmax/tanh, pointwise, IO keep the proven 256-thread code paths.
__global__ __launch_bounds__(512) void k_lstm_all(const u16* __restrict__ xD,
    const void* __restrict__ h0, const void* __restrict__ c0,
    const u16* __restrict__ wBx, const u16* __restrict__ wBh, const float* __restrict__ bh,
    void* __restrict__ dout, const int* __restrict__ flag){
  __shared__ u16 Xa[16*136];         // x bf16
  __shared__ u16 Ha[16*136];         // h bf16
  __shared__ float glds[4*16*132];   // [gate][px][132-pad ch] f32 (gate0 reused for hn f32)
  __shared__ float part[4*16*132];   // h-part partial sums f32
  __shared__ float Cls[16*132];      // C state f32
  __shared__ u16 hst[16*136];        // h-new bf16 staging
  int t = threadIdx.x, bid = blockIdx.x;
  int pix0 = bid*16;
  int fl = *flag;
  // ---- init h (bf16) and C (f32) from h0/c0 [c][4096] ----
  if (t < 256){
    int c = t >> 1, half = t & 1;
    int pxb = half*8;
    if (fl){
      const float* hp = (const float*)h0 + (size_t)c*4096 + pix0 + pxb;
      const float* cp = (const float*)c0 + (size_t)c*4096 + pix0 + pxb;
      #pragma unroll
      for (int i=0;i<8;i++){
        Ha[(pxb+i)*136 + c] = f2b_u(hp[i]);
        Cls[(pxb+i)*132 + c] = cp[i];
      }
    } else {
      const u16* hp = (const u16*)h0 + (size_t)c*4096 + pix0 + pxb;
      const u16* cp = (const u16*)c0 + (size_t)c*4096 + pix0 + pxb;
      #pragma unroll
      for (int i=0;i<8;i++){
        Ha[(pxb+i)*136 + c] = hp[i];
        Cls[(pxb+i)*132 + c] = b2f_u((u32)cp[i]);
      }
    }
  }
  int w = t >> 6, lane = t & 63, fr = lane & 15, fg = lane >> 4;
  int g = w & 3, ks = w >> 2;
  const u16* wSel = ks ? wBh : wBx;
  const u16* aSel = ks ? Ha : Xa;
  for (int n = 0; n < 16; n++){
    if (t < 256){ // load x tile
      int px = t >> 4, c0v = (t & 15)*8;
      *reinterpret_cast<uint4*>(&Xa[px*136 + c0v]) =
        *reinterpret_cast<const uint4*>(xD + ((size_t)n*4096 + pix0 + px)*128 + c0v);
    }
    __syncthreads();
    // gates GEMM: wave (g, ks): half-K over 128 channels of gate g
    f32x4 acc[8];
    {
      bf16x8 a[4];
      #pragma unroll
      for (int k=0;k<4;k++)
        a[k] = *reinterpret_cast<const bf16x8*>(&aSel[fr*136 + k*32 + fg*8]);
      #pragma unroll
      for (int j=0;j<8;j++){
        int o = g*128 + j*16 + fr;
        f32x4 d;
        if (ks == 0){ float bv = bh[o]; d = {bv,bv,bv,bv}; }
        else        { d = {0.f,0.f,0.f,0.f}; }
        const u16* wp = wSel + (size_t)o*128 + fg*8;
        #pragma unroll
        for (int k=0;k<4;k++){
          bf16x8 b = *reinterpret_cast<const bf16x8*>(wp + k*32);
          d = __builtin_amdgcn_mfma_f32_16x16x32_bf16(a[k], b, d, 0, 0, 0);
        }
        acc[j] = d;
      }
    }
    if (ks == 1){
      #pragma unroll
      for (int j=0;j<8;j++)
        #pragma unroll
        for (int r=0;r<4;r++)
          part[(g*16 + fg*4 + r)*132 + j*16 + fr] = acc[j][r];
    }
    __syncthreads();
    if (ks == 0){
      #pragma unroll
      for (int j=0;j<8;j++)
        #pragma unroll
        for (int r=0;r<4;r++)
          acc[j][r] += part[(g*16 + fg*4 + r)*132 + j*16 + fr];
      // activation: g==2 -> tanh; else channel-softmax (register butterfly over fc lanes)
      if (g == 2){
        #pragma unroll
        for (int j=0;j<8;j++)
          #pragma unroll
          for (int r=0;r<4;r++)
            glds[(g*16 + fg*4 + r)*132 + j*16 + fr] = tanhf(acc[j][r]);
      } else {
        #pragma unroll
        for (int r=0;r<4;r++){
          float mx = acc[0][r];
          #pragma unroll
          for (int j=1;j<8;j++) mx = fmaxf(mx, acc[j][r]);
          mx = fmaxf(mx, __shfl_xor(mx, 1));
          mx = fmaxf(mx, __shfl_xor(mx, 2));
          mx = fmaxf(mx, __shfl_xor(mx, 4));
          mx = fmaxf(mx, __shfl_xor(mx, 8));
          float e[8], sum = 0.f;
          #pragma unroll
          for (int j=0;j<8;j++){ e[j] = expf(acc[j][r] - mx); sum += e[j]; }
          sum += __shfl_xor(sum, 1);
          sum += __shfl_xor(sum, 2);
          sum += __shfl_xor(sum, 4);
          sum += __shfl_xor(sum, 8);
          float inv = 1.0f/sum;
          #pragma unroll
          for (int j=0;j<8;j++)
            glds[(g*16 + fg*4 + r)*132 + j*16 + fr] = e[j]*inv;
        }
      }
    }
    __syncthreads();
    // pointwise update: thread = (chg = t&15, px = t>>4); C in LDS
    if (t < 256){
      int chg = t & 15, px = t >> 4;
      int ch0 = chg*8;
      float fv[8], iv[8], sv[8], ov[8], cc[8];
      #pragma unroll
      for (int q2=0;q2<2;q2++){
        *reinterpret_cast<float4*>(&fv[q2*4]) = *reinterpret_cast<const float4*>(&glds[(0*16+px)*132 + ch0 + q2*4]);
        *reinterpret_cast<float4*>(&iv[q2*4]) = *reinterpret_cast<const float4*>(&glds[(1*16+px)*132 + ch0 + q2*4]);
        *reinterpret_cast<float4*>(&sv[q2*4]) = *reinterpret_cast<const float4*>(&glds[(2*16+px)*132 + ch0 + q2*4]);
        *reinterpret_cast<float4*>(&ov[q2*4]) = *reinterpret_cast<const float4*>(&glds[(3*16+px)*132 + ch0 + q2*4]);
        *reinterpret_cast<float4*>(&cc[q2*4]) = *reinterpret_cast<const float4*>(&Cls[px*132 + ch0 + q2*4]);
      }
      float cn[8], hn[8];
      #pragma unroll
      for (int j=0;j<8;j++){
        cn[j] = fv[j]*cc[j] + iv[j]*sv[j];
        hn[j] = ov[j]*tanhf(cn[j]);
      }
      #pragma unroll
      for (int q2=0;q2<2;q2++)
        *reinterpret_cast<float4*>(&Cls[px*132 + ch0 + q2*4]) = *reinterpret_cast<const float4*>(&cn[q2*4]);
      uint4 pk;
      pk.x = (u32)f2b_u(hn[0]) | ((u32)f2b_u(hn[1]) << 16);
      pk.y = (u32)f2b_u(hn[2]) | ((u32)f2b_u(hn[3]) << 16);
      pk.z = (u32)f2b_u(hn[4]) | ((u32)f2b_u(hn[5]) << 16);
      pk.w = (u32)f2b_u(hn[6]) | ((u32)f2b_u(hn[7]) << 16);
      *reinterpret_cast<uint4*>(&Ha[px*136 + ch0])  = pk;
      *reinterpret_cast<uint4*>(&hst[px*136 + ch0]) = pk;
      if (n == 15){
        // stash fp32 hn into glds gate-0 region (same cell this thread just read; no race)
        #pragma unroll
        for (int q2=0;q2<2;q2++)
          *reinterpret_cast<float4*>(&glds[px*132 + ch0 + q2*4]) = *reinterpret_cast<const float4*>(&hn[q2*4]);
      }
    }
    __syncthreads();
    // coalesced hs write (channel-major d_out)
    if (t < 256){
      int ch = t >> 1, ph = t & 1;
      size_t ob = (size_t)n*524288 + (size_t)ch*4096 + pix0 + ph*8;
      if (fl){
        float* df = (float*)dout;
        float v[8];
        #pragma unroll
        for (int i=0;i<8;i++) v[i] = b2f_u((u32)hst[(ph*8+i)*136 + ch]);
        *reinterpret_cast<float4*>(df + ob)     = make_float4(v[0],v[1],v[2],v[3]);
        *reinterpret_cast<float4*>(df + ob + 4) = make_float4(v[4],v[5],v[6],v[7]);
      } else {
        u16* db = (u16*)dout;
        uint4 pk;
        pk.x = (u32)hst[(ph*8+0)*136 + ch] | ((u32)hst[(ph*8+1)*136 + ch] << 16);
        pk.y = (u32)hst[(ph*8+2)*136 + ch] | ((u32)hst[(ph*8+3)*136 + ch] << 16);
        pk.z = (u32)hst[(ph*8+4)*136 + ch] | ((u32)hst[(ph*8+5)*136 + ch] << 16);
        pk.w = (u32)hst[(ph*8+6)*136 + ch] | ((u32)hst[(ph*8+7)*136 + ch] << 16);
        *reinterpret_cast<uint4*>(db + ob) = pk;
      }
    }
  }
  __syncthreads();
  // ---- final hf (fp32 from glds), Cf (fp32 from Cls) ----
  if (t < 256){
    int c = t >> 1, half = t & 1;
    int pxb = half*8;
    if (fl){
      float hv[8], cv[8];
      #pragma unroll
      for (int i=0;i<8;i++){ hv[i] = glds[(pxb+i)*132 + c]; cv[i] = Cls[(pxb+i)*132 + c]; }
      float* df = (float*)dout;
      size_t hb = 8388608u + (size_t)c*4096 + pix0 + pxb;
      size_t cb = 8912896u + (size_t)c*4096 + pix0 + pxb;
      *reinterpret_cast<float4*>(df + hb)     = make_float4(hv[0],hv[1],hv[2],hv[3]);
      *reinterpret_cast<float4*>(df + hb + 4) = make_float4(hv[4],hv[5],hv[6],hv[7]);
      *reinterpret_cast<float4*>(df + cb)     = make_float4(cv[0],cv[1],cv[2],cv[3]);
      *reinterpret_cast<float4*>(df + cb + 4) = make_float4(cv[4],cv[5],cv[6],cv[7]);
    } else {
      u16* db = (u16*)dout;
      uint4 hp, cp2;
      hp.x = (u32)hst[(pxb+0)*136 + c] | ((u32)hst[(pxb+1)*136 + c] << 16);
      hp.y = (u32)hst[(pxb+2)*136 + c] | ((u32)hst[(pxb+3)*136 + c] << 16);
      hp.z = (u32)hst[(pxb+4)*136 + c] | ((u32)hst[(pxb+5)*136 + c] << 16);
      hp.w = (u32)hst[(pxb+6)*136 + c] | ((u32)hst[(pxb+7)*136 + c] << 16);
      cp2.x = (u32)f2b_u(Cls[(pxb+0)*132 + c]) | ((u32)f2b_u(Cls[(pxb+1)*132 + c]) << 16);
      cp2.y = (u32)f2b_u(Cls[(pxb+2)*132 + c]) | ((u32)f2b_u(Cls[(pxb+3)*132 + c]) << 16);
      cp2.z = (u32)f2b_u(Cls[(pxb+4)*132 + c]) | ((u32)f2b_u(Cls[(pxb+5)*132 + c]) << 16);
      cp2.w = (u32)f2b_u(Cls[(pxb+6)*132 + c]) | ((u32)f2b_u(Cls[(pxb+7)*132 + c]) << 16);
      *reinterpret_cast<uint4*>(db + 8388608u + (size_t)c*4096 + pix0 + pxb) = hp;
      *reinterpret_cast<uint4*>(db + 8912896u + (size_t)c*4096 + pix0 + pxb) = cp2;
    }
  }
}

extern "C" void kernel_launch(void* const* d_in, const int* in_sizes, int n_in,
                              void* d_out, int out_size, void* d_ws, size_t ws_size,
                              hipStream_t stream) {
  const void* x      = d_in[0];
  const void* h0     = d_in[1];
  const void* c0     = d_in[2];
  const void* conv_w = d_in[3];
  const void* conv_b = d_in[4];
  const void* qkv1_w = d_in[5];
  const void* qkv1_b = d_in[6];
  const void* m1w1   = d_in[7];
  const void* m1b1   = d_in[8];
  const void* m1w2   = d_in[9];
  const void* m1b2   = d_in[10];
  const void* qkv2_w = d_in[11];
  const void* qkv2_b = d_in[12];
  const void* m2w1   = d_in[13];
  const void* m2b1   = d_in[14];
  const void* m2w2   = d_in[15];
  const void* m2b2   = d_in[16];
  const void* lwx    = d_in[17];
  const void* lwh    = d_in[18];
  const void* lbh    = d_in[19];

  char* p = (char*)d_ws;
  auto alloc = [&](size_t bytes)->void*{
    void* r = (void*)p; p += (bytes + 255) & ~(size_t)255; return r;
  };
  int*   flag    = (int*)alloc(256);
  u16* wB_conv = (u16*)alloc(128*512*2);       // bf16, native [co][ci*4+ky*2+kx]
  u16* wB_qkv1 = (u16*)alloc(384*128*2);       // bf16, original [o][k]
  u16* wB_m1a  = (u16*)alloc(512*128*2);
  u16* wB_m1b  = (u16*)alloc(128*512*2);
  u16* wB_qkv2 = (u16*)alloc(384*128*2);
  u16* wB_m2a  = (u16*)alloc(512*128*2);
  u16* wB_m2b  = (u16*)alloc(128*512*2);
  u16* wBx     = (u16*)alloc(512*128*2);       // bf16, original [o][k] (LSTM x)
  u16* wBh     = (u16*)alloc(512*128*2);       // bf16, original [o][k] (LSTM h)
  float* bf_conv = (float*)alloc(128*4);
  float* bf_qkv1 = (float*)alloc(384*4);
  float* bf_m1b1 = (float*)alloc(512*4);
  float* bf_m1b2 = (float*)alloc(128*4);
  float* bf_qkv2 = (float*)alloc(384*4);
  float* bf_m2b1 = (float*)alloc(512*4);
  float* bf_m2b2 = (float*)alloc(128*4);
  float* bf_lbh  = (float*)alloc(512*4);
  u16* R0   = (u16*)alloc(16777216);   // bufA -> bufC/y
  u16* Rbig = (u16*)alloc(33554432);   // bufB (front) -> kvbuf -> bufD (front)

  u16* bufA = R0;
  u16* bufB = Rbig;
  u16* bufC = R0;          // also y (attn writes in place)
  u16* qbuf = (u16*)d_out; // hs region used as scratch; dead before first LSTM write
  u16* kvbuf = Rbig;
  u16* bufD = Rbig;

  k_detect<<<1, 256, 0, stream>>>((const u32*)x, flag);

  k_prep<<<2187, 256, 0, stream>>>(
      conv_w, qkv1_w, m1w1, m1w2, qkv2_w, m2w1, m2w2, lwx, lwh,
      conv_b, qkv1_b, m1b1, m1b2, qkv2_b, m2b1, m2b2, lbh,
      wB_conv, wB_qkv1, wB_m1a, wB_m1b, wB_qkv2, wB_m2a, wB_m2b,
      wBx, wBh,
      bf_conv, bf_qkv1, bf_m1b1, bf_m1b2, bf_qkv2, bf_m2b1, bf_m2b2, bf_lbh,
      flag);

  k_conv<<<512, 256, 0, stream>>>(x, wB_conv, bf_conv, bufA, flag);
  k_msa1<<<4096, 256, 0, stream>>>(bufA, wB_qkv1, bf_qkv1, bufB);
  k_mlp<1><<<2048, 256, 0, stream>>>(bufB, wB_m1a, bf_m1b1, wB_m1b, bf_m1b2, bufC);
  k_qkv2<<<4096, 256, 0, stream>>>(bufC, wB_qkv2, bf_qkv2, qbuf, kvbuf);
  k_attn2<<<2048, 256, 0, stream>>>(qbuf, kvbuf, bufC);          // y = x + attn, in place
  k_mlp<2><<<2048, 256, 0, stream>>>(bufC, wB_m2a, bf_m2b1, wB_m2b, bf_m2b2, bufD);

  k_lstm_all<<<256, 512, 0, stream>>>(bufD, h0, c0, wBx, wBh, bf_lbh, d_out, flag);
}